// Round 11
// baseline (715.492 us; speedup 1.0000x reference)
//
#include <hip/hip_runtime.h>
#include <hip/hip_bf16.h>
#include <hip/hip_fp16.h>

#define NN   100000
#define EE   1600000
#define ETOT (EE + NN)
#define GG   256
#define BNEPS 1e-5f
#define NBK  391          // buckets of 256 nodes: (NN+255)/256
#define PADTOT (ETOT + NBK * 2048 + 64)
#define PSPLIT 16

typedef float floatx2 __attribute__((ext_vector_type(2)));
typedef short s16x8 __attribute__((ext_vector_type(8)));
typedef float f32x4v __attribute__((ext_vector_type(4)));

__device__ __forceinline__ unsigned short f2bf(float f) {
    unsigned u = __float_as_uint(f);
    unsigned r = u + 0x7FFF + ((u >> 16) & 1);
    return (unsigned short)(r >> 16);
}

// ---------------- CSR build: bucketed partition (single-writer cache lines) --

__global__ __launch_bounds__(256) void bucket_count_kernel(
    const int* __restrict__ ei, int* __restrict__ bucket_cnt)
{
    __shared__ int cnt[NBK];
    for (int i = threadIdx.x; i < NBK; i += 256) cnt[i] = 0;
    __syncthreads();
    int base = blockIdx.x * 8192;
    for (int k = threadIdx.x; k < 8192; k += 256) {
        int e = base + k;
        if (e < ETOT) {
            int dst = (e < EE) ? ei[EE + e] : (e - EE);
            atomicAdd(&cnt[dst >> 8], 1);
        }
    }
    __syncthreads();
    for (int i = threadIdx.x; i < NBK; i += 256)
        if (cnt[i]) atomicAdd(&bucket_cnt[i], cnt[i]);
}

__global__ __launch_bounds__(512) void bucket_scan_kernel(
    const int* __restrict__ bucket_cnt, int* __restrict__ bucket_base,
    int* __restrict__ gcursor)
{
    __shared__ int s[512];
    int t = threadIdx.x;
    int v = (t < NBK) ? bucket_cnt[t] : 0;
    s[t] = v;
    __syncthreads();
    int x = v;
    for (int o = 1; o < 512; o <<= 1) {
        int y = (t >= o) ? s[t - o] : 0;
        __syncthreads();
        x += y;
        s[t] = x;
        __syncthreads();
    }
    if (t < NBK) { bucket_base[t] = x - v; gcursor[t] = x - v; }
    if (t == 0) bucket_base[NBK] = ETOT;
}

__global__ __launch_bounds__(256) void partition_kernel(
    const int* __restrict__ ei, int* __restrict__ gcursor, int* __restrict__ part)
{
    __shared__ int cnt[NBK];
    __shared__ int basel[NBK];
    for (int i = threadIdx.x; i < NBK; i += 256) cnt[i] = 0;
    __syncthreads();
    int base = blockIdx.x * 4096;
    for (int k = threadIdx.x; k < 4096; k += 256) {
        int e = base + k;
        if (e < ETOT) {
            int dst = (e < EE) ? ei[EE + e] : (e - EE);
            atomicAdd(&cnt[dst >> 8], 1);
        }
    }
    __syncthreads();
    for (int i = threadIdx.x; i < NBK; i += 256) {
        int c = cnt[i];
        basel[i] = c ? atomicAdd(&gcursor[i], c) : 0;
        cnt[i] = 0;   // reuse as intra-block cursor
    }
    __syncthreads();
    for (int k = threadIdx.x; k < 4096; k += 256) {
        int e = base + k;
        if (e < ETOT) {
            int src, dst;
            if (e < EE) { src = ei[e]; dst = ei[EE + e]; }
            else        { src = e - EE; dst = e - EE; }
            int b = dst >> 8;
            int slot = atomicAdd(&cnt[b], 1);
            part[basel[b] + slot] = src | ((dst & 255) << 17);
        }
    }
}

// Padded CSR: per-node segments rounded up to 8 entries (pad src = 0),
// 8-aligned starts → aggregate loop needs no masking and uses int4 loads.
__global__ __launch_bounds__(256) void csr_build_kernel(
    const int* __restrict__ part, const int* __restrict__ bucket_base,
    int* __restrict__ row2_start, int* __restrict__ row2_deg,
    int* __restrict__ csr2_src)
{
    __shared__ int degs[256];
    __shared__ int sc[256];
    __shared__ int cur[256];
    int b = blockIdx.x;
    int t = threadIdx.x;
    int beg = bucket_base[b], end = bucket_base[b + 1];
    int pbase = ((beg + 7) & ~7) + 2048 * b;
    degs[t] = 0;
    __syncthreads();
    for (int j = beg + t; j < end; j += 256)
        atomicAdd(&degs[(part[j] >> 17) & 255], 1);
    __syncthreads();
    int dg = degs[t];
    int pdeg = (dg + 7) & ~7;
    sc[t] = pdeg;
    __syncthreads();
    int x = pdeg;
    for (int o = 1; o < 256; o <<= 1) {
        int y = (t >= o) ? sc[t - o] : 0;
        __syncthreads();
        x += y;
        sc[t] = x;
        __syncthreads();
    }
    int start2 = pbase + (x - pdeg);
    int node = b * 256 + t;
    if (node < NN) { row2_start[node] = start2; row2_deg[node] = dg; }
    cur[t] = start2;
    __syncthreads();
    for (int j = beg + t; j < end; j += 256) {
        int pv = part[j];
        int pos = atomicAdd(&cur[(pv >> 17) & 255], 1);
        csr2_src[pos] = pv & 0x1FFFF;
    }
    for (int k = dg; k < pdeg; ++k) csr2_src[start2 + k] = 0;
}

// ---------------- per-layer edge softmax weights (both heads, fp32) ----------

__global__ __launch_bounds__(256) void edgew_kernel(
    const int* __restrict__ csr2_src, const int* __restrict__ row2_start,
    const int* __restrict__ row2_deg,
    const float2* __restrict__ esrc, const float2* __restrict__ edst,
    float2* __restrict__ csr_w, int nN)
{
    int n = blockIdx.x * 4 + (threadIdx.x >> 6);
    int lane = threadIdx.x & 63;
    if (n >= nN) return;
    float2 ed = edst[n];
    int s2 = row2_start[n];
    int dg = row2_deg[n];
    int pc = (dg + 7) & ~7;
    for (int j = lane; j < pc; j += 64) {
        float2 w = make_float2(0.f, 0.f);
        if (j < dg) {
            int i = csr2_src[s2 + j];
            float2 es = esrc[i];
            float a0 = es.x + ed.x; a0 = (a0 > 0.f) ? a0 : 0.2f * a0;
            float a1 = es.y + ed.y; a1 = (a1 > 0.f) ? a1 : 0.2f * a1;
            w.x = __expf(a0);
            w.y = __expf(a1);
        }
        csr_w[s2 + j] = w;
    }
}

// ---------------- layer-1 feature transform (K=5); h stored fp8 e4m3 ---------

__global__ __launch_bounds__(256) void feat1_kernel(
    const float* __restrict__ xin, const float* __restrict__ W,
    const float* __restrict__ pw, const float* __restrict__ pb,
    const float* __restrict__ a_src, const float* __restrict__ a_dst,
    unsigned char* __restrict__ h8, float* __restrict__ esrc, float* __restrict__ edst,
    float* __restrict__ rout, int nN)
{
    constexpr int F_IN = 5, F_OUT = 64;
    int t = threadIdx.x;
    int n = blockIdx.x * 4 + t / F_OUT;
    int f = t % F_OUT;
    if (n >= nN) return;
    float acc = 0.f, racc = 0.f;
#pragma unroll
    for (int k = 0; k < F_IN; ++k) {
        float xv = xin[n * F_IN + k];
        acc  += xv * W[k * F_OUT + f];
        racc += xv * pw[k * F_OUT + f];
    }
    float other = __shfl_xor(acc, 1, 64);
    if ((f & 1) == 0) {
        int p = __builtin_amdgcn_cvt_pk_fp8_f32(acc, other, 0, false);
        *(unsigned short*)(h8 + (size_t)n * F_OUT + f) = (unsigned short)(p & 0xFFFF);
    }
    rout[(size_t)n * F_OUT + f] = racc + pb[f];
    float es = acc * a_src[f];
    float ed = acc * a_dst[f];
#pragma unroll
    for (int off = 16; off > 0; off >>= 1) {
        es += __shfl_xor(es, off, 32);
        ed += __shfl_xor(ed, off, 32);
    }
    if ((t & 31) == 0) {
        int head = (f >> 5) & 1;
        esrc[n * 2 + head] = es;
        edst[n * 2 + head] = ed;
    }
}

// ---------------- weight fragment prep (bf16 hi/lo split, MFMA B layout) -----
// wfrag unit u = ((nt*(K/32)+ks)*2 + hilo)*64 + lane, 8 bf16 per unit:
// B[k = ks*32 + (lane>>4)*8 + j][n = nt*16 + (lane&15)], cols 0..127 = W,
// 128..255 = pw.

template<int K>
__global__ __launch_bounds__(256) void prep_w_kernel(
    const float* __restrict__ W, const float* __restrict__ pw,
    short* __restrict__ wfrag)
{
    constexpr int KS = K / 32;
    int unit = blockIdx.x * 256 + threadIdx.x;
    int total = 16 * KS * 2 * 64;
    if (unit >= total) return;
    int lane = unit & 63;
    int rest = unit >> 6;
    int hilo = rest & 1;
    int fk = rest >> 1;
    int ks = fk % KS;
    int nt = fk / KS;
    int n = nt * 16 + (lane & 15);
    int k0 = ks * 32 + (lane >> 4) * 8;
    const float* src = (n < 128) ? (W + n) : (pw + (n - 128));
    s16x8 out;
#pragma unroll
    for (int j = 0; j < 8; ++j) {
        float wv = src[(size_t)(k0 + j) * 128];
        unsigned short hi = f2bf(wv);
        if (hilo == 0) {
            out[j] = (short)hi;
        } else {
            float fhi = __uint_as_float(((unsigned)hi) << 16);
            out[j] = (short)f2bf(wv - fhi);
        }
    }
    *(s16x8*)(wfrag + (size_t)unit * 8) = out;
}

// ---------------- MFMA feature transform (layers 2,3; N=256 = W‖pw) ----------
// Block = 256 threads = 4 waves, 16 nodes/wave. x → bf16 (single), weights
// hi+lo bf16 (2 chained MFMAs) so weight-quantization error ~2^-16 —
// the systematic component that would survive graph pooling.
// Layouts per m89/m120-verified mappings:
//   A[m=lane&15][k=(lane>>4)*8+j], C/D: col=lane&15, row=(lane>>4)*4+reg.

template<int K>
__global__ __launch_bounds__(256) void mfma_feat_kernel(
    const float* __restrict__ xin, const short* __restrict__ wfrag,
    const float* __restrict__ pb,
    const float* __restrict__ a_src, const float* __restrict__ a_dst,
    unsigned char* __restrict__ h8, float* __restrict__ esrc, float* __restrict__ edst,
    float* __restrict__ rout)
{
    constexpr int KS = K / 32;    // MFMA k-steps
    constexpr int CH = K / 8;     // 16-byte chunks per node row
    __shared__ short xs[4 * CH * 16 * 8];

    const int tid = threadIdx.x;
    const int base = blockIdx.x * 64;

    // stage x tile → bf16 LDS in fragment-friendly chunk order
    constexpr int NF4 = 64 * K / 4;
    for (int idx = tid; idx < NF4; idx += 256) {
        int node = idx / (K / 4);
        int kq = idx % (K / 4);
        int gn = base + node; if (gn > NN - 1) gn = NN - 1;
        float4 v = *(const float4*)(xin + (size_t)gn * K + kq * 4);
        int wv = node >> 4, mm = node & 15, t = kq >> 1, half = kq & 1;
        short4 o;
        o.x = (short)f2bf(v.x); o.y = (short)f2bf(v.y);
        o.z = (short)f2bf(v.z); o.w = (short)f2bf(v.w);
        *(short4*)&xs[(((wv * CH + t) * 16 + mm) * 8) + half * 4] = o;
    }
    __syncthreads();

    const int w = tid >> 6;
    const int lane = tid & 63;
    const int quad = lane >> 4;
    const int m = lane & 15;
    const int nodeb = base + w * 16 + quad * 4;   // + r

    s16x8 afrag[KS];
#pragma unroll
    for (int ks = 0; ks < KS; ++ks)
        afrag[ks] = *(const s16x8*)&xs[((w * CH + (ks * 4 + quad)) * 16 + m) * 8];

    float es0[4] = {0.f, 0.f, 0.f, 0.f};
    float es1[4] = {0.f, 0.f, 0.f, 0.f};
    float ed0[4] = {0.f, 0.f, 0.f, 0.f};
    float ed1[4] = {0.f, 0.f, 0.f, 0.f};

#pragma unroll
    for (int nt = 0; nt < 16; ++nt) {
        f32x4v c = {0.f, 0.f, 0.f, 0.f};
#pragma unroll
        for (int ks = 0; ks < KS; ++ks) {
            s16x8 bh = *(const s16x8*)(wfrag + (size_t)(((nt * KS + ks) * 2 + 0) * 64 + lane) * 8);
            s16x8 bl = *(const s16x8*)(wfrag + (size_t)(((nt * KS + ks) * 2 + 1) * 64 + lane) * 8);
            c = __builtin_amdgcn_mfma_f32_16x16x32_bf16(afrag[ks], bh, c, 0, 0, 0);
            c = __builtin_amdgcn_mfma_f32_16x16x32_bf16(afrag[ks], bl, c, 0, 0, 0);
        }
        if (nt < 8) {
            int col = nt * 16 + m;
            float av = a_src[col], dv = a_dst[col];
#pragma unroll
            for (int r = 0; r < 4; ++r) {
                float val = c[r];
                float pes = val * av, ped = val * dv;
#pragma unroll
                for (int off = 8; off > 0; off >>= 1) {
                    pes += __shfl_xor(pes, off, 16);
                    ped += __shfl_xor(ped, off, 16);
                }
                if (nt < 4) { es0[r] += pes; ed0[r] += ped; }
                else        { es1[r] += pes; ed1[r] += ped; }
                float partner = __shfl_xor(val, 1, 16);
                int node = nodeb + r;
                if ((m & 1) == 0 && node < NN) {
                    int p = __builtin_amdgcn_cvt_pk_fp8_f32(val, partner, 0, false);
                    *(unsigned short*)(h8 + (size_t)node * 128 + col) = (unsigned short)(p & 0xFFFF);
                }
            }
        } else {
            int col = (nt - 8) * 16 + m;
            float bv = pb[col];
#pragma unroll
            for (int r = 0; r < 4; ++r) {
                int node = nodeb + r;
                if (node < NN)
                    rout[(size_t)node * 128 + col] = c[r] + bv;
            }
        }
    }
    if (m == 0) {
#pragma unroll
        for (int r = 0; r < 4; ++r) {
            int node = nodeb + r;
            if (node < NN) {
                ((float2*)esrc)[node] = make_float2(es0[r], es1[r]);
                ((float2*)edst)[node] = make_float2(ed0[r], ed1[r]);
            }
        }
    }
}

// ---------------- fused aggregate, F=128 (fp8 h, padded CSR, precomputed w) --
// No local arrays (R8 lesson: SROA failure → LDS demotion). Named scalars only.

__global__ __launch_bounds__(256) void aggregate128_kernel(
    const unsigned short* __restrict__ h8s,
    const int* __restrict__ row2_start, const int* __restrict__ row2_deg,
    const int* __restrict__ csr2_src, const float2* __restrict__ csr_w,
    const float* __restrict__ bias, const float* __restrict__ bng,
    const float* __restrict__ bnb, const float* __restrict__ bnm,
    const float* __restrict__ bnv, float* __restrict__ out, int nN)
{
    int w = threadIdx.x >> 6;
    int lane = threadIdx.x & 63;
    int n = blockIdx.x * 4 + w;
    if (n >= nN) return;
    bool hi = lane >= 32;
    int s2 = row2_start[n];
    int dg = row2_deg[n];
    int pc = (dg + 7) & ~7;
    const int4* sp = (const int4*)(csr2_src + s2);
    const float4* wp = (const float4*)(csr_w + s2);
    float s = 0.f, ax = 0.f, ay = 0.f;
    for (int j = 0; j < pc; j += 8) {
        int4 ia = sp[(j >> 2) + 0];
        int4 ib = sp[(j >> 2) + 1];
        float4 wa = wp[(j >> 1) + 0];
        float4 wb = wp[(j >> 1) + 1];
        float4 wc = wp[(j >> 1) + 2];
        float4 wd = wp[(j >> 1) + 3];
        unsigned short v0 = h8s[(size_t)ia.x * 64 + lane];
        unsigned short v1 = h8s[(size_t)ia.y * 64 + lane];
        unsigned short v2 = h8s[(size_t)ia.z * 64 + lane];
        unsigned short v3 = h8s[(size_t)ia.w * 64 + lane];
        unsigned short v4 = h8s[(size_t)ib.x * 64 + lane];
        unsigned short v5 = h8s[(size_t)ib.y * 64 + lane];
        unsigned short v6 = h8s[(size_t)ib.z * 64 + lane];
        unsigned short v7 = h8s[(size_t)ib.w * 64 + lane];
        float g0 = hi ? wa.y : wa.x;
        float g1 = hi ? wa.w : wa.z;
        float g2 = hi ? wb.y : wb.x;
        float g3 = hi ? wb.w : wb.z;
        float g4 = hi ? wc.y : wc.x;
        float g5 = hi ? wc.w : wc.z;
        float g6 = hi ? wd.y : wd.x;
        float g7 = hi ? wd.w : wd.z;
        floatx2 f0 = __builtin_amdgcn_cvt_pk_f32_fp8((int)v0, false);
        floatx2 f1 = __builtin_amdgcn_cvt_pk_f32_fp8((int)v1, false);
        floatx2 f2 = __builtin_amdgcn_cvt_pk_f32_fp8((int)v2, false);
        floatx2 f3 = __builtin_amdgcn_cvt_pk_f32_fp8((int)v3, false);
        floatx2 f4 = __builtin_amdgcn_cvt_pk_f32_fp8((int)v4, false);
        floatx2 f5 = __builtin_amdgcn_cvt_pk_f32_fp8((int)v5, false);
        floatx2 f6 = __builtin_amdgcn_cvt_pk_f32_fp8((int)v6, false);
        floatx2 f7 = __builtin_amdgcn_cvt_pk_f32_fp8((int)v7, false);
        ax = fmaf(g0, f0.x, ax); ay = fmaf(g0, f0.y, ay);
        ax = fmaf(g1, f1.x, ax); ay = fmaf(g1, f1.y, ay);
        ax = fmaf(g2, f2.x, ax); ay = fmaf(g2, f2.y, ay);
        ax = fmaf(g3, f3.x, ax); ay = fmaf(g3, f3.y, ay);
        ax = fmaf(g4, f4.x, ax); ay = fmaf(g4, f4.y, ay);
        ax = fmaf(g5, f5.x, ax); ay = fmaf(g5, f5.y, ay);
        ax = fmaf(g6, f6.x, ax); ay = fmaf(g6, f6.y, ay);
        ax = fmaf(g7, f7.x, ax); ay = fmaf(g7, f7.y, ay);
        s += ((g0 + g1) + (g2 + g3)) + ((g4 + g5) + (g6 + g7));
    }
    float inv = 1.f / (s + 1e-16f);
    int f0i = 2 * lane, f1i = 2 * lane + 1;
    float o0 = bng[f0i] * (ax * inv + bias[f0i] - bnm[f0i]) * rsqrtf(bnv[f0i] + BNEPS) + bnb[f0i];
    float o1 = bng[f1i] * (ay * inv + bias[f1i] - bnm[f1i]) * rsqrtf(bnv[f1i] + BNEPS) + bnb[f1i];
    float2* op = (float2*)(out + (size_t)n * 128) + lane;
    float2 prev = *op;
    prev.x += fmaxf(o0, 0.f);
    prev.y += fmaxf(o1, 0.f);
    *op = prev;
}

// ---------------- fused aggregate, F=64 ---------------------------------------

__global__ __launch_bounds__(256) void aggregate64_kernel(
    const unsigned char* __restrict__ h8,
    const int* __restrict__ row2_start, const int* __restrict__ row2_deg,
    const int* __restrict__ csr2_src, const float2* __restrict__ csr_w,
    const float* __restrict__ bias, const float* __restrict__ bng,
    const float* __restrict__ bnb, const float* __restrict__ bnm,
    const float* __restrict__ bnv, float* __restrict__ out, int nN)
{
    int w = threadIdx.x >> 6;
    int lane = threadIdx.x & 63;
    int n = blockIdx.x * 4 + w;
    if (n >= nN) return;
    bool hi = lane >= 32;
    int s2 = row2_start[n];
    int dg = row2_deg[n];
    int pc = (dg + 7) & ~7;
    const int4* sp = (const int4*)(csr2_src + s2);
    const float4* wp = (const float4*)(csr_w + s2);
    float s = 0.f, acc = 0.f;
    for (int j = 0; j < pc; j += 8) {
        int4 ia = sp[(j >> 2) + 0];
        int4 ib = sp[(j >> 2) + 1];
        float4 wa = wp[(j >> 1) + 0];
        float4 wb = wp[(j >> 1) + 1];
        float4 wc = wp[(j >> 1) + 2];
        float4 wd = wp[(j >> 1) + 3];
        unsigned char v0 = h8[(size_t)ia.x * 64 + lane];
        unsigned char v1 = h8[(size_t)ia.y * 64 + lane];
        unsigned char v2 = h8[(size_t)ia.z * 64 + lane];
        unsigned char v3 = h8[(size_t)ia.w * 64 + lane];
        unsigned char v4 = h8[(size_t)ib.x * 64 + lane];
        unsigned char v5 = h8[(size_t)ib.y * 64 + lane];
        unsigned char v6 = h8[(size_t)ib.z * 64 + lane];
        unsigned char v7 = h8[(size_t)ib.w * 64 + lane];
        float g0 = hi ? wa.y : wa.x;
        float g1 = hi ? wa.w : wa.z;
        float g2 = hi ? wb.y : wb.x;
        float g3 = hi ? wb.w : wb.z;
        float g4 = hi ? wc.y : wc.x;
        float g5 = hi ? wc.w : wc.z;
        float g6 = hi ? wd.y : wd.x;
        float g7 = hi ? wd.w : wd.z;
        acc = fmaf(g0, __builtin_amdgcn_cvt_f32_fp8((int)v0, 0), acc);
        acc = fmaf(g1, __builtin_amdgcn_cvt_f32_fp8((int)v1, 0), acc);
        acc = fmaf(g2, __builtin_amdgcn_cvt_f32_fp8((int)v2, 0), acc);
        acc = fmaf(g3, __builtin_amdgcn_cvt_f32_fp8((int)v3, 0), acc);
        acc = fmaf(g4, __builtin_amdgcn_cvt_f32_fp8((int)v4, 0), acc);
        acc = fmaf(g5, __builtin_amdgcn_cvt_f32_fp8((int)v5, 0), acc);
        acc = fmaf(g6, __builtin_amdgcn_cvt_f32_fp8((int)v6, 0), acc);
        acc = fmaf(g7, __builtin_amdgcn_cvt_f32_fp8((int)v7, 0), acc);
        s += ((g0 + g1) + (g2 + g3)) + ((g4 + g5) + (g6 + g7));
    }
    int f = lane;
    float g = acc / (s + 1e-16f);
    float vv = bng[f] * (g + bias[f] - bnm[f]) * rsqrtf(bnv[f] + BNEPS) + bnb[f];
    out[(size_t)n * 64 + f] = fmaxf(vv, 0.f) + out[(size_t)n * 64 + f];
}

// ---------------- pooling, two-phase ----------------

__global__ __launch_bounds__(128) void pool_partial_kernel(
    const float* __restrict__ hfin, const int* __restrict__ batch,
    float* __restrict__ ppart)
{
    int g = blockIdx.x / PSPLIT;
    int p = blockIdx.x % PSPLIT;
    int f = threadIdx.x;
    int lo = 0, hi = NN;
    while (lo < hi) { int mid = (lo + hi) >> 1; if (batch[mid] < g) lo = mid + 1; else hi = mid; }
    int start = lo;
    hi = NN;
    while (lo < hi) { int mid = (lo + hi) >> 1; if (batch[mid] < g + 1) lo = mid + 1; else hi = mid; }
    int end = lo;
    int len = end - start;
    int chunk = (len + PSPLIT - 1) / PSPLIT;
    int i0 = start + p * chunk;
    int i1 = i0 + chunk; if (i1 > end) i1 = end;
    float acc = 0.f;
    for (int i = i0; i < i1; ++i) acc += hfin[(size_t)i * 128 + f];
    ppart[((size_t)g * PSPLIT + p) * 128 + f] = acc;
}

// ---------------- MLP head (folds partial-sum reduce + mean) -----------------

__global__ __launch_bounds__(128) void head_kernel(
    const float* __restrict__ ppart, const int* __restrict__ batch,
    const float* __restrict__ fw, const float* __restrict__ fb,
    const float* __restrict__ g4, const float* __restrict__ be4,
    const float* __restrict__ m4, const float* __restrict__ v4,
    const float* __restrict__ l1w, const float* __restrict__ l1b,
    const float* __restrict__ l2w, const float* __restrict__ l2b,
    float* __restrict__ out)
{
    __shared__ float p[128];
    __shared__ float z1[32];
    __shared__ float z2[32];
    int g = blockIdx.x, t = threadIdx.x;
    int lo = 0, hi = NN;
    while (lo < hi) { int mid = (lo + hi) >> 1; if (batch[mid] < g) lo = mid + 1; else hi = mid; }
    int start = lo;
    hi = NN;
    while (lo < hi) { int mid = (lo + hi) >> 1; if (batch[mid] < g + 1) lo = mid + 1; else hi = mid; }
    float cnt = (float)(lo - start);
    float acc = 0.f;
#pragma unroll
    for (int q = 0; q < PSPLIT; ++q)
        acc += ppart[((size_t)g * PSPLIT + q) * 128 + t];
    p[t] = acc / fmaxf(cnt, 1.0f);
    __syncthreads();
    if (t < 32) {
        float a = fb[t];
        for (int k = 0; k < 128; ++k) a += p[k] * fw[k * 32 + t];
        float val = g4[t] * (a - m4[t]) * rsqrtf(v4[t] + BNEPS) + be4[t];
        z1[t] = fmaxf(val, 0.f);
    }
    __syncthreads();
    if (t < 32) {
        float a = l1b[t];
        for (int k = 0; k < 32; ++k) a += z1[k] * l1w[k * 32 + t];
        z2[t] = fmaxf(a, 0.f);
    }
    __syncthreads();
    if (t < 10) {
        float a = l2b[t];
        for (int k = 0; k < 32; ++k) a += z2[k] * l2w[k * 10 + t];
        out[g * 10 + t] = a;
    }
}

// ---------------- launch ----------------

extern "C" void kernel_launch(void* const* d_in, const int* in_sizes, int n_in,
                              void* d_out, int out_size, void* d_ws, size_t ws_size,
                              hipStream_t stream) {
    const float* x     = (const float*)d_in[0];
    const int*   ei    = (const int*)d_in[1];
    const int*   batch = (const int*)d_in[2];
    const float* w1  = (const float*)d_in[3];
    const float* as1 = (const float*)d_in[4];
    const float* ad1 = (const float*)d_in[5];
    const float* b1  = (const float*)d_in[6];
    const float* g1  = (const float*)d_in[7];
    const float* be1 = (const float*)d_in[8];
    const float* m1  = (const float*)d_in[9];
    const float* v1  = (const float*)d_in[10];
    const float* p1w = (const float*)d_in[11];
    const float* p1b = (const float*)d_in[12];
    const float* w2  = (const float*)d_in[13];
    const float* as2 = (const float*)d_in[14];
    const float* ad2 = (const float*)d_in[15];
    const float* b2  = (const float*)d_in[16];
    const float* g2  = (const float*)d_in[17];
    const float* be2 = (const float*)d_in[18];
    const float* m2  = (const float*)d_in[19];
    const float* v2  = (const float*)d_in[20];
    const float* p2w = (const float*)d_in[21];
    const float* p2b = (const float*)d_in[22];
    const float* w3  = (const float*)d_in[23];
    const float* as3 = (const float*)d_in[24];
    const float* ad3 = (const float*)d_in[25];
    const float* b3  = (const float*)d_in[26];
    const float* g3  = (const float*)d_in[27];
    const float* be3 = (const float*)d_in[28];
    const float* m3  = (const float*)d_in[29];
    const float* v3  = (const float*)d_in[30];
    const float* p3w = (const float*)d_in[31];
    const float* p3b = (const float*)d_in[32];
    const float* fw  = (const float*)d_in[33];
    const float* fb  = (const float*)d_in[34];
    const float* g4  = (const float*)d_in[35];
    const float* be4 = (const float*)d_in[36];
    const float* m4  = (const float*)d_in[37];
    const float* v4  = (const float*)d_in[38];
    const float* l1w = (const float*)d_in[39];
    const float* l1b = (const float*)d_in[40];
    const float* l2w = (const float*)d_in[41];
    const float* l2b = (const float*)d_in[42];

    char* ws = (char*)d_ws;
    size_t off = 0;
    auto alloc = [&](size_t bytes) -> char* {
        char* p = ws + off;
        off += (bytes + 255) & ~(size_t)255;
        return p;
    };
    int*    bucket_cnt  = (int*)alloc((NBK) * sizeof(int));
    int*    bucket_base = (int*)alloc((NBK + 1) * sizeof(int));
    int*    gcursor     = (int*)alloc((NBK) * sizeof(int));
    int*    part        = (int*)alloc((size_t)ETOT * sizeof(int));
    int*    row2_start  = (int*)alloc(NN * sizeof(int));
    int*    row2_deg    = (int*)alloc(NN * sizeof(int));
    int*    csr2_src    = (int*)alloc((size_t)PADTOT * sizeof(int));
    float2* csr_w       = (float2*)alloc((size_t)PADTOT * sizeof(float2));
    unsigned char* h8   = (unsigned char*)alloc((size_t)NN * 128);
    float*  bufB        = (float*)alloc((size_t)NN * 128 * sizeof(float));
    float*  bufC        = (float*)alloc((size_t)NN * 128 * sizeof(float));
    float*  esrc        = (float*)alloc((size_t)NN * 2 * sizeof(float));
    float*  edst        = (float*)alloc((size_t)NN * 2 * sizeof(float));
    float*  ppart       = (float*)alloc((size_t)GG * PSPLIT * 128 * sizeof(float));
    short*  wfrag2      = (short*)alloc((size_t)16 * 2 * 2 * 64 * 8 * sizeof(short));
    short*  wfrag3      = (short*)alloc((size_t)16 * 4 * 2 * 64 * 8 * sizeof(short));

    // ---- weight fragment prep (independent of everything else) ----
    prep_w_kernel<64><<<16, 256, 0, stream>>>(w2, p2w, wfrag2);
    prep_w_kernel<128><<<32, 256, 0, stream>>>(w3, p3w, wfrag3);

    // ---- CSR build (bucketed partition, padded layout) ----
    hipMemsetAsync(bucket_cnt, 0, NBK * sizeof(int), stream);
    bucket_count_kernel<<<(ETOT + 8191) / 8192, 256, 0, stream>>>(ei, bucket_cnt);
    bucket_scan_kernel<<<1, 512, 0, stream>>>(bucket_cnt, bucket_base, gcursor);
    partition_kernel<<<(ETOT + 4095) / 4096, 256, 0, stream>>>(ei, gcursor, part);
    csr_build_kernel<<<NBK, 256, 0, stream>>>(part, bucket_base, row2_start, row2_deg, csr2_src);

    // ---- layer 1: x[N,5] -> bufB[N,64] ----
    feat1_kernel<<<(NN + 3) / 4, 256, 0, stream>>>(
        x, w1, p1w, p1b, as1, ad1, h8, esrc, edst, bufB, NN);
    edgew_kernel<<<(NN + 3) / 4, 256, 0, stream>>>(
        csr2_src, row2_start, row2_deg, (const float2*)esrc, (const float2*)edst, csr_w, NN);
    aggregate64_kernel<<<(NN + 3) / 4, 256, 0, stream>>>(
        h8, row2_start, row2_deg, csr2_src, csr_w,
        b1, g1, be1, m1, v1, bufB, NN);

    // ---- layer 2: bufB[N,64] -> bufC[N,128] ----
    mfma_feat_kernel<64><<<(NN + 63) / 64, 256, 0, stream>>>(
        bufB, wfrag2, p2b, as2, ad2, h8, esrc, edst, bufC);
    edgew_kernel<<<(NN + 3) / 4, 256, 0, stream>>>(
        csr2_src, row2_start, row2_deg, (const float2*)esrc, (const float2*)edst, csr_w, NN);
    aggregate128_kernel<<<(NN + 3) / 4, 256, 0, stream>>>(
        (const unsigned short*)h8, row2_start, row2_deg, csr2_src, csr_w,
        b2, g2, be2, m2, v2, bufC, NN);

    // ---- layer 3: bufC[N,128] -> bufB[N,128] ----
    mfma_feat_kernel<128><<<(NN + 63) / 64, 256, 0, stream>>>(
        bufC, wfrag3, p3b, as3, ad3, h8, esrc, edst, bufB);
    edgew_kernel<<<(NN + 3) / 4, 256, 0, stream>>>(
        csr2_src, row2_start, row2_deg, (const float2*)esrc, (const float2*)edst, csr_w, NN);
    aggregate128_kernel<<<(NN + 3) / 4, 256, 0, stream>>>(
        (const unsigned short*)h8, row2_start, row2_deg, csr2_src, csr_w,
        b3, g3, be3, m3, v3, bufB, NN);

    // ---- pool (two-phase) + head ----
    pool_partial_kernel<<<GG * PSPLIT, 128, 0, stream>>>(bufB, batch, ppart);
    head_kernel<<<GG, 128, 0, stream>>>(ppart, batch, fw, fb, g4, be4, m4, v4,
                                        l1w, l1b, l2w, l2b, (float*)d_out);
}

// Round 12
// 674.997 us; speedup vs baseline: 1.0600x; 1.0600x over previous
//
#include <hip/hip_runtime.h>
#include <hip/hip_bf16.h>
#include <hip/hip_fp16.h>

#define NN   100000
#define EE   1600000
#define ETOT (EE + NN)
#define GG   256
#define BNEPS 1e-5f
#define NBK  391          // buckets of 256 nodes: (NN+255)/256
#define PADTOT (ETOT + NBK * 2048 + 64)
#define PSPLIT 16

typedef float floatx2 __attribute__((ext_vector_type(2)));
typedef short s16x8 __attribute__((ext_vector_type(8)));
typedef float f32x4v __attribute__((ext_vector_type(4)));

__device__ __forceinline__ unsigned short f2bf(float f) {
    unsigned u = __float_as_uint(f);
    unsigned r = u + 0x7FFF + ((u >> 16) & 1);
    return (unsigned short)(r >> 16);
}

// ---------------- CSR build: bucketed partition (single-writer cache lines) --

__global__ __launch_bounds__(256) void bucket_count_kernel(
    const int* __restrict__ ei, int* __restrict__ bucket_cnt)
{
    __shared__ int cnt[NBK];
    for (int i = threadIdx.x; i < NBK; i += 256) cnt[i] = 0;
    __syncthreads();
    int base = blockIdx.x * 8192;
    for (int k = threadIdx.x; k < 8192; k += 256) {
        int e = base + k;
        if (e < ETOT) {
            int dst = (e < EE) ? ei[EE + e] : (e - EE);
            atomicAdd(&cnt[dst >> 8], 1);
        }
    }
    __syncthreads();
    for (int i = threadIdx.x; i < NBK; i += 256)
        if (cnt[i]) atomicAdd(&bucket_cnt[i], cnt[i]);
}

__global__ __launch_bounds__(512) void bucket_scan_kernel(
    const int* __restrict__ bucket_cnt, int* __restrict__ bucket_base,
    int* __restrict__ gcursor)
{
    __shared__ int s[512];
    int t = threadIdx.x;
    int v = (t < NBK) ? bucket_cnt[t] : 0;
    s[t] = v;
    __syncthreads();
    int x = v;
    for (int o = 1; o < 512; o <<= 1) {
        int y = (t >= o) ? s[t - o] : 0;
        __syncthreads();
        x += y;
        s[t] = x;
        __syncthreads();
    }
    if (t < NBK) { bucket_base[t] = x - v; gcursor[t] = x - v; }
    if (t == 0) bucket_base[NBK] = ETOT;
}

__global__ __launch_bounds__(256) void partition_kernel(
    const int* __restrict__ ei, int* __restrict__ gcursor, int* __restrict__ part)
{
    __shared__ int cnt[NBK];
    __shared__ int basel[NBK];
    for (int i = threadIdx.x; i < NBK; i += 256) cnt[i] = 0;
    __syncthreads();
    int base = blockIdx.x * 4096;
    for (int k = threadIdx.x; k < 4096; k += 256) {
        int e = base + k;
        if (e < ETOT) {
            int dst = (e < EE) ? ei[EE + e] : (e - EE);
            atomicAdd(&cnt[dst >> 8], 1);
        }
    }
    __syncthreads();
    for (int i = threadIdx.x; i < NBK; i += 256) {
        int c = cnt[i];
        basel[i] = c ? atomicAdd(&gcursor[i], c) : 0;
        cnt[i] = 0;   // reuse as intra-block cursor
    }
    __syncthreads();
    for (int k = threadIdx.x; k < 4096; k += 256) {
        int e = base + k;
        if (e < ETOT) {
            int src, dst;
            if (e < EE) { src = ei[e]; dst = ei[EE + e]; }
            else        { src = e - EE; dst = e - EE; }
            int b = dst >> 8;
            int slot = atomicAdd(&cnt[b], 1);
            part[basel[b] + slot] = src | ((dst & 255) << 17);
        }
    }
}

// Padded CSR: per-node segments rounded up to 8 entries (pad src = 0),
// 8-aligned starts → aggregate loop needs no masking and uses int4 loads.
__global__ __launch_bounds__(256) void csr_build_kernel(
    const int* __restrict__ part, const int* __restrict__ bucket_base,
    int* __restrict__ row2_start, int* __restrict__ row2_deg,
    int* __restrict__ csr2_src)
{
    __shared__ int degs[256];
    __shared__ int sc[256];
    __shared__ int cur[256];
    int b = blockIdx.x;
    int t = threadIdx.x;
    int beg = bucket_base[b], end = bucket_base[b + 1];
    int pbase = ((beg + 7) & ~7) + 2048 * b;
    degs[t] = 0;
    __syncthreads();
    for (int j = beg + t; j < end; j += 256)
        atomicAdd(&degs[(part[j] >> 17) & 255], 1);
    __syncthreads();
    int dg = degs[t];
    int pdeg = (dg + 7) & ~7;
    sc[t] = pdeg;
    __syncthreads();
    int x = pdeg;
    for (int o = 1; o < 256; o <<= 1) {
        int y = (t >= o) ? sc[t - o] : 0;
        __syncthreads();
        x += y;
        sc[t] = x;
        __syncthreads();
    }
    int start2 = pbase + (x - pdeg);
    int node = b * 256 + t;
    if (node < NN) { row2_start[node] = start2; row2_deg[node] = dg; }
    cur[t] = start2;
    __syncthreads();
    for (int j = beg + t; j < end; j += 256) {
        int pv = part[j];
        int pos = atomicAdd(&cur[(pv >> 17) & 255], 1);
        csr2_src[pos] = pv & 0x1FFFF;
    }
    for (int k = dg; k < pdeg; ++k) csr2_src[start2 + k] = 0;
}

// ---------------- per-layer edge softmax weights (both heads, fp32) ----------

__global__ __launch_bounds__(256) void edgew_kernel(
    const int* __restrict__ csr2_src, const int* __restrict__ row2_start,
    const int* __restrict__ row2_deg,
    const float2* __restrict__ esrc, const float2* __restrict__ edst,
    float2* __restrict__ csr_w, int nN)
{
    int n = blockIdx.x * 4 + (threadIdx.x >> 6);
    int lane = threadIdx.x & 63;
    if (n >= nN) return;
    float2 ed = edst[n];
    int s2 = row2_start[n];
    int dg = row2_deg[n];
    int pc = (dg + 7) & ~7;
    for (int j = lane; j < pc; j += 64) {
        float2 w = make_float2(0.f, 0.f);
        if (j < dg) {
            int i = csr2_src[s2 + j];
            float2 es = esrc[i];
            float a0 = es.x + ed.x; a0 = (a0 > 0.f) ? a0 : 0.2f * a0;
            float a1 = es.y + ed.y; a1 = (a1 > 0.f) ? a1 : 0.2f * a1;
            w.x = __expf(a0);
            w.y = __expf(a1);
        }
        csr_w[s2 + j] = w;
    }
}

// ---------------- layer-1 feature transform (K=5); h stored fp8 e4m3 ---------

__global__ __launch_bounds__(256) void feat1_kernel(
    const float* __restrict__ xin, const float* __restrict__ W,
    const float* __restrict__ pw, const float* __restrict__ pb,
    const float* __restrict__ a_src, const float* __restrict__ a_dst,
    unsigned char* __restrict__ h8, float* __restrict__ esrc, float* __restrict__ edst,
    float* __restrict__ rout, int nN)
{
    constexpr int F_IN = 5, F_OUT = 64;
    int t = threadIdx.x;
    int n = blockIdx.x * 4 + t / F_OUT;
    int f = t % F_OUT;
    if (n >= nN) return;
    float acc = 0.f, racc = 0.f;
#pragma unroll
    for (int k = 0; k < F_IN; ++k) {
        float xv = xin[n * F_IN + k];
        acc  += xv * W[k * F_OUT + f];
        racc += xv * pw[k * F_OUT + f];
    }
    float other = __shfl_xor(acc, 1, 64);
    if ((f & 1) == 0) {
        int p = __builtin_amdgcn_cvt_pk_fp8_f32(acc, other, 0, false);
        *(unsigned short*)(h8 + (size_t)n * F_OUT + f) = (unsigned short)(p & 0xFFFF);
    }
    rout[(size_t)n * F_OUT + f] = racc + pb[f];
    float es = acc * a_src[f];
    float ed = acc * a_dst[f];
#pragma unroll
    for (int off = 16; off > 0; off >>= 1) {
        es += __shfl_xor(es, off, 32);
        ed += __shfl_xor(ed, off, 32);
    }
    if ((t & 31) == 0) {
        int head = (f >> 5) & 1;
        esrc[n * 2 + head] = es;
        edst[n * 2 + head] = ed;
    }
}

// ---------------- weight fragment prep (bf16 hi/lo split, MFMA B layout) -----
// wfrag unit u = ((nt*(K/32)+ks)*2 + hilo)*64 + lane, 8 bf16 per unit:
// B[k = ks*32 + (lane>>4)*8 + j][n = nt*16 + (lane&15)], cols 0..127 = W,
// 128..255 = pw.

template<int K>
__global__ __launch_bounds__(256) void prep_w_kernel(
    const float* __restrict__ W, const float* __restrict__ pw,
    short* __restrict__ wfrag)
{
    constexpr int KS = K / 32;
    int unit = blockIdx.x * 256 + threadIdx.x;
    int total = 16 * KS * 2 * 64;
    if (unit >= total) return;
    int lane = unit & 63;
    int rest = unit >> 6;
    int hilo = rest & 1;
    int fk = rest >> 1;
    int ks = fk % KS;
    int nt = fk / KS;
    int n = nt * 16 + (lane & 15);
    int k0 = ks * 32 + (lane >> 4) * 8;
    const float* src = (n < 128) ? (W + n) : (pw + (n - 128));
    s16x8 out;
#pragma unroll
    for (int j = 0; j < 8; ++j) {
        float wv = src[(size_t)(k0 + j) * 128];
        unsigned short hi = f2bf(wv);
        if (hilo == 0) {
            out[j] = (short)hi;
        } else {
            float fhi = __uint_as_float(((unsigned)hi) << 16);
            out[j] = (short)f2bf(wv - fhi);
        }
    }
    *(s16x8*)(wfrag + (size_t)unit * 8) = out;
}

// ---------------- MFMA feature transform (layers 2,3; N=256 = W‖pw) ----------
// R11 post-mortem: per-nt dependent chains + low concurrency = latency-bound
// (MfmaUtil 4.8%, VALU 11%, layer2==layer3 duration). v2: 128 nodes/block,
// each wave owns TWO A-tiles (32 nodes) → 2 interleaved MFMA chains (ILP×2),
// B-fragment loads amortized over 2× nodes; e-logit partials accumulated as
// plain FMAs per nt and shuffle-reduced ONCE at the end.

template<int K>
__global__ __launch_bounds__(256) void mfma_feat_kernel(
    const float* __restrict__ xin, const short* __restrict__ wfrag,
    const float* __restrict__ pb,
    const float* __restrict__ a_src, const float* __restrict__ a_dst,
    unsigned char* __restrict__ h8, float* __restrict__ esrc, float* __restrict__ edst,
    float* __restrict__ rout)
{
    constexpr int KS = K / 32;    // MFMA k-steps
    constexpr int CH = K / 8;     // 16-byte chunks per node row
    __shared__ short xs[8 * CH * 16 * 8];   // 8 tiles of 16 nodes

    const int tid = threadIdx.x;
    const int base = blockIdx.x * 128;

    // stage x tile → bf16 LDS in fragment-friendly chunk order
    constexpr int NF4 = 128 * K / 4;
    for (int idx = tid; idx < NF4; idx += 256) {
        int node = idx / (K / 4);
        int kq = idx % (K / 4);
        int gn = base + node; if (gn > NN - 1) gn = NN - 1;
        float4 v = *(const float4*)(xin + (size_t)gn * K + kq * 4);
        int tt = node >> 4, mm = node & 15, t = kq >> 1, half = kq & 1;
        short4 o;
        o.x = (short)f2bf(v.x); o.y = (short)f2bf(v.y);
        o.z = (short)f2bf(v.z); o.w = (short)f2bf(v.w);
        *(short4*)&xs[(((tt * CH + t) * 16 + mm) * 8) + half * 4] = o;
    }
    __syncthreads();

    const int w = tid >> 6;
    const int lane = tid & 63;
    const int quad = lane >> 4;
    const int m = lane & 15;
    const int node0 = base + w * 32 + quad * 4;   // tile0 rows +r
    const int node1 = node0 + 16;                 // tile1 rows +r

    s16x8 a0[KS], a1[KS];
#pragma unroll
    for (int ks = 0; ks < KS; ++ks) {
        a0[ks] = *(const s16x8*)&xs[(((w * 2 + 0) * CH + (ks * 4 + quad)) * 16 + m) * 8];
        a1[ks] = *(const s16x8*)&xs[(((w * 2 + 1) * CH + (ks * 4 + quad)) * 16 + m) * 8];
    }

    // e-logit partial accumulators: [tile][head][r]
    float es0h0[4] = {0.f,0.f,0.f,0.f}, es0h1[4] = {0.f,0.f,0.f,0.f};
    float ed0h0[4] = {0.f,0.f,0.f,0.f}, ed0h1[4] = {0.f,0.f,0.f,0.f};
    float es1h0[4] = {0.f,0.f,0.f,0.f}, es1h1[4] = {0.f,0.f,0.f,0.f};
    float ed1h0[4] = {0.f,0.f,0.f,0.f}, ed1h1[4] = {0.f,0.f,0.f,0.f};

#pragma unroll
    for (int nt = 0; nt < 16; ++nt) {
        s16x8 b[2 * KS];
#pragma unroll
        for (int i = 0; i < 2 * KS; ++i)
            b[i] = *(const s16x8*)(wfrag + (size_t)((nt * KS * 2 + i) * 64 + lane) * 8);
        f32x4v c0 = {0.f, 0.f, 0.f, 0.f};
        f32x4v c1 = {0.f, 0.f, 0.f, 0.f};
#pragma unroll
        for (int ks = 0; ks < KS; ++ks) {
            c0 = __builtin_amdgcn_mfma_f32_16x16x32_bf16(a0[ks], b[2 * ks + 0], c0, 0, 0, 0);
            c1 = __builtin_amdgcn_mfma_f32_16x16x32_bf16(a1[ks], b[2 * ks + 0], c1, 0, 0, 0);
            c0 = __builtin_amdgcn_mfma_f32_16x16x32_bf16(a0[ks], b[2 * ks + 1], c0, 0, 0, 0);
            c1 = __builtin_amdgcn_mfma_f32_16x16x32_bf16(a1[ks], b[2 * ks + 1], c1, 0, 0, 0);
        }
        if (nt < 8) {
            int col = nt * 16 + m;
            float av = a_src[col], dv = a_dst[col];
#pragma unroll
            for (int r = 0; r < 4; ++r) {
                float v0 = c0[r], v1 = c1[r];
                if (nt < 4) {
                    es0h0[r] = fmaf(v0, av, es0h0[r]); ed0h0[r] = fmaf(v0, dv, ed0h0[r]);
                    es1h0[r] = fmaf(v1, av, es1h0[r]); ed1h0[r] = fmaf(v1, dv, ed1h0[r]);
                } else {
                    es0h1[r] = fmaf(v0, av, es0h1[r]); ed0h1[r] = fmaf(v0, dv, ed0h1[r]);
                    es1h1[r] = fmaf(v1, av, es1h1[r]); ed1h1[r] = fmaf(v1, dv, ed1h1[r]);
                }
                float p0 = __shfl_xor(v0, 1, 16);
                float p1 = __shfl_xor(v1, 1, 16);
                if ((m & 1) == 0) {
                    if (node0 + r < NN) {
                        int p = __builtin_amdgcn_cvt_pk_fp8_f32(v0, p0, 0, false);
                        *(unsigned short*)(h8 + (size_t)(node0 + r) * 128 + col) = (unsigned short)(p & 0xFFFF);
                    }
                    if (node1 + r < NN) {
                        int p = __builtin_amdgcn_cvt_pk_fp8_f32(v1, p1, 0, false);
                        *(unsigned short*)(h8 + (size_t)(node1 + r) * 128 + col) = (unsigned short)(p & 0xFFFF);
                    }
                }
            }
        } else {
            int col = (nt - 8) * 16 + m;
            float bv = pb[col];
#pragma unroll
            for (int r = 0; r < 4; ++r) {
                if (node0 + r < NN) rout[(size_t)(node0 + r) * 128 + col] = c0[r] + bv;
                if (node1 + r < NN) rout[(size_t)(node1 + r) * 128 + col] = c1[r] + bv;
            }
        }
    }

    // single shuffle-reduce of the e-logit partials over the 16 m-lanes
#pragma unroll
    for (int r = 0; r < 4; ++r) {
#pragma unroll
        for (int off = 8; off > 0; off >>= 1) {
            es0h0[r] += __shfl_xor(es0h0[r], off, 16);
            es0h1[r] += __shfl_xor(es0h1[r], off, 16);
            ed0h0[r] += __shfl_xor(ed0h0[r], off, 16);
            ed0h1[r] += __shfl_xor(ed0h1[r], off, 16);
            es1h0[r] += __shfl_xor(es1h0[r], off, 16);
            es1h1[r] += __shfl_xor(es1h1[r], off, 16);
            ed1h0[r] += __shfl_xor(ed1h0[r], off, 16);
            ed1h1[r] += __shfl_xor(ed1h1[r], off, 16);
        }
    }
    if (m == 0) {
#pragma unroll
        for (int r = 0; r < 4; ++r) {
            if (node0 + r < NN) {
                ((float2*)esrc)[node0 + r] = make_float2(es0h0[r], es0h1[r]);
                ((float2*)edst)[node0 + r] = make_float2(ed0h0[r], ed0h1[r]);
            }
            if (node1 + r < NN) {
                ((float2*)esrc)[node1 + r] = make_float2(es1h0[r], es1h1[r]);
                ((float2*)edst)[node1 + r] = make_float2(ed1h0[r], ed1h1[r]);
            }
        }
    }
}

// ---------------- fused aggregate, F=128 (fp8 h, padded CSR, precomputed w) --
// No local arrays with punned fills (R8 lesson). Named scalars only.

__global__ __launch_bounds__(256) void aggregate128_kernel(
    const unsigned short* __restrict__ h8s,
    const int* __restrict__ row2_start, const int* __restrict__ row2_deg,
    const int* __restrict__ csr2_src, const float2* __restrict__ csr_w,
    const float* __restrict__ bias, const float* __restrict__ bng,
    const float* __restrict__ bnb, const float* __restrict__ bnm,
    const float* __restrict__ bnv, float* __restrict__ out, int nN)
{
    int w = threadIdx.x >> 6;
    int lane = threadIdx.x & 63;
    int n = blockIdx.x * 4 + w;
    if (n >= nN) return;
    bool hi = lane >= 32;
    int s2 = row2_start[n];
    int dg = row2_deg[n];
    int pc = (dg + 7) & ~7;
    const int4* sp = (const int4*)(csr2_src + s2);
    const float4* wp = (const float4*)(csr_w + s2);
    float s = 0.f, ax = 0.f, ay = 0.f;
    for (int j = 0; j < pc; j += 8) {
        int4 ia = sp[(j >> 2) + 0];
        int4 ib = sp[(j >> 2) + 1];
        float4 wa = wp[(j >> 1) + 0];
        float4 wb = wp[(j >> 1) + 1];
        float4 wc = wp[(j >> 1) + 2];
        float4 wd = wp[(j >> 1) + 3];
        unsigned short v0 = h8s[(size_t)ia.x * 64 + lane];
        unsigned short v1 = h8s[(size_t)ia.y * 64 + lane];
        unsigned short v2 = h8s[(size_t)ia.z * 64 + lane];
        unsigned short v3 = h8s[(size_t)ia.w * 64 + lane];
        unsigned short v4 = h8s[(size_t)ib.x * 64 + lane];
        unsigned short v5 = h8s[(size_t)ib.y * 64 + lane];
        unsigned short v6 = h8s[(size_t)ib.z * 64 + lane];
        unsigned short v7 = h8s[(size_t)ib.w * 64 + lane];
        float g0 = hi ? wa.y : wa.x;
        float g1 = hi ? wa.w : wa.z;
        float g2 = hi ? wb.y : wb.x;
        float g3 = hi ? wb.w : wb.z;
        float g4 = hi ? wc.y : wc.x;
        float g5 = hi ? wc.w : wc.z;
        float g6 = hi ? wd.y : wd.x;
        float g7 = hi ? wd.w : wd.z;
        floatx2 f0 = __builtin_amdgcn_cvt_pk_f32_fp8((int)v0, false);
        floatx2 f1 = __builtin_amdgcn_cvt_pk_f32_fp8((int)v1, false);
        floatx2 f2 = __builtin_amdgcn_cvt_pk_f32_fp8((int)v2, false);
        floatx2 f3 = __builtin_amdgcn_cvt_pk_f32_fp8((int)v3, false);
        floatx2 f4 = __builtin_amdgcn_cvt_pk_f32_fp8((int)v4, false);
        floatx2 f5 = __builtin_amdgcn_cvt_pk_f32_fp8((int)v5, false);
        floatx2 f6 = __builtin_amdgcn_cvt_pk_f32_fp8((int)v6, false);
        floatx2 f7 = __builtin_amdgcn_cvt_pk_f32_fp8((int)v7, false);
        ax = fmaf(g0, f0.x, ax); ay = fmaf(g0, f0.y, ay);
        ax = fmaf(g1, f1.x, ax); ay = fmaf(g1, f1.y, ay);
        ax = fmaf(g2, f2.x, ax); ay = fmaf(g2, f2.y, ay);
        ax = fmaf(g3, f3.x, ax); ay = fmaf(g3, f3.y, ay);
        ax = fmaf(g4, f4.x, ax); ay = fmaf(g4, f4.y, ay);
        ax = fmaf(g5, f5.x, ax); ay = fmaf(g5, f5.y, ay);
        ax = fmaf(g6, f6.x, ax); ay = fmaf(g6, f6.y, ay);
        ax = fmaf(g7, f7.x, ax); ay = fmaf(g7, f7.y, ay);
        s += ((g0 + g1) + (g2 + g3)) + ((g4 + g5) + (g6 + g7));
    }
    float inv = 1.f / (s + 1e-16f);
    int f0i = 2 * lane, f1i = 2 * lane + 1;
    float o0 = bng[f0i] * (ax * inv + bias[f0i] - bnm[f0i]) * rsqrtf(bnv[f0i] + BNEPS) + bnb[f0i];
    float o1 = bng[f1i] * (ay * inv + bias[f1i] - bnm[f1i]) * rsqrtf(bnv[f1i] + BNEPS) + bnb[f1i];
    float2* op = (float2*)(out + (size_t)n * 128) + lane;
    float2 prev = *op;
    prev.x += fmaxf(o0, 0.f);
    prev.y += fmaxf(o1, 0.f);
    *op = prev;
}

// ---------------- fused aggregate, F=64 ---------------------------------------

__global__ __launch_bounds__(256) void aggregate64_kernel(
    const unsigned char* __restrict__ h8,
    const int* __restrict__ row2_start, const int* __restrict__ row2_deg,
    const int* __restrict__ csr2_src, const float2* __restrict__ csr_w,
    const float* __restrict__ bias, const float* __restrict__ bng,
    const float* __restrict__ bnb, const float* __restrict__ bnm,
    const float* __restrict__ bnv, float* __restrict__ out, int nN)
{
    int w = threadIdx.x >> 6;
    int lane = threadIdx.x & 63;
    int n = blockIdx.x * 4 + w;
    if (n >= nN) return;
    bool hi = lane >= 32;
    int s2 = row2_start[n];
    int dg = row2_deg[n];
    int pc = (dg + 7) & ~7;
    const int4* sp = (const int4*)(csr2_src + s2);
    const float4* wp = (const float4*)(csr_w + s2);
    float s = 0.f, acc = 0.f;
    for (int j = 0; j < pc; j += 8) {
        int4 ia = sp[(j >> 2) + 0];
        int4 ib = sp[(j >> 2) + 1];
        float4 wa = wp[(j >> 1) + 0];
        float4 wb = wp[(j >> 1) + 1];
        float4 wc = wp[(j >> 1) + 2];
        float4 wd = wp[(j >> 1) + 3];
        unsigned char v0 = h8[(size_t)ia.x * 64 + lane];
        unsigned char v1 = h8[(size_t)ia.y * 64 + lane];
        unsigned char v2 = h8[(size_t)ia.z * 64 + lane];
        unsigned char v3 = h8[(size_t)ia.w * 64 + lane];
        unsigned char v4 = h8[(size_t)ib.x * 64 + lane];
        unsigned char v5 = h8[(size_t)ib.y * 64 + lane];
        unsigned char v6 = h8[(size_t)ib.z * 64 + lane];
        unsigned char v7 = h8[(size_t)ib.w * 64 + lane];
        float g0 = hi ? wa.y : wa.x;
        float g1 = hi ? wa.w : wa.z;
        float g2 = hi ? wb.y : wb.x;
        float g3 = hi ? wb.w : wb.z;
        float g4 = hi ? wc.y : wc.x;
        float g5 = hi ? wc.w : wc.z;
        float g6 = hi ? wd.y : wd.x;
        float g7 = hi ? wd.w : wd.z;
        acc = fmaf(g0, __builtin_amdgcn_cvt_f32_fp8((int)v0, 0), acc);
        acc = fmaf(g1, __builtin_amdgcn_cvt_f32_fp8((int)v1, 0), acc);
        acc = fmaf(g2, __builtin_amdgcn_cvt_f32_fp8((int)v2, 0), acc);
        acc = fmaf(g3, __builtin_amdgcn_cvt_f32_fp8((int)v3, 0), acc);
        acc = fmaf(g4, __builtin_amdgcn_cvt_f32_fp8((int)v4, 0), acc);
        acc = fmaf(g5, __builtin_amdgcn_cvt_f32_fp8((int)v5, 0), acc);
        acc = fmaf(g6, __builtin_amdgcn_cvt_f32_fp8((int)v6, 0), acc);
        acc = fmaf(g7, __builtin_amdgcn_cvt_f32_fp8((int)v7, 0), acc);
        s += ((g0 + g1) + (g2 + g3)) + ((g4 + g5) + (g6 + g7));
    }
    int f = lane;
    float g = acc / (s + 1e-16f);
    float vv = bng[f] * (g + bias[f] - bnm[f]) * rsqrtf(bnv[f] + BNEPS) + bnb[f];
    out[(size_t)n * 64 + f] = fmaxf(vv, 0.f) + out[(size_t)n * 64 + f];
}

// ---------------- pooling, two-phase ----------------

__global__ __launch_bounds__(128) void pool_partial_kernel(
    const float* __restrict__ hfin, const int* __restrict__ batch,
    float* __restrict__ ppart)
{
    int g = blockIdx.x / PSPLIT;
    int p = blockIdx.x % PSPLIT;
    int f = threadIdx.x;
    int lo = 0, hi = NN;
    while (lo < hi) { int mid = (lo + hi) >> 1; if (batch[mid] < g) lo = mid + 1; else hi = mid; }
    int start = lo;
    hi = NN;
    while (lo < hi) { int mid = (lo + hi) >> 1; if (batch[mid] < g + 1) lo = mid + 1; else hi = mid; }
    int end = lo;
    int len = end - start;
    int chunk = (len + PSPLIT - 1) / PSPLIT;
    int i0 = start + p * chunk;
    int i1 = i0 + chunk; if (i1 > end) i1 = end;
    float acc = 0.f;
    for (int i = i0; i < i1; ++i) acc += hfin[(size_t)i * 128 + f];
    ppart[((size_t)g * PSPLIT + p) * 128 + f] = acc;
}

// ---------------- MLP head (folds partial-sum reduce + mean) -----------------

__global__ __launch_bounds__(128) void head_kernel(
    const float* __restrict__ ppart, const int* __restrict__ batch,
    const float* __restrict__ fw, const float* __restrict__ fb,
    const float* __restrict__ g4, const float* __restrict__ be4,
    const float* __restrict__ m4, const float* __restrict__ v4,
    const float* __restrict__ l1w, const float* __restrict__ l1b,
    const float* __restrict__ l2w, const float* __restrict__ l2b,
    float* __restrict__ out)
{
    __shared__ float p[128];
    __shared__ float z1[32];
    __shared__ float z2[32];
    int g = blockIdx.x, t = threadIdx.x;
    int lo = 0, hi = NN;
    while (lo < hi) { int mid = (lo + hi) >> 1; if (batch[mid] < g) lo = mid + 1; else hi = mid; }
    int start = lo;
    hi = NN;
    while (lo < hi) { int mid = (lo + hi) >> 1; if (batch[mid] < g + 1) lo = mid + 1; else hi = mid; }
    float cnt = (float)(lo - start);
    float acc = 0.f;
#pragma unroll
    for (int q = 0; q < PSPLIT; ++q)
        acc += ppart[((size_t)g * PSPLIT + q) * 128 + t];
    p[t] = acc / fmaxf(cnt, 1.0f);
    __syncthreads();
    if (t < 32) {
        float a = fb[t];
        for (int k = 0; k < 128; ++k) a += p[k] * fw[k * 32 + t];
        float val = g4[t] * (a - m4[t]) * rsqrtf(v4[t] + BNEPS) + be4[t];
        z1[t] = fmaxf(val, 0.f);
    }
    __syncthreads();
    if (t < 32) {
        float a = l1b[t];
        for (int k = 0; k < 32; ++k) a += z1[k] * l1w[k * 32 + t];
        z2[t] = fmaxf(a, 0.f);
    }
    __syncthreads();
    if (t < 10) {
        float a = l2b[t];
        for (int k = 0; k < 32; ++k) a += z2[k] * l2w[k * 10 + t];
        out[g * 10 + t] = a;
    }
}

// ---------------- launch ----------------

extern "C" void kernel_launch(void* const* d_in, const int* in_sizes, int n_in,
                              void* d_out, int out_size, void* d_ws, size_t ws_size,
                              hipStream_t stream) {
    const float* x     = (const float*)d_in[0];
    const int*   ei    = (const int*)d_in[1];
    const int*   batch = (const int*)d_in[2];
    const float* w1  = (const float*)d_in[3];
    const float* as1 = (const float*)d_in[4];
    const float* ad1 = (const float*)d_in[5];
    const float* b1  = (const float*)d_in[6];
    const float* g1  = (const float*)d_in[7];
    const float* be1 = (const float*)d_in[8];
    const float* m1  = (const float*)d_in[9];
    const float* v1  = (const float*)d_in[10];
    const float* p1w = (const float*)d_in[11];
    const float* p1b = (const float*)d_in[12];
    const float* w2  = (const float*)d_in[13];
    const float* as2 = (const float*)d_in[14];
    const float* ad2 = (const float*)d_in[15];
    const float* b2  = (const float*)d_in[16];
    const float* g2  = (const float*)d_in[17];
    const float* be2 = (const float*)d_in[18];
    const float* m2  = (const float*)d_in[19];
    const float* v2  = (const float*)d_in[20];
    const float* p2w = (const float*)d_in[21];
    const float* p2b = (const float*)d_in[22];
    const float* w3  = (const float*)d_in[23];
    const float* as3 = (const float*)d_in[24];
    const float* ad3 = (const float*)d_in[25];
    const float* b3  = (const float*)d_in[26];
    const float* g3  = (const float*)d_in[27];
    const float* be3 = (const float*)d_in[28];
    const float* m3  = (const float*)d_in[29];
    const float* v3  = (const float*)d_in[30];
    const float* p3w = (const float*)d_in[31];
    const float* p3b = (const float*)d_in[32];
    const float* fw  = (const float*)d_in[33];
    const float* fb  = (const float*)d_in[34];
    const float* g4  = (const float*)d_in[35];
    const float* be4 = (const float*)d_in[36];
    const float* m4  = (const float*)d_in[37];
    const float* v4  = (const float*)d_in[38];
    const float* l1w = (const float*)d_in[39];
    const float* l1b = (const float*)d_in[40];
    const float* l2w = (const float*)d_in[41];
    const float* l2b = (const float*)d_in[42];

    char* ws = (char*)d_ws;
    size_t off = 0;
    auto alloc = [&](size_t bytes) -> char* {
        char* p = ws + off;
        off += (bytes + 255) & ~(size_t)255;
        return p;
    };
    int*    bucket_cnt  = (int*)alloc((NBK) * sizeof(int));
    int*    bucket_base = (int*)alloc((NBK + 1) * sizeof(int));
    int*    gcursor     = (int*)alloc((NBK) * sizeof(int));
    int*    part        = (int*)alloc((size_t)ETOT * sizeof(int));
    int*    row2_start  = (int*)alloc(NN * sizeof(int));
    int*    row2_deg    = (int*)alloc(NN * sizeof(int));
    int*    csr2_src    = (int*)alloc((size_t)PADTOT * sizeof(int));
    float2* csr_w       = (float2*)alloc((size_t)PADTOT * sizeof(float2));
    unsigned char* h8   = (unsigned char*)alloc((size_t)NN * 128);
    float*  bufB        = (float*)alloc((size_t)NN * 128 * sizeof(float));
    float*  bufC        = (float*)alloc((size_t)NN * 128 * sizeof(float));
    float*  esrc        = (float*)alloc((size_t)NN * 2 * sizeof(float));
    float*  edst        = (float*)alloc((size_t)NN * 2 * sizeof(float));
    float*  ppart       = (float*)alloc((size_t)GG * PSPLIT * 128 * sizeof(float));
    short*  wfrag2      = (short*)alloc((size_t)16 * 2 * 2 * 64 * 8 * sizeof(short));
    short*  wfrag3      = (short*)alloc((size_t)16 * 4 * 2 * 64 * 8 * sizeof(short));

    // ---- weight fragment prep (independent of everything else) ----
    prep_w_kernel<64><<<16, 256, 0, stream>>>(w2, p2w, wfrag2);
    prep_w_kernel<128><<<32, 256, 0, stream>>>(w3, p3w, wfrag3);

    // ---- CSR build (bucketed partition, padded layout) ----
    hipMemsetAsync(bucket_cnt, 0, NBK * sizeof(int), stream);
    bucket_count_kernel<<<(ETOT + 8191) / 8192, 256, 0, stream>>>(ei, bucket_cnt);
    bucket_scan_kernel<<<1, 512, 0, stream>>>(bucket_cnt, bucket_base, gcursor);
    partition_kernel<<<(ETOT + 4095) / 4096, 256, 0, stream>>>(ei, gcursor, part);
    csr_build_kernel<<<NBK, 256, 0, stream>>>(part, bucket_base, row2_start, row2_deg, csr2_src);

    // ---- layer 1: x[N,5] -> bufB[N,64] ----
    feat1_kernel<<<(NN + 3) / 4, 256, 0, stream>>>(
        x, w1, p1w, p1b, as1, ad1, h8, esrc, edst, bufB, NN);
    edgew_kernel<<<(NN + 3) / 4, 256, 0, stream>>>(
        csr2_src, row2_start, row2_deg, (const float2*)esrc, (const float2*)edst, csr_w, NN);
    aggregate64_kernel<<<(NN + 3) / 4, 256, 0, stream>>>(
        h8, row2_start, row2_deg, csr2_src, csr_w,
        b1, g1, be1, m1, v1, bufB, NN);

    // ---- layer 2: bufB[N,64] -> bufC[N,128] ----
    mfma_feat_kernel<64><<<(NN + 127) / 128, 256, 0, stream>>>(
        bufB, wfrag2, p2b, as2, ad2, h8, esrc, edst, bufC);
    edgew_kernel<<<(NN + 3) / 4, 256, 0, stream>>>(
        csr2_src, row2_start, row2_deg, (const float2*)esrc, (const float2*)edst, csr_w, NN);
    aggregate128_kernel<<<(NN + 3) / 4, 256, 0, stream>>>(
        (const unsigned short*)h8, row2_start, row2_deg, csr2_src, csr_w,
        b2, g2, be2, m2, v2, bufC, NN);

    // ---- layer 3: bufC[N,128] -> bufB[N,128] ----
    mfma_feat_kernel<128><<<(NN + 127) / 128, 256, 0, stream>>>(
        bufC, wfrag3, p3b, as3, ad3, h8, esrc, edst, bufB);
    edgew_kernel<<<(NN + 3) / 4, 256, 0, stream>>>(
        csr2_src, row2_start, row2_deg, (const float2*)esrc, (const float2*)edst, csr_w, NN);
    aggregate128_kernel<<<(NN + 3) / 4, 256, 0, stream>>>(
        (const unsigned short*)h8, row2_start, row2_deg, csr2_src, csr_w,
        b3, g3, be3, m3, v3, bufB, NN);

    // ---- pool (two-phase) + head ----
    pool_partial_kernel<<<GG * PSPLIT, 128, 0, stream>>>(bufB, batch, ppart);
    head_kernel<<<GG, 128, 0, stream>>>(ppart, batch, fw, fb, g4, be4, m4, v4,
                                        l1w, l1b, l2w, l2b, (float*)d_out);
}

// Round 13
// 672.947 us; speedup vs baseline: 1.0632x; 1.0030x over previous
//
#include <hip/hip_runtime.h>
#include <hip/hip_bf16.h>
#include <hip/hip_fp16.h>

#define NN   100000
#define EE   1600000
#define ETOT (EE + NN)
#define GG   256
#define BNEPS 1e-5f
#define NBK  391          // buckets of 256 nodes: (NN+255)/256
#define PADTOT (ETOT + NBK * 2048 + 64)
#define PSPLIT 16

typedef float floatx2 __attribute__((ext_vector_type(2)));
typedef short s16x8 __attribute__((ext_vector_type(8)));
typedef float f32x4v __attribute__((ext_vector_type(4)));

__device__ __forceinline__ unsigned short f2bf(float f) {
    unsigned u = __float_as_uint(f);
    unsigned r = u + 0x7FFF + ((u >> 16) & 1);
    return (unsigned short)(r >> 16);
}
__device__ __forceinline__ float bf2f(unsigned short b) {
    return __uint_as_float(((unsigned)b) << 16);
}

// ---------------- CSR build: bucketed partition (single-writer cache lines) --

__global__ __launch_bounds__(256) void bucket_count_kernel(
    const int* __restrict__ ei, int* __restrict__ bucket_cnt)
{
    __shared__ int cnt[NBK];
    for (int i = threadIdx.x; i < NBK; i += 256) cnt[i] = 0;
    __syncthreads();
    int base = blockIdx.x * 8192;
    for (int k = threadIdx.x; k < 8192; k += 256) {
        int e = base + k;
        if (e < ETOT) {
            int dst = (e < EE) ? ei[EE + e] : (e - EE);
            atomicAdd(&cnt[dst >> 8], 1);
        }
    }
    __syncthreads();
    for (int i = threadIdx.x; i < NBK; i += 256)
        if (cnt[i]) atomicAdd(&bucket_cnt[i], cnt[i]);
}

// also plants the -inf esrc sentinel used by pad edges (src = NN)
__global__ __launch_bounds__(512) void bucket_scan_kernel(
    const int* __restrict__ bucket_cnt, int* __restrict__ bucket_base,
    int* __restrict__ gcursor, float* __restrict__ esrcs)
{
    __shared__ int s[512];
    int t = threadIdx.x;
    int v = (t < NBK) ? bucket_cnt[t] : 0;
    s[t] = v;
    __syncthreads();
    int x = v;
    for (int o = 1; o < 512; o <<= 1) {
        int y = (t >= o) ? s[t - o] : 0;
        __syncthreads();
        x += y;
        s[t] = x;
        __syncthreads();
    }
    if (t < NBK) { bucket_base[t] = x - v; gcursor[t] = x - v; }
    if (t == 0) {
        bucket_base[NBK] = ETOT;
        esrcs[2 * NN]     = __int_as_float(0xFF800000);  // -inf
        esrcs[2 * NN + 1] = __int_as_float(0xFF800000);
    }
}

__global__ __launch_bounds__(256) void partition_kernel(
    const int* __restrict__ ei, int* __restrict__ gcursor, int* __restrict__ part)
{
    __shared__ int cnt[NBK];
    __shared__ int basel[NBK];
    for (int i = threadIdx.x; i < NBK; i += 256) cnt[i] = 0;
    __syncthreads();
    int base = blockIdx.x * 4096;
    for (int k = threadIdx.x; k < 4096; k += 256) {
        int e = base + k;
        if (e < ETOT) {
            int dst = (e < EE) ? ei[EE + e] : (e - EE);
            atomicAdd(&cnt[dst >> 8], 1);
        }
    }
    __syncthreads();
    for (int i = threadIdx.x; i < NBK; i += 256) {
        int c = cnt[i];
        basel[i] = c ? atomicAdd(&gcursor[i], c) : 0;
        cnt[i] = 0;   // reuse as intra-block cursor
    }
    __syncthreads();
    for (int k = threadIdx.x; k < 4096; k += 256) {
        int e = base + k;
        if (e < ETOT) {
            int src, dst;
            if (e < EE) { src = ei[e]; dst = ei[EE + e]; }
            else        { src = e - EE; dst = e - EE; }
            int b = dst >> 8;
            int slot = atomicAdd(&cnt[b], 1);
            part[basel[b] + slot] = src | ((dst & 255) << 17);
        }
    }
}

// Padded CSR: per-node segments rounded up to 8 entries, pad src = NN
// (sentinel: esrc[NN] = -inf → exp weight 0, so no masking needed in aggs).
__global__ __launch_bounds__(256) void csr_build_kernel(
    const int* __restrict__ part, const int* __restrict__ bucket_base,
    int* __restrict__ row2_start, int* __restrict__ row2_deg,
    int* __restrict__ csr2_src)
{
    __shared__ int degs[256];
    __shared__ int sc[256];
    __shared__ int cur[256];
    int b = blockIdx.x;
    int t = threadIdx.x;
    int beg = bucket_base[b], end = bucket_base[b + 1];
    int pbase = ((beg + 7) & ~7) + 2048 * b;
    degs[t] = 0;
    __syncthreads();
    for (int j = beg + t; j < end; j += 256)
        atomicAdd(&degs[(part[j] >> 17) & 255], 1);
    __syncthreads();
    int dg = degs[t];
    int pdeg = (dg + 7) & ~7;
    sc[t] = pdeg;
    __syncthreads();
    int x = pdeg;
    for (int o = 1; o < 256; o <<= 1) {
        int y = (t >= o) ? sc[t - o] : 0;
        __syncthreads();
        x += y;
        sc[t] = x;
        __syncthreads();
    }
    int start2 = pbase + (x - pdeg);
    int node = b * 256 + t;
    if (node < NN) { row2_start[node] = start2; row2_deg[node] = dg; }
    cur[t] = start2;
    __syncthreads();
    for (int j = beg + t; j < end; j += 256) {
        int pv = part[j];
        int pos = atomicAdd(&cur[(pv >> 17) & 255], 1);
        csr2_src[pos] = pv & 0x1FFFF;
    }
    for (int k = dg; k < pdeg; ++k) csr2_src[start2 + k] = NN;
}

// ---------------- layer-1 feature transform (K=5); h fp8, rout bf16 ----------

__global__ __launch_bounds__(256) void feat1_kernel(
    const float* __restrict__ xin, const float* __restrict__ W,
    const float* __restrict__ pw, const float* __restrict__ pb,
    const float* __restrict__ a_src, const float* __restrict__ a_dst,
    unsigned char* __restrict__ h8, float* __restrict__ esrc, float* __restrict__ edst,
    unsigned short* __restrict__ rout16, int nN)
{
    constexpr int F_IN = 5, F_OUT = 64;
    int t = threadIdx.x;
    int n = blockIdx.x * 4 + t / F_OUT;
    int f = t % F_OUT;
    if (n >= nN) return;
    float acc = 0.f, racc = 0.f;
#pragma unroll
    for (int k = 0; k < F_IN; ++k) {
        float xv = xin[n * F_IN + k];
        acc  += xv * W[k * F_OUT + f];
        racc += xv * pw[k * F_OUT + f];
    }
    float other = __shfl_xor(acc, 1, 64);
    if ((f & 1) == 0) {
        int p = __builtin_amdgcn_cvt_pk_fp8_f32(acc, other, 0, false);
        *(unsigned short*)(h8 + (size_t)n * F_OUT + f) = (unsigned short)(p & 0xFFFF);
    }
    rout16[(size_t)n * F_OUT + f] = f2bf(racc + pb[f]);
    float es = acc * a_src[f];
    float ed = acc * a_dst[f];
#pragma unroll
    for (int off = 16; off > 0; off >>= 1) {
        es += __shfl_xor(es, off, 32);
        ed += __shfl_xor(ed, off, 32);
    }
    if ((t & 31) == 0) {
        int head = (f >> 5) & 1;
        esrc[n * 2 + head] = es;
        edst[n * 2 + head] = ed;
    }
}

// ---------------- weight fragment prep (bf16 hi/lo split, MFMA B layout) -----

template<int K>
__global__ __launch_bounds__(256) void prep_w_kernel(
    const float* __restrict__ W, const float* __restrict__ pw,
    short* __restrict__ wfrag)
{
    constexpr int KS = K / 32;
    int unit = blockIdx.x * 256 + threadIdx.x;
    int total = 16 * KS * 2 * 64;
    if (unit >= total) return;
    int lane = unit & 63;
    int rest = unit >> 6;
    int hilo = rest & 1;
    int fk = rest >> 1;
    int ks = fk % KS;
    int nt = fk / KS;
    int n = nt * 16 + (lane & 15);
    int k0 = ks * 32 + (lane >> 4) * 8;
    const float* src = (n < 128) ? (W + n) : (pw + (n - 128));
    s16x8 out;
#pragma unroll
    for (int j = 0; j < 8; ++j) {
        float wv = src[(size_t)(k0 + j) * 128];
        unsigned short hi = f2bf(wv);
        if (hilo == 0) {
            out[j] = (short)hi;
        } else {
            float fhi = __uint_as_float(((unsigned)hi) << 16);
            out[j] = (short)f2bf(wv - fhi);
        }
    }
    *(s16x8*)(wfrag + (size_t)unit * 8) = out;
}

// ---------------- MFMA feature transform (layers 2,3; N=256 = W‖pw) ----------
// Input x now bf16 → staging is a pure 16B-chunk copy (no converts).
// Dual A-tile per wave (R12 win), deferred e-logit reductions.

template<int K>
__global__ __launch_bounds__(256) void mfma_feat_kernel(
    const unsigned short* __restrict__ xin16, const short* __restrict__ wfrag,
    const float* __restrict__ pb,
    const float* __restrict__ a_src, const float* __restrict__ a_dst,
    unsigned char* __restrict__ h8, float* __restrict__ esrc, float* __restrict__ edst,
    unsigned short* __restrict__ rout16)
{
    constexpr int KS = K / 32;    // MFMA k-steps
    constexpr int CH = K / 8;     // 8-feature (16 B) chunks per node row
    __shared__ s16x8 xs[8 * CH * 16];   // 8 tiles of 16 nodes

    const int tid = threadIdx.x;
    const int base = blockIdx.x * 128;

    for (int idx = tid; idx < 128 * CH; idx += 256) {
        int node = idx / CH;
        int ch = idx % CH;
        int gn = base + node; if (gn > NN - 1) gn = NN - 1;
        s16x8 v = *(const s16x8*)(xin16 + (size_t)gn * K + ch * 8);
        int tt = node >> 4, mm = node & 15;
        xs[(tt * CH + ch) * 16 + mm] = v;
    }
    __syncthreads();

    const int w = tid >> 6;
    const int lane = tid & 63;
    const int quad = lane >> 4;
    const int m = lane & 15;
    const int node0 = base + w * 32 + quad * 4;   // tile0 rows +r
    const int node1 = node0 + 16;                 // tile1 rows +r

    s16x8 a0[KS], a1[KS];
#pragma unroll
    for (int ks = 0; ks < KS; ++ks) {
        a0[ks] = xs[((w * 2 + 0) * CH + (ks * 4 + quad)) * 16 + m];
        a1[ks] = xs[((w * 2 + 1) * CH + (ks * 4 + quad)) * 16 + m];
    }

    float es0h0[4] = {0.f,0.f,0.f,0.f}, es0h1[4] = {0.f,0.f,0.f,0.f};
    float ed0h0[4] = {0.f,0.f,0.f,0.f}, ed0h1[4] = {0.f,0.f,0.f,0.f};
    float es1h0[4] = {0.f,0.f,0.f,0.f}, es1h1[4] = {0.f,0.f,0.f,0.f};
    float ed1h0[4] = {0.f,0.f,0.f,0.f}, ed1h1[4] = {0.f,0.f,0.f,0.f};

#pragma unroll
    for (int nt = 0; nt < 16; ++nt) {
        s16x8 b[2 * KS];
#pragma unroll
        for (int i = 0; i < 2 * KS; ++i)
            b[i] = *(const s16x8*)(wfrag + (size_t)((nt * KS * 2 + i) * 64 + lane) * 8);
        f32x4v c0 = {0.f, 0.f, 0.f, 0.f};
        f32x4v c1 = {0.f, 0.f, 0.f, 0.f};
#pragma unroll
        for (int ks = 0; ks < KS; ++ks) {
            c0 = __builtin_amdgcn_mfma_f32_16x16x32_bf16(a0[ks], b[2 * ks + 0], c0, 0, 0, 0);
            c1 = __builtin_amdgcn_mfma_f32_16x16x32_bf16(a1[ks], b[2 * ks + 0], c1, 0, 0, 0);
            c0 = __builtin_amdgcn_mfma_f32_16x16x32_bf16(a0[ks], b[2 * ks + 1], c0, 0, 0, 0);
            c1 = __builtin_amdgcn_mfma_f32_16x16x32_bf16(a1[ks], b[2 * ks + 1], c1, 0, 0, 0);
        }
        if (nt < 8) {
            int col = nt * 16 + m;
            float av = a_src[col], dv = a_dst[col];
#pragma unroll
            for (int r = 0; r < 4; ++r) {
                float v0 = c0[r], v1 = c1[r];
                if (nt < 4) {
                    es0h0[r] = fmaf(v0, av, es0h0[r]); ed0h0[r] = fmaf(v0, dv, ed0h0[r]);
                    es1h0[r] = fmaf(v1, av, es1h0[r]); ed1h0[r] = fmaf(v1, dv, ed1h0[r]);
                } else {
                    es0h1[r] = fmaf(v0, av, es0h1[r]); ed0h1[r] = fmaf(v0, dv, ed0h1[r]);
                    es1h1[r] = fmaf(v1, av, es1h1[r]); ed1h1[r] = fmaf(v1, dv, ed1h1[r]);
                }
                float p0 = __shfl_xor(v0, 1, 16);
                float p1 = __shfl_xor(v1, 1, 16);
                if ((m & 1) == 0) {
                    if (node0 + r < NN) {
                        int p = __builtin_amdgcn_cvt_pk_fp8_f32(v0, p0, 0, false);
                        *(unsigned short*)(h8 + (size_t)(node0 + r) * 128 + col) = (unsigned short)(p & 0xFFFF);
                    }
                    if (node1 + r < NN) {
                        int p = __builtin_amdgcn_cvt_pk_fp8_f32(v1, p1, 0, false);
                        *(unsigned short*)(h8 + (size_t)(node1 + r) * 128 + col) = (unsigned short)(p & 0xFFFF);
                    }
                }
            }
        } else {
            int col = (nt - 8) * 16 + m;
            float bv = pb[col];
#pragma unroll
            for (int r = 0; r < 4; ++r) {
                if (node0 + r < NN) rout16[(size_t)(node0 + r) * 128 + col] = f2bf(c0[r] + bv);
                if (node1 + r < NN) rout16[(size_t)(node1 + r) * 128 + col] = f2bf(c1[r] + bv);
            }
        }
    }

#pragma unroll
    for (int r = 0; r < 4; ++r) {
#pragma unroll
        for (int off = 8; off > 0; off >>= 1) {
            es0h0[r] += __shfl_xor(es0h0[r], off, 16);
            es0h1[r] += __shfl_xor(es0h1[r], off, 16);
            ed0h0[r] += __shfl_xor(ed0h0[r], off, 16);
            ed0h1[r] += __shfl_xor(ed0h1[r], off, 16);
            es1h0[r] += __shfl_xor(es1h0[r], off, 16);
            es1h1[r] += __shfl_xor(es1h1[r], off, 16);
            ed1h0[r] += __shfl_xor(ed1h0[r], off, 16);
            ed1h1[r] += __shfl_xor(ed1h1[r], off, 16);
        }
    }
    if (m == 0) {
#pragma unroll
        for (int r = 0; r < 4; ++r) {
            if (node0 + r < NN) {
                ((float2*)esrc)[node0 + r] = make_float2(es0h0[r], es0h1[r]);
                ((float2*)edst)[node0 + r] = make_float2(ed0h0[r], ed0h1[r]);
            }
            if (node1 + r < NN) {
                ((float2*)esrc)[node1 + r] = make_float2(es1h0[r], es1h1[r]);
                ((float2*)edst)[node1 + r] = make_float2(ed1h0[r], ed1h1[r]);
            }
        }
    }
}

// ---------------- fused aggregate, F=128 (fp8 h, fused exp, bf16 out) --------
// Pad edges carry src=NN whose esrc is -inf → exp weight 0 (no masking).
// Named scalars only (R8 lesson).

__global__ __launch_bounds__(256) void aggregate128_kernel(
    const unsigned short* __restrict__ h8s,
    const int* __restrict__ row2_start, const int* __restrict__ row2_deg,
    const int* __restrict__ csr2_src,
    const float2* __restrict__ esrc, const float2* __restrict__ edst,
    const float* __restrict__ bias, const float* __restrict__ bng,
    const float* __restrict__ bnb, const float* __restrict__ bnm,
    const float* __restrict__ bnv, unsigned short* __restrict__ io16, int nN)
{
    int w = threadIdx.x >> 6;
    int lane = threadIdx.x & 63;
    int n = blockIdx.x * 4 + w;
    if (n >= nN) return;
    bool hi = lane >= 32;
    float2 edv = edst[n];
    float ed = hi ? edv.y : edv.x;
    int s2 = row2_start[n];
    int dg = row2_deg[n];
    int pc = (dg + 7) & ~7;
    const int4* sp = (const int4*)(csr2_src + s2);
    float s = 0.f, ax = 0.f, ay = 0.f;
    for (int j = 0; j < pc; j += 8) {
        int4 ia = sp[(j >> 2) + 0];
        int4 ib = sp[(j >> 2) + 1];
        float2 q0 = esrc[ia.x];
        float2 q1 = esrc[ia.y];
        float2 q2 = esrc[ia.z];
        float2 q3 = esrc[ia.w];
        float2 q4 = esrc[ib.x];
        float2 q5 = esrc[ib.y];
        float2 q6 = esrc[ib.z];
        float2 q7 = esrc[ib.w];
        unsigned short v0 = h8s[(size_t)ia.x * 64 + lane];
        unsigned short v1 = h8s[(size_t)ia.y * 64 + lane];
        unsigned short v2 = h8s[(size_t)ia.z * 64 + lane];
        unsigned short v3 = h8s[(size_t)ia.w * 64 + lane];
        unsigned short v4 = h8s[(size_t)ib.x * 64 + lane];
        unsigned short v5 = h8s[(size_t)ib.y * 64 + lane];
        unsigned short v6 = h8s[(size_t)ib.z * 64 + lane];
        unsigned short v7 = h8s[(size_t)ib.w * 64 + lane];
        float a0 = (hi ? q0.y : q0.x) + ed; a0 = (a0 > 0.f) ? a0 : 0.2f * a0;
        float a1 = (hi ? q1.y : q1.x) + ed; a1 = (a1 > 0.f) ? a1 : 0.2f * a1;
        float a2 = (hi ? q2.y : q2.x) + ed; a2 = (a2 > 0.f) ? a2 : 0.2f * a2;
        float a3 = (hi ? q3.y : q3.x) + ed; a3 = (a3 > 0.f) ? a3 : 0.2f * a3;
        float a4 = (hi ? q4.y : q4.x) + ed; a4 = (a4 > 0.f) ? a4 : 0.2f * a4;
        float a5 = (hi ? q5.y : q5.x) + ed; a5 = (a5 > 0.f) ? a5 : 0.2f * a5;
        float a6 = (hi ? q6.y : q6.x) + ed; a6 = (a6 > 0.f) ? a6 : 0.2f * a6;
        float a7 = (hi ? q7.y : q7.x) + ed; a7 = (a7 > 0.f) ? a7 : 0.2f * a7;
        float g0 = __expf(a0);
        float g1 = __expf(a1);
        float g2 = __expf(a2);
        float g3 = __expf(a3);
        float g4 = __expf(a4);
        float g5 = __expf(a5);
        float g6 = __expf(a6);
        float g7 = __expf(a7);
        floatx2 f0 = __builtin_amdgcn_cvt_pk_f32_fp8((int)v0, false);
        floatx2 f1 = __builtin_amdgcn_cvt_pk_f32_fp8((int)v1, false);
        floatx2 f2 = __builtin_amdgcn_cvt_pk_f32_fp8((int)v2, false);
        floatx2 f3 = __builtin_amdgcn_cvt_pk_f32_fp8((int)v3, false);
        floatx2 f4 = __builtin_amdgcn_cvt_pk_f32_fp8((int)v4, false);
        floatx2 f5 = __builtin_amdgcn_cvt_pk_f32_fp8((int)v5, false);
        floatx2 f6 = __builtin_amdgcn_cvt_pk_f32_fp8((int)v6, false);
        floatx2 f7 = __builtin_amdgcn_cvt_pk_f32_fp8((int)v7, false);
        ax = fmaf(g0, f0.x, ax); ay = fmaf(g0, f0.y, ay);
        ax = fmaf(g1, f1.x, ax); ay = fmaf(g1, f1.y, ay);
        ax = fmaf(g2, f2.x, ax); ay = fmaf(g2, f2.y, ay);
        ax = fmaf(g3, f3.x, ax); ay = fmaf(g3, f3.y, ay);
        ax = fmaf(g4, f4.x, ax); ay = fmaf(g4, f4.y, ay);
        ax = fmaf(g5, f5.x, ax); ay = fmaf(g5, f5.y, ay);
        ax = fmaf(g6, f6.x, ax); ay = fmaf(g6, f6.y, ay);
        ax = fmaf(g7, f7.x, ax); ay = fmaf(g7, f7.y, ay);
        s += ((g0 + g1) + (g2 + g3)) + ((g4 + g5) + (g6 + g7));
    }
    float inv = 1.f / (s + 1e-16f);
    int f0i = 2 * lane, f1i = 2 * lane + 1;
    float o0 = bng[f0i] * (ax * inv + bias[f0i] - bnm[f0i]) * rsqrtf(bnv[f0i] + BNEPS) + bnb[f0i];
    float o1 = bng[f1i] * (ay * inv + bias[f1i] - bnm[f1i]) * rsqrtf(bnv[f1i] + BNEPS) + bnb[f1i];
    unsigned* iop = (unsigned*)(io16 + (size_t)n * 128) + lane;
    unsigned pu = *iop;
    float r0 = fmaxf(o0, 0.f) + __uint_as_float((pu & 0xFFFFu) << 16);
    float r1 = fmaxf(o1, 0.f) + __uint_as_float(pu & 0xFFFF0000u);
    *iop = (unsigned)f2bf(r0) | ((unsigned)f2bf(r1) << 16);
}

// ---------------- fused aggregate, F=64 ---------------------------------------

__global__ __launch_bounds__(256) void aggregate64_kernel(
    const unsigned char* __restrict__ h8,
    const int* __restrict__ row2_start, const int* __restrict__ row2_deg,
    const int* __restrict__ csr2_src,
    const float2* __restrict__ esrc, const float2* __restrict__ edst,
    const float* __restrict__ bias, const float* __restrict__ bng,
    const float* __restrict__ bnb, const float* __restrict__ bnm,
    const float* __restrict__ bnv, unsigned short* __restrict__ io16, int nN)
{
    int w = threadIdx.x >> 6;
    int lane = threadIdx.x & 63;
    int n = blockIdx.x * 4 + w;
    if (n >= nN) return;
    bool hi = lane >= 32;
    float2 edv = edst[n];
    float ed = hi ? edv.y : edv.x;
    int s2 = row2_start[n];
    int dg = row2_deg[n];
    int pc = (dg + 7) & ~7;
    const int4* sp = (const int4*)(csr2_src + s2);
    float s = 0.f, acc = 0.f;
    for (int j = 0; j < pc; j += 8) {
        int4 ia = sp[(j >> 2) + 0];
        int4 ib = sp[(j >> 2) + 1];
        float2 q0 = esrc[ia.x];
        float2 q1 = esrc[ia.y];
        float2 q2 = esrc[ia.z];
        float2 q3 = esrc[ia.w];
        float2 q4 = esrc[ib.x];
        float2 q5 = esrc[ib.y];
        float2 q6 = esrc[ib.z];
        float2 q7 = esrc[ib.w];
        unsigned char v0 = h8[(size_t)ia.x * 64 + lane];
        unsigned char v1 = h8[(size_t)ia.y * 64 + lane];
        unsigned char v2 = h8[(size_t)ia.z * 64 + lane];
        unsigned char v3 = h8[(size_t)ia.w * 64 + lane];
        unsigned char v4 = h8[(size_t)ib.x * 64 + lane];
        unsigned char v5 = h8[(size_t)ib.y * 64 + lane];
        unsigned char v6 = h8[(size_t)ib.z * 64 + lane];
        unsigned char v7 = h8[(size_t)ib.w * 64 + lane];
        float a0 = (hi ? q0.y : q0.x) + ed; a0 = (a0 > 0.f) ? a0 : 0.2f * a0;
        float a1 = (hi ? q1.y : q1.x) + ed; a1 = (a1 > 0.f) ? a1 : 0.2f * a1;
        float a2 = (hi ? q2.y : q2.x) + ed; a2 = (a2 > 0.f) ? a2 : 0.2f * a2;
        float a3 = (hi ? q3.y : q3.x) + ed; a3 = (a3 > 0.f) ? a3 : 0.2f * a3;
        float a4 = (hi ? q4.y : q4.x) + ed; a4 = (a4 > 0.f) ? a4 : 0.2f * a4;
        float a5 = (hi ? q5.y : q5.x) + ed; a5 = (a5 > 0.f) ? a5 : 0.2f * a5;
        float a6 = (hi ? q6.y : q6.x) + ed; a6 = (a6 > 0.f) ? a6 : 0.2f * a6;
        float a7 = (hi ? q7.y : q7.x) + ed; a7 = (a7 > 0.f) ? a7 : 0.2f * a7;
        float g0 = __expf(a0);
        float g1 = __expf(a1);
        float g2 = __expf(a2);
        float g3 = __expf(a3);
        float g4 = __expf(a4);
        float g5 = __expf(a5);
        float g6 = __expf(a6);
        float g7 = __expf(a7);
        acc = fmaf(g0, __builtin_amdgcn_cvt_f32_fp8((int)v0, 0), acc);
        acc = fmaf(g1, __builtin_amdgcn_cvt_f32_fp8((int)v1, 0), acc);
        acc = fmaf(g2, __builtin_amdgcn_cvt_f32_fp8((int)v2, 0), acc);
        acc = fmaf(g3, __builtin_amdgcn_cvt_f32_fp8((int)v3, 0), acc);
        acc = fmaf(g4, __builtin_amdgcn_cvt_f32_fp8((int)v4, 0), acc);
        acc = fmaf(g5, __builtin_amdgcn_cvt_f32_fp8((int)v5, 0), acc);
        acc = fmaf(g6, __builtin_amdgcn_cvt_f32_fp8((int)v6, 0), acc);
        acc = fmaf(g7, __builtin_amdgcn_cvt_f32_fp8((int)v7, 0), acc);
        s += ((g0 + g1) + (g2 + g3)) + ((g4 + g5) + (g6 + g7));
    }
    int f = lane;
    float g = acc / (s + 1e-16f);
    float vv = bng[f] * (g + bias[f] - bnm[f]) * rsqrtf(bnv[f] + BNEPS) + bnb[f];
    float prev = bf2f(io16[(size_t)n * 64 + f]);
    io16[(size_t)n * 64 + f] = f2bf(fmaxf(vv, 0.f) + prev);
}

// ---------------- pooling, two-phase (bf16 input) ----------------

__global__ __launch_bounds__(128) void pool_partial_kernel(
    const unsigned short* __restrict__ hf16, const int* __restrict__ batch,
    float* __restrict__ ppart)
{
    int g = blockIdx.x / PSPLIT;
    int p = blockIdx.x % PSPLIT;
    int f = threadIdx.x;
    int lo = 0, hi = NN;
    while (lo < hi) { int mid = (lo + hi) >> 1; if (batch[mid] < g) lo = mid + 1; else hi = mid; }
    int start = lo;
    hi = NN;
    while (lo < hi) { int mid = (lo + hi) >> 1; if (batch[mid] < g + 1) lo = mid + 1; else hi = mid; }
    int end = lo;
    int len = end - start;
    int chunk = (len + PSPLIT - 1) / PSPLIT;
    int i0 = start + p * chunk;
    int i1 = i0 + chunk; if (i1 > end) i1 = end;
    float acc = 0.f;
    for (int i = i0; i < i1; ++i) acc += bf2f(hf16[(size_t)i * 128 + f]);
    ppart[((size_t)g * PSPLIT + p) * 128 + f] = acc;
}

// ---------------- MLP head (folds partial-sum reduce + mean) -----------------

__global__ __launch_bounds__(128) void head_kernel(
    const float* __restrict__ ppart, const int* __restrict__ batch,
    const float* __restrict__ fw, const float* __restrict__ fb,
    const float* __restrict__ g4, const float* __restrict__ be4,
    const float* __restrict__ m4, const float* __restrict__ v4,
    const float* __restrict__ l1w, const float* __restrict__ l1b,
    const float* __restrict__ l2w, const float* __restrict__ l2b,
    float* __restrict__ out)
{
    __shared__ float p[128];
    __shared__ float z1[32];
    __shared__ float z2[32];
    int g = blockIdx.x, t = threadIdx.x;
    int lo = 0, hi = NN;
    while (lo < hi) { int mid = (lo + hi) >> 1; if (batch[mid] < g) lo = mid + 1; else hi = mid; }
    int start = lo;
    hi = NN;
    while (lo < hi) { int mid = (lo + hi) >> 1; if (batch[mid] < g + 1) lo = mid + 1; else hi = mid; }
    float cnt = (float)(lo - start);
    float acc = 0.f;
#pragma unroll
    for (int q = 0; q < PSPLIT; ++q)
        acc += ppart[((size_t)g * PSPLIT + q) * 128 + t];
    p[t] = acc / fmaxf(cnt, 1.0f);
    __syncthreads();
    if (t < 32) {
        float a = fb[t];
        for (int k = 0; k < 128; ++k) a += p[k] * fw[k * 32 + t];
        float val = g4[t] * (a - m4[t]) * rsqrtf(v4[t] + BNEPS) + be4[t];
        z1[t] = fmaxf(val, 0.f);
    }
    __syncthreads();
    if (t < 32) {
        float a = l1b[t];
        for (int k = 0; k < 32; ++k) a += z1[k] * l1w[k * 32 + t];
        z2[t] = fmaxf(a, 0.f);
    }
    __syncthreads();
    if (t < 10) {
        float a = l2b[t];
        for (int k = 0; k < 32; ++k) a += z2[k] * l2w[k * 10 + t];
        out[g * 10 + t] = a;
    }
}

// ---------------- launch ----------------

extern "C" void kernel_launch(void* const* d_in, const int* in_sizes, int n_in,
                              void* d_out, int out_size, void* d_ws, size_t ws_size,
                              hipStream_t stream) {
    const float* x     = (const float*)d_in[0];
    const int*   ei    = (const int*)d_in[1];
    const int*   batch = (const int*)d_in[2];
    const float* w1  = (const float*)d_in[3];
    const float* as1 = (const float*)d_in[4];
    const float* ad1 = (const float*)d_in[5];
    const float* b1  = (const float*)d_in[6];
    const float* g1  = (const float*)d_in[7];
    const float* be1 = (const float*)d_in[8];
    const float* m1  = (const float*)d_in[9];
    const float* v1  = (const float*)d_in[10];
    const float* p1w = (const float*)d_in[11];
    const float* p1b = (const float*)d_in[12];
    const float* w2  = (const float*)d_in[13];
    const float* as2 = (const float*)d_in[14];
    const float* ad2 = (const float*)d_in[15];
    const float* b2  = (const float*)d_in[16];
    const float* g2  = (const float*)d_in[17];
    const float* be2 = (const float*)d_in[18];
    const float* m2  = (const float*)d_in[19];
    const float* v2  = (const float*)d_in[20];
    const float* p2w = (const float*)d_in[21];
    const float* p2b = (const float*)d_in[22];
    const float* w3  = (const float*)d_in[23];
    const float* as3 = (const float*)d_in[24];
    const float* ad3 = (const float*)d_in[25];
    const float* b3  = (const float*)d_in[26];
    const float* g3  = (const float*)d_in[27];
    const float* be3 = (const float*)d_in[28];
    const float* m3  = (const float*)d_in[29];
    const float* v3  = (const float*)d_in[30];
    const float* p3w = (const float*)d_in[31];
    const float* p3b = (const float*)d_in[32];
    const float* fw  = (const float*)d_in[33];
    const float* fb  = (const float*)d_in[34];
    const float* g4  = (const float*)d_in[35];
    const float* be4 = (const float*)d_in[36];
    const float* m4  = (const float*)d_in[37];
    const float* v4  = (const float*)d_in[38];
    const float* l1w = (const float*)d_in[39];
    const float* l1b = (const float*)d_in[40];
    const float* l2w = (const float*)d_in[41];
    const float* l2b = (const float*)d_in[42];

    char* ws = (char*)d_ws;
    size_t off = 0;
    auto alloc = [&](size_t bytes) -> char* {
        char* p = ws + off;
        off += (bytes + 255) & ~(size_t)255;
        return p;
    };
    int*    bucket_cnt  = (int*)alloc((NBK) * sizeof(int));
    int*    bucket_base = (int*)alloc((NBK + 1) * sizeof(int));
    int*    gcursor     = (int*)alloc((NBK) * sizeof(int));
    int*    part        = (int*)alloc((size_t)ETOT * sizeof(int));
    int*    row2_start  = (int*)alloc(NN * sizeof(int));
    int*    row2_deg    = (int*)alloc(NN * sizeof(int));
    int*    csr2_src    = (int*)alloc((size_t)PADTOT * sizeof(int));
    unsigned char*  h8  = (unsigned char*)alloc((size_t)(NN + 1) * 128);
    unsigned short* hb1 = (unsigned short*)alloc((size_t)NN * 64 * sizeof(short));
    unsigned short* hb2 = (unsigned short*)alloc((size_t)NN * 128 * sizeof(short));
    unsigned short* hb3 = (unsigned short*)alloc((size_t)NN * 128 * sizeof(short));
    float*  esrc        = (float*)alloc((size_t)(NN + 1) * 2 * sizeof(float));
    float*  edst        = (float*)alloc((size_t)NN * 2 * sizeof(float));
    float*  ppart       = (float*)alloc((size_t)GG * PSPLIT * 128 * sizeof(float));
    short*  wfrag2      = (short*)alloc((size_t)16 * 2 * 2 * 64 * 8 * sizeof(short));
    short*  wfrag3      = (short*)alloc((size_t)16 * 4 * 2 * 64 * 8 * sizeof(short));

    // ---- weight fragment prep (independent of everything else) ----
    prep_w_kernel<64><<<16, 256, 0, stream>>>(w2, p2w, wfrag2);
    prep_w_kernel<128><<<32, 256, 0, stream>>>(w3, p3w, wfrag3);

    // ---- CSR build (bucketed partition, padded layout, NN sentinel pads) ----
    hipMemsetAsync(bucket_cnt, 0, NBK * sizeof(int), stream);
    bucket_count_kernel<<<(ETOT + 8191) / 8192, 256, 0, stream>>>(ei, bucket_cnt);
    bucket_scan_kernel<<<1, 512, 0, stream>>>(bucket_cnt, bucket_base, gcursor, esrc);
    partition_kernel<<<(ETOT + 4095) / 4096, 256, 0, stream>>>(ei, gcursor, part);
    csr_build_kernel<<<NBK, 256, 0, stream>>>(part, bucket_base, row2_start, row2_deg, csr2_src);

    // ---- layer 1: x[N,5] -> hb1[N,64] (bf16) ----
    feat1_kernel<<<(NN + 3) / 4, 256, 0, stream>>>(
        x, w1, p1w, p1b, as1, ad1, h8, esrc, edst, hb1, NN);
    aggregate64_kernel<<<(NN + 3) / 4, 256, 0, stream>>>(
        h8, row2_start, row2_deg, csr2_src, (const float2*)esrc, (const float2*)edst,
        b1, g1, be1, m1, v1, hb1, NN);

    // ---- layer 2: hb1 -> hb2[N,128] (bf16) ----
    mfma_feat_kernel<64><<<(NN + 127) / 128, 256, 0, stream>>>(
        hb1, wfrag2, p2b, as2, ad2, h8, esrc, edst, hb2);
    aggregate128_kernel<<<(NN + 3) / 4, 256, 0, stream>>>(
        (const unsigned short*)h8, row2_start, row2_deg, csr2_src,
        (const float2*)esrc, (const float2*)edst,
        b2, g2, be2, m2, v2, hb2, NN);

    // ---- layer 3: hb2 -> hb3[N,128] (bf16) ----
    mfma_feat_kernel<128><<<(NN + 127) / 128, 256, 0, stream>>>(
        hb2, wfrag3, p3b, as3, ad3, h8, esrc, edst, hb3);
    aggregate128_kernel<<<(NN + 3) / 4, 256, 0, stream>>>(
        (const unsigned short*)h8, row2_start, row2_deg, csr2_src,
        (const float2*)esrc, (const float2*)edst,
        b3, g3, be3, m3, v3, hb3, NN);

    // ---- pool (two-phase) + head ----
    pool_partial_kernel<<<GG * PSPLIT, 128, 0, stream>>>(hb3, batch, ppart);
    head_kernel<<<GG, 128, 0, stream>>>(ppart, batch, fw, fb, g4, be4, m4, v4,
                                        l1w, l1b, l2w, l2b, (float*)d_out);
}

// Round 14
// 618.250 us; speedup vs baseline: 1.1573x; 1.0885x over previous
//
#include <hip/hip_runtime.h>
#include <hip/hip_bf16.h>
#include <hip/hip_fp16.h>

#define NN   100000
#define EE   1600000
#define ETOT (EE + NN)
#define GG   256
#define BNEPS 1e-5f
#define NBK  391          // buckets of 256 nodes: (NN+255)/256
#define PADTOT (ETOT + NBK * 2048 + 64)
#define PSPLIT 16

typedef float floatx2 __attribute__((ext_vector_type(2)));
typedef short s16x8 __attribute__((ext_vector_type(8)));
typedef float f32x4v __attribute__((ext_vector_type(4)));

__device__ __forceinline__ unsigned short f2bf(float f) {
    unsigned u = __float_as_uint(f);
    unsigned r = u + 0x7FFF + ((u >> 16) & 1);
    return (unsigned short)(r >> 16);
}
__device__ __forceinline__ float bf2f(unsigned short b) {
    return __uint_as_float(((unsigned)b) << 16);
}

// ---------------- CSR build: bucketed partition (single-writer cache lines) --

__global__ __launch_bounds__(256) void bucket_count_kernel(
    const int* __restrict__ ei, int* __restrict__ bucket_cnt)
{
    __shared__ int cnt[NBK];
    for (int i = threadIdx.x; i < NBK; i += 256) cnt[i] = 0;
    __syncthreads();
    int base = blockIdx.x * 8192;
    for (int k = threadIdx.x; k < 8192; k += 256) {
        int e = base + k;
        if (e < ETOT) {
            int dst = (e < EE) ? ei[EE + e] : (e - EE);
            atomicAdd(&cnt[dst >> 8], 1);
        }
    }
    __syncthreads();
    for (int i = threadIdx.x; i < NBK; i += 256)
        if (cnt[i]) atomicAdd(&bucket_cnt[i], cnt[i]);
}

// also plants the -inf esrc sentinel used by pad edges (src = NN)
__global__ __launch_bounds__(512) void bucket_scan_kernel(
    const int* __restrict__ bucket_cnt, int* __restrict__ bucket_base,
    int* __restrict__ gcursor, float* __restrict__ esrcs)
{
    __shared__ int s[512];
    int t = threadIdx.x;
    int v = (t < NBK) ? bucket_cnt[t] : 0;
    s[t] = v;
    __syncthreads();
    int x = v;
    for (int o = 1; o < 512; o <<= 1) {
        int y = (t >= o) ? s[t - o] : 0;
        __syncthreads();
        x += y;
        s[t] = x;
        __syncthreads();
    }
    if (t < NBK) { bucket_base[t] = x - v; gcursor[t] = x - v; }
    if (t == 0) {
        bucket_base[NBK] = ETOT;
        esrcs[2 * NN]     = __int_as_float(0xFF800000);  // -inf
        esrcs[2 * NN + 1] = __int_as_float(0xFF800000);
    }
}

__global__ __launch_bounds__(256) void partition_kernel(
    const int* __restrict__ ei, int* __restrict__ gcursor, int* __restrict__ part)
{
    __shared__ int cnt[NBK];
    __shared__ int basel[NBK];
    for (int i = threadIdx.x; i < NBK; i += 256) cnt[i] = 0;
    __syncthreads();
    int base = blockIdx.x * 4096;
    for (int k = threadIdx.x; k < 4096; k += 256) {
        int e = base + k;
        if (e < ETOT) {
            int dst = (e < EE) ? ei[EE + e] : (e - EE);
            atomicAdd(&cnt[dst >> 8], 1);
        }
    }
    __syncthreads();
    for (int i = threadIdx.x; i < NBK; i += 256) {
        int c = cnt[i];
        basel[i] = c ? atomicAdd(&gcursor[i], c) : 0;
        cnt[i] = 0;   // reuse as intra-block cursor
    }
    __syncthreads();
    for (int k = threadIdx.x; k < 4096; k += 256) {
        int e = base + k;
        if (e < ETOT) {
            int src, dst;
            if (e < EE) { src = ei[e]; dst = ei[EE + e]; }
            else        { src = e - EE; dst = e - EE; }
            int b = dst >> 8;
            int slot = atomicAdd(&cnt[b], 1);
            part[basel[b] + slot] = src | ((dst & 255) << 17);
        }
    }
}

// Padded CSR: per-node segments rounded up to 8 entries, pad src = NN
// (sentinel: esrc[NN] = -inf → exp weight 0, so no masking anywhere).
__global__ __launch_bounds__(256) void csr_build_kernel(
    const int* __restrict__ part, const int* __restrict__ bucket_base,
    int* __restrict__ row2_start, int* __restrict__ row2_deg,
    int* __restrict__ csr2_src)
{
    __shared__ int degs[256];
    __shared__ int sc[256];
    __shared__ int cur[256];
    int b = blockIdx.x;
    int t = threadIdx.x;
    int beg = bucket_base[b], end = bucket_base[b + 1];
    int pbase = ((beg + 7) & ~7) + 2048 * b;
    degs[t] = 0;
    __syncthreads();
    for (int j = beg + t; j < end; j += 256)
        atomicAdd(&degs[(part[j] >> 17) & 255], 1);
    __syncthreads();
    int dg = degs[t];
    int pdeg = (dg + 7) & ~7;
    sc[t] = pdeg;
    __syncthreads();
    int x = pdeg;
    for (int o = 1; o < 256; o <<= 1) {
        int y = (t >= o) ? sc[t - o] : 0;
        __syncthreads();
        x += y;
        sc[t] = x;
        __syncthreads();
    }
    int start2 = pbase + (x - pdeg);
    int node = b * 256 + t;
    if (node < NN) { row2_start[node] = start2; row2_deg[node] = dg; }
    cur[t] = start2;
    __syncthreads();
    for (int j = beg + t; j < end; j += 256) {
        int pv = part[j];
        int pos = atomicAdd(&cur[(pv >> 17) & 255], 1);
        csr2_src[pos] = pv & 0x1FFFF;
    }
    for (int k = dg; k < pdeg; ++k) csr2_src[start2 + k] = NN;
}

// ---------------- per-layer edge softmax weights (packed 2×bf16) -------------
// Unmasked: pad slots read src=NN → esrc=-inf → exp=0 → packed 0.

__global__ __launch_bounds__(256) void edgew_kernel(
    const int* __restrict__ csr2_src, const int* __restrict__ row2_start,
    const int* __restrict__ row2_deg,
    const float2* __restrict__ esrc, const float2* __restrict__ edst,
    unsigned* __restrict__ csr_w, int nN)
{
    int n = blockIdx.x * 4 + (threadIdx.x >> 6);
    int lane = threadIdx.x & 63;
    if (n >= nN) return;
    float2 ed = edst[n];
    int s2 = row2_start[n];
    int dg = row2_deg[n];
    int pc = (dg + 7) & ~7;
    for (int j = lane; j < pc; j += 64) {
        int i = csr2_src[s2 + j];
        float2 es = esrc[i];
        float a0 = es.x + ed.x; a0 = (a0 > 0.f) ? a0 : 0.2f * a0;
        float a1 = es.y + ed.y; a1 = (a1 > 0.f) ? a1 : 0.2f * a1;
        unsigned w = (unsigned)f2bf(__expf(a0)) | ((unsigned)f2bf(__expf(a1)) << 16);
        csr_w[s2 + j] = w;
    }
}

// ---------------- layer-1 feature transform (K=5); h fp8, rout bf16 ----------

__global__ __launch_bounds__(256) void feat1_kernel(
    const float* __restrict__ xin, const float* __restrict__ W,
    const float* __restrict__ pw, const float* __restrict__ pb,
    const float* __restrict__ a_src, const float* __restrict__ a_dst,
    unsigned char* __restrict__ h8, float* __restrict__ esrc, float* __restrict__ edst,
    unsigned short* __restrict__ rout16, int nN)
{
    constexpr int F_IN = 5, F_OUT = 64;
    int t = threadIdx.x;
    int n = blockIdx.x * 4 + t / F_OUT;
    int f = t % F_OUT;
    if (n >= nN) return;
    float acc = 0.f, racc = 0.f;
#pragma unroll
    for (int k = 0; k < F_IN; ++k) {
        float xv = xin[n * F_IN + k];
        acc  += xv * W[k * F_OUT + f];
        racc += xv * pw[k * F_OUT + f];
    }
    float other = __shfl_xor(acc, 1, 64);
    if ((f & 1) == 0) {
        int p = __builtin_amdgcn_cvt_pk_fp8_f32(acc, other, 0, false);
        *(unsigned short*)(h8 + (size_t)n * F_OUT + f) = (unsigned short)(p & 0xFFFF);
    }
    rout16[(size_t)n * F_OUT + f] = f2bf(racc + pb[f]);
    float es = acc * a_src[f];
    float ed = acc * a_dst[f];
#pragma unroll
    for (int off = 16; off > 0; off >>= 1) {
        es += __shfl_xor(es, off, 32);
        ed += __shfl_xor(ed, off, 32);
    }
    if ((t & 31) == 0) {
        int head = (f >> 5) & 1;
        esrc[n * 2 + head] = es;
        edst[n * 2 + head] = ed;
    }
}

// ---------------- weight fragment prep (bf16 hi/lo split, MFMA B layout) -----

template<int K>
__global__ __launch_bounds__(256) void prep_w_kernel(
    const float* __restrict__ W, const float* __restrict__ pw,
    short* __restrict__ wfrag)
{
    constexpr int KS = K / 32;
    int unit = blockIdx.x * 256 + threadIdx.x;
    int total = 16 * KS * 2 * 64;
    if (unit >= total) return;
    int lane = unit & 63;
    int rest = unit >> 6;
    int hilo = rest & 1;
    int fk = rest >> 1;
    int ks = fk % KS;
    int nt = fk / KS;
    int n = nt * 16 + (lane & 15);
    int k0 = ks * 32 + (lane >> 4) * 8;
    const float* src = (n < 128) ? (W + n) : (pw + (n - 128));
    s16x8 out;
#pragma unroll
    for (int j = 0; j < 8; ++j) {
        float wv = src[(size_t)(k0 + j) * 128];
        unsigned short hi = f2bf(wv);
        if (hilo == 0) {
            out[j] = (short)hi;
        } else {
            float fhi = __uint_as_float(((unsigned)hi) << 16);
            out[j] = (short)f2bf(wv - fhi);
        }
    }
    *(s16x8*)(wfrag + (size_t)unit * 8) = out;
}

// ---------------- MFMA feature transform (layers 2,3; N=256 = W‖pw) ----------

template<int K>
__global__ __launch_bounds__(256) void mfma_feat_kernel(
    const unsigned short* __restrict__ xin16, const short* __restrict__ wfrag,
    const float* __restrict__ pb,
    const float* __restrict__ a_src, const float* __restrict__ a_dst,
    unsigned char* __restrict__ h8, float* __restrict__ esrc, float* __restrict__ edst,
    unsigned short* __restrict__ rout16)
{
    constexpr int KS = K / 32;    // MFMA k-steps
    constexpr int CH = K / 8;     // 8-feature (16 B) chunks per node row
    __shared__ s16x8 xs[8 * CH * 16];   // 8 tiles of 16 nodes

    const int tid = threadIdx.x;
    const int base = blockIdx.x * 128;

    for (int idx = tid; idx < 128 * CH; idx += 256) {
        int node = idx / CH;
        int ch = idx % CH;
        int gn = base + node; if (gn > NN - 1) gn = NN - 1;
        s16x8 v = *(const s16x8*)(xin16 + (size_t)gn * K + ch * 8);
        int tt = node >> 4, mm = node & 15;
        xs[(tt * CH + ch) * 16 + mm] = v;
    }
    __syncthreads();

    const int w = tid >> 6;
    const int lane = tid & 63;
    const int quad = lane >> 4;
    const int m = lane & 15;
    const int node0 = base + w * 32 + quad * 4;   // tile0 rows +r
    const int node1 = node0 + 16;                 // tile1 rows +r

    s16x8 a0[KS], a1[KS];
#pragma unroll
    for (int ks = 0; ks < KS; ++ks) {
        a0[ks] = xs[((w * 2 + 0) * CH + (ks * 4 + quad)) * 16 + m];
        a1[ks] = xs[((w * 2 + 1) * CH + (ks * 4 + quad)) * 16 + m];
    }

    float es0h0[4] = {0.f,0.f,0.f,0.f}, es0h1[4] = {0.f,0.f,0.f,0.f};
    float ed0h0[4] = {0.f,0.f,0.f,0.f}, ed0h1[4] = {0.f,0.f,0.f,0.f};
    float es1h0[4] = {0.f,0.f,0.f,0.f}, es1h1[4] = {0.f,0.f,0.f,0.f};
    float ed1h0[4] = {0.f,0.f,0.f,0.f}, ed1h1[4] = {0.f,0.f,0.f,0.f};

#pragma unroll
    for (int nt = 0; nt < 16; ++nt) {
        s16x8 b[2 * KS];
#pragma unroll
        for (int i = 0; i < 2 * KS; ++i)
            b[i] = *(const s16x8*)(wfrag + (size_t)((nt * KS * 2 + i) * 64 + lane) * 8);
        f32x4v c0 = {0.f, 0.f, 0.f, 0.f};
        f32x4v c1 = {0.f, 0.f, 0.f, 0.f};
#pragma unroll
        for (int ks = 0; ks < KS; ++ks) {
            c0 = __builtin_amdgcn_mfma_f32_16x16x32_bf16(a0[ks], b[2 * ks + 0], c0, 0, 0, 0);
            c1 = __builtin_amdgcn_mfma_f32_16x16x32_bf16(a1[ks], b[2 * ks + 0], c1, 0, 0, 0);
            c0 = __builtin_amdgcn_mfma_f32_16x16x32_bf16(a0[ks], b[2 * ks + 1], c0, 0, 0, 0);
            c1 = __builtin_amdgcn_mfma_f32_16x16x32_bf16(a1[ks], b[2 * ks + 1], c1, 0, 0, 0);
        }
        if (nt < 8) {
            int col = nt * 16 + m;
            float av = a_src[col], dv = a_dst[col];
#pragma unroll
            for (int r = 0; r < 4; ++r) {
                float v0 = c0[r], v1 = c1[r];
                if (nt < 4) {
                    es0h0[r] = fmaf(v0, av, es0h0[r]); ed0h0[r] = fmaf(v0, dv, ed0h0[r]);
                    es1h0[r] = fmaf(v1, av, es1h0[r]); ed1h0[r] = fmaf(v1, dv, ed1h0[r]);
                } else {
                    es0h1[r] = fmaf(v0, av, es0h1[r]); ed0h1[r] = fmaf(v0, dv, ed0h1[r]);
                    es1h1[r] = fmaf(v1, av, es1h1[r]); ed1h1[r] = fmaf(v1, dv, ed1h1[r]);
                }
                float p0 = __shfl_xor(v0, 1, 16);
                float p1 = __shfl_xor(v1, 1, 16);
                if ((m & 1) == 0) {
                    if (node0 + r < NN) {
                        int p = __builtin_amdgcn_cvt_pk_fp8_f32(v0, p0, 0, false);
                        *(unsigned short*)(h8 + (size_t)(node0 + r) * 128 + col) = (unsigned short)(p & 0xFFFF);
                    }
                    if (node1 + r < NN) {
                        int p = __builtin_amdgcn_cvt_pk_fp8_f32(v1, p1, 0, false);
                        *(unsigned short*)(h8 + (size_t)(node1 + r) * 128 + col) = (unsigned short)(p & 0xFFFF);
                    }
                }
            }
        } else {
            int col = (nt - 8) * 16 + m;
            float bv = pb[col];
#pragma unroll
            for (int r = 0; r < 4; ++r) {
                if (node0 + r < NN) rout16[(size_t)(node0 + r) * 128 + col] = f2bf(c0[r] + bv);
                if (node1 + r < NN) rout16[(size_t)(node1 + r) * 128 + col] = f2bf(c1[r] + bv);
            }
        }
    }

#pragma unroll
    for (int r = 0; r < 4; ++r) {
#pragma unroll
        for (int off = 8; off > 0; off >>= 1) {
            es0h0[r] += __shfl_xor(es0h0[r], off, 16);
            es0h1[r] += __shfl_xor(es0h1[r], off, 16);
            ed0h0[r] += __shfl_xor(ed0h0[r], off, 16);
            ed0h1[r] += __shfl_xor(ed0h1[r], off, 16);
            es1h0[r] += __shfl_xor(es1h0[r], off, 16);
            es1h1[r] += __shfl_xor(es1h1[r], off, 16);
            ed1h0[r] += __shfl_xor(ed1h0[r], off, 16);
            ed1h1[r] += __shfl_xor(ed1h1[r], off, 16);
        }
    }
    if (m == 0) {
#pragma unroll
        for (int r = 0; r < 4; ++r) {
            if (node0 + r < NN) {
                ((float2*)esrc)[node0 + r] = make_float2(es0h0[r], es0h1[r]);
                ((float2*)edst)[node0 + r] = make_float2(ed0h0[r], ed0h1[r]);
            }
            if (node1 + r < NN) {
                ((float2*)esrc)[node1 + r] = make_float2(es1h0[r], es1h1[r]);
                ((float2*)edst)[node1 + r] = make_float2(ed1h0[r], ed1h1[r]);
            }
        }
    }
}

// ---------------- fused aggregate, F=128 (fp8 h, packed bf16 weights) --------
// Weight extraction: g = uint_as_float(hi ? (w & 0xFFFF0000) : (w << 16)).
// Named scalars only (R8 lesson).

__global__ __launch_bounds__(256) void aggregate128_kernel(
    const unsigned short* __restrict__ h8s,
    const int* __restrict__ row2_start, const int* __restrict__ row2_deg,
    const int* __restrict__ csr2_src, const unsigned* __restrict__ csr_w,
    const float* __restrict__ bias, const float* __restrict__ bng,
    const float* __restrict__ bnb, const float* __restrict__ bnm,
    const float* __restrict__ bnv, unsigned short* __restrict__ io16, int nN)
{
    int w = threadIdx.x >> 6;
    int lane = threadIdx.x & 63;
    int n = blockIdx.x * 4 + w;
    if (n >= nN) return;
    bool hi = lane >= 32;
    int s2 = row2_start[n];
    int dg = row2_deg[n];
    int pc = (dg + 7) & ~7;
    const int4* sp = (const int4*)(csr2_src + s2);
    const uint4* wp = (const uint4*)(csr_w + s2);
    float s = 0.f, ax = 0.f, ay = 0.f;
    for (int j = 0; j < pc; j += 8) {
        int4 ia = sp[(j >> 2) + 0];
        int4 ib = sp[(j >> 2) + 1];
        uint4 wa = wp[(j >> 2) + 0];
        uint4 wb = wp[(j >> 2) + 1];
        unsigned short v0 = h8s[(size_t)ia.x * 64 + lane];
        unsigned short v1 = h8s[(size_t)ia.y * 64 + lane];
        unsigned short v2 = h8s[(size_t)ia.z * 64 + lane];
        unsigned short v3 = h8s[(size_t)ia.w * 64 + lane];
        unsigned short v4 = h8s[(size_t)ib.x * 64 + lane];
        unsigned short v5 = h8s[(size_t)ib.y * 64 + lane];
        unsigned short v6 = h8s[(size_t)ib.z * 64 + lane];
        unsigned short v7 = h8s[(size_t)ib.w * 64 + lane];
        float g0 = __uint_as_float(hi ? (wa.x & 0xFFFF0000u) : (wa.x << 16));
        float g1 = __uint_as_float(hi ? (wa.y & 0xFFFF0000u) : (wa.y << 16));
        float g2 = __uint_as_float(hi ? (wa.z & 0xFFFF0000u) : (wa.z << 16));
        float g3 = __uint_as_float(hi ? (wa.w & 0xFFFF0000u) : (wa.w << 16));
        float g4 = __uint_as_float(hi ? (wb.x & 0xFFFF0000u) : (wb.x << 16));
        float g5 = __uint_as_float(hi ? (wb.y & 0xFFFF0000u) : (wb.y << 16));
        float g6 = __uint_as_float(hi ? (wb.z & 0xFFFF0000u) : (wb.z << 16));
        float g7 = __uint_as_float(hi ? (wb.w & 0xFFFF0000u) : (wb.w << 16));
        floatx2 f0 = __builtin_amdgcn_cvt_pk_f32_fp8((int)v0, false);
        floatx2 f1 = __builtin_amdgcn_cvt_pk_f32_fp8((int)v1, false);
        floatx2 f2 = __builtin_amdgcn_cvt_pk_f32_fp8((int)v2, false);
        floatx2 f3 = __builtin_amdgcn_cvt_pk_f32_fp8((int)v3, false);
        floatx2 f4 = __builtin_amdgcn_cvt_pk_f32_fp8((int)v4, false);
        floatx2 f5 = __builtin_amdgcn_cvt_pk_f32_fp8((int)v5, false);
        floatx2 f6 = __builtin_amdgcn_cvt_pk_f32_fp8((int)v6, false);
        floatx2 f7 = __builtin_amdgcn_cvt_pk_f32_fp8((int)v7, false);
        ax = fmaf(g0, f0.x, ax); ay = fmaf(g0, f0.y, ay);
        ax = fmaf(g1, f1.x, ax); ay = fmaf(g1, f1.y, ay);
        ax = fmaf(g2, f2.x, ax); ay = fmaf(g2, f2.y, ay);
        ax = fmaf(g3, f3.x, ax); ay = fmaf(g3, f3.y, ay);
        ax = fmaf(g4, f4.x, ax); ay = fmaf(g4, f4.y, ay);
        ax = fmaf(g5, f5.x, ax); ay = fmaf(g5, f5.y, ay);
        ax = fmaf(g6, f6.x, ax); ay = fmaf(g6, f6.y, ay);
        ax = fmaf(g7, f7.x, ax); ay = fmaf(g7, f7.y, ay);
        s += ((g0 + g1) + (g2 + g3)) + ((g4 + g5) + (g6 + g7));
    }
    float inv = 1.f / (s + 1e-16f);
    int f0i = 2 * lane, f1i = 2 * lane + 1;
    float o0 = bng[f0i] * (ax * inv + bias[f0i] - bnm[f0i]) * rsqrtf(bnv[f0i] + BNEPS) + bnb[f0i];
    float o1 = bng[f1i] * (ay * inv + bias[f1i] - bnm[f1i]) * rsqrtf(bnv[f1i] + BNEPS) + bnb[f1i];
    unsigned* iop = (unsigned*)(io16 + (size_t)n * 128) + lane;
    unsigned pu = *iop;
    float r0 = fmaxf(o0, 0.f) + __uint_as_float((pu & 0xFFFFu) << 16);
    float r1 = fmaxf(o1, 0.f) + __uint_as_float(pu & 0xFFFF0000u);
    *iop = (unsigned)f2bf(r0) | ((unsigned)f2bf(r1) << 16);
}

// ---------------- fused aggregate, F=64 ---------------------------------------

__global__ __launch_bounds__(256) void aggregate64_kernel(
    const unsigned char* __restrict__ h8,
    const int* __restrict__ row2_start, const int* __restrict__ row2_deg,
    const int* __restrict__ csr2_src, const unsigned* __restrict__ csr_w,
    const float* __restrict__ bias, const float* __restrict__ bng,
    const float* __restrict__ bnb, const float* __restrict__ bnm,
    const float* __restrict__ bnv, unsigned short* __restrict__ io16, int nN)
{
    int w = threadIdx.x >> 6;
    int lane = threadIdx.x & 63;
    int n = blockIdx.x * 4 + w;
    if (n >= nN) return;
    bool hi = lane >= 32;
    int s2 = row2_start[n];
    int dg = row2_deg[n];
    int pc = (dg + 7) & ~7;
    const int4* sp = (const int4*)(csr2_src + s2);
    const uint4* wp = (const uint4*)(csr_w + s2);
    float s = 0.f, acc = 0.f;
    for (int j = 0; j < pc; j += 8) {
        int4 ia = sp[(j >> 2) + 0];
        int4 ib = sp[(j >> 2) + 1];
        uint4 wa = wp[(j >> 2) + 0];
        uint4 wb = wp[(j >> 2) + 1];
        unsigned char v0 = h8[(size_t)ia.x * 64 + lane];
        unsigned char v1 = h8[(size_t)ia.y * 64 + lane];
        unsigned char v2 = h8[(size_t)ia.z * 64 + lane];
        unsigned char v3 = h8[(size_t)ia.w * 64 + lane];
        unsigned char v4 = h8[(size_t)ib.x * 64 + lane];
        unsigned char v5 = h8[(size_t)ib.y * 64 + lane];
        unsigned char v6 = h8[(size_t)ib.z * 64 + lane];
        unsigned char v7 = h8[(size_t)ib.w * 64 + lane];
        float g0 = __uint_as_float(hi ? (wa.x & 0xFFFF0000u) : (wa.x << 16));
        float g1 = __uint_as_float(hi ? (wa.y & 0xFFFF0000u) : (wa.y << 16));
        float g2 = __uint_as_float(hi ? (wa.z & 0xFFFF0000u) : (wa.z << 16));
        float g3 = __uint_as_float(hi ? (wa.w & 0xFFFF0000u) : (wa.w << 16));
        float g4 = __uint_as_float(hi ? (wb.x & 0xFFFF0000u) : (wb.x << 16));
        float g5 = __uint_as_float(hi ? (wb.y & 0xFFFF0000u) : (wb.y << 16));
        float g6 = __uint_as_float(hi ? (wb.z & 0xFFFF0000u) : (wb.z << 16));
        float g7 = __uint_as_float(hi ? (wb.w & 0xFFFF0000u) : (wb.w << 16));
        acc = fmaf(g0, __builtin_amdgcn_cvt_f32_fp8((int)v0, 0), acc);
        acc = fmaf(g1, __builtin_amdgcn_cvt_f32_fp8((int)v1, 0), acc);
        acc = fmaf(g2, __builtin_amdgcn_cvt_f32_fp8((int)v2, 0), acc);
        acc = fmaf(g3, __builtin_amdgcn_cvt_f32_fp8((int)v3, 0), acc);
        acc = fmaf(g4, __builtin_amdgcn_cvt_f32_fp8((int)v4, 0), acc);
        acc = fmaf(g5, __builtin_amdgcn_cvt_f32_fp8((int)v5, 0), acc);
        acc = fmaf(g6, __builtin_amdgcn_cvt_f32_fp8((int)v6, 0), acc);
        acc = fmaf(g7, __builtin_amdgcn_cvt_f32_fp8((int)v7, 0), acc);
        s += ((g0 + g1) + (g2 + g3)) + ((g4 + g5) + (g6 + g7));
    }
    int f = lane;
    float g = acc / (s + 1e-16f);
    float vv = bng[f] * (g + bias[f] - bnm[f]) * rsqrtf(bnv[f] + BNEPS) + bnb[f];
    float prev = bf2f(io16[(size_t)n * 64 + f]);
    io16[(size_t)n * 64 + f] = f2bf(fmaxf(vv, 0.f) + prev);
}

// ---------------- pooling, two-phase (bf16 input) ----------------

__global__ __launch_bounds__(128) void pool_partial_kernel(
    const unsigned short* __restrict__ hf16, const int* __restrict__ batch,
    float* __restrict__ ppart)
{
    int g = blockIdx.x / PSPLIT;
    int p = blockIdx.x % PSPLIT;
    int f = threadIdx.x;
    int lo = 0, hi = NN;
    while (lo < hi) { int mid = (lo + hi) >> 1; if (batch[mid] < g) lo = mid + 1; else hi = mid; }
    int start = lo;
    hi = NN;
    while (lo < hi) { int mid = (lo + hi) >> 1; if (batch[mid] < g + 1) lo = mid + 1; else hi = mid; }
    int end = lo;
    int len = end - start;
    int chunk = (len + PSPLIT - 1) / PSPLIT;
    int i0 = start + p * chunk;
    int i1 = i0 + chunk; if (i1 > end) i1 = end;
    float acc = 0.f;
    for (int i = i0; i < i1; ++i) acc += bf2f(hf16[(size_t)i * 128 + f]);
    ppart[((size_t)g * PSPLIT + p) * 128 + f] = acc;
}

// ---------------- MLP head (folds partial-sum reduce + mean) -----------------

__global__ __launch_bounds__(128) void head_kernel(
    const float* __restrict__ ppart, const int* __restrict__ batch,
    const float* __restrict__ fw, const float* __restrict__ fb,
    const float* __restrict__ g4, const float* __restrict__ be4,
    const float* __restrict__ m4, const float* __restrict__ v4,
    const float* __restrict__ l1w, const float* __restrict__ l1b,
    const float* __restrict__ l2w, const float* __restrict__ l2b,
    float* __restrict__ out)
{
    __shared__ float p[128];
    __shared__ float z1[32];
    __shared__ float z2[32];
    int g = blockIdx.x, t = threadIdx.x;
    int lo = 0, hi = NN;
    while (lo < hi) { int mid = (lo + hi) >> 1; if (batch[mid] < g) lo = mid + 1; else hi = mid; }
    int start = lo;
    hi = NN;
    while (lo < hi) { int mid = (lo + hi) >> 1; if (batch[mid] < g + 1) lo = mid + 1; else hi = mid; }
    float cnt = (float)(lo - start);
    float acc = 0.f;
#pragma unroll
    for (int q = 0; q < PSPLIT; ++q)
        acc += ppart[((size_t)g * PSPLIT + q) * 128 + t];
    p[t] = acc / fmaxf(cnt, 1.0f);
    __syncthreads();
    if (t < 32) {
        float a = fb[t];
        for (int k = 0; k < 128; ++k) a += p[k] * fw[k * 32 + t];
        float val = g4[t] * (a - m4[t]) * rsqrtf(v4[t] + BNEPS) + be4[t];
        z1[t] = fmaxf(val, 0.f);
    }
    __syncthreads();
    if (t < 32) {
        float a = l1b[t];
        for (int k = 0; k < 32; ++k) a += z1[k] * l1w[k * 32 + t];
        z2[t] = fmaxf(a, 0.f);
    }
    __syncthreads();
    if (t < 10) {
        float a = l2b[t];
        for (int k = 0; k < 32; ++k) a += z2[k] * l2w[k * 10 + t];
        out[g * 10 + t] = a;
    }
}

// ---------------- launch ----------------

extern "C" void kernel_launch(void* const* d_in, const int* in_sizes, int n_in,
                              void* d_out, int out_size, void* d_ws, size_t ws_size,
                              hipStream_t stream) {
    const float* x     = (const float*)d_in[0];
    const int*   ei    = (const int*)d_in[1];
    const int*   batch = (const int*)d_in[2];
    const float* w1  = (const float*)d_in[3];
    const float* as1 = (const float*)d_in[4];
    const float* ad1 = (const float*)d_in[5];
    const float* b1  = (const float*)d_in[6];
    const float* g1  = (const float*)d_in[7];
    const float* be1 = (const float*)d_in[8];
    const float* m1  = (const float*)d_in[9];
    const float* v1  = (const float*)d_in[10];
    const float* p1w = (const float*)d_in[11];
    const float* p1b = (const float*)d_in[12];
    const float* w2  = (const float*)d_in[13];
    const float* as2 = (const float*)d_in[14];
    const float* ad2 = (const float*)d_in[15];
    const float* b2  = (const float*)d_in[16];
    const float* g2  = (const float*)d_in[17];
    const float* be2 = (const float*)d_in[18];
    const float* m2  = (const float*)d_in[19];
    const float* v2  = (const float*)d_in[20];
    const float* p2w = (const float*)d_in[21];
    const float* p2b = (const float*)d_in[22];
    const float* w3  = (const float*)d_in[23];
    const float* as3 = (const float*)d_in[24];
    const float* ad3 = (const float*)d_in[25];
    const float* b3  = (const float*)d_in[26];
    const float* g3  = (const float*)d_in[27];
    const float* be3 = (const float*)d_in[28];
    const float* m3  = (const float*)d_in[29];
    const float* v3  = (const float*)d_in[30];
    const float* p3w = (const float*)d_in[31];
    const float* p3b = (const float*)d_in[32];
    const float* fw  = (const float*)d_in[33];
    const float* fb  = (const float*)d_in[34];
    const float* g4  = (const float*)d_in[35];
    const float* be4 = (const float*)d_in[36];
    const float* m4  = (const float*)d_in[37];
    const float* v4  = (const float*)d_in[38];
    const float* l1w = (const float*)d_in[39];
    const float* l1b = (const float*)d_in[40];
    const float* l2w = (const float*)d_in[41];
    const float* l2b = (const float*)d_in[42];

    char* ws = (char*)d_ws;
    size_t off = 0;
    auto alloc = [&](size_t bytes) -> char* {
        char* p = ws + off;
        off += (bytes + 255) & ~(size_t)255;
        return p;
    };
    int*    bucket_cnt  = (int*)alloc((NBK) * sizeof(int));
    int*    bucket_base = (int*)alloc((NBK + 1) * sizeof(int));
    int*    gcursor     = (int*)alloc((NBK) * sizeof(int));
    int*    part        = (int*)alloc((size_t)ETOT * sizeof(int));
    int*    row2_start  = (int*)alloc(NN * sizeof(int));
    int*    row2_deg    = (int*)alloc(NN * sizeof(int));
    int*    csr2_src    = (int*)alloc((size_t)PADTOT * sizeof(int));
    unsigned* csr_w     = (unsigned*)alloc((size_t)PADTOT * sizeof(unsigned));
    unsigned char*  h8  = (unsigned char*)alloc((size_t)(NN + 1) * 128);
    unsigned short* hb1 = (unsigned short*)alloc((size_t)NN * 64 * sizeof(short));
    unsigned short* hb2 = (unsigned short*)alloc((size_t)NN * 128 * sizeof(short));
    unsigned short* hb3 = (unsigned short*)alloc((size_t)NN * 128 * sizeof(short));
    float*  esrc        = (float*)alloc((size_t)(NN + 1) * 2 * sizeof(float));
    float*  edst        = (float*)alloc((size_t)NN * 2 * sizeof(float));
    float*  ppart       = (float*)alloc((size_t)GG * PSPLIT * 128 * sizeof(float));
    short*  wfrag2      = (short*)alloc((size_t)16 * 2 * 2 * 64 * 8 * sizeof(short));
    short*  wfrag3      = (short*)alloc((size_t)16 * 4 * 2 * 64 * 8 * sizeof(short));

    // ---- weight fragment prep (independent of everything else) ----
    prep_w_kernel<64><<<16, 256, 0, stream>>>(w2, p2w, wfrag2);
    prep_w_kernel<128><<<32, 256, 0, stream>>>(w3, p3w, wfrag3);

    // ---- CSR build (bucketed partition, padded layout, NN sentinel pads) ----
    hipMemsetAsync(bucket_cnt, 0, NBK * sizeof(int), stream);
    bucket_count_kernel<<<(ETOT + 8191) / 8192, 256, 0, stream>>>(ei, bucket_cnt);
    bucket_scan_kernel<<<1, 512, 0, stream>>>(bucket_cnt, bucket_base, gcursor, esrc);
    partition_kernel<<<(ETOT + 4095) / 4096, 256, 0, stream>>>(ei, gcursor, part);
    csr_build_kernel<<<NBK, 256, 0, stream>>>(part, bucket_base, row2_start, row2_deg, csr2_src);

    // ---- layer 1: x[N,5] -> hb1[N,64] (bf16) ----
    feat1_kernel<<<(NN + 3) / 4, 256, 0, stream>>>(
        x, w1, p1w, p1b, as1, ad1, h8, esrc, edst, hb1, NN);
    edgew_kernel<<<(NN + 3) / 4, 256, 0, stream>>>(
        csr2_src, row2_start, row2_deg, (const float2*)esrc, (const float2*)edst, csr_w, NN);
    aggregate64_kernel<<<(NN + 3) / 4, 256, 0, stream>>>(
        h8, row2_start, row2_deg, csr2_src, csr_w,
        b1, g1, be1, m1, v1, hb1, NN);

    // ---- layer 2: hb1 -> hb2[N,128] (bf16) ----
    mfma_feat_kernel<64><<<(NN + 127) / 128, 256, 0, stream>>>(
        hb1, wfrag2, p2b, as2, ad2, h8, esrc, edst, hb2);
    edgew_kernel<<<(NN + 3) / 4, 256, 0, stream>>>(
        csr2_src, row2_start, row2_deg, (const float2*)esrc, (const float2*)edst, csr_w, NN);
    aggregate128_kernel<<<(NN + 3) / 4, 256, 0, stream>>>(
        (const unsigned short*)h8, row2_start, row2_deg, csr2_src, csr_w,
        b2, g2, be2, m2, v2, hb2, NN);

    // ---- layer 3: hb2 -> hb3[N,128] (bf16) ----
    mfma_feat_kernel<128><<<(NN + 127) / 128, 256, 0, stream>>>(
        hb2, wfrag3, p3b, as3, ad3, h8, esrc, edst, hb3);
    edgew_kernel<<<(NN + 3) / 4, 256, 0, stream>>>(
        csr2_src, row2_start, row2_deg, (const float2*)esrc, (const float2*)edst, csr_w, NN);
    aggregate128_kernel<<<(NN + 3) / 4, 256, 0, stream>>>(
        (const unsigned short*)h8, row2_start, row2_deg, csr2_src, csr_w,
        b3, g3, be3, m3, v3, hb3, NN);

    // ---- pool (two-phase) + head ----
    pool_partial_kernel<<<GG * PSPLIT, 128, 0, stream>>>(hb3, batch, ppart);
    head_kernel<<<GG, 128, 0, stream>>>(ppart, batch, fw, fb, g4, be4, m4, v4,
                                        l1w, l1b, l2w, l2b, (float*)d_out);
}

// Round 15
// 595.934 us; speedup vs baseline: 1.2006x; 1.0374x over previous
//
#include <hip/hip_runtime.h>
#include <hip/hip_bf16.h>
#include <hip/hip_fp16.h>

#define NN   100000
#define EE   1600000
#define ETOT (EE + NN)
#define GG   256
#define BNEPS 1e-5f
#define NBK  391          // buckets of 256 nodes: (NN+255)/256
#define PADTOT (ETOT + NBK * 2048 + 64)
#define PSPLIT 16

typedef float floatx2 __attribute__((ext_vector_type(2)));
typedef short s16x8 __attribute__((ext_vector_type(8)));
typedef float f32x4v __attribute__((ext_vector_type(4)));

__device__ __forceinline__ unsigned short f2bf(float f) {
    unsigned u = __float_as_uint(f);
    unsigned r = u + 0x7FFF + ((u >> 16) & 1);
    return (unsigned short)(r >> 16);
}
__device__ __forceinline__ float bf2f(unsigned short b) {
    return __uint_as_float(((unsigned)b) << 16);
}

// ---------------- CSR build: bucketed partition (single-writer cache lines) --

__global__ __launch_bounds__(256) void bucket_count_kernel(
    const int* __restrict__ ei, int* __restrict__ bucket_cnt)
{
    __shared__ int cnt[NBK];
    for (int i = threadIdx.x; i < NBK; i += 256) cnt[i] = 0;
    __syncthreads();
    int base = blockIdx.x * 8192;
    for (int k = threadIdx.x; k < 8192; k += 256) {
        int e = base + k;
        if (e < ETOT) {
            int dst = (e < EE) ? ei[EE + e] : (e - EE);
            atomicAdd(&cnt[dst >> 8], 1);
        }
    }
    __syncthreads();
    for (int i = threadIdx.x; i < NBK; i += 256)
        if (cnt[i]) atomicAdd(&bucket_cnt[i], cnt[i]);
}

// also plants the -inf esrc sentinel used by pad edges (src = NN)
__global__ __launch_bounds__(512) void bucket_scan_kernel(
    const int* __restrict__ bucket_cnt, int* __restrict__ bucket_base,
    int* __restrict__ gcursor, float* __restrict__ esrcs)
{
    __shared__ int s[512];
    int t = threadIdx.x;
    int v = (t < NBK) ? bucket_cnt[t] : 0;
    s[t] = v;
    __syncthreads();
    int x = v;
    for (int o = 1; o < 512; o <<= 1) {
        int y = (t >= o) ? s[t - o] : 0;
        __syncthreads();
        x += y;
        s[t] = x;
        __syncthreads();
    }
    if (t < NBK) { bucket_base[t] = x - v; gcursor[t] = x - v; }
    if (t == 0) {
        bucket_base[NBK] = ETOT;
        esrcs[2 * NN]     = __int_as_float(0xFF800000);  // -inf
        esrcs[2 * NN + 1] = __int_as_float(0xFF800000);
    }
}

__global__ __launch_bounds__(256) void partition_kernel(
    const int* __restrict__ ei, int* __restrict__ gcursor, int* __restrict__ part)
{
    __shared__ int cnt[NBK];
    __shared__ int basel[NBK];
    for (int i = threadIdx.x; i < NBK; i += 256) cnt[i] = 0;
    __syncthreads();
    int base = blockIdx.x * 4096;
    for (int k = threadIdx.x; k < 4096; k += 256) {
        int e = base + k;
        if (e < ETOT) {
            int dst = (e < EE) ? ei[EE + e] : (e - EE);
            atomicAdd(&cnt[dst >> 8], 1);
        }
    }
    __syncthreads();
    for (int i = threadIdx.x; i < NBK; i += 256) {
        int c = cnt[i];
        basel[i] = c ? atomicAdd(&gcursor[i], c) : 0;
        cnt[i] = 0;   // reuse as intra-block cursor
    }
    __syncthreads();
    for (int k = threadIdx.x; k < 4096; k += 256) {
        int e = base + k;
        if (e < ETOT) {
            int src, dst;
            if (e < EE) { src = ei[e]; dst = ei[EE + e]; }
            else        { src = e - EE; dst = e - EE; }
            int b = dst >> 8;
            int slot = atomicAdd(&cnt[b], 1);
            part[basel[b] + slot] = src | ((dst & 255) << 17);
        }
    }
}

// Padded CSR: per-node segments rounded up to 8 entries, pad src = NN
// (sentinel: esrc[NN] = -inf → exp weight 0, so no masking anywhere).
__global__ __launch_bounds__(256) void csr_build_kernel(
    const int* __restrict__ part, const int* __restrict__ bucket_base,
    int* __restrict__ row2_start, int* __restrict__ row2_deg,
    int* __restrict__ csr2_src)
{
    __shared__ int degs[256];
    __shared__ int sc[256];
    __shared__ int cur[256];
    int b = blockIdx.x;
    int t = threadIdx.x;
    int beg = bucket_base[b], end = bucket_base[b + 1];
    int pbase = ((beg + 7) & ~7) + 2048 * b;
    degs[t] = 0;
    __syncthreads();
    for (int j = beg + t; j < end; j += 256)
        atomicAdd(&degs[(part[j] >> 17) & 255], 1);
    __syncthreads();
    int dg = degs[t];
    int pdeg = (dg + 7) & ~7;
    sc[t] = pdeg;
    __syncthreads();
    int x = pdeg;
    for (int o = 1; o < 256; o <<= 1) {
        int y = (t >= o) ? sc[t - o] : 0;
        __syncthreads();
        x += y;
        sc[t] = x;
        __syncthreads();
    }
    int start2 = pbase + (x - pdeg);
    int node = b * 256 + t;
    if (node < NN) { row2_start[node] = start2; row2_deg[node] = dg; }
    cur[t] = start2;
    __syncthreads();
    for (int j = beg + t; j < end; j += 256) {
        int pv = part[j];
        int pos = atomicAdd(&cur[(pv >> 17) & 255], 1);
        csr2_src[pos] = pv & 0x1FFFF;
    }
    for (int k = dg; k < pdeg; ++k) csr2_src[start2 + k] = NN;
}

// ---------------- per-layer edge softmax weights (packed 2×bf16) -------------
// Unmasked: pad slots read src=NN → esrc=-inf → exp=0 → packed 0.

__global__ __launch_bounds__(256) void edgew_kernel(
    const int* __restrict__ csr2_src, const int* __restrict__ row2_start,
    const int* __restrict__ row2_deg,
    const float2* __restrict__ esrc, const float2* __restrict__ edst,
    unsigned* __restrict__ csr_w, int nN)
{
    int n = blockIdx.x * 4 + (threadIdx.x >> 6);
    int lane = threadIdx.x & 63;
    if (n >= nN) return;
    float2 ed = edst[n];
    int s2 = row2_start[n];
    int dg = row2_deg[n];
    int pc = (dg + 7) & ~7;
    for (int j = lane; j < pc; j += 64) {
        int i = csr2_src[s2 + j];
        float2 es = esrc[i];
        float a0 = es.x + ed.x; a0 = (a0 > 0.f) ? a0 : 0.2f * a0;
        float a1 = es.y + ed.y; a1 = (a1 > 0.f) ? a1 : 0.2f * a1;
        unsigned w = (unsigned)f2bf(__expf(a0)) | ((unsigned)f2bf(__expf(a1)) << 16);
        csr_w[s2 + j] = w;
    }
}

// ---------------- layer-1 feature transform (K=5); h fp8, rout bf16 ----------

__global__ __launch_bounds__(256) void feat1_kernel(
    const float* __restrict__ xin, const float* __restrict__ W,
    const float* __restrict__ pw, const float* __restrict__ pb,
    const float* __restrict__ a_src, const float* __restrict__ a_dst,
    unsigned char* __restrict__ h8, float* __restrict__ esrc, float* __restrict__ edst,
    unsigned short* __restrict__ rout16, int nN)
{
    constexpr int F_IN = 5, F_OUT = 64;
    int t = threadIdx.x;
    int n = blockIdx.x * 4 + t / F_OUT;
    int f = t % F_OUT;
    if (n >= nN) return;
    float acc = 0.f, racc = 0.f;
#pragma unroll
    for (int k = 0; k < F_IN; ++k) {
        float xv = xin[n * F_IN + k];
        acc  += xv * W[k * F_OUT + f];
        racc += xv * pw[k * F_OUT + f];
    }
    float other = __shfl_xor(acc, 1, 64);
    if ((f & 1) == 0) {
        int p = __builtin_amdgcn_cvt_pk_fp8_f32(acc, other, 0, false);
        *(unsigned short*)(h8 + (size_t)n * F_OUT + f) = (unsigned short)(p & 0xFFFF);
    }
    rout16[(size_t)n * F_OUT + f] = f2bf(racc + pb[f]);
    float es = acc * a_src[f];
    float ed = acc * a_dst[f];
#pragma unroll
    for (int off = 16; off > 0; off >>= 1) {
        es += __shfl_xor(es, off, 32);
        ed += __shfl_xor(ed, off, 32);
    }
    if ((t & 31) == 0) {
        int head = (f >> 5) & 1;
        esrc[n * 2 + head] = es;
        edst[n * 2 + head] = ed;
    }
}

// ---------------- weight fragment prep (bf16 hi/lo split, MFMA B layout) -----

template<int K>
__global__ __launch_bounds__(256) void prep_w_kernel(
    const float* __restrict__ W, const float* __restrict__ pw,
    short* __restrict__ wfrag)
{
    constexpr int KS = K / 32;
    int unit = blockIdx.x * 256 + threadIdx.x;
    int total = 16 * KS * 2 * 64;
    if (unit >= total) return;
    int lane = unit & 63;
    int rest = unit >> 6;
    int hilo = rest & 1;
    int fk = rest >> 1;
    int ks = fk % KS;
    int nt = fk / KS;
    int n = nt * 16 + (lane & 15);
    int k0 = ks * 32 + (lane >> 4) * 8;
    const float* src = (n < 128) ? (W + n) : (pw + (n - 128));
    s16x8 out;
#pragma unroll
    for (int j = 0; j < 8; ++j) {
        float wv = src[(size_t)(k0 + j) * 128];
        unsigned short hi = f2bf(wv);
        if (hilo == 0) {
            out[j] = (short)hi;
        } else {
            float fhi = __uint_as_float(((unsigned)hi) << 16);
            out[j] = (short)f2bf(wv - fhi);
        }
    }
    *(s16x8*)(wfrag + (size_t)unit * 8) = out;
}

// ---------------- MFMA feature transform (layers 2,3; N=256 = W‖pw) ----------
// R14 post-mortem: all pipes idle at 79 µs → suspected sub-word global-store
// serialization (128 × 2-byte scattered stores/wave). v3: outputs staged in
// LDS (unguarded ushort writes), then block-wide dwordx4 coalesced flush.
// smem reused: staging xs → output tiles (barrier-separated).
// LDS row strides padded (144/272 B) so quads land 16 banks apart.

template<int K>
__global__ __launch_bounds__(256) void mfma_feat_kernel(
    const unsigned short* __restrict__ xin16, const short* __restrict__ wfrag,
    const float* __restrict__ pb,
    const float* __restrict__ a_src, const float* __restrict__ a_dst,
    unsigned char* __restrict__ h8, float* __restrict__ esrc, float* __restrict__ edst,
    unsigned short* __restrict__ rout16)
{
    constexpr int KS = K / 32;    // MFMA k-steps
    constexpr int CH = K / 8;     // 8-feature (16 B) chunks per node row
    // smem: phase 1 = xs staging (8*CH*16 s16x8 ≤ 32 KB); phase 2 = outputs
    // (h8 tile 128×144 B = 18432, rout tile 128×272 B = 34816; total 53248).
    __shared__ __align__(16) char smem[53248];
    s16x8* xs = (s16x8*)smem;
    unsigned short* h8lds = (unsigned short*)smem;             // stride 72 ushorts
    unsigned short* rolds = (unsigned short*)(smem + 18432);   // stride 136 ushorts

    const int tid = threadIdx.x;
    const int base = blockIdx.x * 128;

    for (int idx = tid; idx < 128 * CH; idx += 256) {
        int node = idx / CH;
        int ch = idx % CH;
        int gn = base + node; if (gn > NN - 1) gn = NN - 1;
        s16x8 v = *(const s16x8*)(xin16 + (size_t)gn * K + ch * 8);
        int tt = node >> 4, mm = node & 15;
        xs[(tt * CH + ch) * 16 + mm] = v;
    }
    __syncthreads();

    const int w = tid >> 6;
    const int lane = tid & 63;
    const int quad = lane >> 4;
    const int m = lane & 15;
    const int l0 = w * 32 + quad * 4;   // local row, tile0 (+r)
    const int l1 = l0 + 16;             // local row, tile1 (+r)
    const int node0 = base + l0;
    const int node1 = base + l1;

    s16x8 a0[KS], a1[KS];
#pragma unroll
    for (int ks = 0; ks < KS; ++ks) {
        a0[ks] = xs[((w * 2 + 0) * CH + (ks * 4 + quad)) * 16 + m];
        a1[ks] = xs[((w * 2 + 1) * CH + (ks * 4 + quad)) * 16 + m];
    }
    __syncthreads();   // xs dead; smem becomes output tile

    float es0h0[4] = {0.f,0.f,0.f,0.f}, es0h1[4] = {0.f,0.f,0.f,0.f};
    float ed0h0[4] = {0.f,0.f,0.f,0.f}, ed0h1[4] = {0.f,0.f,0.f,0.f};
    float es1h0[4] = {0.f,0.f,0.f,0.f}, es1h1[4] = {0.f,0.f,0.f,0.f};
    float ed1h0[4] = {0.f,0.f,0.f,0.f}, ed1h1[4] = {0.f,0.f,0.f,0.f};

#pragma unroll
    for (int nt = 0; nt < 16; ++nt) {
        s16x8 b[2 * KS];
#pragma unroll
        for (int i = 0; i < 2 * KS; ++i)
            b[i] = *(const s16x8*)(wfrag + (size_t)((nt * KS * 2 + i) * 64 + lane) * 8);
        f32x4v c0 = {0.f, 0.f, 0.f, 0.f};
        f32x4v c1 = {0.f, 0.f, 0.f, 0.f};
#pragma unroll
        for (int ks = 0; ks < KS; ++ks) {
            c0 = __builtin_amdgcn_mfma_f32_16x16x32_bf16(a0[ks], b[2 * ks + 0], c0, 0, 0, 0);
            c1 = __builtin_amdgcn_mfma_f32_16x16x32_bf16(a1[ks], b[2 * ks + 0], c1, 0, 0, 0);
            c0 = __builtin_amdgcn_mfma_f32_16x16x32_bf16(a0[ks], b[2 * ks + 1], c0, 0, 0, 0);
            c1 = __builtin_amdgcn_mfma_f32_16x16x32_bf16(a1[ks], b[2 * ks + 1], c1, 0, 0, 0);
        }
        if (nt < 8) {
            int col = nt * 16 + m;
            float av = a_src[col], dv = a_dst[col];
#pragma unroll
            for (int r = 0; r < 4; ++r) {
                float v0 = c0[r], v1 = c1[r];
                if (nt < 4) {
                    es0h0[r] = fmaf(v0, av, es0h0[r]); ed0h0[r] = fmaf(v0, dv, ed0h0[r]);
                    es1h0[r] = fmaf(v1, av, es1h0[r]); ed1h0[r] = fmaf(v1, dv, ed1h0[r]);
                } else {
                    es0h1[r] = fmaf(v0, av, es0h1[r]); ed0h1[r] = fmaf(v0, dv, ed0h1[r]);
                    es1h1[r] = fmaf(v1, av, es1h1[r]); ed1h1[r] = fmaf(v1, dv, ed1h1[r]);
                }
                float p0 = __shfl_xor(v0, 1, 16);
                float p1 = __shfl_xor(v1, 1, 16);
                if ((m & 1) == 0) {
                    int us = nt * 8 + (m >> 1);   // ushort index within row
                    int pk0 = __builtin_amdgcn_cvt_pk_fp8_f32(v0, p0, 0, false);
                    int pk1 = __builtin_amdgcn_cvt_pk_fp8_f32(v1, p1, 0, false);
                    h8lds[(l0 + r) * 72 + us] = (unsigned short)(pk0 & 0xFFFF);
                    h8lds[(l1 + r) * 72 + us] = (unsigned short)(pk1 & 0xFFFF);
                }
            }
        } else {
            int col = (nt - 8) * 16 + m;
            float bv = pb[col];
#pragma unroll
            for (int r = 0; r < 4; ++r) {
                rolds[(l0 + r) * 136 + col] = f2bf(c0[r] + bv);
                rolds[(l1 + r) * 136 + col] = f2bf(c1[r] + bv);
            }
        }
    }

    // e-logit reduce + store (unchanged)
#pragma unroll
    for (int r = 0; r < 4; ++r) {
#pragma unroll
        for (int off = 8; off > 0; off >>= 1) {
            es0h0[r] += __shfl_xor(es0h0[r], off, 16);
            es0h1[r] += __shfl_xor(es0h1[r], off, 16);
            ed0h0[r] += __shfl_xor(ed0h0[r], off, 16);
            ed0h1[r] += __shfl_xor(ed0h1[r], off, 16);
            es1h0[r] += __shfl_xor(es1h0[r], off, 16);
            es1h1[r] += __shfl_xor(es1h1[r], off, 16);
            ed1h0[r] += __shfl_xor(ed1h0[r], off, 16);
            ed1h1[r] += __shfl_xor(ed1h1[r], off, 16);
        }
    }
    if (m == 0) {
#pragma unroll
        for (int r = 0; r < 4; ++r) {
            if (node0 + r < NN) {
                ((float2*)esrc)[node0 + r] = make_float2(es0h0[r], es0h1[r]);
                ((float2*)edst)[node0 + r] = make_float2(ed0h0[r], ed0h1[r]);
            }
            if (node1 + r < NN) {
                ((float2*)esrc)[node1 + r] = make_float2(es1h0[r], es1h1[r]);
                ((float2*)edst)[node1 + r] = make_float2(ed1h0[r], ed1h1[r]);
            }
        }
    }

    __syncthreads();
    // flush h8 tile: 128 rows × 8 dwordx4
    for (int i = tid; i < 128 * 8; i += 256) {
        int row = i >> 3, ch = i & 7;
        int node = base + row;
        if (node < NN) {
            int4 v = *(const int4*)(smem + row * 144 + ch * 16);
            *(int4*)(h8 + (size_t)node * 128 + ch * 16) = v;
        }
    }
    // flush rout tile: 128 rows × 16 dwordx4
    for (int i = tid; i < 128 * 16; i += 256) {
        int row = i >> 4, ch = i & 15;
        int node = base + row;
        if (node < NN) {
            int4 v = *(const int4*)(smem + 18432 + row * 272 + ch * 16);
            *(int4*)((char*)rout16 + (size_t)node * 256 + ch * 16) = v;
        }
    }
}

// ---------------- fused aggregate, F=128 (fp8 h, packed bf16 weights) --------

__global__ __launch_bounds__(256) void aggregate128_kernel(
    const unsigned short* __restrict__ h8s,
    const int* __restrict__ row2_start, const int* __restrict__ row2_deg,
    const int* __restrict__ csr2_src, const unsigned* __restrict__ csr_w,
    const float* __restrict__ bias, const float* __restrict__ bng,
    const float* __restrict__ bnb, const float* __restrict__ bnm,
    const float* __restrict__ bnv, unsigned short* __restrict__ io16, int nN)
{
    int w = threadIdx.x >> 6;
    int lane = threadIdx.x & 63;
    int n = blockIdx.x * 4 + w;
    if (n >= nN) return;
    bool hi = lane >= 32;
    int s2 = row2_start[n];
    int dg = row2_deg[n];
    int pc = (dg + 7) & ~7;
    const int4* sp = (const int4*)(csr2_src + s2);
    const uint4* wp = (const uint4*)(csr_w + s2);
    float s = 0.f, ax = 0.f, ay = 0.f;
    for (int j = 0; j < pc; j += 8) {
        int4 ia = sp[(j >> 2) + 0];
        int4 ib = sp[(j >> 2) + 1];
        uint4 wa = wp[(j >> 2) + 0];
        uint4 wb = wp[(j >> 2) + 1];
        unsigned short v0 = h8s[(size_t)ia.x * 64 + lane];
        unsigned short v1 = h8s[(size_t)ia.y * 64 + lane];
        unsigned short v2 = h8s[(size_t)ia.z * 64 + lane];
        unsigned short v3 = h8s[(size_t)ia.w * 64 + lane];
        unsigned short v4 = h8s[(size_t)ib.x * 64 + lane];
        unsigned short v5 = h8s[(size_t)ib.y * 64 + lane];
        unsigned short v6 = h8s[(size_t)ib.z * 64 + lane];
        unsigned short v7 = h8s[(size_t)ib.w * 64 + lane];
        float g0 = __uint_as_float(hi ? (wa.x & 0xFFFF0000u) : (wa.x << 16));
        float g1 = __uint_as_float(hi ? (wa.y & 0xFFFF0000u) : (wa.y << 16));
        float g2 = __uint_as_float(hi ? (wa.z & 0xFFFF0000u) : (wa.z << 16));
        float g3 = __uint_as_float(hi ? (wa.w & 0xFFFF0000u) : (wa.w << 16));
        float g4 = __uint_as_float(hi ? (wb.x & 0xFFFF0000u) : (wb.x << 16));
        float g5 = __uint_as_float(hi ? (wb.y & 0xFFFF0000u) : (wb.y << 16));
        float g6 = __uint_as_float(hi ? (wb.z & 0xFFFF0000u) : (wb.z << 16));
        float g7 = __uint_as_float(hi ? (wb.w & 0xFFFF0000u) : (wb.w << 16));
        floatx2 f0 = __builtin_amdgcn_cvt_pk_f32_fp8((int)v0, false);
        floatx2 f1 = __builtin_amdgcn_cvt_pk_f32_fp8((int)v1, false);
        floatx2 f2 = __builtin_amdgcn_cvt_pk_f32_fp8((int)v2, false);
        floatx2 f3 = __builtin_amdgcn_cvt_pk_f32_fp8((int)v3, false);
        floatx2 f4 = __builtin_amdgcn_cvt_pk_f32_fp8((int)v4, false);
        floatx2 f5 = __builtin_amdgcn_cvt_pk_f32_fp8((int)v5, false);
        floatx2 f6 = __builtin_amdgcn_cvt_pk_f32_fp8((int)v6, false);
        floatx2 f7 = __builtin_amdgcn_cvt_pk_f32_fp8((int)v7, false);
        ax = fmaf(g0, f0.x, ax); ay = fmaf(g0, f0.y, ay);
        ax = fmaf(g1, f1.x, ax); ay = fmaf(g1, f1.y, ay);
        ax = fmaf(g2, f2.x, ax); ay = fmaf(g2, f2.y, ay);
        ax = fmaf(g3, f3.x, ax); ay = fmaf(g3, f3.y, ay);
        ax = fmaf(g4, f4.x, ax); ay = fmaf(g4, f4.y, ay);
        ax = fmaf(g5, f5.x, ax); ay = fmaf(g5, f5.y, ay);
        ax = fmaf(g6, f6.x, ax); ay = fmaf(g6, f6.y, ay);
        ax = fmaf(g7, f7.x, ax); ay = fmaf(g7, f7.y, ay);
        s += ((g0 + g1) + (g2 + g3)) + ((g4 + g5) + (g6 + g7));
    }
    float inv = 1.f / (s + 1e-16f);
    int f0i = 2 * lane, f1i = 2 * lane + 1;
    float o0 = bng[f0i] * (ax * inv + bias[f0i] - bnm[f0i]) * rsqrtf(bnv[f0i] + BNEPS) + bnb[f0i];
    float o1 = bng[f1i] * (ay * inv + bias[f1i] - bnm[f1i]) * rsqrtf(bnv[f1i] + BNEPS) + bnb[f1i];
    unsigned* iop = (unsigned*)(io16 + (size_t)n * 128) + lane;
    unsigned pu = *iop;
    float r0 = fmaxf(o0, 0.f) + __uint_as_float((pu & 0xFFFFu) << 16);
    float r1 = fmaxf(o1, 0.f) + __uint_as_float(pu & 0xFFFF0000u);
    *iop = (unsigned)f2bf(r0) | ((unsigned)f2bf(r1) << 16);
}

// ---------------- fused aggregate, F=64 ---------------------------------------

__global__ __launch_bounds__(256) void aggregate64_kernel(
    const unsigned char* __restrict__ h8,
    const int* __restrict__ row2_start, const int* __restrict__ row2_deg,
    const int* __restrict__ csr2_src, const unsigned* __restrict__ csr_w,
    const float* __restrict__ bias, const float* __restrict__ bng,
    const float* __restrict__ bnb, const float* __restrict__ bnm,
    const float* __restrict__ bnv, unsigned short* __restrict__ io16, int nN)
{
    int w = threadIdx.x >> 6;
    int lane = threadIdx.x & 63;
    int n = blockIdx.x * 4 + w;
    if (n >= nN) return;
    bool hi = lane >= 32;
    int s2 = row2_start[n];
    int dg = row2_deg[n];
    int pc = (dg + 7) & ~7;
    const int4* sp = (const int4*)(csr2_src + s2);
    const uint4* wp = (const uint4*)(csr_w + s2);
    float s = 0.f, acc = 0.f;
    for (int j = 0; j < pc; j += 8) {
        int4 ia = sp[(j >> 2) + 0];
        int4 ib = sp[(j >> 2) + 1];
        uint4 wa = wp[(j >> 2) + 0];
        uint4 wb = wp[(j >> 2) + 1];
        unsigned char v0 = h8[(size_t)ia.x * 64 + lane];
        unsigned char v1 = h8[(size_t)ia.y * 64 + lane];
        unsigned char v2 = h8[(size_t)ia.z * 64 + lane];
        unsigned char v3 = h8[(size_t)ia.w * 64 + lane];
        unsigned char v4 = h8[(size_t)ib.x * 64 + lane];
        unsigned char v5 = h8[(size_t)ib.y * 64 + lane];
        unsigned char v6 = h8[(size_t)ib.z * 64 + lane];
        unsigned char v7 = h8[(size_t)ib.w * 64 + lane];
        float g0 = __uint_as_float(hi ? (wa.x & 0xFFFF0000u) : (wa.x << 16));
        float g1 = __uint_as_float(hi ? (wa.y & 0xFFFF0000u) : (wa.y << 16));
        float g2 = __uint_as_float(hi ? (wa.z & 0xFFFF0000u) : (wa.z << 16));
        float g3 = __uint_as_float(hi ? (wa.w & 0xFFFF0000u) : (wa.w << 16));
        float g4 = __uint_as_float(hi ? (wb.x & 0xFFFF0000u) : (wb.x << 16));
        float g5 = __uint_as_float(hi ? (wb.y & 0xFFFF0000u) : (wb.y << 16));
        float g6 = __uint_as_float(hi ? (wb.z & 0xFFFF0000u) : (wb.z << 16));
        float g7 = __uint_as_float(hi ? (wb.w & 0xFFFF0000u) : (wb.w << 16));
        acc = fmaf(g0, __builtin_amdgcn_cvt_f32_fp8((int)v0, 0), acc);
        acc = fmaf(g1, __builtin_amdgcn_cvt_f32_fp8((int)v1, 0), acc);
        acc = fmaf(g2, __builtin_amdgcn_cvt_f32_fp8((int)v2, 0), acc);
        acc = fmaf(g3, __builtin_amdgcn_cvt_f32_fp8((int)v3, 0), acc);
        acc = fmaf(g4, __builtin_amdgcn_cvt_f32_fp8((int)v4, 0), acc);
        acc = fmaf(g5, __builtin_amdgcn_cvt_f32_fp8((int)v5, 0), acc);
        acc = fmaf(g6, __builtin_amdgcn_cvt_f32_fp8((int)v6, 0), acc);
        acc = fmaf(g7, __builtin_amdgcn_cvt_f32_fp8((int)v7, 0), acc);
        s += ((g0 + g1) + (g2 + g3)) + ((g4 + g5) + (g6 + g7));
    }
    int f = lane;
    float g = acc / (s + 1e-16f);
    float vv = bng[f] * (g + bias[f] - bnm[f]) * rsqrtf(bnv[f] + BNEPS) + bnb[f];
    float prev = bf2f(io16[(size_t)n * 64 + f]);
    io16[(size_t)n * 64 + f] = f2bf(fmaxf(vv, 0.f) + prev);
}

// ---------------- pooling, two-phase (bf16 input) ----------------

__global__ __launch_bounds__(128) void pool_partial_kernel(
    const unsigned short* __restrict__ hf16, const int* __restrict__ batch,
    float* __restrict__ ppart)
{
    int g = blockIdx.x / PSPLIT;
    int p = blockIdx.x % PSPLIT;
    int f = threadIdx.x;
    int lo = 0, hi = NN;
    while (lo < hi) { int mid = (lo + hi) >> 1; if (batch[mid] < g) lo = mid + 1; else hi = mid; }
    int start = lo;
    hi = NN;
    while (lo < hi) { int mid = (lo + hi) >> 1; if (batch[mid] < g + 1) lo = mid + 1; else hi = mid; }
    int end = lo;
    int len = end - start;
    int chunk = (len + PSPLIT - 1) / PSPLIT;
    int i0 = start + p * chunk;
    int i1 = i0 + chunk; if (i1 > end) i1 = end;
    float acc = 0.f;
    for (int i = i0; i < i1; ++i) acc += bf2f(hf16[(size_t)i * 128 + f]);
    ppart[((size_t)g * PSPLIT + p) * 128 + f] = acc;
}

// ---------------- MLP head (folds partial-sum reduce + mean) -----------------

__global__ __launch_bounds__(128) void head_kernel(
    const float* __restrict__ ppart, const int* __restrict__ batch,
    const float* __restrict__ fw, const float* __restrict__ fb,
    const float* __restrict__ g4, const float* __restrict__ be4,
    const float* __restrict__ m4, const float* __restrict__ v4,
    const float* __restrict__ l1w, const float* __restrict__ l1b,
    const float* __restrict__ l2w, const float* __restrict__ l2b,
    float* __restrict__ out)
{
    __shared__ float p[128];
    __shared__ float z1[32];
    __shared__ float z2[32];
    int g = blockIdx.x, t = threadIdx.x;
    int lo = 0, hi = NN;
    while (lo < hi) { int mid = (lo + hi) >> 1; if (batch[mid] < g) lo = mid + 1; else hi = mid; }
    int start = lo;
    hi = NN;
    while (lo < hi) { int mid = (lo + hi) >> 1; if (batch[mid] < g + 1) lo = mid + 1; else hi = mid; }
    float cnt = (float)(lo - start);
    float acc = 0.f;
#pragma unroll
    for (int q = 0; q < PSPLIT; ++q)
        acc += ppart[((size_t)g * PSPLIT + q) * 128 + t];
    p[t] = acc / fmaxf(cnt, 1.0f);
    __syncthreads();
    if (t < 32) {
        float a = fb[t];
        for (int k = 0; k < 128; ++k) a += p[k] * fw[k * 32 + t];
        float val = g4[t] * (a - m4[t]) * rsqrtf(v4[t] + BNEPS) + be4[t];
        z1[t] = fmaxf(val, 0.f);
    }
    __syncthreads();
    if (t < 32) {
        float a = l1b[t];
        for (int k = 0; k < 32; ++k) a += z1[k] * l1w[k * 32 + t];
        z2[t] = fmaxf(a, 0.f);
    }
    __syncthreads();
    if (t < 10) {
        float a = l2b[t];
        for (int k = 0; k < 32; ++k) a += z2[k] * l2w[k * 10 + t];
        out[g * 10 + t] = a;
    }
}

// ---------------- launch ----------------

extern "C" void kernel_launch(void* const* d_in, const int* in_sizes, int n_in,
                              void* d_out, int out_size, void* d_ws, size_t ws_size,
                              hipStream_t stream) {
    const float* x     = (const float*)d_in[0];
    const int*   ei    = (const int*)d_in[1];
    const int*   batch = (const int*)d_in[2];
    const float* w1  = (const float*)d_in[3];
    const float* as1 = (const float*)d_in[4];
    const float* ad1 = (const float*)d_in[5];
    const float* b1  = (const float*)d_in[6];
    const float* g1  = (const float*)d_in[7];
    const float* be1 = (const float*)d_in[8];
    const float* m1  = (const float*)d_in[9];
    const float* v1  = (const float*)d_in[10];
    const float* p1w = (const float*)d_in[11];
    const float* p1b = (const float*)d_in[12];
    const float* w2  = (const float*)d_in[13];
    const float* as2 = (const float*)d_in[14];
    const float* ad2 = (const float*)d_in[15];
    const float* b2  = (const float*)d_in[16];
    const float* g2  = (const float*)d_in[17];
    const float* be2 = (const float*)d_in[18];
    const float* m2  = (const float*)d_in[19];
    const float* v2  = (const float*)d_in[20];
    const float* p2w = (const float*)d_in[21];
    const float* p2b = (const float*)d_in[22];
    const float* w3  = (const float*)d_in[23];
    const float* as3 = (const float*)d_in[24];
    const float* ad3 = (const float*)d_in[25];
    const float* b3  = (const float*)d_in[26];
    const float* g3  = (const float*)d_in[27];
    const float* be3 = (const float*)d_in[28];
    const float* m3  = (const float*)d_in[29];
    const float* v3  = (const float*)d_in[30];
    const float* p3w = (const float*)d_in[31];
    const float* p3b = (const float*)d_in[32];
    const float* fw  = (const float*)d_in[33];
    const float* fb  = (const float*)d_in[34];
    const float* g4  = (const float*)d_in[35];
    const float* be4 = (const float*)d_in[36];
    const float* m4  = (const float*)d_in[37];
    const float* v4  = (const float*)d_in[38];
    const float* l1w = (const float*)d_in[39];
    const float* l1b = (const float*)d_in[40];
    const float* l2w = (const float*)d_in[41];
    const float* l2b = (const float*)d_in[42];

    char* ws = (char*)d_ws;
    size_t off = 0;
    auto alloc = [&](size_t bytes) -> char* {
        char* p = ws + off;
        off += (bytes + 255) & ~(size_t)255;
        return p;
    };
    int*    bucket_cnt  = (int*)alloc((NBK) * sizeof(int));
    int*    bucket_base = (int*)alloc((NBK + 1) * sizeof(int));
    int*    gcursor     = (int*)alloc((NBK) * sizeof(int));
    int*    part        = (int*)alloc((size_t)ETOT * sizeof(int));
    int*    row2_start  = (int*)alloc(NN * sizeof(int));
    int*    row2_deg    = (int*)alloc(NN * sizeof(int));
    int*    csr2_src    = (int*)alloc((size_t)PADTOT * sizeof(int));
    unsigned* csr_w     = (unsigned*)alloc((size_t)PADTOT * sizeof(unsigned));
    unsigned char*  h8  = (unsigned char*)alloc((size_t)(NN + 1) * 128);
    unsigned short* hb1 = (unsigned short*)alloc((size_t)NN * 64 * sizeof(short));
    unsigned short* hb2 = (unsigned short*)alloc((size_t)NN * 128 * sizeof(short));
    unsigned short* hb3 = (unsigned short*)alloc((size_t)NN * 128 * sizeof(short));
    float*  esrc        = (float*)alloc((size_t)(NN + 1) * 2 * sizeof(float));
    float*  edst        = (float*)alloc((size_t)NN * 2 * sizeof(float));
    float*  ppart       = (float*)alloc((size_t)GG * PSPLIT * 128 * sizeof(float));
    short*  wfrag2      = (short*)alloc((size_t)16 * 2 * 2 * 64 * 8 * sizeof(short));
    short*  wfrag3      = (short*)alloc((size_t)16 * 4 * 2 * 64 * 8 * sizeof(short));

    // ---- weight fragment prep (independent of everything else) ----
    prep_w_kernel<64><<<16, 256, 0, stream>>>(w2, p2w, wfrag2);
    prep_w_kernel<128><<<32, 256, 0, stream>>>(w3, p3w, wfrag3);

    // ---- CSR build (bucketed partition, padded layout, NN sentinel pads) ----
    hipMemsetAsync(bucket_cnt, 0, NBK * sizeof(int), stream);
    bucket_count_kernel<<<(ETOT + 8191) / 8192, 256, 0, stream>>>(ei, bucket_cnt);
    bucket_scan_kernel<<<1, 512, 0, stream>>>(bucket_cnt, bucket_base, gcursor, esrc);
    partition_kernel<<<(ETOT + 4095) / 4096, 256, 0, stream>>>(ei, gcursor, part);
    csr_build_kernel<<<NBK, 256, 0, stream>>>(part, bucket_base, row2_start, row2_deg, csr2_src);

    // ---- layer 1: x[N,5] -> hb1[N,64] (bf16) ----
    feat1_kernel<<<(NN + 3) / 4, 256, 0, stream>>>(
        x, w1, p1w, p1b, as1, ad1, h8, esrc, edst, hb1, NN);
    edgew_kernel<<<(NN + 3) / 4, 256, 0, stream>>>(
        csr2_src, row2_start, row2_deg, (const float2*)esrc, (const float2*)edst, csr_w, NN);
    aggregate64_kernel<<<(NN + 3) / 4, 256, 0, stream>>>(
        h8, row2_start, row2_deg, csr2_src, csr_w,
        b1, g1, be1, m1, v1, hb1, NN);

    // ---- layer 2: hb1 -> hb2[N,128] (bf16) ----
    mfma_feat_kernel<64><<<(NN + 127) / 128, 256, 0, stream>>>(
        hb1, wfrag2, p2b, as2, ad2, h8, esrc, edst, hb2);
    edgew_kernel<<<(NN + 3) / 4, 256, 0, stream>>>(
        csr2_src, row2_start, row2_deg, (const float2*)esrc, (const float2*)edst, csr_w, NN);
    aggregate128_kernel<<<(NN + 3) / 4, 256, 0, stream>>>(
        (const unsigned short*)h8, row2_start, row2_deg, csr2_src, csr_w,
        b2, g2, be2, m2, v2, hb2, NN);

    // ---- layer 3: hb2 -> hb3[N,128] (bf16) ----
    mfma_feat_kernel<128><<<(NN + 127) / 128, 256, 0, stream>>>(
        hb2, wfrag3, p3b, as3, ad3, h8, esrc, edst, hb3);
    edgew_kernel<<<(NN + 3) / 4, 256, 0, stream>>>(
        csr2_src, row2_start, row2_deg, (const float2*)esrc, (const float2*)edst, csr_w, NN);
    aggregate128_kernel<<<(NN + 3) / 4, 256, 0, stream>>>(
        (const unsigned short*)h8, row2_start, row2_deg, csr2_src, csr_w,
        b3, g3, be3, m3, v3, hb3, NN);

    // ---- pool (two-phase) + head ----
    pool_partial_kernel<<<GG * PSPLIT, 128, 0, stream>>>(hb3, batch, ppart);
    head_kernel<<<GG, 128, 0, stream>>>(ppart, batch, fw, fb, g4, be4, m4, v4,
                                        l1w, l1b, l2w, l2b, (float*)d_out);
}

// Round 16
// 595.367 us; speedup vs baseline: 1.2018x; 1.0010x over previous
//
#include <hip/hip_runtime.h>
#include <hip/hip_bf16.h>
#include <hip/hip_fp16.h>

#define NN   100000
#define EE   1600000
#define ETOT (EE + NN)
#define GG   256
#define BNEPS 1e-5f
#define NBK  391          // buckets of 256 nodes: (NN+255)/256
#define PADTOT (ETOT + NBK * 2048 + 64)
#define PSPLIT 16

typedef float floatx2 __attribute__((ext_vector_type(2)));
typedef short s16x8 __attribute__((ext_vector_type(8)));
typedef float f32x4v __attribute__((ext_vector_type(4)));

__device__ __forceinline__ unsigned short f2bf(float f) {
    unsigned u = __float_as_uint(f);
    unsigned r = u + 0x7FFF + ((u >> 16) & 1);
    return (unsigned short)(r >> 16);
}
__device__ __forceinline__ float bf2f(unsigned short b) {
    return __uint_as_float(((unsigned)b) << 16);
}

// ---------------- CSR build: bucketed partition (single-writer cache lines) --

__global__ __launch_bounds__(256) void bucket_count_kernel(
    const int* __restrict__ ei, int* __restrict__ bucket_cnt)
{
    __shared__ int cnt[NBK];
    for (int i = threadIdx.x; i < NBK; i += 256) cnt[i] = 0;
    __syncthreads();
    int base = blockIdx.x * 8192;
    for (int k = threadIdx.x; k < 8192; k += 256) {
        int e = base + k;
        if (e < ETOT) {
            int dst = (e < EE) ? ei[EE + e] : (e - EE);
            atomicAdd(&cnt[dst >> 8], 1);
        }
    }
    __syncthreads();
    for (int i = threadIdx.x; i < NBK; i += 256)
        if (cnt[i]) atomicAdd(&bucket_cnt[i], cnt[i]);
}

// also plants the -inf esrc sentinel used by pad edges (src = NN)
__global__ __launch_bounds__(512) void bucket_scan_kernel(
    const int* __restrict__ bucket_cnt, int* __restrict__ bucket_base,
    int* __restrict__ gcursor, float* __restrict__ esrcs)
{
    __shared__ int s[512];
    int t = threadIdx.x;
    int v = (t < NBK) ? bucket_cnt[t] : 0;
    s[t] = v;
    __syncthreads();
    int x = v;
    for (int o = 1; o < 512; o <<= 1) {
        int y = (t >= o) ? s[t - o] : 0;
        __syncthreads();
        x += y;
        s[t] = x;
        __syncthreads();
    }
    if (t < NBK) { bucket_base[t] = x - v; gcursor[t] = x - v; }
    if (t == 0) {
        bucket_base[NBK] = ETOT;
        esrcs[2 * NN]     = __int_as_float(0xFF800000);  // -inf
        esrcs[2 * NN + 1] = __int_as_float(0xFF800000);
    }
}

__global__ __launch_bounds__(256) void partition_kernel(
    const int* __restrict__ ei, int* __restrict__ gcursor, int* __restrict__ part)
{
    __shared__ int cnt[NBK];
    __shared__ int basel[NBK];
    for (int i = threadIdx.x; i < NBK; i += 256) cnt[i] = 0;
    __syncthreads();
    int base = blockIdx.x * 4096;
    for (int k = threadIdx.x; k < 4096; k += 256) {
        int e = base + k;
        if (e < ETOT) {
            int dst = (e < EE) ? ei[EE + e] : (e - EE);
            atomicAdd(&cnt[dst >> 8], 1);
        }
    }
    __syncthreads();
    for (int i = threadIdx.x; i < NBK; i += 256) {
        int c = cnt[i];
        basel[i] = c ? atomicAdd(&gcursor[i], c) : 0;
        cnt[i] = 0;   // reuse as intra-block cursor
    }
    __syncthreads();
    for (int k = threadIdx.x; k < 4096; k += 256) {
        int e = base + k;
        if (e < ETOT) {
            int src, dst;
            if (e < EE) { src = ei[e]; dst = ei[EE + e]; }
            else        { src = e - EE; dst = e - EE; }
            int b = dst >> 8;
            int slot = atomicAdd(&cnt[b], 1);
            part[basel[b] + slot] = src | ((dst & 255) << 17);
        }
    }
}

// Padded CSR: per-node segments rounded up to 8 entries, pad src = NN
// (sentinel: esrc[NN] = -inf → exp weight 0, so no masking anywhere).
__global__ __launch_bounds__(256) void csr_build_kernel(
    const int* __restrict__ part, const int* __restrict__ bucket_base,
    int* __restrict__ row2_start, int* __restrict__ row2_deg,
    int* __restrict__ csr2_src)
{
    __shared__ int degs[256];
    __shared__ int sc[256];
    __shared__ int cur[256];
    int b = blockIdx.x;
    int t = threadIdx.x;
    int beg = bucket_base[b], end = bucket_base[b + 1];
    int pbase = ((beg + 7) & ~7) + 2048 * b;
    degs[t] = 0;
    __syncthreads();
    for (int j = beg + t; j < end; j += 256)
        atomicAdd(&degs[(part[j] >> 17) & 255], 1);
    __syncthreads();
    int dg = degs[t];
    int pdeg = (dg + 7) & ~7;
    sc[t] = pdeg;
    __syncthreads();
    int x = pdeg;
    for (int o = 1; o < 256; o <<= 1) {
        int y = (t >= o) ? sc[t - o] : 0;
        __syncthreads();
        x += y;
        sc[t] = x;
        __syncthreads();
    }
    int start2 = pbase + (x - pdeg);
    int node = b * 256 + t;
    if (node < NN) { row2_start[node] = start2; row2_deg[node] = dg; }
    cur[t] = start2;
    __syncthreads();
    for (int j = beg + t; j < end; j += 256) {
        int pv = part[j];
        int pos = atomicAdd(&cur[(pv >> 17) & 255], 1);
        csr2_src[pos] = pv & 0x1FFFF;
    }
    for (int k = dg; k < pdeg; ++k) csr2_src[start2 + k] = NN;
}

// ---------------- per-layer edge softmax weights (packed 2×bf16) -------------
// Unmasked: pad slots read src=NN → esrc=-inf → exp=0 → packed 0.

__global__ __launch_bounds__(256) void edgew_kernel(
    const int* __restrict__ csr2_src, const int* __restrict__ row2_start,
    const int* __restrict__ row2_deg,
    const float2* __restrict__ esrc, const float2* __restrict__ edst,
    unsigned* __restrict__ csr_w, int nN)
{
    int n = blockIdx.x * 4 + (threadIdx.x >> 6);
    int lane = threadIdx.x & 63;
    if (n >= nN) return;
    float2 ed = edst[n];
    int s2 = row2_start[n];
    int dg = row2_deg[n];
    int pc = (dg + 7) & ~7;
    for (int j = lane; j < pc; j += 64) {
        int i = csr2_src[s2 + j];
        float2 es = esrc[i];
        float a0 = es.x + ed.x; a0 = (a0 > 0.f) ? a0 : 0.2f * a0;
        float a1 = es.y + ed.y; a1 = (a1 > 0.f) ? a1 : 0.2f * a1;
        unsigned w = (unsigned)f2bf(__expf(a0)) | ((unsigned)f2bf(__expf(a1)) << 16);
        csr_w[s2 + j] = w;
    }
}

// ---------------- layer-1 feature transform (K=5); h fp8, rout bf16 ----------

__global__ __launch_bounds__(256) void feat1_kernel(
    const float* __restrict__ xin, const float* __restrict__ W,
    const float* __restrict__ pw, const float* __restrict__ pb,
    const float* __restrict__ a_src, const float* __restrict__ a_dst,
    unsigned char* __restrict__ h8, float* __restrict__ esrc, float* __restrict__ edst,
    unsigned short* __restrict__ rout16, int nN)
{
    constexpr int F_IN = 5, F_OUT = 64;
    int t = threadIdx.x;
    int n = blockIdx.x * 4 + t / F_OUT;
    int f = t % F_OUT;
    if (n >= nN) return;
    float acc = 0.f, racc = 0.f;
#pragma unroll
    for (int k = 0; k < F_IN; ++k) {
        float xv = xin[n * F_IN + k];
        acc  += xv * W[k * F_OUT + f];
        racc += xv * pw[k * F_OUT + f];
    }
    float other = __shfl_xor(acc, 1, 64);
    if ((f & 1) == 0) {
        int p = __builtin_amdgcn_cvt_pk_fp8_f32(acc, other, 0, false);
        *(unsigned short*)(h8 + (size_t)n * F_OUT + f) = (unsigned short)(p & 0xFFFF);
    }
    rout16[(size_t)n * F_OUT + f] = f2bf(racc + pb[f]);
    float es = acc * a_src[f];
    float ed = acc * a_dst[f];
#pragma unroll
    for (int off = 16; off > 0; off >>= 1) {
        es += __shfl_xor(es, off, 32);
        ed += __shfl_xor(ed, off, 32);
    }
    if ((t & 31) == 0) {
        int head = (f >> 5) & 1;
        esrc[n * 2 + head] = es;
        edst[n * 2 + head] = ed;
    }
}

// ---------------- weight fragment prep (bf16 hi/lo split, MFMA B layout) -----

template<int K>
__global__ __launch_bounds__(256) void prep_w_kernel(
    const float* __restrict__ W, const float* __restrict__ pw,
    short* __restrict__ wfrag)
{
    constexpr int KS = K / 32;
    int unit = blockIdx.x * 256 + threadIdx.x;
    int total = 16 * KS * 2 * 64;
    if (unit >= total) return;
    int lane = unit & 63;
    int rest = unit >> 6;
    int hilo = rest & 1;
    int fk = rest >> 1;
    int ks = fk % KS;
    int nt = fk / KS;
    int n = nt * 16 + (lane & 15);
    int k0 = ks * 32 + (lane >> 4) * 8;
    const float* src = (n < 128) ? (W + n) : (pw + (n - 128));
    s16x8 out;
#pragma unroll
    for (int j = 0; j < 8; ++j) {
        float wv = src[(size_t)(k0 + j) * 128];
        unsigned short hi = f2bf(wv);
        if (hilo == 0) {
            out[j] = (short)hi;
        } else {
            float fhi = __uint_as_float(((unsigned)hi) << 16);
            out[j] = (short)f2bf(wv - fhi);
        }
    }
    *(s16x8*)(wfrag + (size_t)unit * 8) = out;
}

// ---------------- MFMA feature transform (layers 2,3; N=256 = W‖pw) ----------
// LDS-staged outputs (R15 win: no sub-word global stores).

template<int K>
__global__ __launch_bounds__(256) void mfma_feat_kernel(
    const unsigned short* __restrict__ xin16, const short* __restrict__ wfrag,
    const float* __restrict__ pb,
    const float* __restrict__ a_src, const float* __restrict__ a_dst,
    unsigned char* __restrict__ h8, float* __restrict__ esrc, float* __restrict__ edst,
    unsigned short* __restrict__ rout16)
{
    constexpr int KS = K / 32;    // MFMA k-steps
    constexpr int CH = K / 8;     // 8-feature (16 B) chunks per node row
    __shared__ __align__(16) char smem[53248];
    s16x8* xs = (s16x8*)smem;
    unsigned short* h8lds = (unsigned short*)smem;             // stride 72 ushorts
    unsigned short* rolds = (unsigned short*)(smem + 18432);   // stride 136 ushorts

    const int tid = threadIdx.x;
    const int base = blockIdx.x * 128;

    for (int idx = tid; idx < 128 * CH; idx += 256) {
        int node = idx / CH;
        int ch = idx % CH;
        int gn = base + node; if (gn > NN - 1) gn = NN - 1;
        s16x8 v = *(const s16x8*)(xin16 + (size_t)gn * K + ch * 8);
        int tt = node >> 4, mm = node & 15;
        xs[(tt * CH + ch) * 16 + mm] = v;
    }
    __syncthreads();

    const int w = tid >> 6;
    const int lane = tid & 63;
    const int quad = lane >> 4;
    const int m = lane & 15;
    const int l0 = w * 32 + quad * 4;   // local row, tile0 (+r)
    const int l1 = l0 + 16;             // local row, tile1 (+r)
    const int node0 = base + l0;
    const int node1 = base + l1;

    s16x8 a0[KS], a1[KS];
#pragma unroll
    for (int ks = 0; ks < KS; ++ks) {
        a0[ks] = xs[((w * 2 + 0) * CH + (ks * 4 + quad)) * 16 + m];
        a1[ks] = xs[((w * 2 + 1) * CH + (ks * 4 + quad)) * 16 + m];
    }
    __syncthreads();   // xs dead; smem becomes output tile

    float es0h0[4] = {0.f,0.f,0.f,0.f}, es0h1[4] = {0.f,0.f,0.f,0.f};
    float ed0h0[4] = {0.f,0.f,0.f,0.f}, ed0h1[4] = {0.f,0.f,0.f,0.f};
    float es1h0[4] = {0.f,0.f,0.f,0.f}, es1h1[4] = {0.f,0.f,0.f,0.f};
    float ed1h0[4] = {0.f,0.f,0.f,0.f}, ed1h1[4] = {0.f,0.f,0.f,0.f};

#pragma unroll
    for (int nt = 0; nt < 16; ++nt) {
        s16x8 b[2 * KS];
#pragma unroll
        for (int i = 0; i < 2 * KS; ++i)
            b[i] = *(const s16x8*)(wfrag + (size_t)((nt * KS * 2 + i) * 64 + lane) * 8);
        f32x4v c0 = {0.f, 0.f, 0.f, 0.f};
        f32x4v c1 = {0.f, 0.f, 0.f, 0.f};
#pragma unroll
        for (int ks = 0; ks < KS; ++ks) {
            c0 = __builtin_amdgcn_mfma_f32_16x16x32_bf16(a0[ks], b[2 * ks + 0], c0, 0, 0, 0);
            c1 = __builtin_amdgcn_mfma_f32_16x16x32_bf16(a1[ks], b[2 * ks + 0], c1, 0, 0, 0);
            c0 = __builtin_amdgcn_mfma_f32_16x16x32_bf16(a0[ks], b[2 * ks + 1], c0, 0, 0, 0);
            c1 = __builtin_amdgcn_mfma_f32_16x16x32_bf16(a1[ks], b[2 * ks + 1], c1, 0, 0, 0);
        }
        if (nt < 8) {
            int col = nt * 16 + m;
            float av = a_src[col], dv = a_dst[col];
#pragma unroll
            for (int r = 0; r < 4; ++r) {
                float v0 = c0[r], v1 = c1[r];
                if (nt < 4) {
                    es0h0[r] = fmaf(v0, av, es0h0[r]); ed0h0[r] = fmaf(v0, dv, ed0h0[r]);
                    es1h0[r] = fmaf(v1, av, es1h0[r]); ed1h0[r] = fmaf(v1, dv, ed1h0[r]);
                } else {
                    es0h1[r] = fmaf(v0, av, es0h1[r]); ed0h1[r] = fmaf(v0, dv, ed0h1[r]);
                    es1h1[r] = fmaf(v1, av, es1h1[r]); ed1h1[r] = fmaf(v1, dv, ed1h1[r]);
                }
                float p0 = __shfl_xor(v0, 1, 16);
                float p1 = __shfl_xor(v1, 1, 16);
                if ((m & 1) == 0) {
                    int us = nt * 8 + (m >> 1);   // ushort index within row
                    int pk0 = __builtin_amdgcn_cvt_pk_fp8_f32(v0, p0, 0, false);
                    int pk1 = __builtin_amdgcn_cvt_pk_fp8_f32(v1, p1, 0, false);
                    h8lds[(l0 + r) * 72 + us] = (unsigned short)(pk0 & 0xFFFF);
                    h8lds[(l1 + r) * 72 + us] = (unsigned short)(pk1 & 0xFFFF);
                }
            }
        } else {
            int col = (nt - 8) * 16 + m;
            float bv = pb[col];
#pragma unroll
            for (int r = 0; r < 4; ++r) {
                rolds[(l0 + r) * 136 + col] = f2bf(c0[r] + bv);
                rolds[(l1 + r) * 136 + col] = f2bf(c1[r] + bv);
            }
        }
    }

#pragma unroll
    for (int r = 0; r < 4; ++r) {
#pragma unroll
        for (int off = 8; off > 0; off >>= 1) {
            es0h0[r] += __shfl_xor(es0h0[r], off, 16);
            es0h1[r] += __shfl_xor(es0h1[r], off, 16);
            ed0h0[r] += __shfl_xor(ed0h0[r], off, 16);
            ed0h1[r] += __shfl_xor(ed0h1[r], off, 16);
            es1h0[r] += __shfl_xor(es1h0[r], off, 16);
            es1h1[r] += __shfl_xor(es1h1[r], off, 16);
            ed1h0[r] += __shfl_xor(ed1h0[r], off, 16);
            ed1h1[r] += __shfl_xor(ed1h1[r], off, 16);
        }
    }
    if (m == 0) {
#pragma unroll
        for (int r = 0; r < 4; ++r) {
            if (node0 + r < NN) {
                ((float2*)esrc)[node0 + r] = make_float2(es0h0[r], es0h1[r]);
                ((float2*)edst)[node0 + r] = make_float2(ed0h0[r], ed0h1[r]);
            }
            if (node1 + r < NN) {
                ((float2*)esrc)[node1 + r] = make_float2(es1h0[r], es1h1[r]);
                ((float2*)edst)[node1 + r] = make_float2(ed1h0[r], ed1h1[r]);
            }
        }
    }

    __syncthreads();
    for (int i = tid; i < 128 * 8; i += 256) {
        int row = i >> 3, ch = i & 7;
        int node = base + row;
        if (node < NN) {
            int4 v = *(const int4*)(smem + row * 144 + ch * 16);
            *(int4*)(h8 + (size_t)node * 128 + ch * 16) = v;
        }
    }
    for (int i = tid; i < 128 * 16; i += 256) {
        int row = i >> 4, ch = i & 15;
        int node = base + row;
        if (node < NN) {
            int4 v = *(const int4*)(smem + 18432 + row * 272 + ch * 16);
            *(int4*)((char*)rout16 + (size_t)node * 256 + ch * 16) = v;
        }
    }
}

// ---------------- fused aggregate, F=128 (half-wave dword gathers) -----------
// Lanes 0..31 process even-paired edges, 32..63 the odd partner: each lane
// gathers a dword (4 fp8 features) → 4 VMEM per 8 edges (was 8 ushort).
// Partials combined across halves once via shfl_xor(·,32). Named scalars only.

__global__ __launch_bounds__(256) void aggregate128_kernel(
    const unsigned char* __restrict__ h8,
    const int* __restrict__ row2_start, const int* __restrict__ row2_deg,
    const int* __restrict__ csr2_src, const unsigned* __restrict__ csr_w,
    const float* __restrict__ bias, const float* __restrict__ bng,
    const float* __restrict__ bnb, const float* __restrict__ bnm,
    const float* __restrict__ bnv, unsigned short* __restrict__ io16, int nN)
{
    int w = threadIdx.x >> 6;
    int lane = threadIdx.x & 63;
    int n = blockIdx.x * 4 + w;
    if (n >= nN) return;
    bool hi32 = lane >= 32;
    int fl = lane & 31;               // feature dword index (features 4fl..4fl+3)
    bool headhi = (lane >> 4) & 1;    // features 64..127 ↔ fl in 16..31
    int s2 = row2_start[n];
    int dg = row2_deg[n];
    int pc = (dg + 7) & ~7;
    const int4* sp = (const int4*)(csr2_src + s2);
    const uint4* wp = (const uint4*)(csr_w + s2);
    float s = 0.f, a0 = 0.f, a1 = 0.f, a2 = 0.f, a3 = 0.f;
    for (int j = 0; j < pc; j += 8) {
        int4 ia = sp[(j >> 2) + 0];
        int4 ib = sp[(j >> 2) + 1];
        uint4 wa = wp[(j >> 2) + 0];
        uint4 wb = wp[(j >> 2) + 1];
        int i0 = hi32 ? ia.y : ia.x;
        int i1 = hi32 ? ia.w : ia.z;
        int i2 = hi32 ? ib.y : ib.x;
        int i3 = hi32 ? ib.w : ib.z;
        unsigned d0 = *(const unsigned*)(h8 + (size_t)i0 * 128 + fl * 4);
        unsigned d1 = *(const unsigned*)(h8 + (size_t)i1 * 128 + fl * 4);
        unsigned d2 = *(const unsigned*)(h8 + (size_t)i2 * 128 + fl * 4);
        unsigned d3 = *(const unsigned*)(h8 + (size_t)i3 * 128 + fl * 4);
        unsigned w0 = hi32 ? wa.y : wa.x;
        unsigned w1 = hi32 ? wa.w : wa.z;
        unsigned w2 = hi32 ? wb.y : wb.x;
        unsigned w3 = hi32 ? wb.w : wb.z;
        float g0 = __uint_as_float(headhi ? (w0 & 0xFFFF0000u) : (w0 << 16));
        float g1 = __uint_as_float(headhi ? (w1 & 0xFFFF0000u) : (w1 << 16));
        float g2 = __uint_as_float(headhi ? (w2 & 0xFFFF0000u) : (w2 << 16));
        float g3 = __uint_as_float(headhi ? (w3 & 0xFFFF0000u) : (w3 << 16));
        floatx2 lo0 = __builtin_amdgcn_cvt_pk_f32_fp8((int)d0, false);
        floatx2 hi0 = __builtin_amdgcn_cvt_pk_f32_fp8((int)d0, true);
        floatx2 lo1 = __builtin_amdgcn_cvt_pk_f32_fp8((int)d1, false);
        floatx2 hi1 = __builtin_amdgcn_cvt_pk_f32_fp8((int)d1, true);
        floatx2 lo2 = __builtin_amdgcn_cvt_pk_f32_fp8((int)d2, false);
        floatx2 hi2 = __builtin_amdgcn_cvt_pk_f32_fp8((int)d2, true);
        floatx2 lo3 = __builtin_amdgcn_cvt_pk_f32_fp8((int)d3, false);
        floatx2 hi3 = __builtin_amdgcn_cvt_pk_f32_fp8((int)d3, true);
        a0 = fmaf(g0, lo0.x, a0); a1 = fmaf(g0, lo0.y, a1);
        a2 = fmaf(g0, hi0.x, a2); a3 = fmaf(g0, hi0.y, a3);
        a0 = fmaf(g1, lo1.x, a0); a1 = fmaf(g1, lo1.y, a1);
        a2 = fmaf(g1, hi1.x, a2); a3 = fmaf(g1, hi1.y, a3);
        a0 = fmaf(g2, lo2.x, a0); a1 = fmaf(g2, lo2.y, a1);
        a2 = fmaf(g2, hi2.x, a2); a3 = fmaf(g2, hi2.y, a3);
        a0 = fmaf(g3, lo3.x, a0); a1 = fmaf(g3, lo3.y, a1);
        a2 = fmaf(g3, hi3.x, a2); a3 = fmaf(g3, hi3.y, a3);
        s += ((g0 + g1) + (g2 + g3));
    }
    // combine halves (partner lane holds same features, other edge set)
    a0 += __shfl_xor(a0, 32);
    a1 += __shfl_xor(a1, 32);
    a2 += __shfl_xor(a2, 32);
    a3 += __shfl_xor(a3, 32);
    s  += __shfl_xor(s, 32);
    if (!hi32) {
        float inv = 1.f / (s + 1e-16f);
        int f0 = fl * 4;
        float o0 = bng[f0+0] * (a0 * inv + bias[f0+0] - bnm[f0+0]) * rsqrtf(bnv[f0+0] + BNEPS) + bnb[f0+0];
        float o1 = bng[f0+1] * (a1 * inv + bias[f0+1] - bnm[f0+1]) * rsqrtf(bnv[f0+1] + BNEPS) + bnb[f0+1];
        float o2 = bng[f0+2] * (a2 * inv + bias[f0+2] - bnm[f0+2]) * rsqrtf(bnv[f0+2] + BNEPS) + bnb[f0+2];
        float o3 = bng[f0+3] * (a3 * inv + bias[f0+3] - bnm[f0+3]) * rsqrtf(bnv[f0+3] + BNEPS) + bnb[f0+3];
        uint2* iop = (uint2*)(io16 + (size_t)n * 128 + f0);
        uint2 pu = *iop;
        float r0 = fmaxf(o0, 0.f) + __uint_as_float((pu.x & 0xFFFFu) << 16);
        float r1 = fmaxf(o1, 0.f) + __uint_as_float(pu.x & 0xFFFF0000u);
        float r2 = fmaxf(o2, 0.f) + __uint_as_float((pu.y & 0xFFFFu) << 16);
        float r3 = fmaxf(o3, 0.f) + __uint_as_float(pu.y & 0xFFFF0000u);
        uint2 ov;
        ov.x = (unsigned)f2bf(r0) | ((unsigned)f2bf(r1) << 16);
        ov.y = (unsigned)f2bf(r2) | ((unsigned)f2bf(r3) << 16);
        *iop = ov;
    }
}

// ---------------- fused aggregate, F=64 (quarter-wave dword gathers) ---------
// Lane's quarter qw = lane>>4 picks one of 4 edges per step; fl = lane&15
// covers the 64 B row (features 4fl..4fl+3). 2 VMEM per 8 edges.

__global__ __launch_bounds__(256) void aggregate64_kernel(
    const unsigned char* __restrict__ h8,
    const int* __restrict__ row2_start, const int* __restrict__ row2_deg,
    const int* __restrict__ csr2_src, const unsigned* __restrict__ csr_w,
    const float* __restrict__ bias, const float* __restrict__ bng,
    const float* __restrict__ bnb, const float* __restrict__ bnm,
    const float* __restrict__ bnv, unsigned short* __restrict__ io16, int nN)
{
    int w = threadIdx.x >> 6;
    int lane = threadIdx.x & 63;
    int n = blockIdx.x * 4 + w;
    if (n >= nN) return;
    int qw = lane >> 4;               // quarter: which edge in group of 4
    int fl = lane & 15;               // feature dword (features 4fl..4fl+3)
    bool headhi = (fl >> 3) & 1;      // features 32..63 ↔ fl in 8..15
    int s2 = row2_start[n];
    int dg = row2_deg[n];
    int pc = (dg + 7) & ~7;
    const int4* sp = (const int4*)(csr2_src + s2);
    const uint4* wp = (const uint4*)(csr_w + s2);
    float s = 0.f, a0 = 0.f, a1 = 0.f, a2 = 0.f, a3 = 0.f;
    for (int j = 0; j < pc; j += 8) {
        int4 ia = sp[(j >> 2) + 0];
        int4 ib = sp[(j >> 2) + 1];
        uint4 wa = wp[(j >> 2) + 0];
        uint4 wb = wp[(j >> 2) + 1];
        int i0 = (qw == 0) ? ia.x : (qw == 1) ? ia.y : (qw == 2) ? ia.z : ia.w;
        int i1 = (qw == 0) ? ib.x : (qw == 1) ? ib.y : (qw == 2) ? ib.z : ib.w;
        unsigned w0 = (qw == 0) ? wa.x : (qw == 1) ? wa.y : (qw == 2) ? wa.z : wa.w;
        unsigned w1 = (qw == 0) ? wb.x : (qw == 1) ? wb.y : (qw == 2) ? wb.z : wb.w;
        unsigned d0 = *(const unsigned*)(h8 + (size_t)i0 * 64 + fl * 4);
        unsigned d1 = *(const unsigned*)(h8 + (size_t)i1 * 64 + fl * 4);
        float g0 = __uint_as_float(headhi ? (w0 & 0xFFFF0000u) : (w0 << 16));
        float g1 = __uint_as_float(headhi ? (w1 & 0xFFFF0000u) : (w1 << 16));
        floatx2 lo0 = __builtin_amdgcn_cvt_pk_f32_fp8((int)d0, false);
        floatx2 hi0 = __builtin_amdgcn_cvt_pk_f32_fp8((int)d0, true);
        floatx2 lo1 = __builtin_amdgcn_cvt_pk_f32_fp8((int)d1, false);
        floatx2 hi1 = __builtin_amdgcn_cvt_pk_f32_fp8((int)d1, true);
        a0 = fmaf(g0, lo0.x, a0); a1 = fmaf(g0, lo0.y, a1);
        a2 = fmaf(g0, hi0.x, a2); a3 = fmaf(g0, hi0.y, a3);
        a0 = fmaf(g1, lo1.x, a0); a1 = fmaf(g1, lo1.y, a1);
        a2 = fmaf(g1, hi1.x, a2); a3 = fmaf(g1, hi1.y, a3);
        s += (g0 + g1);
    }
    a0 += __shfl_xor(a0, 16); a0 += __shfl_xor(a0, 32);
    a1 += __shfl_xor(a1, 16); a1 += __shfl_xor(a1, 32);
    a2 += __shfl_xor(a2, 16); a2 += __shfl_xor(a2, 32);
    a3 += __shfl_xor(a3, 16); a3 += __shfl_xor(a3, 32);
    s  += __shfl_xor(s, 16);  s  += __shfl_xor(s, 32);
    if (lane < 16) {
        float inv = 1.f / (s + 1e-16f);
        int f0 = fl * 4;
        float o0 = bng[f0+0] * (a0 * inv + bias[f0+0] - bnm[f0+0]) * rsqrtf(bnv[f0+0] + BNEPS) + bnb[f0+0];
        float o1 = bng[f0+1] * (a1 * inv + bias[f0+1] - bnm[f0+1]) * rsqrtf(bnv[f0+1] + BNEPS) + bnb[f0+1];
        float o2 = bng[f0+2] * (a2 * inv + bias[f0+2] - bnm[f0+2]) * rsqrtf(bnv[f0+2] + BNEPS) + bnb[f0+2];
        float o3 = bng[f0+3] * (a3 * inv + bias[f0+3] - bnm[f0+3]) * rsqrtf(bnv[f0+3] + BNEPS) + bnb[f0+3];
        uint2* iop = (uint2*)(io16 + (size_t)n * 64 + f0);
        uint2 pu = *iop;
        float r0 = fmaxf(o0, 0.f) + __uint_as_float((pu.x & 0xFFFFu) << 16);
        float r1 = fmaxf(o1, 0.f) + __uint_as_float(pu.x & 0xFFFF0000u);
        float r2 = fmaxf(o2, 0.f) + __uint_as_float((pu.y & 0xFFFFu) << 16);
        float r3 = fmaxf(o3, 0.f) + __uint_as_float(pu.y & 0xFFFF0000u);
        uint2 ov;
        ov.x = (unsigned)f2bf(r0) | ((unsigned)f2bf(r1) << 16);
        ov.y = (unsigned)f2bf(r2) | ((unsigned)f2bf(r3) << 16);
        *iop = ov;
    }
}

// ---------------- pooling, two-phase (bf16 input) ----------------

__global__ __launch_bounds__(128) void pool_partial_kernel(
    const unsigned short* __restrict__ hf16, const int* __restrict__ batch,
    float* __restrict__ ppart)
{
    int g = blockIdx.x / PSPLIT;
    int p = blockIdx.x % PSPLIT;
    int f = threadIdx.x;
    int lo = 0, hi = NN;
    while (lo < hi) { int mid = (lo + hi) >> 1; if (batch[mid] < g) lo = mid + 1; else hi = mid; }
    int start = lo;
    hi = NN;
    while (lo < hi) { int mid = (lo + hi) >> 1; if (batch[mid] < g + 1) lo = mid + 1; else hi = mid; }
    int end = lo;
    int len = end - start;
    int chunk = (len + PSPLIT - 1) / PSPLIT;
    int i0 = start + p * chunk;
    int i1 = i0 + chunk; if (i1 > end) i1 = end;
    float acc = 0.f;
    for (int i = i0; i < i1; ++i) acc += bf2f(hf16[(size_t)i * 128 + f]);
    ppart[((size_t)g * PSPLIT + p) * 128 + f] = acc;
}

// ---------------- MLP head (folds partial-sum reduce + mean) -----------------

__global__ __launch_bounds__(128) void head_kernel(
    const float* __restrict__ ppart, const int* __restrict__ batch,
    const float* __restrict__ fw, const float* __restrict__ fb,
    const float* __restrict__ g4, const float* __restrict__ be4,
    const float* __restrict__ m4, const float* __restrict__ v4,
    const float* __restrict__ l1w, const float* __restrict__ l1b,
    const float* __restrict__ l2w, const float* __restrict__ l2b,
    float* __restrict__ out)
{
    __shared__ float p[128];
    __shared__ float z1[32];
    __shared__ float z2[32];
    int g = blockIdx.x, t = threadIdx.x;
    int lo = 0, hi = NN;
    while (lo < hi) { int mid = (lo + hi) >> 1; if (batch[mid] < g) lo = mid + 1; else hi = mid; }
    int start = lo;
    hi = NN;
    while (lo < hi) { int mid = (lo + hi) >> 1; if (batch[mid] < g + 1) lo = mid + 1; else hi = mid; }
    float cnt = (float)(lo - start);
    float acc = 0.f;
#pragma unroll
    for (int q = 0; q < PSPLIT; ++q)
        acc += ppart[((size_t)g * PSPLIT + q) * 128 + t];
    p[t] = acc / fmaxf(cnt, 1.0f);
    __syncthreads();
    if (t < 32) {
        float a = fb[t];
        for (int k = 0; k < 128; ++k) a += p[k] * fw[k * 32 + t];
        float val = g4[t] * (a - m4[t]) * rsqrtf(v4[t] + BNEPS) + be4[t];
        z1[t] = fmaxf(val, 0.f);
    }
    __syncthreads();
    if (t < 32) {
        float a = l1b[t];
        for (int k = 0; k < 32; ++k) a += z1[k] * l1w[k * 32 + t];
        z2[t] = fmaxf(a, 0.f);
    }
    __syncthreads();
    if (t < 10) {
        float a = l2b[t];
        for (int k = 0; k < 32; ++k) a += z2[k] * l2w[k * 10 + t];
        out[g * 10 + t] = a;
    }
}

// ---------------- launch ----------------

extern "C" void kernel_launch(void* const* d_in, const int* in_sizes, int n_in,
                              void* d_out, int out_size, void* d_ws, size_t ws_size,
                              hipStream_t stream) {
    const float* x     = (const float*)d_in[0];
    const int*   ei    = (const int*)d_in[1];
    const int*   batch = (const int*)d_in[2];
    const float* w1  = (const float*)d_in[3];
    const float* as1 = (const float*)d_in[4];
    const float* ad1 = (const float*)d_in[5];
    const float* b1  = (const float*)d_in[6];
    const float* g1  = (const float*)d_in[7];
    const float* be1 = (const float*)d_in[8];
    const float* m1  = (const float*)d_in[9];
    const float* v1  = (const float*)d_in[10];
    const float* p1w = (const float*)d_in[11];
    const float* p1b = (const float*)d_in[12];
    const float* w2  = (const float*)d_in[13];
    const float* as2 = (const float*)d_in[14];
    const float* ad2 = (const float*)d_in[15];
    const float* b2  = (const float*)d_in[16];
    const float* g2  = (const float*)d_in[17];
    const float* be2 = (const float*)d_in[18];
    const float* m2  = (const float*)d_in[19];
    const float* v2  = (const float*)d_in[20];
    const float* p2w = (const float*)d_in[21];
    const float* p2b = (const float*)d_in[22];
    const float* w3  = (const float*)d_in[23];
    const float* as3 = (const float*)d_in[24];
    const float* ad3 = (const float*)d_in[25];
    const float* b3  = (const float*)d_in[26];
    const float* g3  = (const float*)d_in[27];
    const float* be3 = (const float*)d_in[28];
    const float* m3  = (const float*)d_in[29];
    const float* v3  = (const float*)d_in[30];
    const float* p3w = (const float*)d_in[31];
    const float* p3b = (const float*)d_in[32];
    const float* fw  = (const float*)d_in[33];
    const float* fb  = (const float*)d_in[34];
    const float* g4  = (const float*)d_in[35];
    const float* be4 = (const float*)d_in[36];
    const float* m4  = (const float*)d_in[37];
    const float* v4  = (const float*)d_in[38];
    const float* l1w = (const float*)d_in[39];
    const float* l1b = (const float*)d_in[40];
    const float* l2w = (const float*)d_in[41];
    const float* l2b = (const float*)d_in[42];

    char* ws = (char*)d_ws;
    size_t off = 0;
    auto alloc = [&](size_t bytes) -> char* {
        char* p = ws + off;
        off += (bytes + 255) & ~(size_t)255;
        return p;
    };
    int*    bucket_cnt  = (int*)alloc((NBK) * sizeof(int));
    int*    bucket_base = (int*)alloc((NBK + 1) * sizeof(int));
    int*    gcursor     = (int*)alloc((NBK) * sizeof(int));
    int*    part        = (int*)alloc((size_t)ETOT * sizeof(int));
    int*    row2_start  = (int*)alloc(NN * sizeof(int));
    int*    row2_deg    = (int*)alloc(NN * sizeof(int));
    int*    csr2_src    = (int*)alloc((size_t)PADTOT * sizeof(int));
    unsigned* csr_w     = (unsigned*)alloc((size_t)PADTOT * sizeof(unsigned));
    unsigned char*  h8  = (unsigned char*)alloc((size_t)(NN + 1) * 128);
    unsigned short* hb1 = (unsigned short*)alloc((size_t)NN * 64 * sizeof(short));
    unsigned short* hb2 = (unsigned short*)alloc((size_t)NN * 128 * sizeof(short));
    unsigned short* hb3 = (unsigned short*)alloc((size_t)NN * 128 * sizeof(short));
    float*  esrc        = (float*)alloc((size_t)(NN + 1) * 2 * sizeof(float));
    float*  edst        = (float*)alloc((size_t)NN * 2 * sizeof(float));
    float*  ppart       = (float*)alloc((size_t)GG * PSPLIT * 128 * sizeof(float));
    short*  wfrag2      = (short*)alloc((size_t)16 * 2 * 2 * 64 * 8 * sizeof(short));
    short*  wfrag3      = (short*)alloc((size_t)16 * 4 * 2 * 64 * 8 * sizeof(short));

    // ---- weight fragment prep (independent of everything else) ----
    prep_w_kernel<64><<<16, 256, 0, stream>>>(w2, p2w, wfrag2);
    prep_w_kernel<128><<<32, 256, 0, stream>>>(w3, p3w, wfrag3);

    // ---- CSR build (bucketed partition, padded layout, NN sentinel pads) ----
    hipMemsetAsync(bucket_cnt, 0, NBK * sizeof(int), stream);
    bucket_count_kernel<<<(ETOT + 8191) / 8192, 256, 0, stream>>>(ei, bucket_cnt);
    bucket_scan_kernel<<<1, 512, 0, stream>>>(bucket_cnt, bucket_base, gcursor, esrc);
    partition_kernel<<<(ETOT + 4095) / 4096, 256, 0, stream>>>(ei, gcursor, part);
    csr_build_kernel<<<NBK, 256, 0, stream>>>(part, bucket_base, row2_start, row2_deg, csr2_src);

    // ---- layer 1: x[N,5] -> hb1[N,64] (bf16) ----
    feat1_kernel<<<(NN + 3) / 4, 256, 0, stream>>>(
        x, w1, p1w, p1b, as1, ad1, h8, esrc, edst, hb1, NN);
    edgew_kernel<<<(NN + 3) / 4, 256, 0, stream>>>(
        csr2_src, row2_start, row2_deg, (const float2*)esrc, (const float2*)edst, csr_w, NN);
    aggregate64_kernel<<<(NN + 3) / 4, 256, 0, stream>>>(
        h8, row2_start, row2_deg, csr2_src, csr_w,
        b1, g1, be1, m1, v1, hb1, NN);

    // ---- layer 2: hb1 -> hb2[N,128] (bf16) ----
    mfma_feat_kernel<64><<<(NN + 127) / 128, 256, 0, stream>>>(
        hb1, wfrag2, p2b, as2, ad2, h8, esrc, edst, hb2);
    edgew_kernel<<<(NN + 3) / 4, 256, 0, stream>>>(
        csr2_src, row2_start, row2_deg, (const float2*)esrc, (const float2*)edst, csr_w, NN);
    aggregate128_kernel<<<(NN + 3) / 4, 256, 0, stream>>>(
        h8, row2_start, row2_deg, csr2_src, csr_w,
        b2, g2, be2, m2, v2, hb2, NN);

    // ---- layer 3: hb2 -> hb3[N,128] (bf16) ----
    mfma_feat_kernel<128><<<(NN + 127) / 128, 256, 0, stream>>>(
        hb2, wfrag3, p3b, as3, ad3, h8, esrc, edst, hb3);
    edgew_kernel<<<(NN + 3) / 4, 256, 0, stream>>>(
        csr2_src, row2_start, row2_deg, (const float2*)esrc, (const float2*)edst, csr_w, NN);
    aggregate128_kernel<<<(NN + 3) / 4, 256, 0, stream>>>(
        h8, row2_start, row2_deg, csr2_src, csr_w,
        b3, g3, be3, m3, v3, hb3, NN);

    // ---- pool (two-phase) + head ----
    pool_partial_kernel<<<GG * PSPLIT, 128, 0, stream>>>(hb3, batch, ppart);
    head_kernel<<<GG, 128, 0, stream>>>(ppart, batch, fw, fb, g4, be4, m4, v4,
                                        l1w, l1b, l2w, l2b, (float*)d_out);
}

// Round 17
// 581.524 us; speedup vs baseline: 1.2304x; 1.0238x over previous
//
#include <hip/hip_runtime.h>
#include <hip/hip_bf16.h>
#include <hip/hip_fp16.h>

#define NN   100000
#define EE   1600000
#define ETOT (EE + NN)
#define GG   256
#define BNEPS 1e-5f
#define NBK  391          // buckets of 256 nodes: (NN+255)/256
#define PADTOT (ETOT + NBK * 4096 + 64)
#define PSPLIT 16

typedef float floatx2 __attribute__((ext_vector_type(2)));
typedef short s16x8 __attribute__((ext_vector_type(8)));
typedef float f32x4v __attribute__((ext_vector_type(4)));

__device__ __forceinline__ unsigned short f2bf(float f) {
    unsigned u = __float_as_uint(f);
    unsigned r = u + 0x7FFF + ((u >> 16) & 1);
    return (unsigned short)(r >> 16);
}
__device__ __forceinline__ float bf2f(unsigned short b) {
    return __uint_as_float(((unsigned)b) << 16);
}

// ---------------- CSR build: bucketed partition (single-writer cache lines) --

__global__ __launch_bounds__(256) void bucket_count_kernel(
    const int* __restrict__ ei, int* __restrict__ bucket_cnt)
{
    __shared__ int cnt[NBK];
    for (int i = threadIdx.x; i < NBK; i += 256) cnt[i] = 0;
    __syncthreads();
    int base = blockIdx.x * 8192;
    for (int k = threadIdx.x; k < 8192; k += 256) {
        int e = base + k;
        if (e < ETOT) {
            int dst = (e < EE) ? ei[EE + e] : (e - EE);
            atomicAdd(&cnt[dst >> 8], 1);
        }
    }
    __syncthreads();
    for (int i = threadIdx.x; i < NBK; i += 256)
        if (cnt[i]) atomicAdd(&bucket_cnt[i], cnt[i]);
}

// also plants the -inf esrc sentinel used by pad edges (src = NN)
__global__ __launch_bounds__(512) void bucket_scan_kernel(
    const int* __restrict__ bucket_cnt, int* __restrict__ bucket_base,
    int* __restrict__ gcursor, float* __restrict__ esrcs)
{
    __shared__ int s[512];
    int t = threadIdx.x;
    int v = (t < NBK) ? bucket_cnt[t] : 0;
    s[t] = v;
    __syncthreads();
    int x = v;
    for (int o = 1; o < 512; o <<= 1) {
        int y = (t >= o) ? s[t - o] : 0;
        __syncthreads();
        x += y;
        s[t] = x;
        __syncthreads();
    }
    if (t < NBK) { bucket_base[t] = x - v; gcursor[t] = x - v; }
    if (t == 0) {
        bucket_base[NBK] = ETOT;
        esrcs[2 * NN]     = __int_as_float(0xFF800000);  // -inf
        esrcs[2 * NN + 1] = __int_as_float(0xFF800000);
    }
}

__global__ __launch_bounds__(256) void partition_kernel(
    const int* __restrict__ ei, int* __restrict__ gcursor, int* __restrict__ part)
{
    __shared__ int cnt[NBK];
    __shared__ int basel[NBK];
    for (int i = threadIdx.x; i < NBK; i += 256) cnt[i] = 0;
    __syncthreads();
    int base = blockIdx.x * 4096;
    for (int k = threadIdx.x; k < 4096; k += 256) {
        int e = base + k;
        if (e < ETOT) {
            int dst = (e < EE) ? ei[EE + e] : (e - EE);
            atomicAdd(&cnt[dst >> 8], 1);
        }
    }
    __syncthreads();
    for (int i = threadIdx.x; i < NBK; i += 256) {
        int c = cnt[i];
        basel[i] = c ? atomicAdd(&gcursor[i], c) : 0;
        cnt[i] = 0;   // reuse as intra-block cursor
    }
    __syncthreads();
    for (int k = threadIdx.x; k < 4096; k += 256) {
        int e = base + k;
        if (e < ETOT) {
            int src, dst;
            if (e < EE) { src = ei[e]; dst = ei[EE + e]; }
            else        { src = e - EE; dst = e - EE; }
            int b = dst >> 8;
            int slot = atomicAdd(&cnt[b], 1);
            part[basel[b] + slot] = src | ((dst & 255) << 17);
        }
    }
}

// Padded CSR: per-node segments rounded up to 16 entries, pad src = NN
// (sentinel: esrc[NN] = -inf → exp weight 0; pads gather the L1-hot NN row).
__global__ __launch_bounds__(256) void csr_build_kernel(
    const int* __restrict__ part, const int* __restrict__ bucket_base,
    int* __restrict__ row2_start, int* __restrict__ row2_deg,
    int* __restrict__ csr2_src)
{
    __shared__ int degs[256];
    __shared__ int sc[256];
    __shared__ int cur[256];
    int b = blockIdx.x;
    int t = threadIdx.x;
    int beg = bucket_base[b], end = bucket_base[b + 1];
    int pbase = ((beg + 15) & ~15) + 4096 * b;
    degs[t] = 0;
    __syncthreads();
    for (int j = beg + t; j < end; j += 256)
        atomicAdd(&degs[(part[j] >> 17) & 255], 1);
    __syncthreads();
    int dg = degs[t];
    int pdeg = (dg + 15) & ~15;
    sc[t] = pdeg;
    __syncthreads();
    int x = pdeg;
    for (int o = 1; o < 256; o <<= 1) {
        int y = (t >= o) ? sc[t - o] : 0;
        __syncthreads();
        x += y;
        sc[t] = x;
        __syncthreads();
    }
    int start2 = pbase + (x - pdeg);
    int node = b * 256 + t;
    if (node < NN) { row2_start[node] = start2; row2_deg[node] = dg; }
    cur[t] = start2;
    __syncthreads();
    for (int j = beg + t; j < end; j += 256) {
        int pv = part[j];
        int pos = atomicAdd(&cur[(pv >> 17) & 255], 1);
        csr2_src[pos] = pv & 0x1FFFF;
    }
    for (int k = dg; k < pdeg; ++k) csr2_src[start2 + k] = NN;
}

// ---------------- fused BN coefficient prep: sc = g*rsqrt(v+eps),
// sh = (bias - m)*sc + b.  Layer1: 64; layers 2,3: 128.

__global__ __launch_bounds__(128) void prep_bn_kernel(
    const float* b1, const float* g1, const float* be1, const float* m1, const float* v1,
    const float* b2, const float* g2, const float* be2, const float* m2, const float* v2,
    const float* b3, const float* g3, const float* be3, const float* m3, const float* v3,
    float* sc1, float* sh1, float* sc2, float* sh2, float* sc3, float* sh3)
{
    int t = threadIdx.x;
    if (t < 64) {
        float sc = g1[t] * rsqrtf(v1[t] + BNEPS);
        sc1[t] = sc;
        sh1[t] = (b1[t] - m1[t]) * sc + be1[t];
    }
    {
        float sc = g2[t] * rsqrtf(v2[t] + BNEPS);
        sc2[t] = sc;
        sh2[t] = (b2[t] - m2[t]) * sc + be2[t];
    }
    {
        float sc = g3[t] * rsqrtf(v3[t] + BNEPS);
        sc3[t] = sc;
        sh3[t] = (b3[t] - m3[t]) * sc + be3[t];
    }
}

// ---------------- per-layer edge softmax weights (packed 2×bf16) -------------

__global__ __launch_bounds__(256) void edgew_kernel(
    const int* __restrict__ csr2_src, const int* __restrict__ row2_start,
    const int* __restrict__ row2_deg,
    const float2* __restrict__ esrc, const float2* __restrict__ edst,
    unsigned* __restrict__ csr_w, int nN)
{
    int n = blockIdx.x * 4 + (threadIdx.x >> 6);
    int lane = threadIdx.x & 63;
    if (n >= nN) return;
    float2 ed = edst[n];
    int s2 = row2_start[n];
    int dg = row2_deg[n];
    int pc = (dg + 15) & ~15;
    for (int j = lane; j < pc; j += 64) {
        int i = csr2_src[s2 + j];
        float2 es = esrc[i];
        float a0 = es.x + ed.x; a0 = (a0 > 0.f) ? a0 : 0.2f * a0;
        float a1 = es.y + ed.y; a1 = (a1 > 0.f) ? a1 : 0.2f * a1;
        unsigned w = (unsigned)f2bf(__expf(a0)) | ((unsigned)f2bf(__expf(a1)) << 16);
        csr_w[s2 + j] = w;
    }
}

// ---------------- layer-1 feature transform (K=5); h fp8, rout bf16 ----------

__global__ __launch_bounds__(256) void feat1_kernel(
    const float* __restrict__ xin, const float* __restrict__ W,
    const float* __restrict__ pw, const float* __restrict__ pb,
    const float* __restrict__ a_src, const float* __restrict__ a_dst,
    unsigned char* __restrict__ h8, float* __restrict__ esrc, float* __restrict__ edst,
    unsigned short* __restrict__ rout16, int nN)
{
    constexpr int F_IN = 5, F_OUT = 64;
    int t = threadIdx.x;
    int n = blockIdx.x * 4 + t / F_OUT;
    int f = t % F_OUT;
    if (n >= nN) return;
    float acc = 0.f, racc = 0.f;
#pragma unroll
    for (int k = 0; k < F_IN; ++k) {
        float xv = xin[n * F_IN + k];
        acc  += xv * W[k * F_OUT + f];
        racc += xv * pw[k * F_OUT + f];
    }
    float other = __shfl_xor(acc, 1, 64);
    if ((f & 1) == 0) {
        int p = __builtin_amdgcn_cvt_pk_fp8_f32(acc, other, 0, false);
        *(unsigned short*)(h8 + (size_t)n * F_OUT + f) = (unsigned short)(p & 0xFFFF);
    }
    rout16[(size_t)n * F_OUT + f] = f2bf(racc + pb[f]);
    float es = acc * a_src[f];
    float ed = acc * a_dst[f];
#pragma unroll
    for (int off = 16; off > 0; off >>= 1) {
        es += __shfl_xor(es, off, 32);
        ed += __shfl_xor(ed, off, 32);
    }
    if ((t & 31) == 0) {
        int head = (f >> 5) & 1;
        esrc[n * 2 + head] = es;
        edst[n * 2 + head] = ed;
    }
}

// ---------------- weight fragment prep (bf16 hi/lo split, MFMA B layout) -----

template<int K>
__global__ __launch_bounds__(256) void prep_w_kernel(
    const float* __restrict__ W, const float* __restrict__ pw,
    short* __restrict__ wfrag)
{
    constexpr int KS = K / 32;
    int unit = blockIdx.x * 256 + threadIdx.x;
    int total = 16 * KS * 2 * 64;
    if (unit >= total) return;
    int lane = unit & 63;
    int rest = unit >> 6;
    int hilo = rest & 1;
    int fk = rest >> 1;
    int ks = fk % KS;
    int nt = fk / KS;
    int n = nt * 16 + (lane & 15);
    int k0 = ks * 32 + (lane >> 4) * 8;
    const float* src = (n < 128) ? (W + n) : (pw + (n - 128));
    s16x8 out;
#pragma unroll
    for (int j = 0; j < 8; ++j) {
        float wv = src[(size_t)(k0 + j) * 128];
        unsigned short hi = f2bf(wv);
        if (hilo == 0) {
            out[j] = (short)hi;
        } else {
            float fhi = __uint_as_float(((unsigned)hi) << 16);
            out[j] = (short)f2bf(wv - fhi);
        }
    }
    *(s16x8*)(wfrag + (size_t)unit * 8) = out;
}

// ---------------- MFMA feature transform (layers 2,3; N=256 = W‖pw) ----------
// LDS-staged outputs (R15 win: no sub-word global stores).

template<int K>
__global__ __launch_bounds__(256) void mfma_feat_kernel(
    const unsigned short* __restrict__ xin16, const short* __restrict__ wfrag,
    const float* __restrict__ pb,
    const float* __restrict__ a_src, const float* __restrict__ a_dst,
    unsigned char* __restrict__ h8, float* __restrict__ esrc, float* __restrict__ edst,
    unsigned short* __restrict__ rout16)
{
    constexpr int KS = K / 32;    // MFMA k-steps
    constexpr int CH = K / 8;     // 8-feature (16 B) chunks per node row
    __shared__ __align__(16) char smem[53248];
    s16x8* xs = (s16x8*)smem;
    unsigned short* h8lds = (unsigned short*)smem;             // stride 72 ushorts
    unsigned short* rolds = (unsigned short*)(smem + 18432);   // stride 136 ushorts

    const int tid = threadIdx.x;
    const int base = blockIdx.x * 128;

    for (int idx = tid; idx < 128 * CH; idx += 256) {
        int node = idx / CH;
        int ch = idx % CH;
        int gn = base + node; if (gn > NN - 1) gn = NN - 1;
        s16x8 v = *(const s16x8*)(xin16 + (size_t)gn * K + ch * 8);
        int tt = node >> 4, mm = node & 15;
        xs[(tt * CH + ch) * 16 + mm] = v;
    }
    __syncthreads();

    const int w = tid >> 6;
    const int lane = tid & 63;
    const int quad = lane >> 4;
    const int m = lane & 15;
    const int l0 = w * 32 + quad * 4;   // local row, tile0 (+r)
    const int l1 = l0 + 16;             // local row, tile1 (+r)
    const int node0 = base + l0;
    const int node1 = base + l1;

    s16x8 a0[KS], a1[KS];
#pragma unroll
    for (int ks = 0; ks < KS; ++ks) {
        a0[ks] = xs[((w * 2 + 0) * CH + (ks * 4 + quad)) * 16 + m];
        a1[ks] = xs[((w * 2 + 1) * CH + (ks * 4 + quad)) * 16 + m];
    }
    __syncthreads();   // xs dead; smem becomes output tile

    float es0h0[4] = {0.f,0.f,0.f,0.f}, es0h1[4] = {0.f,0.f,0.f,0.f};
    float ed0h0[4] = {0.f,0.f,0.f,0.f}, ed0h1[4] = {0.f,0.f,0.f,0.f};
    float es1h0[4] = {0.f,0.f,0.f,0.f}, es1h1[4] = {0.f,0.f,0.f,0.f};
    float ed1h0[4] = {0.f,0.f,0.f,0.f}, ed1h1[4] = {0.f,0.f,0.f,0.f};

#pragma unroll
    for (int nt = 0; nt < 16; ++nt) {
        s16x8 b[2 * KS];
#pragma unroll
        for (int i = 0; i < 2 * KS; ++i)
            b[i] = *(const s16x8*)(wfrag + (size_t)((nt * KS * 2 + i) * 64 + lane) * 8);
        f32x4v c0 = {0.f, 0.f, 0.f, 0.f};
        f32x4v c1 = {0.f, 0.f, 0.f, 0.f};
#pragma unroll
        for (int ks = 0; ks < KS; ++ks) {
            c0 = __builtin_amdgcn_mfma_f32_16x16x32_bf16(a0[ks], b[2 * ks + 0], c0, 0, 0, 0);
            c1 = __builtin_amdgcn_mfma_f32_16x16x32_bf16(a1[ks], b[2 * ks + 0], c1, 0, 0, 0);
            c0 = __builtin_amdgcn_mfma_f32_16x16x32_bf16(a0[ks], b[2 * ks + 1], c0, 0, 0, 0);
            c1 = __builtin_amdgcn_mfma_f32_16x16x32_bf16(a1[ks], b[2 * ks + 1], c1, 0, 0, 0);
        }
        if (nt < 8) {
            int col = nt * 16 + m;
            float av = a_src[col], dv = a_dst[col];
#pragma unroll
            for (int r = 0; r < 4; ++r) {
                float v0 = c0[r], v1 = c1[r];
                if (nt < 4) {
                    es0h0[r] = fmaf(v0, av, es0h0[r]); ed0h0[r] = fmaf(v0, dv, ed0h0[r]);
                    es1h0[r] = fmaf(v1, av, es1h0[r]); ed1h0[r] = fmaf(v1, dv, ed1h0[r]);
                } else {
                    es0h1[r] = fmaf(v0, av, es0h1[r]); ed0h1[r] = fmaf(v0, dv, ed0h1[r]);
                    es1h1[r] = fmaf(v1, av, es1h1[r]); ed1h1[r] = fmaf(v1, dv, ed1h1[r]);
                }
                float p0 = __shfl_xor(v0, 1, 16);
                float p1 = __shfl_xor(v1, 1, 16);
                if ((m & 1) == 0) {
                    int us = nt * 8 + (m >> 1);   // ushort index within row
                    int pk0 = __builtin_amdgcn_cvt_pk_fp8_f32(v0, p0, 0, false);
                    int pk1 = __builtin_amdgcn_cvt_pk_fp8_f32(v1, p1, 0, false);
                    h8lds[(l0 + r) * 72 + us] = (unsigned short)(pk0 & 0xFFFF);
                    h8lds[(l1 + r) * 72 + us] = (unsigned short)(pk1 & 0xFFFF);
                }
            }
        } else {
            int col = (nt - 8) * 16 + m;
            float bv = pb[col];
#pragma unroll
            for (int r = 0; r < 4; ++r) {
                rolds[(l0 + r) * 136 + col] = f2bf(c0[r] + bv);
                rolds[(l1 + r) * 136 + col] = f2bf(c1[r] + bv);
            }
        }
    }

#pragma unroll
    for (int r = 0; r < 4; ++r) {
#pragma unroll
        for (int off = 8; off > 0; off >>= 1) {
            es0h0[r] += __shfl_xor(es0h0[r], off, 16);
            es0h1[r] += __shfl_xor(es0h1[r], off, 16);
            ed0h0[r] += __shfl_xor(ed0h0[r], off, 16);
            ed0h1[r] += __shfl_xor(ed0h1[r], off, 16);
            es1h0[r] += __shfl_xor(es1h0[r], off, 16);
            es1h1[r] += __shfl_xor(es1h1[r], off, 16);
            ed1h0[r] += __shfl_xor(ed1h0[r], off, 16);
            ed1h1[r] += __shfl_xor(ed1h1[r], off, 16);
        }
    }
    if (m == 0) {
#pragma unroll
        for (int r = 0; r < 4; ++r) {
            if (node0 + r < NN) {
                ((float2*)esrc)[node0 + r] = make_float2(es0h0[r], es0h1[r]);
                ((float2*)edst)[node0 + r] = make_float2(ed0h0[r], ed0h1[r]);
            }
            if (node1 + r < NN) {
                ((float2*)esrc)[node1 + r] = make_float2(es1h0[r], es1h1[r]);
                ((float2*)edst)[node1 + r] = make_float2(ed1h0[r], ed1h1[r]);
            }
        }
    }

    __syncthreads();
    for (int i = tid; i < 128 * 8; i += 256) {
        int row = i >> 3, ch = i & 7;
        int node = base + row;
        if (node < NN) {
            int4 v = *(const int4*)(smem + row * 144 + ch * 16);
            *(int4*)(h8 + (size_t)node * 128 + ch * 16) = v;
        }
    }
    for (int i = tid; i < 128 * 16; i += 256) {
        int row = i >> 4, ch = i & 15;
        int node = base + row;
        if (node < NN) {
            int4 v = *(const int4*)(smem + 18432 + row * 272 + ch * 16);
            *(int4*)((char*)rout16 + (size_t)node * 256 + ch * 16) = v;
        }
    }
}

// ---------------- fused aggregate, F=128 (half-wave dword gathers, unroll16) -
// Fused BN (sc/sh), 8 outstanding gathers per half-wave.

__global__ __launch_bounds__(256) void aggregate128_kernel(
    const unsigned char* __restrict__ h8,
    const int* __restrict__ row2_start, const int* __restrict__ row2_deg,
    const int* __restrict__ csr2_src, const unsigned* __restrict__ csr_w,
    const float* __restrict__ bnsc, const float* __restrict__ bnsh,
    unsigned short* __restrict__ io16, int nN)
{
    int w = threadIdx.x >> 6;
    int lane = threadIdx.x & 63;
    int n = blockIdx.x * 4 + w;
    if (n >= nN) return;
    bool hi32 = lane >= 32;
    int fl = lane & 31;
    bool headhi = (lane >> 4) & 1;
    int s2 = row2_start[n];
    int dg = row2_deg[n];
    int pc = (dg + 15) & ~15;
    const int4* sp = (const int4*)(csr2_src + s2);
    const uint4* wp = (const uint4*)(csr_w + s2);
    float s = 0.f, a0 = 0.f, a1 = 0.f, a2 = 0.f, a3 = 0.f;
    for (int j = 0; j < pc; j += 16) {
        int4 ia = sp[(j >> 2) + 0];
        int4 ib = sp[(j >> 2) + 1];
        int4 ic = sp[(j >> 2) + 2];
        int4 id = sp[(j >> 2) + 3];
        uint4 wa = wp[(j >> 2) + 0];
        uint4 wb = wp[(j >> 2) + 1];
        uint4 wc = wp[(j >> 2) + 2];
        uint4 wd = wp[(j >> 2) + 3];
        int i0 = hi32 ? ia.y : ia.x;
        int i1 = hi32 ? ia.w : ia.z;
        int i2 = hi32 ? ib.y : ib.x;
        int i3 = hi32 ? ib.w : ib.z;
        int i4 = hi32 ? ic.y : ic.x;
        int i5 = hi32 ? ic.w : ic.z;
        int i6 = hi32 ? id.y : id.x;
        int i7 = hi32 ? id.w : id.z;
        unsigned d0 = *(const unsigned*)(h8 + (size_t)i0 * 128 + fl * 4);
        unsigned d1 = *(const unsigned*)(h8 + (size_t)i1 * 128 + fl * 4);
        unsigned d2 = *(const unsigned*)(h8 + (size_t)i2 * 128 + fl * 4);
        unsigned d3 = *(const unsigned*)(h8 + (size_t)i3 * 128 + fl * 4);
        unsigned d4 = *(const unsigned*)(h8 + (size_t)i4 * 128 + fl * 4);
        unsigned d5 = *(const unsigned*)(h8 + (size_t)i5 * 128 + fl * 4);
        unsigned d6 = *(const unsigned*)(h8 + (size_t)i6 * 128 + fl * 4);
        unsigned d7 = *(const unsigned*)(h8 + (size_t)i7 * 128 + fl * 4);
        unsigned w0 = hi32 ? wa.y : wa.x;
        unsigned w1 = hi32 ? wa.w : wa.z;
        unsigned w2 = hi32 ? wb.y : wb.x;
        unsigned w3 = hi32 ? wb.w : wb.z;
        unsigned w4 = hi32 ? wc.y : wc.x;
        unsigned w5 = hi32 ? wc.w : wc.z;
        unsigned w6 = hi32 ? wd.y : wd.x;
        unsigned w7 = hi32 ? wd.w : wd.z;
        float g0 = __uint_as_float(headhi ? (w0 & 0xFFFF0000u) : (w0 << 16));
        float g1 = __uint_as_float(headhi ? (w1 & 0xFFFF0000u) : (w1 << 16));
        float g2 = __uint_as_float(headhi ? (w2 & 0xFFFF0000u) : (w2 << 16));
        float g3 = __uint_as_float(headhi ? (w3 & 0xFFFF0000u) : (w3 << 16));
        float g4 = __uint_as_float(headhi ? (w4 & 0xFFFF0000u) : (w4 << 16));
        float g5 = __uint_as_float(headhi ? (w5 & 0xFFFF0000u) : (w5 << 16));
        float g6 = __uint_as_float(headhi ? (w6 & 0xFFFF0000u) : (w6 << 16));
        float g7 = __uint_as_float(headhi ? (w7 & 0xFFFF0000u) : (w7 << 16));
        floatx2 lo0 = __builtin_amdgcn_cvt_pk_f32_fp8((int)d0, false);
        floatx2 hi0 = __builtin_amdgcn_cvt_pk_f32_fp8((int)d0, true);
        floatx2 lo1 = __builtin_amdgcn_cvt_pk_f32_fp8((int)d1, false);
        floatx2 hi1 = __builtin_amdgcn_cvt_pk_f32_fp8((int)d1, true);
        floatx2 lo2 = __builtin_amdgcn_cvt_pk_f32_fp8((int)d2, false);
        floatx2 hi2 = __builtin_amdgcn_cvt_pk_f32_fp8((int)d2, true);
        floatx2 lo3 = __builtin_amdgcn_cvt_pk_f32_fp8((int)d3, false);
        floatx2 hi3 = __builtin_amdgcn_cvt_pk_f32_fp8((int)d3, true);
        floatx2 lo4 = __builtin_amdgcn_cvt_pk_f32_fp8((int)d4, false);
        floatx2 hi4 = __builtin_amdgcn_cvt_pk_f32_fp8((int)d4, true);
        floatx2 lo5 = __builtin_amdgcn_cvt_pk_f32_fp8((int)d5, false);
        floatx2 hi5 = __builtin_amdgcn_cvt_pk_f32_fp8((int)d5, true);
        floatx2 lo6 = __builtin_amdgcn_cvt_pk_f32_fp8((int)d6, false);
        floatx2 hi6 = __builtin_amdgcn_cvt_pk_f32_fp8((int)d6, true);
        floatx2 lo7 = __builtin_amdgcn_cvt_pk_f32_fp8((int)d7, false);
        floatx2 hi7 = __builtin_amdgcn_cvt_pk_f32_fp8((int)d7, true);
        a0 = fmaf(g0, lo0.x, a0); a1 = fmaf(g0, lo0.y, a1);
        a2 = fmaf(g0, hi0.x, a2); a3 = fmaf(g0, hi0.y, a3);
        a0 = fmaf(g1, lo1.x, a0); a1 = fmaf(g1, lo1.y, a1);
        a2 = fmaf(g1, hi1.x, a2); a3 = fmaf(g1, hi1.y, a3);
        a0 = fmaf(g2, lo2.x, a0); a1 = fmaf(g2, lo2.y, a1);
        a2 = fmaf(g2, hi2.x, a2); a3 = fmaf(g2, hi2.y, a3);
        a0 = fmaf(g3, lo3.x, a0); a1 = fmaf(g3, lo3.y, a1);
        a2 = fmaf(g3, hi3.x, a2); a3 = fmaf(g3, hi3.y, a3);
        a0 = fmaf(g4, lo4.x, a0); a1 = fmaf(g4, lo4.y, a1);
        a2 = fmaf(g4, hi4.x, a2); a3 = fmaf(g4, hi4.y, a3);
        a0 = fmaf(g5, lo5.x, a0); a1 = fmaf(g5, lo5.y, a1);
        a2 = fmaf(g5, hi5.x, a2); a3 = fmaf(g5, hi5.y, a3);
        a0 = fmaf(g6, lo6.x, a0); a1 = fmaf(g6, lo6.y, a1);
        a2 = fmaf(g6, hi6.x, a2); a3 = fmaf(g6, hi6.y, a3);
        a0 = fmaf(g7, lo7.x, a0); a1 = fmaf(g7, lo7.y, a1);
        a2 = fmaf(g7, hi7.x, a2); a3 = fmaf(g7, hi7.y, a3);
        s += (((g0 + g1) + (g2 + g3)) + ((g4 + g5) + (g6 + g7)));
    }
    a0 += __shfl_xor(a0, 32);
    a1 += __shfl_xor(a1, 32);
    a2 += __shfl_xor(a2, 32);
    a3 += __shfl_xor(a3, 32);
    s  += __shfl_xor(s, 32);
    if (!hi32) {
        float inv = 1.f / (s + 1e-16f);
        int f0 = fl * 4;
        float4 sc = *(const float4*)(bnsc + f0);
        float4 sh = *(const float4*)(bnsh + f0);
        float o0 = fmaf(a0 * inv, sc.x, sh.x);
        float o1 = fmaf(a1 * inv, sc.y, sh.y);
        float o2 = fmaf(a2 * inv, sc.z, sh.z);
        float o3 = fmaf(a3 * inv, sc.w, sh.w);
        uint2* iop = (uint2*)(io16 + (size_t)n * 128 + f0);
        uint2 pu = *iop;
        float r0 = fmaxf(o0, 0.f) + __uint_as_float((pu.x & 0xFFFFu) << 16);
        float r1 = fmaxf(o1, 0.f) + __uint_as_float(pu.x & 0xFFFF0000u);
        float r2 = fmaxf(o2, 0.f) + __uint_as_float((pu.y & 0xFFFFu) << 16);
        float r3 = fmaxf(o3, 0.f) + __uint_as_float(pu.y & 0xFFFF0000u);
        uint2 ov;
        ov.x = (unsigned)f2bf(r0) | ((unsigned)f2bf(r1) << 16);
        ov.y = (unsigned)f2bf(r2) | ((unsigned)f2bf(r3) << 16);
        *iop = ov;
    }
}

// ---------------- fused aggregate, F=64 (quarter-wave dword gathers, u16) ----

__global__ __launch_bounds__(256) void aggregate64_kernel(
    const unsigned char* __restrict__ h8,
    const int* __restrict__ row2_start, const int* __restrict__ row2_deg,
    const int* __restrict__ csr2_src, const unsigned* __restrict__ csr_w,
    const float* __restrict__ bnsc, const float* __restrict__ bnsh,
    unsigned short* __restrict__ io16, int nN)
{
    int w = threadIdx.x >> 6;
    int lane = threadIdx.x & 63;
    int n = blockIdx.x * 4 + w;
    if (n >= nN) return;
    int qw = lane >> 4;
    int fl = lane & 15;
    bool headhi = (fl >> 3) & 1;
    int s2 = row2_start[n];
    int dg = row2_deg[n];
    int pc = (dg + 15) & ~15;
    const int4* sp = (const int4*)(csr2_src + s2);
    const uint4* wp = (const uint4*)(csr_w + s2);
    float s = 0.f, a0 = 0.f, a1 = 0.f, a2 = 0.f, a3 = 0.f;
    for (int j = 0; j < pc; j += 16) {
        int4 ia = sp[(j >> 2) + 0];
        int4 ib = sp[(j >> 2) + 1];
        int4 ic = sp[(j >> 2) + 2];
        int4 id = sp[(j >> 2) + 3];
        uint4 wa = wp[(j >> 2) + 0];
        uint4 wb = wp[(j >> 2) + 1];
        uint4 wc = wp[(j >> 2) + 2];
        uint4 wd = wp[(j >> 2) + 3];
        int i0 = (qw == 0) ? ia.x : (qw == 1) ? ia.y : (qw == 2) ? ia.z : ia.w;
        int i1 = (qw == 0) ? ib.x : (qw == 1) ? ib.y : (qw == 2) ? ib.z : ib.w;
        int i2 = (qw == 0) ? ic.x : (qw == 1) ? ic.y : (qw == 2) ? ic.z : ic.w;
        int i3 = (qw == 0) ? id.x : (qw == 1) ? id.y : (qw == 2) ? id.z : id.w;
        unsigned w0 = (qw == 0) ? wa.x : (qw == 1) ? wa.y : (qw == 2) ? wa.z : wa.w;
        unsigned w1 = (qw == 0) ? wb.x : (qw == 1) ? wb.y : (qw == 2) ? wb.z : wb.w;
        unsigned w2 = (qw == 0) ? wc.x : (qw == 1) ? wc.y : (qw == 2) ? wc.z : wc.w;
        unsigned w3 = (qw == 0) ? wd.x : (qw == 1) ? wd.y : (qw == 2) ? wd.z : wd.w;
        unsigned d0 = *(const unsigned*)(h8 + (size_t)i0 * 64 + fl * 4);
        unsigned d1 = *(const unsigned*)(h8 + (size_t)i1 * 64 + fl * 4);
        unsigned d2 = *(const unsigned*)(h8 + (size_t)i2 * 64 + fl * 4);
        unsigned d3 = *(const unsigned*)(h8 + (size_t)i3 * 64 + fl * 4);
        float g0 = __uint_as_float(headhi ? (w0 & 0xFFFF0000u) : (w0 << 16));
        float g1 = __uint_as_float(headhi ? (w1 & 0xFFFF0000u) : (w1 << 16));
        float g2 = __uint_as_float(headhi ? (w2 & 0xFFFF0000u) : (w2 << 16));
        float g3 = __uint_as_float(headhi ? (w3 & 0xFFFF0000u) : (w3 << 16));
        floatx2 lo0 = __builtin_amdgcn_cvt_pk_f32_fp8((int)d0, false);
        floatx2 hi0 = __builtin_amdgcn_cvt_pk_f32_fp8((int)d0, true);
        floatx2 lo1 = __builtin_amdgcn_cvt_pk_f32_fp8((int)d1, false);
        floatx2 hi1 = __builtin_amdgcn_cvt_pk_f32_fp8((int)d1, true);
        floatx2 lo2 = __builtin_amdgcn_cvt_pk_f32_fp8((int)d2, false);
        floatx2 hi2 = __builtin_amdgcn_cvt_pk_f32_fp8((int)d2, true);
        floatx2 lo3 = __builtin_amdgcn_cvt_pk_f32_fp8((int)d3, false);
        floatx2 hi3 = __builtin_amdgcn_cvt_pk_f32_fp8((int)d3, true);
        a0 = fmaf(g0, lo0.x, a0); a1 = fmaf(g0, lo0.y, a1);
        a2 = fmaf(g0, hi0.x, a2); a3 = fmaf(g0, hi0.y, a3);
        a0 = fmaf(g1, lo1.x, a0); a1 = fmaf(g1, lo1.y, a1);
        a2 = fmaf(g1, hi1.x, a2); a3 = fmaf(g1, hi1.y, a3);
        a0 = fmaf(g2, lo2.x, a0); a1 = fmaf(g2, lo2.y, a1);
        a2 = fmaf(g2, hi2.x, a2); a3 = fmaf(g2, hi2.y, a3);
        a0 = fmaf(g3, lo3.x, a0); a1 = fmaf(g3, lo3.y, a1);
        a2 = fmaf(g3, hi3.x, a2); a3 = fmaf(g3, hi3.y, a3);
        s += ((g0 + g1) + (g2 + g3));
    }
    a0 += __shfl_xor(a0, 16); a0 += __shfl_xor(a0, 32);
    a1 += __shfl_xor(a1, 16); a1 += __shfl_xor(a1, 32);
    a2 += __shfl_xor(a2, 16); a2 += __shfl_xor(a2, 32);
    a3 += __shfl_xor(a3, 16); a3 += __shfl_xor(a3, 32);
    s  += __shfl_xor(s, 16);  s  += __shfl_xor(s, 32);
    if (lane < 16) {
        float inv = 1.f / (s + 1e-16f);
        int f0 = fl * 4;
        float4 sc = *(const float4*)(bnsc + f0);
        float4 sh = *(const float4*)(bnsh + f0);
        float o0 = fmaf(a0 * inv, sc.x, sh.x);
        float o1 = fmaf(a1 * inv, sc.y, sh.y);
        float o2 = fmaf(a2 * inv, sc.z, sh.z);
        float o3 = fmaf(a3 * inv, sc.w, sh.w);
        uint2* iop = (uint2*)(io16 + (size_t)n * 64 + f0);
        uint2 pu = *iop;
        float r0 = fmaxf(o0, 0.f) + __uint_as_float((pu.x & 0xFFFFu) << 16);
        float r1 = fmaxf(o1, 0.f) + __uint_as_float(pu.x & 0xFFFF0000u);
        float r2 = fmaxf(o2, 0.f) + __uint_as_float((pu.y & 0xFFFFu) << 16);
        float r3 = fmaxf(o3, 0.f) + __uint_as_float(pu.y & 0xFFFF0000u);
        uint2 ov;
        ov.x = (unsigned)f2bf(r0) | ((unsigned)f2bf(r1) << 16);
        ov.y = (unsigned)f2bf(r2) | ((unsigned)f2bf(r3) << 16);
        *iop = ov;
    }
}

// ---------------- pooling, two-phase (bf16 input) ----------------

__global__ __launch_bounds__(128) void pool_partial_kernel(
    const unsigned short* __restrict__ hf16, const int* __restrict__ batch,
    float* __restrict__ ppart)
{
    int g = blockIdx.x / PSPLIT;
    int p = blockIdx.x % PSPLIT;
    int f = threadIdx.x;
    int lo = 0, hi = NN;
    while (lo < hi) { int mid = (lo + hi) >> 1; if (batch[mid] < g) lo = mid + 1; else hi = mid; }
    int start = lo;
    hi = NN;
    while (lo < hi) { int mid = (lo + hi) >> 1; if (batch[mid] < g + 1) lo = mid + 1; else hi = mid; }
    int end = lo;
    int len = end - start;
    int chunk = (len + PSPLIT - 1) / PSPLIT;
    int i0 = start + p * chunk;
    int i1 = i0 + chunk; if (i1 > end) i1 = end;
    float acc = 0.f;
    for (int i = i0; i < i1; ++i) acc += bf2f(hf16[(size_t)i * 128 + f]);
    ppart[((size_t)g * PSPLIT + p) * 128 + f] = acc;
}

// ---------------- MLP head (folds partial-sum reduce + mean) -----------------

__global__ __launch_bounds__(128) void head_kernel(
    const float* __restrict__ ppart, const int* __restrict__ batch,
    const float* __restrict__ fw, const float* __restrict__ fb,
    const float* __restrict__ g4, const float* __restrict__ be4,
    const float* __restrict__ m4, const float* __restrict__ v4,
    const float* __restrict__ l1w, const float* __restrict__ l1b,
    const float* __restrict__ l2w, const float* __restrict__ l2b,
    float* __restrict__ out)
{
    __shared__ float p[128];
    __shared__ float z1[32];
    __shared__ float z2[32];
    int g = blockIdx.x, t = threadIdx.x;
    int lo = 0, hi = NN;
    while (lo < hi) { int mid = (lo + hi) >> 1; if (batch[mid] < g) lo = mid + 1; else hi = mid; }
    int start = lo;
    hi = NN;
    while (lo < hi) { int mid = (lo + hi) >> 1; if (batch[mid] < g + 1) lo = mid + 1; else hi = mid; }
    float cnt = (float)(lo - start);
    float acc = 0.f;
#pragma unroll
    for (int q = 0; q < PSPLIT; ++q)
        acc += ppart[((size_t)g * PSPLIT + q) * 128 + t];
    p[t] = acc / fmaxf(cnt, 1.0f);
    __syncthreads();
    if (t < 32) {
        float a = fb[t];
        for (int k = 0; k < 128; ++k) a += p[k] * fw[k * 32 + t];
        float val = g4[t] * (a - m4[t]) * rsqrtf(v4[t] + BNEPS) + be4[t];
        z1[t] = fmaxf(val, 0.f);
    }
    __syncthreads();
    if (t < 32) {
        float a = l1b[t];
        for (int k = 0; k < 32; ++k) a += z1[k] * l1w[k * 32 + t];
        z2[t] = fmaxf(a, 0.f);
    }
    __syncthreads();
    if (t < 10) {
        float a = l2b[t];
        for (int k = 0; k < 32; ++k) a += z2[k] * l2w[k * 10 + t];
        out[g * 10 + t] = a;
    }
}

// ---------------- launch ----------------

extern "C" void kernel_launch(void* const* d_in, const int* in_sizes, int n_in,
                              void* d_out, int out_size, void* d_ws, size_t ws_size,
                              hipStream_t stream) {
    const float* x     = (const float*)d_in[0];
    const int*   ei    = (const int*)d_in[1];
    const int*   batch = (const int*)d_in[2];
    const float* w1  = (const float*)d_in[3];
    const float* as1 = (const float*)d_in[4];
    const float* ad1 = (const float*)d_in[5];
    const float* b1  = (const float*)d_in[6];
    const float* g1  = (const float*)d_in[7];
    const float* be1 = (const float*)d_in[8];
    const float* m1  = (const float*)d_in[9];
    const float* v1  = (const float*)d_in[10];
    const float* p1w = (const float*)d_in[11];
    const float* p1b = (const float*)d_in[12];
    const float* w2  = (const float*)d_in[13];
    const float* as2 = (const float*)d_in[14];
    const float* ad2 = (const float*)d_in[15];
    const float* b2  = (const float*)d_in[16];
    const float* g2  = (const float*)d_in[17];
    const float* be2 = (const float*)d_in[18];
    const float* m2  = (const float*)d_in[19];
    const float* v2  = (const float*)d_in[20];
    const float* p2w = (const float*)d_in[21];
    const float* p2b = (const float*)d_in[22];
    const float* w3  = (const float*)d_in[23];
    const float* as3 = (const float*)d_in[24];
    const float* ad3 = (const float*)d_in[25];
    const float* b3  = (const float*)d_in[26];
    const float* g3  = (const float*)d_in[27];
    const float* be3 = (const float*)d_in[28];
    const float* m3  = (const float*)d_in[29];
    const float* v3  = (const float*)d_in[30];
    const float* p3w = (const float*)d_in[31];
    const float* p3b = (const float*)d_in[32];
    const float* fw  = (const float*)d_in[33];
    const float* fb  = (const float*)d_in[34];
    const float* g4  = (const float*)d_in[35];
    const float* be4 = (const float*)d_in[36];
    const float* m4  = (const float*)d_in[37];
    const float* v4  = (const float*)d_in[38];
    const float* l1w = (const float*)d_in[39];
    const float* l1b = (const float*)d_in[40];
    const float* l2w = (const float*)d_in[41];
    const float* l2b = (const float*)d_in[42];

    char* ws = (char*)d_ws;
    size_t off = 0;
    auto alloc = [&](size_t bytes) -> char* {
        char* p = ws + off;
        off += (bytes + 255) & ~(size_t)255;
        return p;
    };
    int*    bucket_cnt  = (int*)alloc((NBK) * sizeof(int));
    int*    bucket_base = (int*)alloc((NBK + 1) * sizeof(int));
    int*    gcursor     = (int*)alloc((NBK) * sizeof(int));
    int*    part        = (int*)alloc((size_t)ETOT * sizeof(int));
    int*    row2_start  = (int*)alloc(NN * sizeof(int));
    int*    row2_deg    = (int*)alloc(NN * sizeof(int));
    int*    csr2_src    = (int*)alloc((size_t)PADTOT * sizeof(int));
    unsigned* csr_w     = (unsigned*)alloc((size_t)PADTOT * sizeof(unsigned));
    unsigned char*  h8  = (unsigned char*)alloc((size_t)(NN + 1) * 128);
    unsigned short* hb1 = (unsigned short*)alloc((size_t)NN * 64 * sizeof(short));
    unsigned short* hb2 = (unsigned short*)alloc((size_t)NN * 128 * sizeof(short));
    unsigned short* hb3 = (unsigned short*)alloc((size_t)NN * 128 * sizeof(short));
    float*  esrc        = (float*)alloc((size_t)(NN + 1) * 2 * sizeof(float));
    float*  edst        = (float*)alloc((size_t)NN * 2 * sizeof(float));
    float*  ppart       = (float*)alloc((size_t)GG * PSPLIT * 128 * sizeof(float));
    short*  wfrag2      = (short*)alloc((size_t)16 * 2 * 2 * 64 * 8 * sizeof(short));
    short*  wfrag3      = (short*)alloc((size_t)16 * 4 * 2 * 64 * 8 * sizeof(short));
    float*  bnsc1       = (float*)alloc(64 * sizeof(float));
    float*  bnsh1       = (float*)alloc(64 * sizeof(float));
    float*  bnsc2       = (float*)alloc(128 * sizeof(float));
    float*  bnsh2       = (float*)alloc(128 * sizeof(float));
    float*  bnsc3       = (float*)alloc(128 * sizeof(float));
    float*  bnsh3       = (float*)alloc(128 * sizeof(float));

    // ---- prep (independent of everything else) ----
    prep_w_kernel<64><<<16, 256, 0, stream>>>(w2, p2w, wfrag2);
    prep_w_kernel<128><<<32, 256, 0, stream>>>(w3, p3w, wfrag3);
    prep_bn_kernel<<<1, 128, 0, stream>>>(b1, g1, be1, m1, v1,
                                          b2, g2, be2, m2, v2,
                                          b3, g3, be3, m3, v3,
                                          bnsc1, bnsh1, bnsc2, bnsh2, bnsc3, bnsh3);

    // ---- CSR build (bucketed partition, padded-16 layout, NN sentinel) ----
    hipMemsetAsync(bucket_cnt, 0, NBK * sizeof(int), stream);
    bucket_count_kernel<<<(ETOT + 8191) / 8192, 256, 0, stream>>>(ei, bucket_cnt);
    bucket_scan_kernel<<<1, 512, 0, stream>>>(bucket_cnt, bucket_base, gcursor, esrc);
    partition_kernel<<<(ETOT + 4095) / 4096, 256, 0, stream>>>(ei, gcursor, part);
    csr_build_kernel<<<NBK, 256, 0, stream>>>(part, bucket_base, row2_start, row2_deg, csr2_src);

    // ---- layer 1: x[N,5] -> hb1[N,64] (bf16) ----
    feat1_kernel<<<(NN + 3) / 4, 256, 0, stream>>>(
        x, w1, p1w, p1b, as1, ad1, h8, esrc, edst, hb1, NN);
    edgew_kernel<<<(NN + 3) / 4, 256, 0, stream>>>(
        csr2_src, row2_start, row2_deg, (const float2*)esrc, (const float2*)edst, csr_w, NN);
    aggregate64_kernel<<<(NN + 3) / 4, 256, 0, stream>>>(
        h8, row2_start, row2_deg, csr2_src, csr_w, bnsc1, bnsh1, hb1, NN);

    // ---- layer 2: hb1 -> hb2[N,128] (bf16) ----
    mfma_feat_kernel<64><<<(NN + 127) / 128, 256, 0, stream>>>(
        hb1, wfrag2, p2b, as2, ad2, h8, esrc, edst, hb2);
    edgew_kernel<<<(NN + 3) / 4, 256, 0, stream>>>(
        csr2_src, row2_start, row2_deg, (const float2*)esrc, (const float2*)edst, csr_w, NN);
    aggregate128_kernel<<<(NN + 3) / 4, 256, 0, stream>>>(
        h8, row2_start, row2_deg, csr2_src, csr_w, bnsc2, bnsh2, hb2, NN);

    // ---- layer 3: hb2 -> hb3[N,128] (bf16) ----
    mfma_feat_kernel<128><<<(NN + 127) / 128, 256, 0, stream>>>(
        hb2, wfrag3, p3b, as3, ad3, h8, esrc, edst, hb3);
    edgew_kernel<<<(NN + 3) / 4, 256, 0, stream>>>(
        csr2_src, row2_start, row2_deg, (const float2*)esrc, (const float2*)edst, csr_w, NN);
    aggregate128_kernel<<<(NN + 3) / 4, 256, 0, stream>>>(
        h8, row2_start, row2_deg, csr2_src, csr_w, bnsc3, bnsh3, hb3, NN);

    // ---- pool (two-phase) + head ----
    pool_partial_kernel<<<GG * PSPLIT, 128, 0, stream>>>(hb3, batch, ppart);
    head_kernel<<<GG, 128, 0, stream>>>(ppart, batch, fw, fb, g4, be4, m4, v4,
                                        l1w, l1b, l2w, l2b, (float*)d_out);
}

// Round 18
// 557.990 us; speedup vs baseline: 1.2823x; 1.0422x over previous
//
#include <hip/hip_runtime.h>
#include <hip/hip_bf16.h>
#include <hip/hip_fp16.h>

#define NN   100000
#define EE   1600000
#define ETOT (EE + NN)
#define GG   256
#define BNEPS 1e-5f
#define NBK  391          // buckets of 256 nodes: (NN+255)/256
#define PADTOT (ETOT + NBK * 4096 + 64)
#define PSPLIT 16

typedef float floatx2 __attribute__((ext_vector_type(2)));
typedef short s16x8 __attribute__((ext_vector_type(8)));
typedef float f32x4v __attribute__((ext_vector_type(4)));

__device__ __forceinline__ unsigned short f2bf(float f) {
    unsigned u = __float_as_uint(f);
    unsigned r = u + 0x7FFF + ((u >> 16) & 1);
    return (unsigned short)(r >> 16);
}
__device__ __forceinline__ float bf2f(unsigned short b) {
    return __uint_as_float(((unsigned)b) << 16);
}

// ---------------- CSR build: bucketed partition (single-writer cache lines) --

__global__ __launch_bounds__(256) void bucket_count_kernel(
    const int* __restrict__ ei, int* __restrict__ bucket_cnt)
{
    __shared__ int cnt[NBK];
    for (int i = threadIdx.x; i < NBK; i += 256) cnt[i] = 0;
    __syncthreads();
    int base = blockIdx.x * 8192;
    for (int k = threadIdx.x; k < 8192; k += 256) {
        int e = base + k;
        if (e < ETOT) {
            int dst = (e < EE) ? ei[EE + e] : (e - EE);
            atomicAdd(&cnt[dst >> 8], 1);
        }
    }
    __syncthreads();
    for (int i = threadIdx.x; i < NBK; i += 256)
        if (cnt[i]) atomicAdd(&bucket_cnt[i], cnt[i]);
}

// also plants the -inf esrc sentinel used by pad edges (src = NN)
__global__ __launch_bounds__(512) void bucket_scan_kernel(
    const int* __restrict__ bucket_cnt, int* __restrict__ bucket_base,
    int* __restrict__ gcursor, float* __restrict__ esrcs)
{
    __shared__ int s[512];
    int t = threadIdx.x;
    int v = (t < NBK) ? bucket_cnt[t] : 0;
    s[t] = v;
    __syncthreads();
    int x = v;
    for (int o = 1; o < 512; o <<= 1) {
        int y = (t >= o) ? s[t - o] : 0;
        __syncthreads();
        x += y;
        s[t] = x;
        __syncthreads();
    }
    if (t < NBK) { bucket_base[t] = x - v; gcursor[t] = x - v; }
    if (t == 0) {
        bucket_base[NBK] = ETOT;
        esrcs[2 * NN]     = __int_as_float(0xFF800000);  // -inf
        esrcs[2 * NN + 1] = __int_as_float(0xFF800000);
    }
}

__global__ __launch_bounds__(256) void partition_kernel(
    const int* __restrict__ ei, int* __restrict__ gcursor, int* __restrict__ part)
{
    __shared__ int cnt[NBK];
    __shared__ int basel[NBK];
    for (int i = threadIdx.x; i < NBK; i += 256) cnt[i] = 0;
    __syncthreads();
    int base = blockIdx.x * 4096;
    for (int k = threadIdx.x; k < 4096; k += 256) {
        int e = base + k;
        if (e < ETOT) {
            int dst = (e < EE) ? ei[EE + e] : (e - EE);
            atomicAdd(&cnt[dst >> 8], 1);
        }
    }
    __syncthreads();
    for (int i = threadIdx.x; i < NBK; i += 256) {
        int c = cnt[i];
        basel[i] = c ? atomicAdd(&gcursor[i], c) : 0;
        cnt[i] = 0;   // reuse as intra-block cursor
    }
    __syncthreads();
    for (int k = threadIdx.x; k < 4096; k += 256) {
        int e = base + k;
        if (e < ETOT) {
            int src, dst;
            if (e < EE) { src = ei[e]; dst = ei[EE + e]; }
            else        { src = e - EE; dst = e - EE; }
            int b = dst >> 8;
            int slot = atomicAdd(&cnt[b], 1);
            part[basel[b] + slot] = src | ((dst & 255) << 17);
        }
    }
}

// Padded CSR: per-node segments rounded up to 16 entries, pad src = NN
// (sentinel: esrc[NN] = -inf → exp weight 0; pads gather the L1-hot NN row).
__global__ __launch_bounds__(256) void csr_build_kernel(
    const int* __restrict__ part, const int* __restrict__ bucket_base,
    int* __restrict__ row2_start, int* __restrict__ row2_deg,
    int* __restrict__ csr2_src)
{
    __shared__ int degs[256];
    __shared__ int sc[256];
    __shared__ int cur[256];
    int b = blockIdx.x;
    int t = threadIdx.x;
    int beg = bucket_base[b], end = bucket_base[b + 1];
    int pbase = ((beg + 15) & ~15) + 4096 * b;
    degs[t] = 0;
    __syncthreads();
    for (int j = beg + t; j < end; j += 256)
        atomicAdd(&degs[(part[j] >> 17) & 255], 1);
    __syncthreads();
    int dg = degs[t];
    int pdeg = (dg + 15) & ~15;
    sc[t] = pdeg;
    __syncthreads();
    int x = pdeg;
    for (int o = 1; o < 256; o <<= 1) {
        int y = (t >= o) ? sc[t - o] : 0;
        __syncthreads();
        x += y;
        sc[t] = x;
        __syncthreads();
    }
    int start2 = pbase + (x - pdeg);
    int node = b * 256 + t;
    if (node < NN) { row2_start[node] = start2; row2_deg[node] = dg; }
    cur[t] = start2;
    __syncthreads();
    for (int j = beg + t; j < end; j += 256) {
        int pv = part[j];
        int pos = atomicAdd(&cur[(pv >> 17) & 255], 1);
        csr2_src[pos] = pv & 0x1FFFF;
    }
    for (int k = dg; k < pdeg; ++k) csr2_src[start2 + k] = NN;
}

// ---------------- merged prep: W-fragments (both layers) + fused BN ----------

template<int K>
__device__ __forceinline__ void prep_w_body(
    int unit, const float* __restrict__ W, const float* __restrict__ pw,
    short* __restrict__ wfrag)
{
    constexpr int KS = K / 32;
    int total = 16 * KS * 2 * 64;
    if (unit >= total) return;
    int lane = unit & 63;
    int rest = unit >> 6;
    int hilo = rest & 1;
    int fk = rest >> 1;
    int ks = fk % KS;
    int nt = fk / KS;
    int n = nt * 16 + (lane & 15);
    int k0 = ks * 32 + (lane >> 4) * 8;
    const float* src = (n < 128) ? (W + n) : (pw + (n - 128));
    s16x8 out;
#pragma unroll
    for (int j = 0; j < 8; ++j) {
        float wv = src[(size_t)(k0 + j) * 128];
        unsigned short hi = f2bf(wv);
        if (hilo == 0) {
            out[j] = (short)hi;
        } else {
            float fhi = __uint_as_float(((unsigned)hi) << 16);
            out[j] = (short)f2bf(wv - fhi);
        }
    }
    *(s16x8*)(wfrag + (size_t)unit * 8) = out;
}

__global__ __launch_bounds__(256) void prep_all_kernel(
    const float* __restrict__ w2, const float* __restrict__ p2w, short* __restrict__ wfrag2,
    const float* __restrict__ w3, const float* __restrict__ p3w, short* __restrict__ wfrag3,
    const float* b1, const float* g1, const float* be1, const float* m1, const float* v1,
    const float* b2, const float* g2, const float* be2, const float* m2, const float* v2,
    const float* b3, const float* g3, const float* be3, const float* m3, const float* v3,
    float* sc1, float* sh1, float* sc2, float* sh2, float* sc3, float* sh3)
{
    int b = blockIdx.x;
    int tid = threadIdx.x;
    if (b < 16) {
        prep_w_body<64>(b * 256 + tid, w2, p2w, wfrag2);
    } else if (b < 48) {
        prep_w_body<128>((b - 16) * 256 + tid, w3, p3w, wfrag3);
    } else {
        int t = tid;
        if (t < 128) {
            if (t < 64) {
                float sc = g1[t] * rsqrtf(v1[t] + BNEPS);
                sc1[t] = sc;
                sh1[t] = (b1[t] - m1[t]) * sc + be1[t];
            }
            {
                float sc = g2[t] * rsqrtf(v2[t] + BNEPS);
                sc2[t] = sc;
                sh2[t] = (b2[t] - m2[t]) * sc + be2[t];
            }
            {
                float sc = g3[t] * rsqrtf(v3[t] + BNEPS);
                sc3[t] = sc;
                sh3[t] = (b3[t] - m3[t]) * sc + be3[t];
            }
        }
    }
}

// ---------------- per-layer edge softmax weights (packed 2×bf16) -------------

__global__ __launch_bounds__(256) void edgew_kernel(
    const int* __restrict__ csr2_src, const int* __restrict__ row2_start,
    const int* __restrict__ row2_deg,
    const float2* __restrict__ esrc, const float2* __restrict__ edst,
    unsigned* __restrict__ csr_w, int nN)
{
    int n = blockIdx.x * 4 + (threadIdx.x >> 6);
    int lane = threadIdx.x & 63;
    if (n >= nN) return;
    float2 ed = edst[n];
    int s2 = row2_start[n];
    int dg = row2_deg[n];
    int pc = (dg + 15) & ~15;
    for (int j = lane; j < pc; j += 64) {
        int i = csr2_src[s2 + j];
        float2 es = esrc[i];
        float a0 = es.x + ed.x; a0 = (a0 > 0.f) ? a0 : 0.2f * a0;
        float a1 = es.y + ed.y; a1 = (a1 > 0.f) ? a1 : 0.2f * a1;
        unsigned w = (unsigned)f2bf(__expf(a0)) | ((unsigned)f2bf(__expf(a1)) << 16);
        csr_w[s2 + j] = w;
    }
}

// ---------------- layer-1 feature transform (K=5); h fp8, rout bf16 ----------

__global__ __launch_bounds__(256) void feat1_kernel(
    const float* __restrict__ xin, const float* __restrict__ W,
    const float* __restrict__ pw, const float* __restrict__ pb,
    const float* __restrict__ a_src, const float* __restrict__ a_dst,
    unsigned char* __restrict__ h8, float* __restrict__ esrc, float* __restrict__ edst,
    unsigned short* __restrict__ rout16, int nN)
{
    constexpr int F_IN = 5, F_OUT = 64;
    int t = threadIdx.x;
    int n = blockIdx.x * 4 + t / F_OUT;
    int f = t % F_OUT;
    if (n >= nN) return;
    float acc = 0.f, racc = 0.f;
#pragma unroll
    for (int k = 0; k < F_IN; ++k) {
        float xv = xin[n * F_IN + k];
        acc  += xv * W[k * F_OUT + f];
        racc += xv * pw[k * F_OUT + f];
    }
    float other = __shfl_xor(acc, 1, 64);
    if ((f & 1) == 0) {
        int p = __builtin_amdgcn_cvt_pk_fp8_f32(acc, other, 0, false);
        *(unsigned short*)(h8 + (size_t)n * F_OUT + f) = (unsigned short)(p & 0xFFFF);
    }
    rout16[(size_t)n * F_OUT + f] = f2bf(racc + pb[f]);
    float es = acc * a_src[f];
    float ed = acc * a_dst[f];
#pragma unroll
    for (int off = 16; off > 0; off >>= 1) {
        es += __shfl_xor(es, off, 32);
        ed += __shfl_xor(ed, off, 32);
    }
    if ((t & 31) == 0) {
        int head = (f >> 5) & 1;
        esrc[n * 2 + head] = es;
        edst[n * 2 + head] = ed;
    }
}

// ---------------- MFMA feature transform (layers 2,3; N=256 = W‖pw) ----------
// LDS-staged outputs (R15 win: no sub-word global stores).

template<int K>
__global__ __launch_bounds__(256) void mfma_feat_kernel(
    const unsigned short* __restrict__ xin16, const short* __restrict__ wfrag,
    const float* __restrict__ pb,
    const float* __restrict__ a_src, const float* __restrict__ a_dst,
    unsigned char* __restrict__ h8, float* __restrict__ esrc, float* __restrict__ edst,
    unsigned short* __restrict__ rout16)
{
    constexpr int KS = K / 32;    // MFMA k-steps
    constexpr int CH = K / 8;     // 8-feature (16 B) chunks per node row
    __shared__ __align__(16) char smem[53248];
    s16x8* xs = (s16x8*)smem;
    unsigned short* h8lds = (unsigned short*)smem;             // stride 72 ushorts
    unsigned short* rolds = (unsigned short*)(smem + 18432);   // stride 136 ushorts

    const int tid = threadIdx.x;
    const int base = blockIdx.x * 128;

    for (int idx = tid; idx < 128 * CH; idx += 256) {
        int node = idx / CH;
        int ch = idx % CH;
        int gn = base + node; if (gn > NN - 1) gn = NN - 1;
        s16x8 v = *(const s16x8*)(xin16 + (size_t)gn * K + ch * 8);
        int tt = node >> 4, mm = node & 15;
        xs[(tt * CH + ch) * 16 + mm] = v;
    }
    __syncthreads();

    const int w = tid >> 6;
    const int lane = tid & 63;
    const int quad = lane >> 4;
    const int m = lane & 15;
    const int l0 = w * 32 + quad * 4;   // local row, tile0 (+r)
    const int l1 = l0 + 16;             // local row, tile1 (+r)
    const int node0 = base + l0;
    const int node1 = base + l1;

    s16x8 a0[KS], a1[KS];
#pragma unroll
    for (int ks = 0; ks < KS; ++ks) {
        a0[ks] = xs[((w * 2 + 0) * CH + (ks * 4 + quad)) * 16 + m];
        a1[ks] = xs[((w * 2 + 1) * CH + (ks * 4 + quad)) * 16 + m];
    }
    __syncthreads();   // xs dead; smem becomes output tile

    float es0h0[4] = {0.f,0.f,0.f,0.f}, es0h1[4] = {0.f,0.f,0.f,0.f};
    float ed0h0[4] = {0.f,0.f,0.f,0.f}, ed0h1[4] = {0.f,0.f,0.f,0.f};
    float es1h0[4] = {0.f,0.f,0.f,0.f}, es1h1[4] = {0.f,0.f,0.f,0.f};
    float ed1h0[4] = {0.f,0.f,0.f,0.f}, ed1h1[4] = {0.f,0.f,0.f,0.f};

#pragma unroll
    for (int nt = 0; nt < 16; ++nt) {
        s16x8 b[2 * KS];
#pragma unroll
        for (int i = 0; i < 2 * KS; ++i)
            b[i] = *(const s16x8*)(wfrag + (size_t)((nt * KS * 2 + i) * 64 + lane) * 8);
        f32x4v c0 = {0.f, 0.f, 0.f, 0.f};
        f32x4v c1 = {0.f, 0.f, 0.f, 0.f};
#pragma unroll
        for (int ks = 0; ks < KS; ++ks) {
            c0 = __builtin_amdgcn_mfma_f32_16x16x32_bf16(a0[ks], b[2 * ks + 0], c0, 0, 0, 0);
            c1 = __builtin_amdgcn_mfma_f32_16x16x32_bf16(a1[ks], b[2 * ks + 0], c1, 0, 0, 0);
            c0 = __builtin_amdgcn_mfma_f32_16x16x32_bf16(a0[ks], b[2 * ks + 1], c0, 0, 0, 0);
            c1 = __builtin_amdgcn_mfma_f32_16x16x32_bf16(a1[ks], b[2 * ks + 1], c1, 0, 0, 0);
        }
        if (nt < 8) {
            int col = nt * 16 + m;
            float av = a_src[col], dv = a_dst[col];
#pragma unroll
            for (int r = 0; r < 4; ++r) {
                float v0 = c0[r], v1 = c1[r];
                if (nt < 4) {
                    es0h0[r] = fmaf(v0, av, es0h0[r]); ed0h0[r] = fmaf(v0, dv, ed0h0[r]);
                    es1h0[r] = fmaf(v1, av, es1h0[r]); ed1h0[r] = fmaf(v1, dv, ed1h0[r]);
                } else {
                    es0h1[r] = fmaf(v0, av, es0h1[r]); ed0h1[r] = fmaf(v0, dv, ed0h1[r]);
                    es1h1[r] = fmaf(v1, av, es1h1[r]); ed1h1[r] = fmaf(v1, dv, ed1h1[r]);
                }
                float p0 = __shfl_xor(v0, 1, 16);
                float p1 = __shfl_xor(v1, 1, 16);
                if ((m & 1) == 0) {
                    int us = nt * 8 + (m >> 1);   // ushort index within row
                    int pk0 = __builtin_amdgcn_cvt_pk_fp8_f32(v0, p0, 0, false);
                    int pk1 = __builtin_amdgcn_cvt_pk_fp8_f32(v1, p1, 0, false);
                    h8lds[(l0 + r) * 72 + us] = (unsigned short)(pk0 & 0xFFFF);
                    h8lds[(l1 + r) * 72 + us] = (unsigned short)(pk1 & 0xFFFF);
                }
            }
        } else {
            int col = (nt - 8) * 16 + m;
            float bv = pb[col];
#pragma unroll
            for (int r = 0; r < 4; ++r) {
                rolds[(l0 + r) * 136 + col] = f2bf(c0[r] + bv);
                rolds[(l1 + r) * 136 + col] = f2bf(c1[r] + bv);
            }
        }
    }

#pragma unroll
    for (int r = 0; r < 4; ++r) {
#pragma unroll
        for (int off = 8; off > 0; off >>= 1) {
            es0h0[r] += __shfl_xor(es0h0[r], off, 16);
            es0h1[r] += __shfl_xor(es0h1[r], off, 16);
            ed0h0[r] += __shfl_xor(ed0h0[r], off, 16);
            ed0h1[r] += __shfl_xor(ed0h1[r], off, 16);
            es1h0[r] += __shfl_xor(es1h0[r], off, 16);
            es1h1[r] += __shfl_xor(es1h1[r], off, 16);
            ed1h0[r] += __shfl_xor(ed1h0[r], off, 16);
            ed1h1[r] += __shfl_xor(ed1h1[r], off, 16);
        }
    }
    if (m == 0) {
#pragma unroll
        for (int r = 0; r < 4; ++r) {
            if (node0 + r < NN) {
                ((float2*)esrc)[node0 + r] = make_float2(es0h0[r], es0h1[r]);
                ((float2*)edst)[node0 + r] = make_float2(ed0h0[r], ed0h1[r]);
            }
            if (node1 + r < NN) {
                ((float2*)esrc)[node1 + r] = make_float2(es1h0[r], es1h1[r]);
                ((float2*)edst)[node1 + r] = make_float2(ed1h0[r], ed1h1[r]);
            }
        }
    }

    __syncthreads();
    for (int i = tid; i < 128 * 8; i += 256) {
        int row = i >> 3, ch = i & 7;
        int node = base + row;
        if (node < NN) {
            int4 v = *(const int4*)(smem + row * 144 + ch * 16);
            *(int4*)(h8 + (size_t)node * 128 + ch * 16) = v;
        }
    }
    for (int i = tid; i < 128 * 16; i += 256) {
        int row = i >> 4, ch = i & 15;
        int node = base + row;
        if (node < NN) {
            int4 v = *(const int4*)(smem + 18432 + row * 272 + ch * 16);
            *(int4*)((char*)rout16 + (size_t)node * 256 + ch * 16) = v;
        }
    }
}

// ---------------- fused aggregate, F=128 (half-wave dword gathers, unroll16) -

__global__ __launch_bounds__(256) void aggregate128_kernel(
    const unsigned char* __restrict__ h8,
    const int* __restrict__ row2_start, const int* __restrict__ row2_deg,
    const int* __restrict__ csr2_src, const unsigned* __restrict__ csr_w,
    const float* __restrict__ bnsc, const float* __restrict__ bnsh,
    unsigned short* __restrict__ io16, int nN)
{
    int w = threadIdx.x >> 6;
    int lane = threadIdx.x & 63;
    int n = blockIdx.x * 4 + w;
    if (n >= nN) return;
    bool hi32 = lane >= 32;
    int fl = lane & 31;
    bool headhi = (lane >> 4) & 1;
    int s2 = row2_start[n];
    int dg = row2_deg[n];
    int pc = (dg + 15) & ~15;
    const int4* sp = (const int4*)(csr2_src + s2);
    const uint4* wp = (const uint4*)(csr_w + s2);
    float s = 0.f, a0 = 0.f, a1 = 0.f, a2 = 0.f, a3 = 0.f;
    for (int j = 0; j < pc; j += 16) {
        int4 ia = sp[(j >> 2) + 0];
        int4 ib = sp[(j >> 2) + 1];
        int4 ic = sp[(j >> 2) + 2];
        int4 id = sp[(j >> 2) + 3];
        uint4 wa = wp[(j >> 2) + 0];
        uint4 wb = wp[(j >> 2) + 1];
        uint4 wc = wp[(j >> 2) + 2];
        uint4 wd = wp[(j >> 2) + 3];
        int i0 = hi32 ? ia.y : ia.x;
        int i1 = hi32 ? ia.w : ia.z;
        int i2 = hi32 ? ib.y : ib.x;
        int i3 = hi32 ? ib.w : ib.z;
        int i4 = hi32 ? ic.y : ic.x;
        int i5 = hi32 ? ic.w : ic.z;
        int i6 = hi32 ? id.y : id.x;
        int i7 = hi32 ? id.w : id.z;
        unsigned d0 = *(const unsigned*)(h8 + (size_t)i0 * 128 + fl * 4);
        unsigned d1 = *(const unsigned*)(h8 + (size_t)i1 * 128 + fl * 4);
        unsigned d2 = *(const unsigned*)(h8 + (size_t)i2 * 128 + fl * 4);
        unsigned d3 = *(const unsigned*)(h8 + (size_t)i3 * 128 + fl * 4);
        unsigned d4 = *(const unsigned*)(h8 + (size_t)i4 * 128 + fl * 4);
        unsigned d5 = *(const unsigned*)(h8 + (size_t)i5 * 128 + fl * 4);
        unsigned d6 = *(const unsigned*)(h8 + (size_t)i6 * 128 + fl * 4);
        unsigned d7 = *(const unsigned*)(h8 + (size_t)i7 * 128 + fl * 4);
        unsigned w0 = hi32 ? wa.y : wa.x;
        unsigned w1 = hi32 ? wa.w : wa.z;
        unsigned w2 = hi32 ? wb.y : wb.x;
        unsigned w3 = hi32 ? wb.w : wb.z;
        unsigned w4 = hi32 ? wc.y : wc.x;
        unsigned w5 = hi32 ? wc.w : wc.z;
        unsigned w6 = hi32 ? wd.y : wd.x;
        unsigned w7 = hi32 ? wd.w : wd.z;
        float g0 = __uint_as_float(headhi ? (w0 & 0xFFFF0000u) : (w0 << 16));
        float g1 = __uint_as_float(headhi ? (w1 & 0xFFFF0000u) : (w1 << 16));
        float g2 = __uint_as_float(headhi ? (w2 & 0xFFFF0000u) : (w2 << 16));
        float g3 = __uint_as_float(headhi ? (w3 & 0xFFFF0000u) : (w3 << 16));
        float g4 = __uint_as_float(headhi ? (w4 & 0xFFFF0000u) : (w4 << 16));
        float g5 = __uint_as_float(headhi ? (w5 & 0xFFFF0000u) : (w5 << 16));
        float g6 = __uint_as_float(headhi ? (w6 & 0xFFFF0000u) : (w6 << 16));
        float g7 = __uint_as_float(headhi ? (w7 & 0xFFFF0000u) : (w7 << 16));
        floatx2 lo0 = __builtin_amdgcn_cvt_pk_f32_fp8((int)d0, false);
        floatx2 hi0 = __builtin_amdgcn_cvt_pk_f32_fp8((int)d0, true);
        floatx2 lo1 = __builtin_amdgcn_cvt_pk_f32_fp8((int)d1, false);
        floatx2 hi1 = __builtin_amdgcn_cvt_pk_f32_fp8((int)d1, true);
        floatx2 lo2 = __builtin_amdgcn_cvt_pk_f32_fp8((int)d2, false);
        floatx2 hi2 = __builtin_amdgcn_cvt_pk_f32_fp8((int)d2, true);
        floatx2 lo3 = __builtin_amdgcn_cvt_pk_f32_fp8((int)d3, false);
        floatx2 hi3 = __builtin_amdgcn_cvt_pk_f32_fp8((int)d3, true);
        floatx2 lo4 = __builtin_amdgcn_cvt_pk_f32_fp8((int)d4, false);
        floatx2 hi4 = __builtin_amdgcn_cvt_pk_f32_fp8((int)d4, true);
        floatx2 lo5 = __builtin_amdgcn_cvt_pk_f32_fp8((int)d5, false);
        floatx2 hi5 = __builtin_amdgcn_cvt_pk_f32_fp8((int)d5, true);
        floatx2 lo6 = __builtin_amdgcn_cvt_pk_f32_fp8((int)d6, false);
        floatx2 hi6 = __builtin_amdgcn_cvt_pk_f32_fp8((int)d6, true);
        floatx2 lo7 = __builtin_amdgcn_cvt_pk_f32_fp8((int)d7, false);
        floatx2 hi7 = __builtin_amdgcn_cvt_pk_f32_fp8((int)d7, true);
        a0 = fmaf(g0, lo0.x, a0); a1 = fmaf(g0, lo0.y, a1);
        a2 = fmaf(g0, hi0.x, a2); a3 = fmaf(g0, hi0.y, a3);
        a0 = fmaf(g1, lo1.x, a0); a1 = fmaf(g1, lo1.y, a1);
        a2 = fmaf(g1, hi1.x, a2); a3 = fmaf(g1, hi1.y, a3);
        a0 = fmaf(g2, lo2.x, a0); a1 = fmaf(g2, lo2.y, a1);
        a2 = fmaf(g2, hi2.x, a2); a3 = fmaf(g2, hi2.y, a3);
        a0 = fmaf(g3, lo3.x, a0); a1 = fmaf(g3, lo3.y, a1);
        a2 = fmaf(g3, hi3.x, a2); a3 = fmaf(g3, hi3.y, a3);
        a0 = fmaf(g4, lo4.x, a0); a1 = fmaf(g4, lo4.y, a1);
        a2 = fmaf(g4, hi4.x, a2); a3 = fmaf(g4, hi4.y, a3);
        a0 = fmaf(g5, lo5.x, a0); a1 = fmaf(g5, lo5.y, a1);
        a2 = fmaf(g5, hi5.x, a2); a3 = fmaf(g5, hi5.y, a3);
        a0 = fmaf(g6, lo6.x, a0); a1 = fmaf(g6, lo6.y, a1);
        a2 = fmaf(g6, hi6.x, a2); a3 = fmaf(g6, hi6.y, a3);
        a0 = fmaf(g7, lo7.x, a0); a1 = fmaf(g7, lo7.y, a1);
        a2 = fmaf(g7, hi7.x, a2); a3 = fmaf(g7, hi7.y, a3);
        s += (((g0 + g1) + (g2 + g3)) + ((g4 + g5) + (g6 + g7)));
    }
    a0 += __shfl_xor(a0, 32);
    a1 += __shfl_xor(a1, 32);
    a2 += __shfl_xor(a2, 32);
    a3 += __shfl_xor(a3, 32);
    s  += __shfl_xor(s, 32);
    if (!hi32) {
        float inv = 1.f / (s + 1e-16f);
        int f0 = fl * 4;
        float4 sc = *(const float4*)(bnsc + f0);
        float4 sh = *(const float4*)(bnsh + f0);
        float o0 = fmaf(a0 * inv, sc.x, sh.x);
        float o1 = fmaf(a1 * inv, sc.y, sh.y);
        float o2 = fmaf(a2 * inv, sc.z, sh.z);
        float o3 = fmaf(a3 * inv, sc.w, sh.w);
        uint2* iop = (uint2*)(io16 + (size_t)n * 128 + f0);
        uint2 pu = *iop;
        float r0 = fmaxf(o0, 0.f) + __uint_as_float((pu.x & 0xFFFFu) << 16);
        float r1 = fmaxf(o1, 0.f) + __uint_as_float(pu.x & 0xFFFF0000u);
        float r2 = fmaxf(o2, 0.f) + __uint_as_float((pu.y & 0xFFFFu) << 16);
        float r3 = fmaxf(o3, 0.f) + __uint_as_float(pu.y & 0xFFFF0000u);
        uint2 ov;
        ov.x = (unsigned)f2bf(r0) | ((unsigned)f2bf(r1) << 16);
        ov.y = (unsigned)f2bf(r2) | ((unsigned)f2bf(r3) << 16);
        *iop = ov;
    }
}

// ---------------- fused aggregate, F=64 (two nodes per wave) -----------------
// Half = node (lanes 0..31 node A, 32..63 node B); quarter within half = edge
// pair; 16 lanes cover the 64 B row. Per-node prologue/epilogue amortized ×2.
// NN = 100000 = 8 × 12500 → no bounds guards.

__global__ __launch_bounds__(256) void aggregate64_kernel(
    const unsigned char* __restrict__ h8,
    const int* __restrict__ row2_start, const int* __restrict__ row2_deg,
    const int* __restrict__ csr2_src, const unsigned* __restrict__ csr_w,
    const float* __restrict__ bnsc, const float* __restrict__ bnsh,
    unsigned short* __restrict__ io16)
{
    int w = threadIdx.x >> 6;
    int lane = threadIdx.x & 63;
    int half = lane >> 5;
    int hl = lane & 31;
    int q  = hl >> 4;                 // edge selector within pair
    int fl = hl & 15;                 // feature dword (features 4fl..4fl+3)
    bool headhi = (fl >> 3) & 1;
    int n = blockIdx.x * 8 + w * 2 + half;
    int s2 = row2_start[n];
    int dg = row2_deg[n];
    int pc = (dg + 15) & ~15;
    const int4* sp = (const int4*)(csr2_src + s2);
    const uint4* wp = (const uint4*)(csr_w + s2);
    float s = 0.f, a0 = 0.f, a1 = 0.f, a2 = 0.f, a3 = 0.f;
    for (int j = 0; j < pc; j += 8) {
        int4 ia = sp[(j >> 2) + 0];
        int4 ib = sp[(j >> 2) + 1];
        uint4 wa = wp[(j >> 2) + 0];
        uint4 wb = wp[(j >> 2) + 1];
        int i0 = q ? ia.y : ia.x;
        int i1 = q ? ia.w : ia.z;
        int i2 = q ? ib.y : ib.x;
        int i3 = q ? ib.w : ib.z;
        unsigned w0 = q ? wa.y : wa.x;
        unsigned w1 = q ? wa.w : wa.z;
        unsigned w2 = q ? wb.y : wb.x;
        unsigned w3 = q ? wb.w : wb.z;
        unsigned d0 = *(const unsigned*)(h8 + (size_t)i0 * 64 + fl * 4);
        unsigned d1 = *(const unsigned*)(h8 + (size_t)i1 * 64 + fl * 4);
        unsigned d2 = *(const unsigned*)(h8 + (size_t)i2 * 64 + fl * 4);
        unsigned d3 = *(const unsigned*)(h8 + (size_t)i3 * 64 + fl * 4);
        float g0 = __uint_as_float(headhi ? (w0 & 0xFFFF0000u) : (w0 << 16));
        float g1 = __uint_as_float(headhi ? (w1 & 0xFFFF0000u) : (w1 << 16));
        float g2 = __uint_as_float(headhi ? (w2 & 0xFFFF0000u) : (w2 << 16));
        float g3 = __uint_as_float(headhi ? (w3 & 0xFFFF0000u) : (w3 << 16));
        floatx2 lo0 = __builtin_amdgcn_cvt_pk_f32_fp8((int)d0, false);
        floatx2 hi0 = __builtin_amdgcn_cvt_pk_f32_fp8((int)d0, true);
        floatx2 lo1 = __builtin_amdgcn_cvt_pk_f32_fp8((int)d1, false);
        floatx2 hi1 = __builtin_amdgcn_cvt_pk_f32_fp8((int)d1, true);
        floatx2 lo2 = __builtin_amdgcn_cvt_pk_f32_fp8((int)d2, false);
        floatx2 hi2 = __builtin_amdgcn_cvt_pk_f32_fp8((int)d2, true);
        floatx2 lo3 = __builtin_amdgcn_cvt_pk_f32_fp8((int)d3, false);
        floatx2 hi3 = __builtin_amdgcn_cvt_pk_f32_fp8((int)d3, true);
        a0 = fmaf(g0, lo0.x, a0); a1 = fmaf(g0, lo0.y, a1);
        a2 = fmaf(g0, hi0.x, a2); a3 = fmaf(g0, hi0.y, a3);
        a0 = fmaf(g1, lo1.x, a0); a1 = fmaf(g1, lo1.y, a1);
        a2 = fmaf(g1, hi1.x, a2); a3 = fmaf(g1, hi1.y, a3);
        a0 = fmaf(g2, lo2.x, a0); a1 = fmaf(g2, lo2.y, a1);
        a2 = fmaf(g2, hi2.x, a2); a3 = fmaf(g2, hi2.y, a3);
        a0 = fmaf(g3, lo3.x, a0); a1 = fmaf(g3, lo3.y, a1);
        a2 = fmaf(g3, hi3.x, a2); a3 = fmaf(g3, hi3.y, a3);
        s += ((g0 + g1) + (g2 + g3));
    }
    // combine the two quarters within each half (xor 16 stays inside the half)
    a0 += __shfl_xor(a0, 16);
    a1 += __shfl_xor(a1, 16);
    a2 += __shfl_xor(a2, 16);
    a3 += __shfl_xor(a3, 16);
    s  += __shfl_xor(s, 16);
    if (hl < 16) {
        float inv = 1.f / (s + 1e-16f);
        int f0 = fl * 4;
        float4 sc = *(const float4*)(bnsc + f0);
        float4 sh = *(const float4*)(bnsh + f0);
        float o0 = fmaf(a0 * inv, sc.x, sh.x);
        float o1 = fmaf(a1 * inv, sc.y, sh.y);
        float o2 = fmaf(a2 * inv, sc.z, sh.z);
        float o3 = fmaf(a3 * inv, sc.w, sh.w);
        uint2* iop = (uint2*)(io16 + (size_t)n * 64 + f0);
        uint2 pu = *iop;
        float r0 = fmaxf(o0, 0.f) + __uint_as_float((pu.x & 0xFFFFu) << 16);
        float r1 = fmaxf(o1, 0.f) + __uint_as_float(pu.x & 0xFFFF0000u);
        float r2 = fmaxf(o2, 0.f) + __uint_as_float((pu.y & 0xFFFFu) << 16);
        float r3 = fmaxf(o3, 0.f) + __uint_as_float(pu.y & 0xFFFF0000u);
        uint2 ov;
        ov.x = (unsigned)f2bf(r0) | ((unsigned)f2bf(r1) << 16);
        ov.y = (unsigned)f2bf(r2) | ((unsigned)f2bf(r3) << 16);
        *iop = ov;
    }
}

// ---------------- pooling, two-phase (bf16 input) ----------------

__global__ __launch_bounds__(128) void pool_partial_kernel(
    const unsigned short* __restrict__ hf16, const int* __restrict__ batch,
    float* __restrict__ ppart)
{
    int g = blockIdx.x / PSPLIT;
    int p = blockIdx.x % PSPLIT;
    int f = threadIdx.x;
    int lo = 0, hi = NN;
    while (lo < hi) { int mid = (lo + hi) >> 1; if (batch[mid] < g) lo = mid + 1; else hi = mid; }
    int start = lo;
    hi = NN;
    while (lo < hi) { int mid = (lo + hi) >> 1; if (batch[mid] < g + 1) lo = mid + 1; else hi = mid; }
    int end = lo;
    int len = end - start;
    int chunk = (len + PSPLIT - 1) / PSPLIT;
    int i0 = start + p * chunk;
    int i1 = i0 + chunk; if (i1 > end) i1 = end;
    float acc = 0.f;
    for (int i = i0; i < i1; ++i) acc += bf2f(hf16[(size_t)i * 128 + f]);
    ppart[((size_t)g * PSPLIT + p) * 128 + f] = acc;
}

// ---------------- MLP head (folds partial-sum reduce + mean) -----------------

__global__ __launch_bounds__(128) void head_kernel(
    const float* __restrict__ ppart, const int* __restrict__ batch,
    const float* __restrict__ fw, const float* __restrict__ fb,
    const float* __restrict__ g4, const float* __restrict__ be4,
    const float* __restrict__ m4, const float* __restrict__ v4,
    const float* __restrict__ l1w, const float* __restrict__ l1b,
    const float* __restrict__ l2w, const float* __restrict__ l2b,
    float* __restrict__ out)
{
    __shared__ float p[128];
    __shared__ float z1[32];
    __shared__ float z2[32];
    int g = blockIdx.x, t = threadIdx.x;
    int lo = 0, hi = NN;
    while (lo < hi) { int mid = (lo + hi) >> 1; if (batch[mid] < g) lo = mid + 1; else hi = mid; }
    int start = lo;
    hi = NN;
    while (lo < hi) { int mid = (lo + hi) >> 1; if (batch[mid] < g + 1) lo = mid + 1; else hi = mid; }
    float cnt = (float)(lo - start);
    float acc = 0.f;
#pragma unroll
    for (int q = 0; q < PSPLIT; ++q)
        acc += ppart[((size_t)g * PSPLIT + q) * 128 + t];
    p[t] = acc / fmaxf(cnt, 1.0f);
    __syncthreads();
    if (t < 32) {
        float a = fb[t];
        for (int k = 0; k < 128; ++k) a += p[k] * fw[k * 32 + t];
        float val = g4[t] * (a - m4[t]) * rsqrtf(v4[t] + BNEPS) + be4[t];
        z1[t] = fmaxf(val, 0.f);
    }
    __syncthreads();
    if (t < 32) {
        float a = l1b[t];
        for (int k = 0; k < 32; ++k) a += z1[k] * l1w[k * 32 + t];
        z2[t] = fmaxf(a, 0.f);
    }
    __syncthreads();
    if (t < 10) {
        float a = l2b[t];
        for (int k = 0; k < 32; ++k) a += z2[k] * l2w[k * 10 + t];
        out[g * 10 + t] = a;
    }
}

// ---------------- launch ----------------

extern "C" void kernel_launch(void* const* d_in, const int* in_sizes, int n_in,
                              void* d_out, int out_size, void* d_ws, size_t ws_size,
                              hipStream_t stream) {
    const float* x     = (const float*)d_in[0];
    const int*   ei    = (const int*)d_in[1];
    const int*   batch = (const int*)d_in[2];
    const float* w1  = (const float*)d_in[3];
    const float* as1 = (const float*)d_in[4];
    const float* ad1 = (const float*)d_in[5];
    const float* b1  = (const float*)d_in[6];
    const float* g1  = (const float*)d_in[7];
    const float* be1 = (const float*)d_in[8];
    const float* m1  = (const float*)d_in[9];
    const float* v1  = (const float*)d_in[10];
    const float* p1w = (const float*)d_in[11];
    const float* p1b = (const float*)d_in[12];
    const float* w2  = (const float*)d_in[13];
    const float* as2 = (const float*)d_in[14];
    const float* ad2 = (const float*)d_in[15];
    const float* b2  = (const float*)d_in[16];
    const float* g2  = (const float*)d_in[17];
    const float* be2 = (const float*)d_in[18];
    const float* m2  = (const float*)d_in[19];
    const float* v2  = (const float*)d_in[20];
    const float* p2w = (const float*)d_in[21];
    const float* p2b = (const float*)d_in[22];
    const float* w3  = (const float*)d_in[23];
    const float* as3 = (const float*)d_in[24];
    const float* ad3 = (const float*)d_in[25];
    const float* b3  = (const float*)d_in[26];
    const float* g3  = (const float*)d_in[27];
    const float* be3 = (const float*)d_in[28];
    const float* m3  = (const float*)d_in[29];
    const float* v3  = (const float*)d_in[30];
    const float* p3w = (const float*)d_in[31];
    const float* p3b = (const float*)d_in[32];
    const float* fw  = (const float*)d_in[33];
    const float* fb  = (const float*)d_in[34];
    const float* g4  = (const float*)d_in[35];
    const float* be4 = (const float*)d_in[36];
    const float* m4  = (const float*)d_in[37];
    const float* v4  = (const float*)d_in[38];
    const float* l1w = (const float*)d_in[39];
    const float* l1b = (const float*)d_in[40];
    const float* l2w = (const float*)d_in[41];
    const float* l2b = (const float*)d_in[42];

    char* ws = (char*)d_ws;
    size_t off = 0;
    auto alloc = [&](size_t bytes) -> char* {
        char* p = ws + off;
        off += (bytes + 255) & ~(size_t)255;
        return p;
    };
    int*    bucket_cnt  = (int*)alloc((NBK) * sizeof(int));
    int*    bucket_base = (int*)alloc((NBK + 1) * sizeof(int));
    int*    gcursor     = (int*)alloc((NBK) * sizeof(int));
    int*    part        = (int*)alloc((size_t)ETOT * sizeof(int));
    int*    row2_start  = (int*)alloc(NN * sizeof(int));
    int*    row2_deg    = (int*)alloc(NN * sizeof(int));
    int*    csr2_src    = (int*)alloc((size_t)PADTOT * sizeof(int));
    unsigned* csr_w     = (unsigned*)alloc((size_t)PADTOT * sizeof(unsigned));
    unsigned char*  h8  = (unsigned char*)alloc((size_t)(NN + 1) * 128);
    unsigned short* hb1 = (unsigned short*)alloc((size_t)NN * 64 * sizeof(short));
    unsigned short* hb2 = (unsigned short*)alloc((size_t)NN * 128 * sizeof(short));
    unsigned short* hb3 = (unsigned short*)alloc((size_t)NN * 128 * sizeof(short));
    float*  esrc        = (float*)alloc((size_t)(NN + 1) * 2 * sizeof(float));
    float*  edst        = (float*)alloc((size_t)NN * 2 * sizeof(float));
    float*  ppart       = (float*)alloc((size_t)GG * PSPLIT * 128 * sizeof(float));
    short*  wfrag2      = (short*)alloc((size_t)16 * 2 * 2 * 64 * 8 * sizeof(short));
    short*  wfrag3      = (short*)alloc((size_t)16 * 4 * 2 * 64 * 8 * sizeof(short));
    float*  bnsc1       = (float*)alloc(64 * sizeof(float));
    float*  bnsh1       = (float*)alloc(64 * sizeof(float));
    float*  bnsc2       = (float*)alloc(128 * sizeof(float));
    float*  bnsh2       = (float*)alloc(128 * sizeof(float));
    float*  bnsc3       = (float*)alloc(128 * sizeof(float));
    float*  bnsh3       = (float*)alloc(128 * sizeof(float));

    // ---- merged prep (W fragments + fused BN) ----
    prep_all_kernel<<<49, 256, 0, stream>>>(
        w2, p2w, wfrag2, w3, p3w, wfrag3,
        b1, g1, be1, m1, v1, b2, g2, be2, m2, v2, b3, g3, be3, m3, v3,
        bnsc1, bnsh1, bnsc2, bnsh2, bnsc3, bnsh3);

    // ---- CSR build (bucketed partition, padded-16 layout, NN sentinel) ----
    hipMemsetAsync(bucket_cnt, 0, NBK * sizeof(int), stream);
    bucket_count_kernel<<<(ETOT + 8191) / 8192, 256, 0, stream>>>(ei, bucket_cnt);
    bucket_scan_kernel<<<1, 512, 0, stream>>>(bucket_cnt, bucket_base, gcursor, esrc);
    partition_kernel<<<(ETOT + 4095) / 4096, 256, 0, stream>>>(ei, gcursor, part);
    csr_build_kernel<<<NBK, 256, 0, stream>>>(part, bucket_base, row2_start, row2_deg, csr2_src);

    // ---- layer 1: x[N,5] -> hb1[N,64] (bf16) ----
    feat1_kernel<<<(NN + 3) / 4, 256, 0, stream>>>(
        x, w1, p1w, p1b, as1, ad1, h8, esrc, edst, hb1, NN);
    edgew_kernel<<<(NN + 3) / 4, 256, 0, stream>>>(
        csr2_src, row2_start, row2_deg, (const float2*)esrc, (const float2*)edst, csr_w, NN);
    aggregate64_kernel<<<NN / 8, 256, 0, stream>>>(
        h8, row2_start, row2_deg, csr2_src, csr_w, bnsc1, bnsh1, hb1);

    // ---- layer 2: hb1 -> hb2[N,128] (bf16) ----
    mfma_feat_kernel<64><<<(NN + 127) / 128, 256, 0, stream>>>(
        hb1, wfrag2, p2b, as2, ad2, h8, esrc, edst, hb2);
    edgew_kernel<<<(NN + 3) / 4, 256, 0, stream>>>(
        csr2_src, row2_start, row2_deg, (const float2*)esrc, (const float2*)edst, csr_w, NN);
    aggregate128_kernel<<<(NN + 3) / 4, 256, 0, stream>>>(
        h8, row2_start, row2_deg, csr2_src, csr_w, bnsc2, bnsh2, hb2, NN);

    // ---- layer 3: hb2 -> hb3[N,128] (bf16) ----
    mfma_feat_kernel<128><<<(NN + 127) / 128, 256, 0, stream>>>(
        hb2, wfrag3, p3b, as3, ad3, h8, esrc, edst, hb3);
    edgew_kernel<<<(NN + 3) / 4, 256, 0, stream>>>(
        csr2_src, row2_start, row2_deg, (const float2*)esrc, (const float2*)edst, csr_w, NN);
    aggregate128_kernel<<<(NN + 3) / 4, 256, 0, stream>>>(
        h8, row2_start, row2_deg, csr2_src, csr_w, bnsc3, bnsh3, hb3, NN);

    // ---- pool (two-phase) + head ----
    pool_partial_kernel<<<GG * PSPLIT, 128, 0, stream>>>(hb3, batch, ppart);
    head_kernel<<<GG, 128, 0, stream>>>(ppart, batch, fw, fb, g4, be4, m4, v4,
                                        l1w, l1b, l2w, l2b, (float*)d_out);
}

// Round 19
// 521.525 us; speedup vs baseline: 1.3719x; 1.0699x over previous
//
#include <hip/hip_runtime.h>
#include <hip/hip_bf16.h>
#include <hip/hip_fp16.h>

#define NN   100000
#define EE   1600000
#define ETOT (EE + NN)
#define GG   256
#define BNEPS 1e-5f
#define NBK  391          // buckets of 256 nodes: (NN+255)/256
#define PADTOT (ETOT + NBK * 4096 + 64)
#define PSPLIT 16

typedef float floatx2 __attribute__((ext_vector_type(2)));
typedef short s16x8 __attribute__((ext_vector_type(8)));
typedef float f32x4v __attribute__((ext_vector_type(4)));

__device__ __forceinline__ unsigned short f2bf(float f) {
    unsigned u = __float_as_uint(f);
    unsigned r = u + 0x7FFF + ((u >> 16) & 1);
    return (unsigned short)(r >> 16);
}
__device__ __forceinline__ float bf2f(unsigned short b) {
    return __uint_as_float(((unsigned)b) << 16);
}

// ---------------- CSR build: bucketed partition (single-writer cache lines) --

__global__ __launch_bounds__(256) void bucket_count_kernel(
    const int* __restrict__ ei, int* __restrict__ bucket_cnt)
{
    __shared__ int cnt[NBK];
    for (int i = threadIdx.x; i < NBK; i += 256) cnt[i] = 0;
    __syncthreads();
    int base = blockIdx.x * 8192;
    for (int k = threadIdx.x; k < 8192; k += 256) {
        int e = base + k;
        if (e < ETOT) {
            int dst = (e < EE) ? ei[EE + e] : (e - EE);
            atomicAdd(&cnt[dst >> 8], 1);
        }
    }
    __syncthreads();
    for (int i = threadIdx.x; i < NBK; i += 256)
        if (cnt[i]) atomicAdd(&bucket_cnt[i], cnt[i]);
}

// also plants the -inf esrc sentinel used by pad edges (src = NN)
__global__ __launch_bounds__(512) void bucket_scan_kernel(
    const int* __restrict__ bucket_cnt, int* __restrict__ bucket_base,
    int* __restrict__ gcursor, float* __restrict__ esrcs)
{
    __shared__ int s[512];
    int t = threadIdx.x;
    int v = (t < NBK) ? bucket_cnt[t] : 0;
    s[t] = v;
    __syncthreads();
    int x = v;
    for (int o = 1; o < 512; o <<= 1) {
        int y = (t >= o) ? s[t - o] : 0;
        __syncthreads();
        x += y;
        s[t] = x;
        __syncthreads();
    }
    if (t < NBK) { bucket_base[t] = x - v; gcursor[t] = x - v; }
    if (t == 0) {
        bucket_base[NBK] = ETOT;
        esrcs[2 * NN]     = __int_as_float(0xFF800000);  // -inf
        esrcs[2 * NN + 1] = __int_as_float(0xFF800000);
    }
}

__global__ __launch_bounds__(256) void partition_kernel(
    const int* __restrict__ ei, int* __restrict__ gcursor, int* __restrict__ part)
{
    __shared__ int cnt[NBK];
    __shared__ int basel[NBK];
    for (int i = threadIdx.x; i < NBK; i += 256) cnt[i] = 0;
    __syncthreads();
    int base = blockIdx.x * 4096;
    for (int k = threadIdx.x; k < 4096; k += 256) {
        int e = base + k;
        if (e < ETOT) {
            int dst = (e < EE) ? ei[EE + e] : (e - EE);
            atomicAdd(&cnt[dst >> 8], 1);
        }
    }
    __syncthreads();
    for (int i = threadIdx.x; i < NBK; i += 256) {
        int c = cnt[i];
        basel[i] = c ? atomicAdd(&gcursor[i], c) : 0;
        cnt[i] = 0;   // reuse as intra-block cursor
    }
    __syncthreads();
    for (int k = threadIdx.x; k < 4096; k += 256) {
        int e = base + k;
        if (e < ETOT) {
            int src, dst;
            if (e < EE) { src = ei[e]; dst = ei[EE + e]; }
            else        { src = e - EE; dst = e - EE; }
            int b = dst >> 8;
            int slot = atomicAdd(&cnt[b], 1);
            part[basel[b] + slot] = src | ((dst & 255) << 17);
        }
    }
}

// Padded CSR: per-node segments rounded up to 16 entries, pad src = NN
// (sentinel: esrc[NN] = -inf → exp weight 0; pads gather the L1-hot NN row).
__global__ __launch_bounds__(256) void csr_build_kernel(
    const int* __restrict__ part, const int* __restrict__ bucket_base,
    int* __restrict__ row2_start, int* __restrict__ row2_deg,
    int* __restrict__ csr2_src)
{
    __shared__ int degs[256];
    __shared__ int sc[256];
    __shared__ int cur[256];
    int b = blockIdx.x;
    int t = threadIdx.x;
    int beg = bucket_base[b], end = bucket_base[b + 1];
    int pbase = ((beg + 15) & ~15) + 4096 * b;
    degs[t] = 0;
    __syncthreads();
    for (int j = beg + t; j < end; j += 256)
        atomicAdd(&degs[(part[j] >> 17) & 255], 1);
    __syncthreads();
    int dg = degs[t];
    int pdeg = (dg + 15) & ~15;
    sc[t] = pdeg;
    __syncthreads();
    int x = pdeg;
    for (int o = 1; o < 256; o <<= 1) {
        int y = (t >= o) ? sc[t - o] : 0;
        __syncthreads();
        x += y;
        sc[t] = x;
        __syncthreads();
    }
    int start2 = pbase + (x - pdeg);
    int node = b * 256 + t;
    if (node < NN) { row2_start[node] = start2; row2_deg[node] = dg; }
    cur[t] = start2;
    __syncthreads();
    for (int j = beg + t; j < end; j += 256) {
        int pv = part[j];
        int pos = atomicAdd(&cur[(pv >> 17) & 255], 1);
        csr2_src[pos] = pv & 0x1FFFF;
    }
    for (int k = dg; k < pdeg; ++k) csr2_src[start2 + k] = NN;
}

// ---------------- merged prep: W-fragments (both layers) + fused BN ----------

template<int K>
__device__ __forceinline__ void prep_w_body(
    int unit, const float* __restrict__ W, const float* __restrict__ pw,
    short* __restrict__ wfrag)
{
    constexpr int KS = K / 32;
    int total = 16 * KS * 2 * 64;
    if (unit >= total) return;
    int lane = unit & 63;
    int rest = unit >> 6;
    int hilo = rest & 1;
    int fk = rest >> 1;
    int ks = fk % KS;
    int nt = fk / KS;
    int n = nt * 16 + (lane & 15);
    int k0 = ks * 32 + (lane >> 4) * 8;
    const float* src = (n < 128) ? (W + n) : (pw + (n - 128));
    s16x8 out;
#pragma unroll
    for (int j = 0; j < 8; ++j) {
        float wv = src[(size_t)(k0 + j) * 128];
        unsigned short hi = f2bf(wv);
        if (hilo == 0) {
            out[j] = (short)hi;
        } else {
            float fhi = __uint_as_float(((unsigned)hi) << 16);
            out[j] = (short)f2bf(wv - fhi);
        }
    }
    *(s16x8*)(wfrag + (size_t)unit * 8) = out;
}

__global__ __launch_bounds__(256) void prep_all_kernel(
    const float* __restrict__ w2, const float* __restrict__ p2w, short* __restrict__ wfrag2,
    const float* __restrict__ w3, const float* __restrict__ p3w, short* __restrict__ wfrag3,
    const float* b1, const float* g1, const float* be1, const float* m1, const float* v1,
    const float* b2, const float* g2, const float* be2, const float* m2, const float* v2,
    const float* b3, const float* g3, const float* be3, const float* m3, const float* v3,
    float* sc1, float* sh1, float* sc2, float* sh2, float* sc3, float* sh3)
{
    int b = blockIdx.x;
    int tid = threadIdx.x;
    if (b < 16) {
        prep_w_body<64>(b * 256 + tid, w2, p2w, wfrag2);
    } else if (b < 48) {
        prep_w_body<128>((b - 16) * 256 + tid, w3, p3w, wfrag3);
    } else {
        int t = tid;
        if (t < 128) {
            if (t < 64) {
                float sc = g1[t] * rsqrtf(v1[t] + BNEPS);
                sc1[t] = sc;
                sh1[t] = (b1[t] - m1[t]) * sc + be1[t];
            }
            {
                float sc = g2[t] * rsqrtf(v2[t] + BNEPS);
                sc2[t] = sc;
                sh2[t] = (b2[t] - m2[t]) * sc + be2[t];
            }
            {
                float sc = g3[t] * rsqrtf(v3[t] + BNEPS);
                sc3[t] = sc;
                sh3[t] = (b3[t] - m3[t]) * sc + be3[t];
            }
        }
    }
}

// ---------------- per-layer edge softmax weights (packed 2×bf16) -------------

__global__ __launch_bounds__(256) void edgew_kernel(
    const int* __restrict__ csr2_src, const int* __restrict__ row2_start,
    const int* __restrict__ row2_deg,
    const float2* __restrict__ esrc, const float2* __restrict__ edst,
    unsigned* __restrict__ csr_w, int nN)
{
    int n = blockIdx.x * 4 + (threadIdx.x >> 6);
    int lane = threadIdx.x & 63;
    if (n >= nN) return;
    float2 ed = edst[n];
    int s2 = row2_start[n];
    int dg = row2_deg[n];
    int pc = (dg + 15) & ~15;
    for (int j = lane; j < pc; j += 64) {
        int i = csr2_src[s2 + j];
        float2 es = esrc[i];
        float a0 = es.x + ed.x; a0 = (a0 > 0.f) ? a0 : 0.2f * a0;
        float a1 = es.y + ed.y; a1 = (a1 > 0.f) ? a1 : 0.2f * a1;
        unsigned w = (unsigned)f2bf(__expf(a0)) | ((unsigned)f2bf(__expf(a1)) << 16);
        csr_w[s2 + j] = w;
    }
}

// ---------------- layer-1 feature transform (K=5); h fp8, rout bf16 ----------

__global__ __launch_bounds__(256) void feat1_kernel(
    const float* __restrict__ xin, const float* __restrict__ W,
    const float* __restrict__ pw, const float* __restrict__ pb,
    const float* __restrict__ a_src, const float* __restrict__ a_dst,
    unsigned char* __restrict__ h8, float* __restrict__ esrc, float* __restrict__ edst,
    unsigned short* __restrict__ rout16, int nN)
{
    constexpr int F_IN = 5, F_OUT = 64;
    int t = threadIdx.x;
    int n = blockIdx.x * 4 + t / F_OUT;
    int f = t % F_OUT;
    if (n >= nN) return;
    float acc = 0.f, racc = 0.f;
#pragma unroll
    for (int k = 0; k < F_IN; ++k) {
        float xv = xin[n * F_IN + k];
        acc  += xv * W[k * F_OUT + f];
        racc += xv * pw[k * F_OUT + f];
    }
    float other = __shfl_xor(acc, 1, 64);
    if ((f & 1) == 0) {
        int p = __builtin_amdgcn_cvt_pk_fp8_f32(acc, other, 0, false);
        *(unsigned short*)(h8 + (size_t)n * F_OUT + f) = (unsigned short)(p & 0xFFFF);
    }
    rout16[(size_t)n * F_OUT + f] = f2bf(racc + pb[f]);
    float es = acc * a_src[f];
    float ed = acc * a_dst[f];
#pragma unroll
    for (int off = 16; off > 0; off >>= 1) {
        es += __shfl_xor(es, off, 32);
        ed += __shfl_xor(ed, off, 32);
    }
    if ((t & 31) == 0) {
        int head = (f >> 5) & 1;
        esrc[n * 2 + head] = es;
        edst[n * 2 + head] = ed;
    }
}

// ---------------- MFMA feature transform (layers 2,3; N=256 = W‖pw) ----------
// LDS-staged outputs (R15 win: no sub-word global stores).

template<int K>
__global__ __launch_bounds__(256) void mfma_feat_kernel(
    const unsigned short* __restrict__ xin16, const short* __restrict__ wfrag,
    const float* __restrict__ pb,
    const float* __restrict__ a_src, const float* __restrict__ a_dst,
    unsigned char* __restrict__ h8, float* __restrict__ esrc, float* __restrict__ edst,
    unsigned short* __restrict__ rout16)
{
    constexpr int KS = K / 32;    // MFMA k-steps
    constexpr int CH = K / 8;     // 8-feature (16 B) chunks per node row
    __shared__ __align__(16) char smem[53248];
    s16x8* xs = (s16x8*)smem;
    unsigned short* h8lds = (unsigned short*)smem;             // stride 72 ushorts
    unsigned short* rolds = (unsigned short*)(smem + 18432);   // stride 136 ushorts

    const int tid = threadIdx.x;
    const int base = blockIdx.x * 128;

    for (int idx = tid; idx < 128 * CH; idx += 256) {
        int node = idx / CH;
        int ch = idx % CH;
        int gn = base + node; if (gn > NN - 1) gn = NN - 1;
        s16x8 v = *(const s16x8*)(xin16 + (size_t)gn * K + ch * 8);
        int tt = node >> 4, mm = node & 15;
        xs[(tt * CH + ch) * 16 + mm] = v;
    }
    __syncthreads();

    const int w = tid >> 6;
    const int lane = tid & 63;
    const int quad = lane >> 4;
    const int m = lane & 15;
    const int l0 = w * 32 + quad * 4;   // local row, tile0 (+r)
    const int l1 = l0 + 16;             // local row, tile1 (+r)
    const int node0 = base + l0;
    const int node1 = base + l1;

    s16x8 a0[KS], a1[KS];
#pragma unroll
    for (int ks = 0; ks < KS; ++ks) {
        a0[ks] = xs[((w * 2 + 0) * CH + (ks * 4 + quad)) * 16 + m];
        a1[ks] = xs[((w * 2 + 1) * CH + (ks * 4 + quad)) * 16 + m];
    }
    __syncthreads();   // xs dead; smem becomes output tile

    float es0h0[4] = {0.f,0.f,0.f,0.f}, es0h1[4] = {0.f,0.f,0.f,0.f};
    float ed0h0[4] = {0.f,0.f,0.f,0.f}, ed0h1[4] = {0.f,0.f,0.f,0.f};
    float es1h0[4] = {0.f,0.f,0.f,0.f}, es1h1[4] = {0.f,0.f,0.f,0.f};
    float ed1h0[4] = {0.f,0.f,0.f,0.f}, ed1h1[4] = {0.f,0.f,0.f,0.f};

#pragma unroll
    for (int nt = 0; nt < 16; ++nt) {
        s16x8 b[2 * KS];
#pragma unroll
        for (int i = 0; i < 2 * KS; ++i)
            b[i] = *(const s16x8*)(wfrag + (size_t)((nt * KS * 2 + i) * 64 + lane) * 8);
        f32x4v c0 = {0.f, 0.f, 0.f, 0.f};
        f32x4v c1 = {0.f, 0.f, 0.f, 0.f};
#pragma unroll
        for (int ks = 0; ks < KS; ++ks) {
            c0 = __builtin_amdgcn_mfma_f32_16x16x32_bf16(a0[ks], b[2 * ks + 0], c0, 0, 0, 0);
            c1 = __builtin_amdgcn_mfma_f32_16x16x32_bf16(a1[ks], b[2 * ks + 0], c1, 0, 0, 0);
            c0 = __builtin_amdgcn_mfma_f32_16x16x32_bf16(a0[ks], b[2 * ks + 1], c0, 0, 0, 0);
            c1 = __builtin_amdgcn_mfma_f32_16x16x32_bf16(a1[ks], b[2 * ks + 1], c1, 0, 0, 0);
        }
        if (nt < 8) {
            int col = nt * 16 + m;
            float av = a_src[col], dv = a_dst[col];
#pragma unroll
            for (int r = 0; r < 4; ++r) {
                float v0 = c0[r], v1 = c1[r];
                if (nt < 4) {
                    es0h0[r] = fmaf(v0, av, es0h0[r]); ed0h0[r] = fmaf(v0, dv, ed0h0[r]);
                    es1h0[r] = fmaf(v1, av, es1h0[r]); ed1h0[r] = fmaf(v1, dv, ed1h0[r]);
                } else {
                    es0h1[r] = fmaf(v0, av, es0h1[r]); ed0h1[r] = fmaf(v0, dv, ed0h1[r]);
                    es1h1[r] = fmaf(v1, av, es1h1[r]); ed1h1[r] = fmaf(v1, dv, ed1h1[r]);
                }
                float p0 = __shfl_xor(v0, 1, 16);
                float p1 = __shfl_xor(v1, 1, 16);
                if ((m & 1) == 0) {
                    int us = nt * 8 + (m >> 1);   // ushort index within row
                    int pk0 = __builtin_amdgcn_cvt_pk_fp8_f32(v0, p0, 0, false);
                    int pk1 = __builtin_amdgcn_cvt_pk_fp8_f32(v1, p1, 0, false);
                    h8lds[(l0 + r) * 72 + us] = (unsigned short)(pk0 & 0xFFFF);
                    h8lds[(l1 + r) * 72 + us] = (unsigned short)(pk1 & 0xFFFF);
                }
            }
        } else {
            int col = (nt - 8) * 16 + m;
            float bv = pb[col];
#pragma unroll
            for (int r = 0; r < 4; ++r) {
                rolds[(l0 + r) * 136 + col] = f2bf(c0[r] + bv);
                rolds[(l1 + r) * 136 + col] = f2bf(c1[r] + bv);
            }
        }
    }

#pragma unroll
    for (int r = 0; r < 4; ++r) {
#pragma unroll
        for (int off = 8; off > 0; off >>= 1) {
            es0h0[r] += __shfl_xor(es0h0[r], off, 16);
            es0h1[r] += __shfl_xor(es0h1[r], off, 16);
            ed0h0[r] += __shfl_xor(ed0h0[r], off, 16);
            ed0h1[r] += __shfl_xor(ed0h1[r], off, 16);
            es1h0[r] += __shfl_xor(es1h0[r], off, 16);
            es1h1[r] += __shfl_xor(es1h1[r], off, 16);
            ed1h0[r] += __shfl_xor(ed1h0[r], off, 16);
            ed1h1[r] += __shfl_xor(ed1h1[r], off, 16);
        }
    }
    if (m == 0) {
#pragma unroll
        for (int r = 0; r < 4; ++r) {
            if (node0 + r < NN) {
                ((float2*)esrc)[node0 + r] = make_float2(es0h0[r], es0h1[r]);
                ((float2*)edst)[node0 + r] = make_float2(ed0h0[r], ed0h1[r]);
            }
            if (node1 + r < NN) {
                ((float2*)esrc)[node1 + r] = make_float2(es1h0[r], es1h1[r]);
                ((float2*)edst)[node1 + r] = make_float2(ed1h0[r], ed1h1[r]);
            }
        }
    }

    __syncthreads();
    for (int i = tid; i < 128 * 8; i += 256) {
        int row = i >> 3, ch = i & 7;
        int node = base + row;
        if (node < NN) {
            int4 v = *(const int4*)(smem + row * 144 + ch * 16);
            *(int4*)(h8 + (size_t)node * 128 + ch * 16) = v;
        }
    }
    for (int i = tid; i < 128 * 16; i += 256) {
        int row = i >> 4, ch = i & 15;
        int node = base + row;
        if (node < NN) {
            int4 v = *(const int4*)(smem + 18432 + row * 272 + ch * 16);
            *(int4*)((char*)rout16 + (size_t)node * 256 + ch * 16) = v;
        }
    }
}

// ---------------- fused aggregate, F=128 (two nodes per wave) ----------------
// R19: half-wave = node (32 lanes × dword cover the 128 B row). No cross-lane
// reduction at all: each lane owns 4 features; s computed in-lane from
// broadcast weight loads. Prologue/epilogue amortized over 2 nodes; idx/w
// selects replaced by half-uniform dword loads. NN = 8 × 12500 → no guards.

__global__ __launch_bounds__(256) void aggregate128_kernel(
    const unsigned char* __restrict__ h8,
    const int* __restrict__ row2_start, const int* __restrict__ row2_deg,
    const int* __restrict__ csr2_src, const unsigned* __restrict__ csr_w,
    const float* __restrict__ bnsc, const float* __restrict__ bnsh,
    unsigned short* __restrict__ io16)
{
    int w = threadIdx.x >> 6;
    int lane = threadIdx.x & 63;
    int half = lane >> 5;
    int fl = lane & 31;               // dword within the 128 B row (4 features)
    bool headhi = fl >= 16;           // features 64..127
    int n = blockIdx.x * 8 + w * 2 + half;
    int s2 = row2_start[n];
    int dg = row2_deg[n];
    int pc = (dg + 15) & ~15;
    const int* sp = csr2_src + s2;
    const unsigned* wp = csr_w + s2;
    float s = 0.f, a0 = 0.f, a1 = 0.f, a2 = 0.f, a3 = 0.f;
    for (int j = 0; j < pc; j += 8) {
        int i0 = sp[j + 0];
        int i1 = sp[j + 1];
        int i2 = sp[j + 2];
        int i3 = sp[j + 3];
        int i4 = sp[j + 4];
        int i5 = sp[j + 5];
        int i6 = sp[j + 6];
        int i7 = sp[j + 7];
        unsigned w0 = wp[j + 0];
        unsigned w1 = wp[j + 1];
        unsigned w2 = wp[j + 2];
        unsigned w3 = wp[j + 3];
        unsigned w4 = wp[j + 4];
        unsigned w5 = wp[j + 5];
        unsigned w6 = wp[j + 6];
        unsigned w7 = wp[j + 7];
        unsigned d0 = *(const unsigned*)(h8 + (size_t)i0 * 128 + fl * 4);
        unsigned d1 = *(const unsigned*)(h8 + (size_t)i1 * 128 + fl * 4);
        unsigned d2 = *(const unsigned*)(h8 + (size_t)i2 * 128 + fl * 4);
        unsigned d3 = *(const unsigned*)(h8 + (size_t)i3 * 128 + fl * 4);
        unsigned d4 = *(const unsigned*)(h8 + (size_t)i4 * 128 + fl * 4);
        unsigned d5 = *(const unsigned*)(h8 + (size_t)i5 * 128 + fl * 4);
        unsigned d6 = *(const unsigned*)(h8 + (size_t)i6 * 128 + fl * 4);
        unsigned d7 = *(const unsigned*)(h8 + (size_t)i7 * 128 + fl * 4);
        float g0 = __uint_as_float(headhi ? (w0 & 0xFFFF0000u) : (w0 << 16));
        float g1 = __uint_as_float(headhi ? (w1 & 0xFFFF0000u) : (w1 << 16));
        float g2 = __uint_as_float(headhi ? (w2 & 0xFFFF0000u) : (w2 << 16));
        float g3 = __uint_as_float(headhi ? (w3 & 0xFFFF0000u) : (w3 << 16));
        float g4 = __uint_as_float(headhi ? (w4 & 0xFFFF0000u) : (w4 << 16));
        float g5 = __uint_as_float(headhi ? (w5 & 0xFFFF0000u) : (w5 << 16));
        float g6 = __uint_as_float(headhi ? (w6 & 0xFFFF0000u) : (w6 << 16));
        float g7 = __uint_as_float(headhi ? (w7 & 0xFFFF0000u) : (w7 << 16));
        floatx2 lo0 = __builtin_amdgcn_cvt_pk_f32_fp8((int)d0, false);
        floatx2 hi0 = __builtin_amdgcn_cvt_pk_f32_fp8((int)d0, true);
        floatx2 lo1 = __builtin_amdgcn_cvt_pk_f32_fp8((int)d1, false);
        floatx2 hi1 = __builtin_amdgcn_cvt_pk_f32_fp8((int)d1, true);
        floatx2 lo2 = __builtin_amdgcn_cvt_pk_f32_fp8((int)d2, false);
        floatx2 hi2 = __builtin_amdgcn_cvt_pk_f32_fp8((int)d2, true);
        floatx2 lo3 = __builtin_amdgcn_cvt_pk_f32_fp8((int)d3, false);
        floatx2 hi3 = __builtin_amdgcn_cvt_pk_f32_fp8((int)d3, true);
        floatx2 lo4 = __builtin_amdgcn_cvt_pk_f32_fp8((int)d4, false);
        floatx2 hi4 = __builtin_amdgcn_cvt_pk_f32_fp8((int)d4, true);
        floatx2 lo5 = __builtin_amdgcn_cvt_pk_f32_fp8((int)d5, false);
        floatx2 hi5 = __builtin_amdgcn_cvt_pk_f32_fp8((int)d5, true);
        floatx2 lo6 = __builtin_amdgcn_cvt_pk_f32_fp8((int)d6, false);
        floatx2 hi6 = __builtin_amdgcn_cvt_pk_f32_fp8((int)d6, true);
        floatx2 lo7 = __builtin_amdgcn_cvt_pk_f32_fp8((int)d7, false);
        floatx2 hi7 = __builtin_amdgcn_cvt_pk_f32_fp8((int)d7, true);
        a0 = fmaf(g0, lo0.x, a0); a1 = fmaf(g0, lo0.y, a1);
        a2 = fmaf(g0, hi0.x, a2); a3 = fmaf(g0, hi0.y, a3);
        a0 = fmaf(g1, lo1.x, a0); a1 = fmaf(g1, lo1.y, a1);
        a2 = fmaf(g1, hi1.x, a2); a3 = fmaf(g1, hi1.y, a3);
        a0 = fmaf(g2, lo2.x, a0); a1 = fmaf(g2, lo2.y, a1);
        a2 = fmaf(g2, hi2.x, a2); a3 = fmaf(g2, hi2.y, a3);
        a0 = fmaf(g3, lo3.x, a0); a1 = fmaf(g3, lo3.y, a1);
        a2 = fmaf(g3, hi3.x, a2); a3 = fmaf(g3, hi3.y, a3);
        a0 = fmaf(g4, lo4.x, a0); a1 = fmaf(g4, lo4.y, a1);
        a2 = fmaf(g4, hi4.x, a2); a3 = fmaf(g4, hi4.y, a3);
        a0 = fmaf(g5, lo5.x, a0); a1 = fmaf(g5, lo5.y, a1);
        a2 = fmaf(g5, hi5.x, a2); a3 = fmaf(g5, hi5.y, a3);
        a0 = fmaf(g6, lo6.x, a0); a1 = fmaf(g6, lo6.y, a1);
        a2 = fmaf(g6, hi6.x, a2); a3 = fmaf(g6, hi6.y, a3);
        a0 = fmaf(g7, lo7.x, a0); a1 = fmaf(g7, lo7.y, a1);
        a2 = fmaf(g7, hi7.x, a2); a3 = fmaf(g7, hi7.y, a3);
        s += (((g0 + g1) + (g2 + g3)) + ((g4 + g5) + (g6 + g7)));
    }
    float inv = 1.f / (s + 1e-16f);
    int f0 = fl * 4;
    float4 sc = *(const float4*)(bnsc + f0);
    float4 sh = *(const float4*)(bnsh + f0);
    float o0 = fmaf(a0 * inv, sc.x, sh.x);
    float o1 = fmaf(a1 * inv, sc.y, sh.y);
    float o2 = fmaf(a2 * inv, sc.z, sh.z);
    float o3 = fmaf(a3 * inv, sc.w, sh.w);
    uint2* iop = (uint2*)(io16 + (size_t)n * 128 + f0);
    uint2 pu = *iop;
    float r0 = fmaxf(o0, 0.f) + __uint_as_float((pu.x & 0xFFFFu) << 16);
    float r1 = fmaxf(o1, 0.f) + __uint_as_float(pu.x & 0xFFFF0000u);
    float r2 = fmaxf(o2, 0.f) + __uint_as_float((pu.y & 0xFFFFu) << 16);
    float r3 = fmaxf(o3, 0.f) + __uint_as_float(pu.y & 0xFFFF0000u);
    uint2 ov;
    ov.x = (unsigned)f2bf(r0) | ((unsigned)f2bf(r1) << 16);
    ov.y = (unsigned)f2bf(r2) | ((unsigned)f2bf(r3) << 16);
    *iop = ov;
}

// ---------------- fused aggregate, F=64 (two nodes per wave) -----------------

__global__ __launch_bounds__(256) void aggregate64_kernel(
    const unsigned char* __restrict__ h8,
    const int* __restrict__ row2_start, const int* __restrict__ row2_deg,
    const int* __restrict__ csr2_src, const unsigned* __restrict__ csr_w,
    const float* __restrict__ bnsc, const float* __restrict__ bnsh,
    unsigned short* __restrict__ io16)
{
    int w = threadIdx.x >> 6;
    int lane = threadIdx.x & 63;
    int half = lane >> 5;
    int hl = lane & 31;
    int q  = hl >> 4;                 // edge selector within pair
    int fl = hl & 15;                 // feature dword (features 4fl..4fl+3)
    bool headhi = (fl >> 3) & 1;
    int n = blockIdx.x * 8 + w * 2 + half;
    int s2 = row2_start[n];
    int dg = row2_deg[n];
    int pc = (dg + 15) & ~15;
    const int4* sp = (const int4*)(csr2_src + s2);
    const uint4* wp = (const uint4*)(csr_w + s2);
    float s = 0.f, a0 = 0.f, a1 = 0.f, a2 = 0.f, a3 = 0.f;
    for (int j = 0; j < pc; j += 8) {
        int4 ia = sp[(j >> 2) + 0];
        int4 ib = sp[(j >> 2) + 1];
        uint4 wa = wp[(j >> 2) + 0];
        uint4 wb = wp[(j >> 2) + 1];
        int i0 = q ? ia.y : ia.x;
        int i1 = q ? ia.w : ia.z;
        int i2 = q ? ib.y : ib.x;
        int i3 = q ? ib.w : ib.z;
        unsigned w0 = q ? wa.y : wa.x;
        unsigned w1 = q ? wa.w : wa.z;
        unsigned w2 = q ? wb.y : wb.x;
        unsigned w3 = q ? wb.w : wb.z;
        unsigned d0 = *(const unsigned*)(h8 + (size_t)i0 * 64 + fl * 4);
        unsigned d1 = *(const unsigned*)(h8 + (size_t)i1 * 64 + fl * 4);
        unsigned d2 = *(const unsigned*)(h8 + (size_t)i2 * 64 + fl * 4);
        unsigned d3 = *(const unsigned*)(h8 + (size_t)i3 * 64 + fl * 4);
        float g0 = __uint_as_float(headhi ? (w0 & 0xFFFF0000u) : (w0 << 16));
        float g1 = __uint_as_float(headhi ? (w1 & 0xFFFF0000u) : (w1 << 16));
        float g2 = __uint_as_float(headhi ? (w2 & 0xFFFF0000u) : (w2 << 16));
        float g3 = __uint_as_float(headhi ? (w3 & 0xFFFF0000u) : (w3 << 16));
        floatx2 lo0 = __builtin_amdgcn_cvt_pk_f32_fp8((int)d0, false);
        floatx2 hi0 = __builtin_amdgcn_cvt_pk_f32_fp8((int)d0, true);
        floatx2 lo1 = __builtin_amdgcn_cvt_pk_f32_fp8((int)d1, false);
        floatx2 hi1 = __builtin_amdgcn_cvt_pk_f32_fp8((int)d1, true);
        floatx2 lo2 = __builtin_amdgcn_cvt_pk_f32_fp8((int)d2, false);
        floatx2 hi2 = __builtin_amdgcn_cvt_pk_f32_fp8((int)d2, true);
        floatx2 lo3 = __builtin_amdgcn_cvt_pk_f32_fp8((int)d3, false);
        floatx2 hi3 = __builtin_amdgcn_cvt_pk_f32_fp8((int)d3, true);
        a0 = fmaf(g0, lo0.x, a0); a1 = fmaf(g0, lo0.y, a1);
        a2 = fmaf(g0, hi0.x, a2); a3 = fmaf(g0, hi0.y, a3);
        a0 = fmaf(g1, lo1.x, a0); a1 = fmaf(g1, lo1.y, a1);
        a2 = fmaf(g1, hi1.x, a2); a3 = fmaf(g1, hi1.y, a3);
        a0 = fmaf(g2, lo2.x, a0); a1 = fmaf(g2, lo2.y, a1);
        a2 = fmaf(g2, hi2.x, a2); a3 = fmaf(g2, hi2.y, a3);
        a0 = fmaf(g3, lo3.x, a0); a1 = fmaf(g3, lo3.y, a1);
        a2 = fmaf(g3, hi3.x, a2); a3 = fmaf(g3, hi3.y, a3);
        s += ((g0 + g1) + (g2 + g3));
    }
    // combine the two quarters within each half (xor 16 stays inside the half)
    a0 += __shfl_xor(a0, 16);
    a1 += __shfl_xor(a1, 16);
    a2 += __shfl_xor(a2, 16);
    a3 += __shfl_xor(a3, 16);
    s  += __shfl_xor(s, 16);
    if (hl < 16) {
        float inv = 1.f / (s + 1e-16f);
        int f0 = fl * 4;
        float4 sc = *(const float4*)(bnsc + f0);
        float4 sh = *(const float4*)(bnsh + f0);
        float o0 = fmaf(a0 * inv, sc.x, sh.x);
        float o1 = fmaf(a1 * inv, sc.y, sh.y);
        float o2 = fmaf(a2 * inv, sc.z, sh.z);
        float o3 = fmaf(a3 * inv, sc.w, sh.w);
        uint2* iop = (uint2*)(io16 + (size_t)n * 64 + f0);
        uint2 pu = *iop;
        float r0 = fmaxf(o0, 0.f) + __uint_as_float((pu.x & 0xFFFFu) << 16);
        float r1 = fmaxf(o1, 0.f) + __uint_as_float(pu.x & 0xFFFF0000u);
        float r2 = fmaxf(o2, 0.f) + __uint_as_float((pu.y & 0xFFFFu) << 16);
        float r3 = fmaxf(o3, 0.f) + __uint_as_float(pu.y & 0xFFFF0000u);
        uint2 ov;
        ov.x = (unsigned)f2bf(r0) | ((unsigned)f2bf(r1) << 16);
        ov.y = (unsigned)f2bf(r2) | ((unsigned)f2bf(r3) << 16);
        *iop = ov;
    }
}

// ---------------- pooling, two-phase (bf16 input) ----------------

__global__ __launch_bounds__(128) void pool_partial_kernel(
    const unsigned short* __restrict__ hf16, const int* __restrict__ batch,
    float* __restrict__ ppart)
{
    int g = blockIdx.x / PSPLIT;
    int p = blockIdx.x % PSPLIT;
    int f = threadIdx.x;
    int lo = 0, hi = NN;
    while (lo < hi) { int mid = (lo + hi) >> 1; if (batch[mid] < g) lo = mid + 1; else hi = mid; }
    int start = lo;
    hi = NN;
    while (lo < hi) { int mid = (lo + hi) >> 1; if (batch[mid] < g + 1) lo = mid + 1; else hi = mid; }
    int end = lo;
    int len = end - start;
    int chunk = (len + PSPLIT - 1) / PSPLIT;
    int i0 = start + p * chunk;
    int i1 = i0 + chunk; if (i1 > end) i1 = end;
    float acc = 0.f;
    for (int i = i0; i < i1; ++i) acc += bf2f(hf16[(size_t)i * 128 + f]);
    ppart[((size_t)g * PSPLIT + p) * 128 + f] = acc;
}

// ---------------- MLP head (folds partial-sum reduce + mean) -----------------

__global__ __launch_bounds__(128) void head_kernel(
    const float* __restrict__ ppart, const int* __restrict__ batch,
    const float* __restrict__ fw, const float* __restrict__ fb,
    const float* __restrict__ g4, const float* __restrict__ be4,
    const float* __restrict__ m4, const float* __restrict__ v4,
    const float* __restrict__ l1w, const float* __restrict__ l1b,
    const float* __restrict__ l2w, const float* __restrict__ l2b,
    float* __restrict__ out)
{
    __shared__ float p[128];
    __shared__ float z1[32];
    __shared__ float z2[32];
    int g = blockIdx.x, t = threadIdx.x;
    int lo = 0, hi = NN;
    while (lo < hi) { int mid = (lo + hi) >> 1; if (batch[mid] < g) lo = mid + 1; else hi = mid; }
    int start = lo;
    hi = NN;
    while (lo < hi) { int mid = (lo + hi) >> 1; if (batch[mid] < g + 1) lo = mid + 1; else hi = mid; }
    float cnt = (float)(lo - start);
    float acc = 0.f;
#pragma unroll
    for (int q = 0; q < PSPLIT; ++q)
        acc += ppart[((size_t)g * PSPLIT + q) * 128 + t];
    p[t] = acc / fmaxf(cnt, 1.0f);
    __syncthreads();
    if (t < 32) {
        float a = fb[t];
        for (int k = 0; k < 128; ++k) a += p[k] * fw[k * 32 + t];
        float val = g4[t] * (a - m4[t]) * rsqrtf(v4[t] + BNEPS) + be4[t];
        z1[t] = fmaxf(val, 0.f);
    }
    __syncthreads();
    if (t < 32) {
        float a = l1b[t];
        for (int k = 0; k < 32; ++k) a += z1[k] * l1w[k * 32 + t];
        z2[t] = fmaxf(a, 0.f);
    }
    __syncthreads();
    if (t < 10) {
        float a = l2b[t];
        for (int k = 0; k < 32; ++k) a += z2[k] * l2w[k * 10 + t];
        out[g * 10 + t] = a;
    }
}

// ---------------- launch ----------------

extern "C" void kernel_launch(void* const* d_in, const int* in_sizes, int n_in,
                              void* d_out, int out_size, void* d_ws, size_t ws_size,
                              hipStream_t stream) {
    const float* x     = (const float*)d_in[0];
    const int*   ei    = (const int*)d_in[1];
    const int*   batch = (const int*)d_in[2];
    const float* w1  = (const float*)d_in[3];
    const float* as1 = (const float*)d_in[4];
    const float* ad1 = (const float*)d_in[5];
    const float* b1  = (const float*)d_in[6];
    const float* g1  = (const float*)d_in[7];
    const float* be1 = (const float*)d_in[8];
    const float* m1  = (const float*)d_in[9];
    const float* v1  = (const float*)d_in[10];
    const float* p1w = (const float*)d_in[11];
    const float* p1b = (const float*)d_in[12];
    const float* w2  = (const float*)d_in[13];
    const float* as2 = (const float*)d_in[14];
    const float* ad2 = (const float*)d_in[15];
    const float* b2  = (const float*)d_in[16];
    const float* g2  = (const float*)d_in[17];
    const float* be2 = (const float*)d_in[18];
    const float* m2  = (const float*)d_in[19];
    const float* v2  = (const float*)d_in[20];
    const float* p2w = (const float*)d_in[21];
    const float* p2b = (const float*)d_in[22];
    const float* w3  = (const float*)d_in[23];
    const float* as3 = (const float*)d_in[24];
    const float* ad3 = (const float*)d_in[25];
    const float* b3  = (const float*)d_in[26];
    const float* g3  = (const float*)d_in[27];
    const float* be3 = (const float*)d_in[28];
    const float* m3  = (const float*)d_in[29];
    const float* v3  = (const float*)d_in[30];
    const float* p3w = (const float*)d_in[31];
    const float* p3b = (const float*)d_in[32];
    const float* fw  = (const float*)d_in[33];
    const float* fb  = (const float*)d_in[34];
    const float* g4  = (const float*)d_in[35];
    const float* be4 = (const float*)d_in[36];
    const float* m4  = (const float*)d_in[37];
    const float* v4  = (const float*)d_in[38];
    const float* l1w = (const float*)d_in[39];
    const float* l1b = (const float*)d_in[40];
    const float* l2w = (const float*)d_in[41];
    const float* l2b = (const float*)d_in[42];

    char* ws = (char*)d_ws;
    size_t off = 0;
    auto alloc = [&](size_t bytes) -> char* {
        char* p = ws + off;
        off += (bytes + 255) & ~(size_t)255;
        return p;
    };
    int*    bucket_cnt  = (int*)alloc((NBK) * sizeof(int));
    int*    bucket_base = (int*)alloc((NBK + 1) * sizeof(int));
    int*    gcursor     = (int*)alloc((NBK) * sizeof(int));
    int*    part        = (int*)alloc((size_t)ETOT * sizeof(int));
    int*    row2_start  = (int*)alloc(NN * sizeof(int));
    int*    row2_deg    = (int*)alloc(NN * sizeof(int));
    int*    csr2_src    = (int*)alloc((size_t)PADTOT * sizeof(int));
    unsigned* csr_w     = (unsigned*)alloc((size_t)PADTOT * sizeof(unsigned));
    unsigned char*  h8  = (unsigned char*)alloc((size_t)(NN + 1) * 128);
    unsigned short* hb1 = (unsigned short*)alloc((size_t)NN * 64 * sizeof(short));
    unsigned short* hb2 = (unsigned short*)alloc((size_t)NN * 128 * sizeof(short));
    unsigned short* hb3 = (unsigned short*)alloc((size_t)NN * 128 * sizeof(short));
    float*  esrc        = (float*)alloc((size_t)(NN + 1) * 2 * sizeof(float));
    float*  edst        = (float*)alloc((size_t)NN * 2 * sizeof(float));
    float*  ppart       = (float*)alloc((size_t)GG * PSPLIT * 128 * sizeof(float));
    short*  wfrag2      = (short*)alloc((size_t)16 * 2 * 2 * 64 * 8 * sizeof(short));
    short*  wfrag3      = (short*)alloc((size_t)16 * 4 * 2 * 64 * 8 * sizeof(short));
    float*  bnsc1       = (float*)alloc(64 * sizeof(float));
    float*  bnsh1       = (float*)alloc(64 * sizeof(float));
    float*  bnsc2       = (float*)alloc(128 * sizeof(float));
    float*  bnsh2       = (float*)alloc(128 * sizeof(float));
    float*  bnsc3       = (float*)alloc(128 * sizeof(float));
    float*  bnsh3       = (float*)alloc(128 * sizeof(float));

    // ---- merged prep (W fragments + fused BN) ----
    prep_all_kernel<<<49, 256, 0, stream>>>(
        w2, p2w, wfrag2, w3, p3w, wfrag3,
        b1, g1, be1, m1, v1, b2, g2, be2, m2, v2, b3, g3, be3, m3, v3,
        bnsc1, bnsh1, bnsc2, bnsh2, bnsc3, bnsh3);

    // ---- CSR build (bucketed partition, padded-16 layout, NN sentinel) ----
    hipMemsetAsync(bucket_cnt, 0, NBK * sizeof(int), stream);
    bucket_count_kernel<<<(ETOT + 8191) / 8192, 256, 0, stream>>>(ei, bucket_cnt);
    bucket_scan_kernel<<<1, 512, 0, stream>>>(bucket_cnt, bucket_base, gcursor, esrc);
    partition_kernel<<<(ETOT + 4095) / 4096, 256, 0, stream>>>(ei, gcursor, part);
    csr_build_kernel<<<NBK, 256, 0, stream>>>(part, bucket_base, row2_start, row2_deg, csr2_src);

    // ---- layer 1: x[N,5] -> hb1[N,64] (bf16) ----
    feat1_kernel<<<(NN + 3) / 4, 256, 0, stream>>>(
        x, w1, p1w, p1b, as1, ad1, h8, esrc, edst, hb1, NN);
    edgew_kernel<<<(NN + 3) / 4, 256, 0, stream>>>(
        csr2_src, row2_start, row2_deg, (const float2*)esrc, (const float2*)edst, csr_w, NN);
    aggregate64_kernel<<<NN / 8, 256, 0, stream>>>(
        h8, row2_start, row2_deg, csr2_src, csr_w, bnsc1, bnsh1, hb1);

    // ---- layer 2: hb1 -> hb2[N,128] (bf16) ----
    mfma_feat_kernel<64><<<(NN + 127) / 128, 256, 0, stream>>>(
        hb1, wfrag2, p2b, as2, ad2, h8, esrc, edst, hb2);
    edgew_kernel<<<(NN + 3) / 4, 256, 0, stream>>>(
        csr2_src, row2_start, row2_deg, (const float2*)esrc, (const float2*)edst, csr_w, NN);
    aggregate128_kernel<<<NN / 8, 256, 0, stream>>>(
        h8, row2_start, row2_deg, csr2_src, csr_w, bnsc2, bnsh2, hb2);

    // ---- layer 3: hb2 -> hb3[N,128] (bf16) ----
    mfma_feat_kernel<128><<<(NN + 127) / 128, 256, 0, stream>>>(
        hb2, wfrag3, p3b, as3, ad3, h8, esrc, edst, hb3);
    edgew_kernel<<<(NN + 3) / 4, 256, 0, stream>>>(
        csr2_src, row2_start, row2_deg, (const float2*)esrc, (const float2*)edst, csr_w, NN);
    aggregate128_kernel<<<NN / 8, 256, 0, stream>>>(
        h8, row2_start, row2_deg, csr2_src, csr_w, bnsc3, bnsh3, hb3);

    // ---- pool (two-phase) + head ----
    pool_partial_kernel<<<GG * PSPLIT, 128, 0, stream>>>(hb3, batch, ppart);
    head_kernel<<<GG, 128, 0, stream>>>(ppart, batch, fw, fb, g4, be4, m4, v4,
                                        l1w, l1b, l2w, l2b, (float*)d_out);
}

// Round 20
// 520.512 us; speedup vs baseline: 1.3746x; 1.0019x over previous
//
#include <hip/hip_runtime.h>
#include <hip/hip_bf16.h>
#include <hip/hip_fp16.h>

#define NN   100000
#define EE   1600000
#define ETOT (EE + NN)
#define GG   256
#define BNEPS 1e-5f
#define NBK  391          // buckets of 256 nodes: (NN+255)/256
#define PADTOT (ETOT + NBK * 4096 + 64)
#define PSPLIT 16

typedef float floatx2 __attribute__((ext_vector_type(2)));
typedef short s16x8 __attribute__((ext_vector_type(8)));
typedef float f32x4v __attribute__((ext_vector_type(4)));

__device__ __forceinline__ unsigned short f2bf(float f) {
    unsigned u = __float_as_uint(f);
    unsigned r = u + 0x7FFF + ((u >> 16) & 1);
    return (unsigned short)(r >> 16);
}
__device__ __forceinline__ float bf2f(unsigned short b) {
    return __uint_as_float(((unsigned)b) << 16);
}
// packed 2xfp32 FMA → v_pk_fma_f32
__device__ __forceinline__ floatx2 pkfma(floatx2 a, floatx2 b, floatx2 c) {
    return __builtin_elementwise_fma(a, b, c);
}

// ---------------- CSR build: bucketed partition (single-writer cache lines) --

__global__ __launch_bounds__(256) void bucket_count_kernel(
    const int* __restrict__ ei, int* __restrict__ bucket_cnt)
{
    __shared__ int cnt[NBK];
    for (int i = threadIdx.x; i < NBK; i += 256) cnt[i] = 0;
    __syncthreads();
    int base = blockIdx.x * 8192;
    for (int k = threadIdx.x; k < 8192; k += 256) {
        int e = base + k;
        if (e < ETOT) {
            int dst = (e < EE) ? ei[EE + e] : (e - EE);
            atomicAdd(&cnt[dst >> 8], 1);
        }
    }
    __syncthreads();
    for (int i = threadIdx.x; i < NBK; i += 256)
        if (cnt[i]) atomicAdd(&bucket_cnt[i], cnt[i]);
}

// also plants the -inf esrc sentinel used by pad edges (src = NN)
__global__ __launch_bounds__(512) void bucket_scan_kernel(
    const int* __restrict__ bucket_cnt, int* __restrict__ bucket_base,
    int* __restrict__ gcursor, float* __restrict__ esrcs)
{
    __shared__ int s[512];
    int t = threadIdx.x;
    int v = (t < NBK) ? bucket_cnt[t] : 0;
    s[t] = v;
    __syncthreads();
    int x = v;
    for (int o = 1; o < 512; o <<= 1) {
        int y = (t >= o) ? s[t - o] : 0;
        __syncthreads();
        x += y;
        s[t] = x;
        __syncthreads();
    }
    if (t < NBK) { bucket_base[t] = x - v; gcursor[t] = x - v; }
    if (t == 0) {
        bucket_base[NBK] = ETOT;
        esrcs[2 * NN]     = __int_as_float(0xFF800000);  // -inf
        esrcs[2 * NN + 1] = __int_as_float(0xFF800000);
    }
}

__global__ __launch_bounds__(256) void partition_kernel(
    const int* __restrict__ ei, int* __restrict__ gcursor, int* __restrict__ part)
{
    __shared__ int cnt[NBK];
    __shared__ int basel[NBK];
    for (int i = threadIdx.x; i < NBK; i += 256) cnt[i] = 0;
    __syncthreads();
    int base = blockIdx.x * 4096;
    for (int k = threadIdx.x; k < 4096; k += 256) {
        int e = base + k;
        if (e < ETOT) {
            int dst = (e < EE) ? ei[EE + e] : (e - EE);
            atomicAdd(&cnt[dst >> 8], 1);
        }
    }
    __syncthreads();
    for (int i = threadIdx.x; i < NBK; i += 256) {
        int c = cnt[i];
        basel[i] = c ? atomicAdd(&gcursor[i], c) : 0;
        cnt[i] = 0;   // reuse as intra-block cursor
    }
    __syncthreads();
    for (int k = threadIdx.x; k < 4096; k += 256) {
        int e = base + k;
        if (e < ETOT) {
            int src, dst;
            if (e < EE) { src = ei[e]; dst = ei[EE + e]; }
            else        { src = e - EE; dst = e - EE; }
            int b = dst >> 8;
            int slot = atomicAdd(&cnt[b], 1);
            part[basel[b] + slot] = src | ((dst & 255) << 17);
        }
    }
}

// Padded CSR: per-node segments rounded up to 16 entries, pad src = NN
// (sentinel: esrc[NN] = -inf → exp weight 0; pads gather the L1-hot NN row).
__global__ __launch_bounds__(256) void csr_build_kernel(
    const int* __restrict__ part, const int* __restrict__ bucket_base,
    int* __restrict__ row2_start, int* __restrict__ row2_deg,
    int* __restrict__ csr2_src)
{
    __shared__ int degs[256];
    __shared__ int sc[256];
    __shared__ int cur[256];
    int b = blockIdx.x;
    int t = threadIdx.x;
    int beg = bucket_base[b], end = bucket_base[b + 1];
    int pbase = ((beg + 15) & ~15) + 4096 * b;
    degs[t] = 0;
    __syncthreads();
    for (int j = beg + t; j < end; j += 256)
        atomicAdd(&degs[(part[j] >> 17) & 255], 1);
    __syncthreads();
    int dg = degs[t];
    int pdeg = (dg + 15) & ~15;
    sc[t] = pdeg;
    __syncthreads();
    int x = pdeg;
    for (int o = 1; o < 256; o <<= 1) {
        int y = (t >= o) ? sc[t - o] : 0;
        __syncthreads();
        x += y;
        sc[t] = x;
        __syncthreads();
    }
    int start2 = pbase + (x - pdeg);
    int node = b * 256 + t;
    if (node < NN) { row2_start[node] = start2; row2_deg[node] = dg; }
    cur[t] = start2;
    __syncthreads();
    for (int j = beg + t; j < end; j += 256) {
        int pv = part[j];
        int pos = atomicAdd(&cur[(pv >> 17) & 255], 1);
        csr2_src[pos] = pv & 0x1FFFF;
    }
    for (int k = dg; k < pdeg; ++k) csr2_src[start2 + k] = NN;
}

// ---------------- merged prep: W-fragments (both layers) + fused BN ----------

template<int K>
__device__ __forceinline__ void prep_w_body(
    int unit, const float* __restrict__ W, const float* __restrict__ pw,
    short* __restrict__ wfrag)
{
    constexpr int KS = K / 32;
    int total = 16 * KS * 2 * 64;
    if (unit >= total) return;
    int lane = unit & 63;
    int rest = unit >> 6;
    int hilo = rest & 1;
    int fk = rest >> 1;
    int ks = fk % KS;
    int nt = fk / KS;
    int n = nt * 16 + (lane & 15);
    int k0 = ks * 32 + (lane >> 4) * 8;
    const float* src = (n < 128) ? (W + n) : (pw + (n - 128));
    s16x8 out;
#pragma unroll
    for (int j = 0; j < 8; ++j) {
        float wv = src[(size_t)(k0 + j) * 128];
        unsigned short hi = f2bf(wv);
        if (hilo == 0) {
            out[j] = (short)hi;
        } else {
            float fhi = __uint_as_float(((unsigned)hi) << 16);
            out[j] = (short)f2bf(wv - fhi);
        }
    }
    *(s16x8*)(wfrag + (size_t)unit * 8) = out;
}

__global__ __launch_bounds__(256) void prep_all_kernel(
    const float* __restrict__ w2, const float* __restrict__ p2w, short* __restrict__ wfrag2,
    const float* __restrict__ w3, const float* __restrict__ p3w, short* __restrict__ wfrag3,
    const float* b1, const float* g1, const float* be1, const float* m1, const float* v1,
    const float* b2, const float* g2, const float* be2, const float* m2, const float* v2,
    const float* b3, const float* g3, const float* be3, const float* m3, const float* v3,
    float* sc1, float* sh1, float* sc2, float* sh2, float* sc3, float* sh3)
{
    int b = blockIdx.x;
    int tid = threadIdx.x;
    if (b < 16) {
        prep_w_body<64>(b * 256 + tid, w2, p2w, wfrag2);
    } else if (b < 48) {
        prep_w_body<128>((b - 16) * 256 + tid, w3, p3w, wfrag3);
    } else {
        int t = tid;
        if (t < 128) {
            if (t < 64) {
                float sc = g1[t] * rsqrtf(v1[t] + BNEPS);
                sc1[t] = sc;
                sh1[t] = (b1[t] - m1[t]) * sc + be1[t];
            }
            {
                float sc = g2[t] * rsqrtf(v2[t] + BNEPS);
                sc2[t] = sc;
                sh2[t] = (b2[t] - m2[t]) * sc + be2[t];
            }
            {
                float sc = g3[t] * rsqrtf(v3[t] + BNEPS);
                sc3[t] = sc;
                sh3[t] = (b3[t] - m3[t]) * sc + be3[t];
            }
        }
    }
}

// ---------------- per-layer edge softmax weights (packed 2×bf16) -------------

__global__ __launch_bounds__(256) void edgew_kernel(
    const int* __restrict__ csr2_src, const int* __restrict__ row2_start,
    const int* __restrict__ row2_deg,
    const float2* __restrict__ esrc, const float2* __restrict__ edst,
    unsigned* __restrict__ csr_w, int nN)
{
    int n = blockIdx.x * 4 + (threadIdx.x >> 6);
    int lane = threadIdx.x & 63;
    if (n >= nN) return;
    float2 ed = edst[n];
    int s2 = row2_start[n];
    int dg = row2_deg[n];
    int pc = (dg + 15) & ~15;
    for (int j = lane; j < pc; j += 64) {
        int i = csr2_src[s2 + j];
        float2 es = esrc[i];
        float a0 = es.x + ed.x; a0 = (a0 > 0.f) ? a0 : 0.2f * a0;
        float a1 = es.y + ed.y; a1 = (a1 > 0.f) ? a1 : 0.2f * a1;
        unsigned w = (unsigned)f2bf(__expf(a0)) | ((unsigned)f2bf(__expf(a1)) << 16);
        csr_w[s2 + j] = w;
    }
}

// ---------------- layer-1 feature transform (K=5); h fp8, rout bf16 ----------

__global__ __launch_bounds__(256) void feat1_kernel(
    const float* __restrict__ xin, const float* __restrict__ W,
    const float* __restrict__ pw, const float* __restrict__ pb,
    const float* __restrict__ a_src, const float* __restrict__ a_dst,
    unsigned char* __restrict__ h8, float* __restrict__ esrc, float* __restrict__ edst,
    unsigned short* __restrict__ rout16, int nN)
{
    constexpr int F_IN = 5, F_OUT = 64;
    int t = threadIdx.x;
    int n = blockIdx.x * 4 + t / F_OUT;
    int f = t % F_OUT;
    if (n >= nN) return;
    float acc = 0.f, racc = 0.f;
#pragma unroll
    for (int k = 0; k < F_IN; ++k) {
        float xv = xin[n * F_IN + k];
        acc  += xv * W[k * F_OUT + f];
        racc += xv * pw[k * F_OUT + f];
    }
    float other = __shfl_xor(acc, 1, 64);
    if ((f & 1) == 0) {
        int p = __builtin_amdgcn_cvt_pk_fp8_f32(acc, other, 0, false);
        *(unsigned short*)(h8 + (size_t)n * F_OUT + f) = (unsigned short)(p & 0xFFFF);
    }
    rout16[(size_t)n * F_OUT + f] = f2bf(racc + pb[f]);
    float es = acc * a_src[f];
    float ed = acc * a_dst[f];
#pragma unroll
    for (int off = 16; off > 0; off >>= 1) {
        es += __shfl_xor(es, off, 32);
        ed += __shfl_xor(ed, off, 32);
    }
    if ((t & 31) == 0) {
        int head = (f >> 5) & 1;
        esrc[n * 2 + head] = es;
        edst[n * 2 + head] = ed;
    }
}

// ---------------- MFMA feature transform (layers 2,3; N=256 = W‖pw) ----------
// LDS-staged outputs (R15 win: no sub-word global stores).

template<int K>
__global__ __launch_bounds__(256) void mfma_feat_kernel(
    const unsigned short* __restrict__ xin16, const short* __restrict__ wfrag,
    const float* __restrict__ pb,
    const float* __restrict__ a_src, const float* __restrict__ a_dst,
    unsigned char* __restrict__ h8, float* __restrict__ esrc, float* __restrict__ edst,
    unsigned short* __restrict__ rout16)
{
    constexpr int KS = K / 32;    // MFMA k-steps
    constexpr int CH = K / 8;     // 8-feature (16 B) chunks per node row
    __shared__ __align__(16) char smem[53248];
    s16x8* xs = (s16x8*)smem;
    unsigned short* h8lds = (unsigned short*)smem;             // stride 72 ushorts
    unsigned short* rolds = (unsigned short*)(smem + 18432);   // stride 136 ushorts

    const int tid = threadIdx.x;
    const int base = blockIdx.x * 128;

    for (int idx = tid; idx < 128 * CH; idx += 256) {
        int node = idx / CH;
        int ch = idx % CH;
        int gn = base + node; if (gn > NN - 1) gn = NN - 1;
        s16x8 v = *(const s16x8*)(xin16 + (size_t)gn * K + ch * 8);
        int tt = node >> 4, mm = node & 15;
        xs[(tt * CH + ch) * 16 + mm] = v;
    }
    __syncthreads();

    const int w = tid >> 6;
    const int lane = tid & 63;
    const int quad = lane >> 4;
    const int m = lane & 15;
    const int l0 = w * 32 + quad * 4;   // local row, tile0 (+r)
    const int l1 = l0 + 16;             // local row, tile1 (+r)
    const int node0 = base + l0;
    const int node1 = base + l1;

    s16x8 a0[KS], a1[KS];
#pragma unroll
    for (int ks = 0; ks < KS; ++ks) {
        a0[ks] = xs[((w * 2 + 0) * CH + (ks * 4 + quad)) * 16 + m];
        a1[ks] = xs[((w * 2 + 1) * CH + (ks * 4 + quad)) * 16 + m];
    }
    __syncthreads();   // xs dead; smem becomes output tile

    float es0h0[4] = {0.f,0.f,0.f,0.f}, es0h1[4] = {0.f,0.f,0.f,0.f};
    float ed0h0[4] = {0.f,0.f,0.f,0.f}, ed0h1[4] = {0.f,0.f,0.f,0.f};
    float es1h0[4] = {0.f,0.f,0.f,0.f}, es1h1[4] = {0.f,0.f,0.f,0.f};
    float ed1h0[4] = {0.f,0.f,0.f,0.f}, ed1h1[4] = {0.f,0.f,0.f,0.f};

#pragma unroll
    for (int nt = 0; nt < 16; ++nt) {
        s16x8 b[2 * KS];
#pragma unroll
        for (int i = 0; i < 2 * KS; ++i)
            b[i] = *(const s16x8*)(wfrag + (size_t)((nt * KS * 2 + i) * 64 + lane) * 8);
        f32x4v c0 = {0.f, 0.f, 0.f, 0.f};
        f32x4v c1 = {0.f, 0.f, 0.f, 0.f};
#pragma unroll
        for (int ks = 0; ks < KS; ++ks) {
            c0 = __builtin_amdgcn_mfma_f32_16x16x32_bf16(a0[ks], b[2 * ks + 0], c0, 0, 0, 0);
            c1 = __builtin_amdgcn_mfma_f32_16x16x32_bf16(a1[ks], b[2 * ks + 0], c1, 0, 0, 0);
            c0 = __builtin_amdgcn_mfma_f32_16x16x32_bf16(a0[ks], b[2 * ks + 1], c0, 0, 0, 0);
            c1 = __builtin_amdgcn_mfma_f32_16x16x32_bf16(a1[ks], b[2 * ks + 1], c1, 0, 0, 0);
        }
        if (nt < 8) {
            int col = nt * 16 + m;
            float av = a_src[col], dv = a_dst[col];
#pragma unroll
            for (int r = 0; r < 4; ++r) {
                float v0 = c0[r], v1 = c1[r];
                if (nt < 4) {
                    es0h0[r] = fmaf(v0, av, es0h0[r]); ed0h0[r] = fmaf(v0, dv, ed0h0[r]);
                    es1h0[r] = fmaf(v1, av, es1h0[r]); ed1h0[r] = fmaf(v1, dv, ed1h0[r]);
                } else {
                    es0h1[r] = fmaf(v0, av, es0h1[r]); ed0h1[r] = fmaf(v0, dv, ed0h1[r]);
                    es1h1[r] = fmaf(v1, av, es1h1[r]); ed1h1[r] = fmaf(v1, dv, ed1h1[r]);
                }
                float p0 = __shfl_xor(v0, 1, 16);
                float p1 = __shfl_xor(v1, 1, 16);
                if ((m & 1) == 0) {
                    int us = nt * 8 + (m >> 1);   // ushort index within row
                    int pk0 = __builtin_amdgcn_cvt_pk_fp8_f32(v0, p0, 0, false);
                    int pk1 = __builtin_amdgcn_cvt_pk_fp8_f32(v1, p1, 0, false);
                    h8lds[(l0 + r) * 72 + us] = (unsigned short)(pk0 & 0xFFFF);
                    h8lds[(l1 + r) * 72 + us] = (unsigned short)(pk1 & 0xFFFF);
                }
            }
        } else {
            int col = (nt - 8) * 16 + m;
            float bv = pb[col];
#pragma unroll
            for (int r = 0; r < 4; ++r) {
                rolds[(l0 + r) * 136 + col] = f2bf(c0[r] + bv);
                rolds[(l1 + r) * 136 + col] = f2bf(c1[r] + bv);
            }
        }
    }

#pragma unroll
    for (int r = 0; r < 4; ++r) {
#pragma unroll
        for (int off = 8; off > 0; off >>= 1) {
            es0h0[r] += __shfl_xor(es0h0[r], off, 16);
            es0h1[r] += __shfl_xor(es0h1[r], off, 16);
            ed0h0[r] += __shfl_xor(ed0h0[r], off, 16);
            ed0h1[r] += __shfl_xor(ed0h1[r], off, 16);
            es1h0[r] += __shfl_xor(es1h0[r], off, 16);
            es1h1[r] += __shfl_xor(es1h1[r], off, 16);
            ed1h0[r] += __shfl_xor(ed1h0[r], off, 16);
            ed1h1[r] += __shfl_xor(ed1h1[r], off, 16);
        }
    }
    if (m == 0) {
#pragma unroll
        for (int r = 0; r < 4; ++r) {
            if (node0 + r < NN) {
                ((float2*)esrc)[node0 + r] = make_float2(es0h0[r], es0h1[r]);
                ((float2*)edst)[node0 + r] = make_float2(ed0h0[r], ed0h1[r]);
            }
            if (node1 + r < NN) {
                ((float2*)esrc)[node1 + r] = make_float2(es1h0[r], es1h1[r]);
                ((float2*)edst)[node1 + r] = make_float2(ed1h0[r], ed1h1[r]);
            }
        }
    }

    __syncthreads();
    for (int i = tid; i < 128 * 8; i += 256) {
        int row = i >> 3, ch = i & 7;
        int node = base + row;
        if (node < NN) {
            int4 v = *(const int4*)(smem + row * 144 + ch * 16);
            *(int4*)(h8 + (size_t)node * 128 + ch * 16) = v;
        }
    }
    for (int i = tid; i < 128 * 16; i += 256) {
        int row = i >> 4, ch = i & 15;
        int node = base + row;
        if (node < NN) {
            int4 v = *(const int4*)(smem + 18432 + row * 272 + ch * 16);
            *(int4*)((char*)rout16 + (size_t)node * 256 + ch * 16) = v;
        }
    }
}

// ---------------- fused aggregate, F=128 (two nodes/wave, pk_fma) ------------

__global__ __launch_bounds__(256) void aggregate128_kernel(
    const unsigned char* __restrict__ h8,
    const int* __restrict__ row2_start, const int* __restrict__ row2_deg,
    const int* __restrict__ csr2_src, const unsigned* __restrict__ csr_w,
    const float* __restrict__ bnsc, const float* __restrict__ bnsh,
    unsigned short* __restrict__ io16)
{
    int w = threadIdx.x >> 6;
    int lane = threadIdx.x & 63;
    int half = lane >> 5;
    int fl = lane & 31;               // dword within the 128 B row (4 features)
    bool headhi = fl >= 16;           // features 64..127
    int n = blockIdx.x * 8 + w * 2 + half;
    int s2 = row2_start[n];
    int dg = row2_deg[n];
    int pc = (dg + 15) & ~15;
    const int* sp = csr2_src + s2;
    const unsigned* wp = csr_w + s2;
    float s = 0.f;
    floatx2 acc01 = {0.f, 0.f}, acc23 = {0.f, 0.f};
    for (int j = 0; j < pc; j += 8) {
        int i0 = sp[j + 0];
        int i1 = sp[j + 1];
        int i2 = sp[j + 2];
        int i3 = sp[j + 3];
        int i4 = sp[j + 4];
        int i5 = sp[j + 5];
        int i6 = sp[j + 6];
        int i7 = sp[j + 7];
        unsigned w0 = wp[j + 0];
        unsigned w1 = wp[j + 1];
        unsigned w2 = wp[j + 2];
        unsigned w3 = wp[j + 3];
        unsigned w4 = wp[j + 4];
        unsigned w5 = wp[j + 5];
        unsigned w6 = wp[j + 6];
        unsigned w7 = wp[j + 7];
        unsigned d0 = *(const unsigned*)(h8 + (size_t)i0 * 128 + fl * 4);
        unsigned d1 = *(const unsigned*)(h8 + (size_t)i1 * 128 + fl * 4);
        unsigned d2 = *(const unsigned*)(h8 + (size_t)i2 * 128 + fl * 4);
        unsigned d3 = *(const unsigned*)(h8 + (size_t)i3 * 128 + fl * 4);
        unsigned d4 = *(const unsigned*)(h8 + (size_t)i4 * 128 + fl * 4);
        unsigned d5 = *(const unsigned*)(h8 + (size_t)i5 * 128 + fl * 4);
        unsigned d6 = *(const unsigned*)(h8 + (size_t)i6 * 128 + fl * 4);
        unsigned d7 = *(const unsigned*)(h8 + (size_t)i7 * 128 + fl * 4);
        float g0 = __uint_as_float(headhi ? (w0 & 0xFFFF0000u) : (w0 << 16));
        float g1 = __uint_as_float(headhi ? (w1 & 0xFFFF0000u) : (w1 << 16));
        float g2 = __uint_as_float(headhi ? (w2 & 0xFFFF0000u) : (w2 << 16));
        float g3 = __uint_as_float(headhi ? (w3 & 0xFFFF0000u) : (w3 << 16));
        float g4 = __uint_as_float(headhi ? (w4 & 0xFFFF0000u) : (w4 << 16));
        float g5 = __uint_as_float(headhi ? (w5 & 0xFFFF0000u) : (w5 << 16));
        float g6 = __uint_as_float(headhi ? (w6 & 0xFFFF0000u) : (w6 << 16));
        float g7 = __uint_as_float(headhi ? (w7 & 0xFFFF0000u) : (w7 << 16));
        floatx2 gv0 = {g0, g0};
        floatx2 gv1 = {g1, g1};
        floatx2 gv2 = {g2, g2};
        floatx2 gv3 = {g3, g3};
        floatx2 gv4 = {g4, g4};
        floatx2 gv5 = {g5, g5};
        floatx2 gv6 = {g6, g6};
        floatx2 gv7 = {g7, g7};
        acc01 = pkfma(gv0, __builtin_amdgcn_cvt_pk_f32_fp8((int)d0, false), acc01);
        acc23 = pkfma(gv0, __builtin_amdgcn_cvt_pk_f32_fp8((int)d0, true),  acc23);
        acc01 = pkfma(gv1, __builtin_amdgcn_cvt_pk_f32_fp8((int)d1, false), acc01);
        acc23 = pkfma(gv1, __builtin_amdgcn_cvt_pk_f32_fp8((int)d1, true),  acc23);
        acc01 = pkfma(gv2, __builtin_amdgcn_cvt_pk_f32_fp8((int)d2, false), acc01);
        acc23 = pkfma(gv2, __builtin_amdgcn_cvt_pk_f32_fp8((int)d2, true),  acc23);
        acc01 = pkfma(gv3, __builtin_amdgcn_cvt_pk_f32_fp8((int)d3, false), acc01);
        acc23 = pkfma(gv3, __builtin_amdgcn_cvt_pk_f32_fp8((int)d3, true),  acc23);
        acc01 = pkfma(gv4, __builtin_amdgcn_cvt_pk_f32_fp8((int)d4, false), acc01);
        acc23 = pkfma(gv4, __builtin_amdgcn_cvt_pk_f32_fp8((int)d4, true),  acc23);
        acc01 = pkfma(gv5, __builtin_amdgcn_cvt_pk_f32_fp8((int)d5, false), acc01);
        acc23 = pkfma(gv5, __builtin_amdgcn_cvt_pk_f32_fp8((int)d5, true),  acc23);
        acc01 = pkfma(gv6, __builtin_amdgcn_cvt_pk_f32_fp8((int)d6, false), acc01);
        acc23 = pkfma(gv6, __builtin_amdgcn_cvt_pk_f32_fp8((int)d6, true),  acc23);
        acc01 = pkfma(gv7, __builtin_amdgcn_cvt_pk_f32_fp8((int)d7, false), acc01);
        acc23 = pkfma(gv7, __builtin_amdgcn_cvt_pk_f32_fp8((int)d7, true),  acc23);
        s += (((g0 + g1) + (g2 + g3)) + ((g4 + g5) + (g6 + g7)));
    }
    float inv = 1.f / (s + 1e-16f);
    int f0 = fl * 4;
    float4 sc = *(const float4*)(bnsc + f0);
    float4 sh = *(const float4*)(bnsh + f0);
    float o0 = fmaf(acc01.x * inv, sc.x, sh.x);
    float o1 = fmaf(acc01.y * inv, sc.y, sh.y);
    float o2 = fmaf(acc23.x * inv, sc.z, sh.z);
    float o3 = fmaf(acc23.y * inv, sc.w, sh.w);
    uint2* iop = (uint2*)(io16 + (size_t)n * 128 + f0);
    uint2 pu = *iop;
    float r0 = fmaxf(o0, 0.f) + __uint_as_float((pu.x & 0xFFFFu) << 16);
    float r1 = fmaxf(o1, 0.f) + __uint_as_float(pu.x & 0xFFFF0000u);
    float r2 = fmaxf(o2, 0.f) + __uint_as_float((pu.y & 0xFFFFu) << 16);
    float r3 = fmaxf(o3, 0.f) + __uint_as_float(pu.y & 0xFFFF0000u);
    uint2 ov;
    ov.x = (unsigned)f2bf(r0) | ((unsigned)f2bf(r1) << 16);
    ov.y = (unsigned)f2bf(r2) | ((unsigned)f2bf(r3) << 16);
    *iop = ov;
}

// ---------------- fused aggregate, F=64 (two nodes/wave, pk_fma) -------------

__global__ __launch_bounds__(256) void aggregate64_kernel(
    const unsigned char* __restrict__ h8,
    const int* __restrict__ row2_start, const int* __restrict__ row2_deg,
    const int* __restrict__ csr2_src, const unsigned* __restrict__ csr_w,
    const float* __restrict__ bnsc, const float* __restrict__ bnsh,
    unsigned short* __restrict__ io16)
{
    int w = threadIdx.x >> 6;
    int lane = threadIdx.x & 63;
    int half = lane >> 5;
    int hl = lane & 31;
    int q  = hl >> 4;                 // edge selector within pair
    int fl = hl & 15;                 // feature dword (features 4fl..4fl+3)
    bool headhi = (fl >> 3) & 1;
    int n = blockIdx.x * 8 + w * 2 + half;
    int s2 = row2_start[n];
    int dg = row2_deg[n];
    int pc = (dg + 15) & ~15;
    const int4* sp = (const int4*)(csr2_src + s2);
    const uint4* wp = (const uint4*)(csr_w + s2);
    float s = 0.f;
    floatx2 acc01 = {0.f, 0.f}, acc23 = {0.f, 0.f};
    for (int j = 0; j < pc; j += 8) {
        int4 ia = sp[(j >> 2) + 0];
        int4 ib = sp[(j >> 2) + 1];
        uint4 wa = wp[(j >> 2) + 0];
        uint4 wb = wp[(j >> 2) + 1];
        int i0 = q ? ia.y : ia.x;
        int i1 = q ? ia.w : ia.z;
        int i2 = q ? ib.y : ib.x;
        int i3 = q ? ib.w : ib.z;
        unsigned w0 = q ? wa.y : wa.x;
        unsigned w1 = q ? wa.w : wa.z;
        unsigned w2 = q ? wb.y : wb.x;
        unsigned w3 = q ? wb.w : wb.z;
        unsigned d0 = *(const unsigned*)(h8 + (size_t)i0 * 64 + fl * 4);
        unsigned d1 = *(const unsigned*)(h8 + (size_t)i1 * 64 + fl * 4);
        unsigned d2 = *(const unsigned*)(h8 + (size_t)i2 * 64 + fl * 4);
        unsigned d3 = *(const unsigned*)(h8 + (size_t)i3 * 64 + fl * 4);
        float g0 = __uint_as_float(headhi ? (w0 & 0xFFFF0000u) : (w0 << 16));
        float g1 = __uint_as_float(headhi ? (w1 & 0xFFFF0000u) : (w1 << 16));
        float g2 = __uint_as_float(headhi ? (w2 & 0xFFFF0000u) : (w2 << 16));
        float g3 = __uint_as_float(headhi ? (w3 & 0xFFFF0000u) : (w3 << 16));
        floatx2 gv0 = {g0, g0};
        floatx2 gv1 = {g1, g1};
        floatx2 gv2 = {g2, g2};
        floatx2 gv3 = {g3, g3};
        acc01 = pkfma(gv0, __builtin_amdgcn_cvt_pk_f32_fp8((int)d0, false), acc01);
        acc23 = pkfma(gv0, __builtin_amdgcn_cvt_pk_f32_fp8((int)d0, true),  acc23);
        acc01 = pkfma(gv1, __builtin_amdgcn_cvt_pk_f32_fp8((int)d1, false), acc01);
        acc23 = pkfma(gv1, __builtin_amdgcn_cvt_pk_f32_fp8((int)d1, true),  acc23);
        acc01 = pkfma(gv2, __builtin_amdgcn_cvt_pk_f32_fp8((int)d2, false), acc01);
        acc23 = pkfma(gv2, __builtin_amdgcn_cvt_pk_f32_fp8((int)d2, true),  acc23);
        acc01 = pkfma(gv3, __builtin_amdgcn_cvt_pk_f32_fp8((int)d3, false), acc01);
        acc23 = pkfma(gv3, __builtin_amdgcn_cvt_pk_f32_fp8((int)d3, true),  acc23);
        s += ((g0 + g1) + (g2 + g3));
    }
    // combine the two quarters within each half (xor 16 stays inside the half)
    acc01.x += __shfl_xor(acc01.x, 16);
    acc01.y += __shfl_xor(acc01.y, 16);
    acc23.x += __shfl_xor(acc23.x, 16);
    acc23.y += __shfl_xor(acc23.y, 16);
    s += __shfl_xor(s, 16);
    if (hl < 16) {
        float inv = 1.f / (s + 1e-16f);
        int f0 = fl * 4;
        float4 sc = *(const float4*)(bnsc + f0);
        float4 sh = *(const float4*)(bnsh + f0);
        float o0 = fmaf(acc01.x * inv, sc.x, sh.x);
        float o1 = fmaf(acc01.y * inv, sc.y, sh.y);
        float o2 = fmaf(acc23.x * inv, sc.z, sh.z);
        float o3 = fmaf(acc23.y * inv, sc.w, sh.w);
        uint2* iop = (uint2*)(io16 + (size_t)n * 64 + f0);
        uint2 pu = *iop;
        float r0 = fmaxf(o0, 0.f) + __uint_as_float((pu.x & 0xFFFFu) << 16);
        float r1 = fmaxf(o1, 0.f) + __uint_as_float(pu.x & 0xFFFF0000u);
        float r2 = fmaxf(o2, 0.f) + __uint_as_float((pu.y & 0xFFFFu) << 16);
        float r3 = fmaxf(o3, 0.f) + __uint_as_float(pu.y & 0xFFFF0000u);
        uint2 ov;
        ov.x = (unsigned)f2bf(r0) | ((unsigned)f2bf(r1) << 16);
        ov.y = (unsigned)f2bf(r2) | ((unsigned)f2bf(r3) << 16);
        *iop = ov;
    }
}

// ---------------- pooling, two-phase (bf16 input) ----------------

__global__ __launch_bounds__(128) void pool_partial_kernel(
    const unsigned short* __restrict__ hf16, const int* __restrict__ batch,
    float* __restrict__ ppart)
{
    int g = blockIdx.x / PSPLIT;
    int p = blockIdx.x % PSPLIT;
    int f = threadIdx.x;
    int lo = 0, hi = NN;
    while (lo < hi) { int mid = (lo + hi) >> 1; if (batch[mid] < g) lo = mid + 1; else hi = mid; }
    int start = lo;
    hi = NN;
    while (lo < hi) { int mid = (lo + hi) >> 1; if (batch[mid] < g + 1) lo = mid + 1; else hi = mid; }
    int end = lo;
    int len = end - start;
    int chunk = (len + PSPLIT - 1) / PSPLIT;
    int i0 = start + p * chunk;
    int i1 = i0 + chunk; if (i1 > end) i1 = end;
    float acc = 0.f;
    for (int i = i0; i < i1; ++i) acc += bf2f(hf16[(size_t)i * 128 + f]);
    ppart[((size_t)g * PSPLIT + p) * 128 + f] = acc;
}

// ---------------- MLP head (folds partial-sum reduce + mean) -----------------

__global__ __launch_bounds__(128) void head_kernel(
    const float* __restrict__ ppart, const int* __restrict__ batch,
    const float* __restrict__ fw, const float* __restrict__ fb,
    const float* __restrict__ g4, const float* __restrict__ be4,
    const float* __restrict__ m4, const float* __restrict__ v4,
    const float* __restrict__ l1w, const float* __restrict__ l1b,
    const float* __restrict__ l2w, const float* __restrict__ l2b,
    float* __restrict__ out)
{
    __shared__ float p[128];
    __shared__ float z1[32];
    __shared__ float z2[32];
    int g = blockIdx.x, t = threadIdx.x;
    int lo = 0, hi = NN;
    while (lo < hi) { int mid = (lo + hi) >> 1; if (batch[mid] < g) lo = mid + 1; else hi = mid; }
    int start = lo;
    hi = NN;
    while (lo < hi) { int mid = (lo + hi) >> 1; if (batch[mid] < g + 1) lo = mid + 1; else hi = mid; }
    float cnt = (float)(lo - start);
    float acc = 0.f;
#pragma unroll
    for (int q = 0; q < PSPLIT; ++q)
        acc += ppart[((size_t)g * PSPLIT + q) * 128 + t];
    p[t] = acc / fmaxf(cnt, 1.0f);
    __syncthreads();
    if (t < 32) {
        float a = fb[t];
        for (int k = 0; k < 128; ++k) a += p[k] * fw[k * 32 + t];
        float val = g4[t] * (a - m4[t]) * rsqrtf(v4[t] + BNEPS) + be4[t];
        z1[t] = fmaxf(val, 0.f);
    }
    __syncthreads();
    if (t < 32) {
        float a = l1b[t];
        for (int k = 0; k < 32; ++k) a += z1[k] * l1w[k * 32 + t];
        z2[t] = fmaxf(a, 0.f);
    }
    __syncthreads();
    if (t < 10) {
        float a = l2b[t];
        for (int k = 0; k < 32; ++k) a += z2[k] * l2w[k * 10 + t];
        out[g * 10 + t] = a;
    }
}

// ---------------- launch ----------------

extern "C" void kernel_launch(void* const* d_in, const int* in_sizes, int n_in,
                              void* d_out, int out_size, void* d_ws, size_t ws_size,
                              hipStream_t stream) {
    const float* x     = (const float*)d_in[0];
    const int*   ei    = (const int*)d_in[1];
    const int*   batch = (const int*)d_in[2];
    const float* w1  = (const float*)d_in[3];
    const float* as1 = (const float*)d_in[4];
    const float* ad1 = (const float*)d_in[5];
    const float* b1  = (const float*)d_in[6];
    const float* g1  = (const float*)d_in[7];
    const float* be1 = (const float*)d_in[8];
    const float* m1  = (const float*)d_in[9];
    const float* v1  = (const float*)d_in[10];
    const float* p1w = (const float*)d_in[11];
    const float* p1b = (const float*)d_in[12];
    const float* w2  = (const float*)d_in[13];
    const float* as2 = (const float*)d_in[14];
    const float* ad2 = (const float*)d_in[15];
    const float* b2  = (const float*)d_in[16];
    const float* g2  = (const float*)d_in[17];
    const float* be2 = (const float*)d_in[18];
    const float* m2  = (const float*)d_in[19];
    const float* v2  = (const float*)d_in[20];
    const float* p2w = (const float*)d_in[21];
    const float* p2b = (const float*)d_in[22];
    const float* w3  = (const float*)d_in[23];
    const float* as3 = (const float*)d_in[24];
    const float* ad3 = (const float*)d_in[25];
    const float* b3  = (const float*)d_in[26];
    const float* g3  = (const float*)d_in[27];
    const float* be3 = (const float*)d_in[28];
    const float* m3  = (const float*)d_in[29];
    const float* v3  = (const float*)d_in[30];
    const float* p3w = (const float*)d_in[31];
    const float* p3b = (const float*)d_in[32];
    const float* fw  = (const float*)d_in[33];
    const float* fb  = (const float*)d_in[34];
    const float* g4  = (const float*)d_in[35];
    const float* be4 = (const float*)d_in[36];
    const float* m4  = (const float*)d_in[37];
    const float* v4  = (const float*)d_in[38];
    const float* l1w = (const float*)d_in[39];
    const float* l1b = (const float*)d_in[40];
    const float* l2w = (const float*)d_in[41];
    const float* l2b = (const float*)d_in[42];

    char* ws = (char*)d_ws;
    size_t off = 0;
    auto alloc = [&](size_t bytes) -> char* {
        char* p = ws + off;
        off += (bytes + 255) & ~(size_t)255;
        return p;
    };
    int*    bucket_cnt  = (int*)alloc((NBK) * sizeof(int));
    int*    bucket_base = (int*)alloc((NBK + 1) * sizeof(int));
    int*    gcursor     = (int*)alloc((NBK) * sizeof(int));
    int*    part        = (int*)alloc((size_t)ETOT * sizeof(int));
    int*    row2_start  = (int*)alloc(NN * sizeof(int));
    int*    row2_deg    = (int*)alloc(NN * sizeof(int));
    int*    csr2_src    = (int*)alloc((size_t)PADTOT * sizeof(int));
    unsigned* csr_w     = (unsigned*)alloc((size_t)PADTOT * sizeof(unsigned));
    unsigned char*  h8  = (unsigned char*)alloc((size_t)(NN + 1) * 128);
    unsigned short* hb1 = (unsigned short*)alloc((size_t)NN * 64 * sizeof(short));
    unsigned short* hb2 = (unsigned short*)alloc((size_t)NN * 128 * sizeof(short));
    unsigned short* hb3 = (unsigned short*)alloc((size_t)NN * 128 * sizeof(short));
    float*  esrc        = (float*)alloc((size_t)(NN + 1) * 2 * sizeof(float));
    float*  edst        = (float*)alloc((size_t)NN * 2 * sizeof(float));
    float*  ppart       = (float*)alloc((size_t)GG * PSPLIT * 128 * sizeof(float));
    short*  wfrag2      = (short*)alloc((size_t)16 * 2 * 2 * 64 * 8 * sizeof(short));
    short*  wfrag3      = (short*)alloc((size_t)16 * 4 * 2 * 64 * 8 * sizeof(short));
    float*  bnsc1       = (float*)alloc(64 * sizeof(float));
    float*  bnsh1       = (float*)alloc(64 * sizeof(float));
    float*  bnsc2       = (float*)alloc(128 * sizeof(float));
    float*  bnsh2       = (float*)alloc(128 * sizeof(float));
    float*  bnsc3       = (float*)alloc(128 * sizeof(float));
    float*  bnsh3       = (float*)alloc(128 * sizeof(float));

    // ---- merged prep (W fragments + fused BN) ----
    prep_all_kernel<<<49, 256, 0, stream>>>(
        w2, p2w, wfrag2, w3, p3w, wfrag3,
        b1, g1, be1, m1, v1, b2, g2, be2, m2, v2, b3, g3, be3, m3, v3,
        bnsc1, bnsh1, bnsc2, bnsh2, bnsc3, bnsh3);

    // ---- CSR build (bucketed partition, padded-16 layout, NN sentinel) ----
    hipMemsetAsync(bucket_cnt, 0, NBK * sizeof(int), stream);
    bucket_count_kernel<<<(ETOT + 8191) / 8192, 256, 0, stream>>>(ei, bucket_cnt);
    bucket_scan_kernel<<<1, 512, 0, stream>>>(bucket_cnt, bucket_base, gcursor, esrc);
    partition_kernel<<<(ETOT + 4095) / 4096, 256, 0, stream>>>(ei, gcursor, part);
    csr_build_kernel<<<NBK, 256, 0, stream>>>(part, bucket_base, row2_start, row2_deg, csr2_src);

    // ---- layer 1: x[N,5] -> hb1[N,64] (bf16) ----
    feat1_kernel<<<(NN + 3) / 4, 256, 0, stream>>>(
        x, w1, p1w, p1b, as1, ad1, h8, esrc, edst, hb1, NN);
    edgew_kernel<<<(NN + 3) / 4, 256, 0, stream>>>(
        csr2_src, row2_start, row2_deg, (const float2*)esrc, (const float2*)edst, csr_w, NN);
    aggregate64_kernel<<<NN / 8, 256, 0, stream>>>(
        h8, row2_start, row2_deg, csr2_src, csr_w, bnsc1, bnsh1, hb1);

    // ---- layer 2: hb1 -> hb2[N,128] (bf16) ----
    mfma_feat_kernel<64><<<(NN + 127) / 128, 256, 0, stream>>>(
        hb1, wfrag2, p2b, as2, ad2, h8, esrc, edst, hb2);
    edgew_kernel<<<(NN + 3) / 4, 256, 0, stream>>>(
        csr2_src, row2_start, row2_deg, (const float2*)esrc, (const float2*)edst, csr_w, NN);
    aggregate128_kernel<<<NN / 8, 256, 0, stream>>>(
        h8, row2_start, row2_deg, csr2_src, csr_w, bnsc2, bnsh2, hb2);

    // ---- layer 3: hb2 -> hb3[N,128] (bf16) ----
    mfma_feat_kernel<128><<<(NN + 127) / 128, 256, 0, stream>>>(
        hb2, wfrag3, p3b, as3, ad3, h8, esrc, edst, hb3);
    edgew_kernel<<<(NN + 3) / 4, 256, 0, stream>>>(
        csr2_src, row2_start, row2_deg, (const float2*)esrc, (const float2*)edst, csr_w, NN);
    aggregate128_kernel<<<NN / 8, 256, 0, stream>>>(
        h8, row2_start, row2_deg, csr2_src, csr_w, bnsc3, bnsh3, hb3);

    // ---- pool (two-phase) + head ----
    pool_partial_kernel<<<GG * PSPLIT, 128, 0, stream>>>(hb3, batch, ppart);
    head_kernel<<<GG, 128, 0, stream>>>(ppart, batch, fw, fb, g4, be4, m4, v4,
                                        l1w, l1b, l2w, l2b, (float*)d_out);
}